// Round 2
// baseline (9970.425 us; speedup 1.0000x reference)
//
#include <hip/hip_runtime.h>
#include <hip/hip_bf16.h>
#include <math.h>

#define NN 16384
#define NG 512
#define NE2 65536
#define NE3 393216
#define DEMB 300
#define DSCH 128
#define NRBF 50
#define NTAB 5120
#define TROWS 5121
#define DMAX 25.0f

__device__ __forceinline__ float sspf(float x) {
  float sp = log1pf(expf(-fabsf(x))) + fmaxf(x, 0.f);
  return sp - 0.69314718055994530942f;
}

// ---------------- small elementwise / scatter kernels ----------------

__global__ void k_counts(const int* __restrict__ batch, float* __restrict__ counts) {
  int i = blockIdx.x * blockDim.x + threadIdx.x;
  if (i < NN) atomicAdd(&counts[batch[i]], 1.0f);
}

__global__ void k_hinit(const int* __restrict__ x2d, const float* __restrict__ e1,
                        const float* __restrict__ e2, float* __restrict__ h) {
  int i = blockIdx.x * blockDim.x + threadIdx.x;
  if (i >= NN * DEMB) return;
  int n = i / DEMB, c = i - n * DEMB;
  h[i] = e1[x2d[2 * n] * DEMB + c] + e2[x2d[2 * n + 1] * DEMB + c];
}

__global__ void k_vninit(const float* __restrict__ vni, float* __restrict__ vn) {
  int i = blockIdx.x * blockDim.x + threadIdx.x;
  if (i >= NG * DEMB) return;
  vn[i] = vni[i % DEMB];
}

__global__ void k_addvn(float* __restrict__ h, const float* __restrict__ vn,
                        const int* __restrict__ batch) {
  int i = blockIdx.x * blockDim.x + threadIdx.x;
  if (i >= NN * DEMB) return;
  int n = i / DEMB, c = i - n * DEMB;
  h[i] += vn[batch[n] * DEMB + c];
}

__global__ void k_gin_edge(const float* __restrict__ h, const int* __restrict__ ei2,
                           const int* __restrict__ ea2, const float* __restrict__ bond1,
                           const float* __restrict__ bond2, float* __restrict__ agg) {
  int i = blockIdx.x * blockDim.x + threadIdx.x;  // e*75 + c4
  if (i >= NE2 * 75) return;
  int e = i / 75, c = i - e * 75;
  int s = ei2[e], d = ei2[NE2 + e];
  int a0 = ea2[2 * e], a1 = ea2[2 * e + 1];
  const float4 hv = *(const float4*)(h + (size_t)s * DEMB + c * 4);
  const float4 b1 = *(const float4*)(bond1 + (size_t)a0 * DEMB + c * 4);
  const float4 b2 = *(const float4*)(bond2 + (size_t)a1 * DEMB + c * 4);
  float4 m;
  m.x = fmaxf(hv.x + b1.x + b2.x, 0.f);
  m.y = fmaxf(hv.y + b1.y + b2.y, 0.f);
  m.z = fmaxf(hv.z + b1.z + b2.z, 0.f);
  m.w = fmaxf(hv.w + b1.w + b2.w, 0.f);
  float* dp = agg + (size_t)d * DEMB + c * 4;
  atomicAdd(dp + 0, m.x);
  atomicAdd(dp + 1, m.y);
  atomicAdd(dp + 2, m.z);
  atomicAdd(dp + 3, m.w);
}

__global__ void k_segsum(const float* __restrict__ x, const int* __restrict__ batch,
                         float* __restrict__ out, int n, int W) {
  int i = blockIdx.x * blockDim.x + threadIdx.x;
  if (i >= n * W) return;
  int r = i / W, c = i - r * W;
  atomicAdd(&out[batch[r] * W + c], x[i]);
}

__global__ void k_div(float* __restrict__ buf, const float* __restrict__ counts, int B, int W) {
  int i = blockIdx.x * blockDim.x + threadIdx.x;
  if (i >= B * W) return;
  buf[i] /= fmaxf(counts[i / W], 1.0f);
}

// distance per 3D edge
__global__ void k_dist(const int* __restrict__ ei3, const float* __restrict__ pos,
                       float* __restrict__ d3) {
  int e = blockIdx.x * blockDim.x + threadIdx.x;
  if (e >= NE3) return;
  int s = ei3[e], d = ei3[NE3 + e];
  float dx = pos[3 * d] - pos[3 * s];
  float dy = pos[3 * d + 1] - pos[3 * s + 1];
  float dz = pos[3 * d + 2] - pos[3 * s + 2];
  d3[e] = sqrtf(dx * dx + dy * dy + dz * dz);
}

// sampled rbf matrix [TROWS,50] + cosine-cutoff row-scale Cs[TROWS]
__global__ void k_rbs(float* __restrict__ rbs, float* __restrict__ Cs) {
  int i = blockIdx.x * blockDim.x + threadIdx.x;
  if (i >= TROWS * NRBF) return;
  int j = i / NRBF, k = i - j * NRBF;
  float dj = (float)j * (DMAX / (float)NTAB);
  const float step = 10.0f / 49.0f;
  const float coeff = -0.5f / (step * step);
  float t = dj - (float)k * step;
  rbs[i] = expf(coeff * t * t);
  if (k == 0) Cs[j] = 0.5f * (cosf(dj * (3.14159265358979323846f / 10.0f)) + 1.0f);
}

__global__ void k_hsinit(const int* __restrict__ z, const float* __restrict__ emb,
                         float* __restrict__ hs) {
  int i = blockIdx.x * blockDim.x + threadIdx.x;
  if (i >= NN * DSCH) return;
  hs[i] = emb[z[i >> 7] * DSCH + (i & 127)];
}

// CFConv via table interpolation: agg3[dst] += lerp(ftab, d)*x1[src]; one edge per wave
__global__ __launch_bounds__(256) void k_conv_tab(const float* __restrict__ d3,
                                                  const float* __restrict__ ftab,
                                                  const float* __restrict__ x1,
                                                  const int* __restrict__ src3,
                                                  const int* __restrict__ dst3,
                                                  float* __restrict__ agg3) {
  int e = blockIdx.x * 4 + (threadIdx.x >> 6);
  int lane = threadIdx.x & 63;
  float dd = d3[e];
  float u = fminf(dd * ((float)NTAB / DMAX), (float)NTAB - 0.001f);
  int idx = (int)u;
  float fr = u - (float)idx;
  int s = src3[e], d = dst3[e];
  float2 t0 = ((const float2*)(ftab + (size_t)idx * 128))[lane];
  float2 t1 = ((const float2*)(ftab + (size_t)(idx + 1) * 128))[lane];
  float2 xv = ((const float2*)(x1 + (size_t)s * 128))[lane];
  float w0 = t0.x + fr * (t1.x - t0.x);
  float w1 = t0.y + fr * (t1.y - t0.y);
  float* dp = agg3 + (size_t)d * 128 + lane * 2;
  atomicAdd(dp + 0, w0 * xv.x);
  atomicAdd(dp + 1, w1 * xv.y);
}

__global__ void k_gate(const float* __restrict__ gh, const float* __restrict__ gW2,
                       const float* __restrict__ gb2, float* __restrict__ g) {
  int m = blockIdx.x * blockDim.x + threadIdx.x;
  if (m >= NG) return;
  float acc = gb2[0];
  for (int k = 0; k < 128; ++k) acc += gh[m * 128 + k] * gW2[k];
  g[m] = 1.0f / (1.0f + expf(-acc));
}

__global__ void k_hf(const float* __restrict__ g, const float* __restrict__ hcat,
                     float* __restrict__ hf) {
  int i = blockIdx.x * blockDim.x + threadIdx.x;
  if (i >= NG * DEMB) return;
  int m = i / DEMB, c = i - m * DEMB;
  float gg = g[m];
  hf[i] = gg * hcat[m * 600 + c] + (1.0f - gg) * hcat[m * 600 + 300 + c];
}

// ---------------- generic fp32 GEMM (64x64 tile): C = act((A[+A2])@B + bias)[*gamma+beta][*rscale][+Cin]
template <int ACT>  // 0 none, 1 relu, 2 ssp
__global__ __launch_bounds__(256) void k_gemm(
    const float* __restrict__ A, const float* __restrict__ A2, const float* __restrict__ B,
    const float* __restrict__ bias, const float* __restrict__ scale,
    const float* __restrict__ shift, const float* __restrict__ rscale,
    const float* __restrict__ Cin, float* __restrict__ Cout, int M, int N, int K, int ldc) {
  __shared__ float sA[16][65];
  __shared__ float sB[16][64];
  int tid = threadIdx.x;
  int tx = tid & 15, ty = tid >> 4;
  int bm = blockIdx.y * 64, bn = blockIdx.x * 64;
  float acc[4][4] = {};
  for (int k0 = 0; k0 < K; k0 += 16) {
#pragma unroll
    for (int t = 0; t < 4; ++t) {
      int i = tid + t * 256;
      int m = i >> 4, kk = i & 15;
      int gm = bm + m, gk = k0 + kk;
      float v = 0.f;
      if (gm < M && gk < K) {
        v = A[(size_t)gm * K + gk];
        if (A2) v += A2[(size_t)gm * K + gk];
      }
      sA[kk][m] = v;
    }
#pragma unroll
    for (int t = 0; t < 4; ++t) {
      int i = tid + t * 256;
      int kk = i >> 6, n = i & 63;
      int gk = k0 + kk, gn = bn + n;
      sB[kk][n] = (gk < K && gn < N) ? B[(size_t)gk * N + gn] : 0.f;
    }
    __syncthreads();
#pragma unroll
    for (int kk = 0; kk < 16; ++kk) {
      float a[4], b[4];
#pragma unroll
      for (int i = 0; i < 4; ++i) a[i] = sA[kk][ty + 16 * i];
#pragma unroll
      for (int j = 0; j < 4; ++j) b[j] = sB[kk][tx + 16 * j];
#pragma unroll
      for (int i = 0; i < 4; ++i)
#pragma unroll
        for (int j = 0; j < 4; ++j) acc[i][j] = fmaf(a[i], b[j], acc[i][j]);
    }
    __syncthreads();
  }
#pragma unroll
  for (int i = 0; i < 4; ++i) {
    int gm = bm + ty + 16 * i;
    if (gm >= M) continue;
    float rs = rscale ? rscale[gm] : 1.0f;
#pragma unroll
    for (int j = 0; j < 4; ++j) {
      int gn = bn + tx + 16 * j;
      if (gn >= N) continue;
      float v = acc[i][j];
      if (bias) v += bias[gn];
      if (scale) v = v * scale[gn] + shift[gn];
      v *= rs;
      if (ACT == 1) v = fmaxf(v, 0.f);
      if (ACT == 2) v = sspf(v);
      if (Cin) v += Cin[(size_t)gm * ldc + gn];
      Cout[(size_t)gm * ldc + gn] = v;
    }
  }
}

// ---------------- big fp32 GEMM (128x128 tile, 8x8 microtile) ----------------
template <int ACT>
__global__ __launch_bounds__(256) void k_gemm128(
    const float* __restrict__ A, const float* __restrict__ A2, const float* __restrict__ B,
    const float* __restrict__ bias, const float* __restrict__ scale,
    const float* __restrict__ shift, const float* __restrict__ Cin, float* __restrict__ Cout,
    int M, int N, int K, int ldc) {
  __shared__ float sA[16][132];
  __shared__ float sB[16][132];
  int tid = threadIdx.x;
  int tx = tid & 15, ty = tid >> 4;
  int bm = blockIdx.y * 128, bn = blockIdx.x * 128;
  float acc[8][8] = {};
  for (int k0 = 0; k0 < K; k0 += 16) {
#pragma unroll
    for (int t = 0; t < 8; ++t) {
      int i = tid + t * 256;
      int m = i >> 4, kk = i & 15;
      int gm = bm + m, gk = k0 + kk;
      float v = 0.f;
      if (gm < M && gk < K) {
        v = A[(size_t)gm * K + gk];
        if (A2) v += A2[(size_t)gm * K + gk];
      }
      sA[kk][m] = v;
    }
#pragma unroll
    for (int t = 0; t < 8; ++t) {
      int i = tid + t * 256;
      int kk = i >> 7, n = i & 127;
      int gk = k0 + kk, gn = bn + n;
      sB[kk][n] = (gk < K && gn < N) ? B[(size_t)gk * N + gn] : 0.f;
    }
    __syncthreads();
#pragma unroll
    for (int kk = 0; kk < 16; ++kk) {
      float a[8], b[8];
#pragma unroll
      for (int i = 0; i < 8; ++i) a[i] = sA[kk][ty * 8 + i];
#pragma unroll
      for (int j = 0; j < 8; ++j) b[j] = sB[kk][tx * 8 + j];
#pragma unroll
      for (int i = 0; i < 8; ++i)
#pragma unroll
        for (int j = 0; j < 8; ++j) acc[i][j] = fmaf(a[i], b[j], acc[i][j]);
    }
    __syncthreads();
  }
#pragma unroll
  for (int i = 0; i < 8; ++i) {
    int gm = bm + ty * 8 + i;
    if (gm >= M) continue;
#pragma unroll
    for (int j = 0; j < 8; ++j) {
      int gn = bn + tx * 8 + j;
      if (gn >= N) continue;
      float v = acc[i][j];
      if (bias) v += bias[gn];
      if (scale) v = v * scale[gn] + shift[gn];
      if (ACT == 1) v = fmaxf(v, 0.f);
      if (ACT == 2) v = sspf(v);
      if (Cin) v += Cin[(size_t)gm * ldc + gn];
      Cout[(size_t)gm * ldc + gn] = v;
    }
  }
}

// ---------------- host ----------------

static inline void run_gemm(hipStream_t st, const float* A, const float* A2, const float* B,
                            const float* bias, const float* scale, const float* shift,
                            const float* rscale, const float* Cin, float* Cout, int M, int N,
                            int K, int ldc, int act) {
  dim3 grid((N + 63) / 64, (M + 63) / 64);
  if (act == 0)
    k_gemm<0><<<grid, 256, 0, st>>>(A, A2, B, bias, scale, shift, rscale, Cin, Cout, M, N, K, ldc);
  else if (act == 1)
    k_gemm<1><<<grid, 256, 0, st>>>(A, A2, B, bias, scale, shift, rscale, Cin, Cout, M, N, K, ldc);
  else
    k_gemm<2><<<grid, 256, 0, st>>>(A, A2, B, bias, scale, shift, rscale, Cin, Cout, M, N, K, ldc);
}

static inline void run_gemm128(hipStream_t st, const float* A, const float* A2, const float* B,
                               const float* bias, const float* scale, const float* shift,
                               const float* Cin, float* Cout, int M, int N, int K, int ldc,
                               int act) {
  dim3 grid((N + 127) / 128, (M + 127) / 128);
  if (act == 0)
    k_gemm128<0><<<grid, 256, 0, st>>>(A, A2, B, bias, scale, shift, Cin, Cout, M, N, K, ldc);
  else if (act == 1)
    k_gemm128<1><<<grid, 256, 0, st>>>(A, A2, B, bias, scale, shift, Cin, Cout, M, N, K, ldc);
  else
    k_gemm128<2><<<grid, 256, 0, st>>>(A, A2, B, bias, scale, shift, Cin, Cout, M, N, K, ldc);
}

extern "C" void kernel_launch(void* const* d_in, const int* in_sizes, int n_in, void* d_out,
                              int out_size, void* d_ws, size_t ws_size, hipStream_t stream) {
  const int* x2d = (const int*)d_in[0];
  const int* ei2 = (const int*)d_in[1];
  const int* ea2 = (const int*)d_in[2];
  const int* batch = (const int*)d_in[3];
  const int* z = (const int*)d_in[4];
  const float* pos = (const float*)d_in[5];
  const int* ei3 = (const int*)d_in[6];
  const float* atom_emb1 = (const float*)d_in[7];
  const float* atom_emb2 = (const float*)d_in[8];
  const float* vn_init = (const float*)d_in[9];
  const float* gin_W1 = (const float*)d_in[10];
  const float* gin_b1 = (const float*)d_in[11];
  const float* gin_W2 = (const float*)d_in[12];
  const float* gin_b2 = (const float*)d_in[13];
  const float* gin_bond1 = (const float*)d_in[14];
  const float* gin_bond2 = (const float*)d_in[15];
  const float* gin_gamma = (const float*)d_in[16];
  const float* gin_beta = (const float*)d_in[17];
  const float* vn_W1 = (const float*)d_in[18];
  const float* vn_b1 = (const float*)d_in[19];
  const float* vn_W2 = (const float*)d_in[20];
  const float* vn_b2 = (const float*)d_in[21];
  const float* sch_emb = (const float*)d_in[22];
  const float* s_mW1 = (const float*)d_in[23];
  const float* s_mb1 = (const float*)d_in[24];
  const float* s_mW2 = (const float*)d_in[25];
  const float* s_mb2 = (const float*)d_in[26];
  const float* s_lin1W = (const float*)d_in[27];
  const float* s_lin2W = (const float*)d_in[28];
  const float* s_lin2b = (const float*)d_in[29];
  const float* s_linW = (const float*)d_in[30];
  const float* s_linb = (const float*)d_in[31];
  const float* p2W = (const float*)d_in[32];
  const float* p2b = (const float*)d_in[33];
  const float* p3W = (const float*)d_in[34];
  const float* p3b = (const float*)d_in[35];
  const float* gW1 = (const float*)d_in[36];
  const float* gb1 = (const float*)d_in[37];
  const float* gW2 = (const float*)d_in[38];
  const float* gb2 = (const float*)d_in[39];
  const float* cW1 = (const float*)d_in[40];
  const float* cb1 = (const float*)d_in[41];
  const float* cW2 = (const float*)d_in[42];
  const float* cb2 = (const float*)d_in[43];

  float* ws = (float*)d_ws;
  // GIN arena [0, 19660800)
  float* h = ws;              // 16384*300
  float* agg = ws + 4915200;  // 16384*300
  float* y1 = ws + 9830400;   // 16384*600
  // SchNet phase aliases onto GIN arena
  float* d3 = ws;              // 393216
  float* rbs = ws + 400000;    // 5121*50 = 256050
  float* Cs = ws + 700000;     // 5121
  float* t1t = ws + 710000;    // 5121*128 = 655488
  float* ftab = ws + 1400000;  // 655488
  float* hs = ws + 2100000;    // 16384*128
  float* x1 = ws + 4200000;    // 16384*128
  float* agg3 = ws + 6300000;  // 16384*128
  float* sx2 = ws + 8400000;   // 16384*128 -> ends 10497152 < 19660800
  // persistent tail
  float* counts = ws + 28442624;  // 512
  float* vn = ws + 28443136;      // 512*300
  float* vnsum = ws + 28596736;   // 512*300
  float* vnh = ws + 28750336;     // 512*600
  float* h2d = ws + 29057536;     // 512*300
  float* h3d = ws + 29211136;     // 512*128
  float* hcat = ws + 29276672;    // 512*600
  float* gh = ws + 29583872;      // 512*128
  float* gbuf = ws + 29649408;    // 512
  float* hf = ws + 29649920;      // 512*300
  float* c1 = ws + 29803520;      // 512*150

  hipMemsetAsync(counts, 0, 512 * sizeof(float), stream);
  k_counts<<<(NN + 255) / 256, 256, 0, stream>>>(batch, counts);

  // ---- GIN ----
  k_hinit<<<(NN * DEMB + 255) / 256, 256, 0, stream>>>(x2d, atom_emb1, atom_emb2, h);
  k_vninit<<<(NG * DEMB + 255) / 256, 256, 0, stream>>>(vn_init, vn);
  for (int l = 0; l < 5; ++l) {
    k_addvn<<<(NN * DEMB + 255) / 256, 256, 0, stream>>>(h, vn, batch);
    hipMemsetAsync(agg, 0, (size_t)NN * DEMB * sizeof(float), stream);
    k_gin_edge<<<(NE2 * 75 + 255) / 256, 256, 0, stream>>>(
        h, ei2, ea2, gin_bond1 + l * 6 * DEMB, gin_bond2 + l * 3 * DEMB, agg);
    run_gemm128(stream, h, agg, gin_W1 + (size_t)l * 180000, gin_b1 + l * 600, nullptr, nullptr,
                nullptr, y1, NN, 600, 300, 600, 1);
    run_gemm128(stream, y1, nullptr, gin_W2 + (size_t)l * 180000, gin_b2 + l * 300,
                gin_gamma + l * 300, gin_beta + l * 300, nullptr, h, NN, 300, 600, 300,
                (l < 4) ? 1 : 0);
    if (l < 4) {
      hipMemsetAsync(vnsum, 0, (size_t)NG * DEMB * sizeof(float), stream);
      k_segsum<<<(NN * DEMB + 255) / 256, 256, 0, stream>>>(h, batch, vnsum, NN, DEMB);
      run_gemm(stream, vnsum, vn, vn_W1 + (size_t)l * 180000, vn_b1 + l * 600, nullptr, nullptr,
               nullptr, nullptr, vnh, NG, 600, 300, 600, 1);
      run_gemm(stream, vnh, nullptr, vn_W2 + (size_t)l * 180000, vn_b2 + l * 300, nullptr, nullptr,
               nullptr, nullptr, vn, NG, 300, 600, 300, 1);
    }
  }
  hipMemsetAsync(h2d, 0, (size_t)NG * DEMB * sizeof(float), stream);
  k_segsum<<<(NN * DEMB + 255) / 256, 256, 0, stream>>>(h, batch, h2d, NN, DEMB);
  k_div<<<(NG * DEMB + 255) / 256, 256, 0, stream>>>(h2d, counts, NG, DEMB);

  // ---- SchNet ----
  k_dist<<<(NE3 + 255) / 256, 256, 0, stream>>>(ei3, pos, d3);
  k_rbs<<<(TROWS * NRBF + 255) / 256, 256, 0, stream>>>(rbs, Cs);
  k_hsinit<<<(NN * DSCH + 255) / 256, 256, 0, stream>>>(z, sch_emb, hs);
  for (int l = 0; l < 6; ++l) {
    // build per-layer filter table F(d) = (ssp(rbf@mW1+mb1)@mW2+mb2)*C(d)
    run_gemm(stream, rbs, nullptr, s_mW1 + (size_t)l * 6400, s_mb1 + l * 128, nullptr, nullptr,
             nullptr, nullptr, t1t, TROWS, 128, 50, 128, 2);
    run_gemm(stream, t1t, nullptr, s_mW2 + (size_t)l * 16384, s_mb2 + l * 128, nullptr, nullptr,
             Cs, nullptr, ftab, TROWS, 128, 128, 128, 0);
    run_gemm(stream, hs, nullptr, s_lin1W + (size_t)l * 16384, nullptr, nullptr, nullptr, nullptr,
             nullptr, x1, NN, 128, 128, 128, 0);
    hipMemsetAsync(agg3, 0, (size_t)NN * DSCH * sizeof(float), stream);
    k_conv_tab<<<NE3 / 4, 256, 0, stream>>>(d3, ftab, x1, ei3, ei3 + NE3, agg3);
    run_gemm(stream, agg3, nullptr, s_lin2W + (size_t)l * 16384, s_lin2b + l * 128, nullptr,
             nullptr, nullptr, nullptr, sx2, NN, 128, 128, 128, 2);
    run_gemm(stream, sx2, nullptr, s_linW + (size_t)l * 16384, s_linb + l * 128, nullptr, nullptr,
             nullptr, hs, hs, NN, 128, 128, 128, 0);
  }
  hipMemsetAsync(h3d, 0, (size_t)NG * DSCH * sizeof(float), stream);
  k_segsum<<<(NN * DSCH + 255) / 256, 256, 0, stream>>>(hs, batch, h3d, NN, DSCH);
  k_div<<<(NG * DSCH + 255) / 256, 256, 0, stream>>>(h3d, counts, NG, DSCH);

  // ---- fusion + classifier ----
  run_gemm(stream, h2d, nullptr, p2W, p2b, nullptr, nullptr, nullptr, nullptr, hcat, NG, 300, 300,
           600, 0);
  run_gemm(stream, h3d, nullptr, p3W, p3b, nullptr, nullptr, nullptr, nullptr, hcat + 300, NG, 300,
           128, 600, 0);
  run_gemm(stream, hcat, nullptr, gW1, gb1, nullptr, nullptr, nullptr, nullptr, gh, NG, 128, 600,
           128, 1);
  k_gate<<<2, 256, 0, stream>>>(gh, gW2, gb2, gbuf);
  k_hf<<<(NG * DEMB + 255) / 256, 256, 0, stream>>>(gbuf, hcat, hf);
  run_gemm(stream, hf, nullptr, cW1, cb1, nullptr, nullptr, nullptr, nullptr, c1, NG, 150, 300, 150,
           1);
  run_gemm(stream, c1, nullptr, cW2, cb2, nullptr, nullptr, nullptr, nullptr, (float*)d_out, NG, 12,
           150, 12, 0);
}

// Round 3
// 6025.049 us; speedup vs baseline: 1.6548x; 1.6548x over previous
//
#include <hip/hip_runtime.h>
#include <hip/hip_bf16.h>
#include <math.h>

#define NN 16384
#define NG 512
#define NE2 65536
#define NE3 393216
#define DEMB 300
#define DSCH 128
#define NRBF 50
#define NTAB 5120
#define TROWS 5121
#define DMAX 25.0f

typedef __attribute__((ext_vector_type(8))) short bf16x8;
typedef __attribute__((ext_vector_type(4))) float f32x4;

__device__ __forceinline__ float sspf(float x) {
  float sp = log1pf(expf(-fabsf(x))) + fmaxf(x, 0.f);
  return sp - 0.69314718055994530942f;
}

__device__ __forceinline__ short f2b(float f) {
  union { float f; unsigned u; } v;
  v.f = f;
  unsigned r = v.u + 0x7FFF + ((v.u >> 16) & 1);  // RNE
  return (short)(r >> 16);
}

// ---------------- small elementwise / scatter kernels ----------------

__global__ void k_counts(const int* __restrict__ batch, float* __restrict__ counts) {
  int i = blockIdx.x * blockDim.x + threadIdx.x;
  if (i < NN) atomicAdd(&counts[batch[i]], 1.0f);
}

__global__ void k_hinit(const int* __restrict__ x2d, const float* __restrict__ e1,
                        const float* __restrict__ e2, float* __restrict__ h) {
  int i = blockIdx.x * blockDim.x + threadIdx.x;
  if (i >= NN * DEMB) return;
  int n = i / DEMB, c = i - n * DEMB;
  h[i] = e1[x2d[2 * n] * DEMB + c] + e2[x2d[2 * n + 1] * DEMB + c];
}

__global__ void k_vninit(const float* __restrict__ vni, float* __restrict__ vn) {
  int i = blockIdx.x * blockDim.x + threadIdx.x;
  if (i >= NG * DEMB) return;
  vn[i] = vni[i % DEMB];
}

__global__ void k_addvn(float* __restrict__ h, const float* __restrict__ vn,
                        const int* __restrict__ batch) {
  int i = blockIdx.x * blockDim.x + threadIdx.x;
  if (i >= NN * DEMB) return;
  int n = i / DEMB, c = i - n * DEMB;
  h[i] += vn[batch[n] * DEMB + c];
}

__global__ void k_gin_edge(const float* __restrict__ h, const int* __restrict__ ei2,
                           const int* __restrict__ ea2, const float* __restrict__ bond1,
                           const float* __restrict__ bond2, float* __restrict__ agg) {
  int i = blockIdx.x * blockDim.x + threadIdx.x;  // e*75 + c4
  if (i >= NE2 * 75) return;
  int e = i / 75, c = i - e * 75;
  int s = ei2[e], d = ei2[NE2 + e];
  int a0 = ea2[2 * e], a1 = ea2[2 * e + 1];
  const float4 hv = *(const float4*)(h + (size_t)s * DEMB + c * 4);
  const float4 b1 = *(const float4*)(bond1 + (size_t)a0 * DEMB + c * 4);
  const float4 b2 = *(const float4*)(bond2 + (size_t)a1 * DEMB + c * 4);
  float4 m;
  m.x = fmaxf(hv.x + b1.x + b2.x, 0.f);
  m.y = fmaxf(hv.y + b1.y + b2.y, 0.f);
  m.z = fmaxf(hv.z + b1.z + b2.z, 0.f);
  m.w = fmaxf(hv.w + b1.w + b2.w, 0.f);
  float* dp = agg + (size_t)d * DEMB + c * 4;
  atomicAdd(dp + 0, m.x);
  atomicAdd(dp + 1, m.y);
  atomicAdd(dp + 2, m.z);
  atomicAdd(dp + 3, m.w);
}

__global__ void k_segsum(const float* __restrict__ x, const int* __restrict__ batch,
                         float* __restrict__ out, int n, int W) {
  int i = blockIdx.x * blockDim.x + threadIdx.x;
  if (i >= n * W) return;
  int r = i / W, c = i - r * W;
  atomicAdd(&out[batch[r] * W + c], x[i]);
}

__global__ void k_div(float* __restrict__ buf, const float* __restrict__ counts, int B, int W) {
  int i = blockIdx.x * blockDim.x + threadIdx.x;
  if (i >= B * W) return;
  buf[i] /= fmaxf(counts[i / W], 1.0f);
}

__global__ void k_dist(const int* __restrict__ ei3, const float* __restrict__ pos,
                       float* __restrict__ d3) {
  int e = blockIdx.x * blockDim.x + threadIdx.x;
  if (e >= NE3) return;
  int s = ei3[e], d = ei3[NE3 + e];
  float dx = pos[3 * d] - pos[3 * s];
  float dy = pos[3 * d + 1] - pos[3 * s + 1];
  float dz = pos[3 * d + 2] - pos[3 * s + 2];
  d3[e] = sqrtf(dx * dx + dy * dy + dz * dz);
}

__global__ void k_rbs(float* __restrict__ rbs, float* __restrict__ Cs) {
  int i = blockIdx.x * blockDim.x + threadIdx.x;
  if (i >= TROWS * NRBF) return;
  int j = i / NRBF, k = i - j * NRBF;
  float dj = (float)j * (DMAX / (float)NTAB);
  const float step = 10.0f / 49.0f;
  const float coeff = -0.5f / (step * step);
  float t = dj - (float)k * step;
  rbs[i] = expf(coeff * t * t);
  if (k == 0) Cs[j] = 0.5f * (cosf(dj * (3.14159265358979323846f / 10.0f)) + 1.0f);
}

__global__ void k_hsinit(const int* __restrict__ z, const float* __restrict__ emb,
                         float* __restrict__ hs) {
  int i = blockIdx.x * blockDim.x + threadIdx.x;
  if (i >= NN * DSCH) return;
  hs[i] = emb[z[i >> 7] * DSCH + (i & 127)];
}

__global__ __launch_bounds__(256) void k_conv_tab(const float* __restrict__ d3,
                                                  const float* __restrict__ ftab,
                                                  const float* __restrict__ x1,
                                                  const int* __restrict__ src3,
                                                  const int* __restrict__ dst3,
                                                  float* __restrict__ agg3) {
  int e = blockIdx.x * 4 + (threadIdx.x >> 6);
  int lane = threadIdx.x & 63;
  float dd = d3[e];
  float u = fminf(dd * ((float)NTAB / DMAX), (float)NTAB - 0.001f);
  int idx = (int)u;
  float fr = u - (float)idx;
  int s = src3[e], d = dst3[e];
  float2 t0 = ((const float2*)(ftab + (size_t)idx * 128))[lane];
  float2 t1 = ((const float2*)(ftab + (size_t)(idx + 1) * 128))[lane];
  float2 xv = ((const float2*)(x1 + (size_t)s * 128))[lane];
  float w0 = t0.x + fr * (t1.x - t0.x);
  float w1 = t0.y + fr * (t1.y - t0.y);
  float* dp = agg3 + (size_t)d * 128 + lane * 2;
  atomicAdd(dp + 0, w0 * xv.x);
  atomicAdd(dp + 1, w1 * xv.y);
}

__global__ void k_gate(const float* __restrict__ gh, const float* __restrict__ gW2,
                       const float* __restrict__ gb2, float* __restrict__ g) {
  int m = blockIdx.x * blockDim.x + threadIdx.x;
  if (m >= NG) return;
  float acc = gb2[0];
  for (int k = 0; k < 128; ++k) acc += gh[m * 128 + k] * gW2[k];
  g[m] = 1.0f / (1.0f + expf(-acc));
}

__global__ void k_hf(const float* __restrict__ g, const float* __restrict__ hcat,
                     float* __restrict__ hf) {
  int i = blockIdx.x * blockDim.x + threadIdx.x;
  if (i >= NG * DEMB) return;
  int m = i / DEMB, c = i - m * DEMB;
  float gg = g[m];
  hf[i] = gg * hcat[m * 600 + c] + (1.0f - gg) * hcat[m * 600 + 300 + c];
}

// ---------------- weight prep: W[l][K][N] f32 -> Wt[l][Np][Kp] bf16 (transposed, zero-padded)
__global__ void k_prepw(const float* __restrict__ W, short* __restrict__ Wt, int K, int N, int Kp,
                        int Np, int L) {
  int i = blockIdx.x * blockDim.x + threadIdx.x;
  int per = Np * Kp;
  if (i >= L * per) return;
  int l = i / per, r = i - l * per;
  int n = r / Kp, k = r - n * Kp;
  float v = (n < N && k < K) ? W[(size_t)l * K * N + (size_t)k * N + n] : 0.f;
  Wt[i] = f2b(v);
}

// ---------------- generic fp32 GEMM (64x64 tile) — small matrices only ----------------
template <int ACT>  // 0 none, 1 relu, 2 ssp
__global__ __launch_bounds__(256) void k_gemm(
    const float* __restrict__ A, const float* __restrict__ A2, const float* __restrict__ B,
    const float* __restrict__ bias, const float* __restrict__ scale,
    const float* __restrict__ shift, const float* __restrict__ rscale,
    const float* __restrict__ Cin, float* __restrict__ Cout, int M, int N, int K, int ldc) {
  __shared__ float sA[16][65];
  __shared__ float sB[16][64];
  int tid = threadIdx.x;
  int tx = tid & 15, ty = tid >> 4;
  int bm = blockIdx.y * 64, bn = blockIdx.x * 64;
  float acc[4][4] = {};
  for (int k0 = 0; k0 < K; k0 += 16) {
#pragma unroll
    for (int t = 0; t < 4; ++t) {
      int i = tid + t * 256;
      int m = i >> 4, kk = i & 15;
      int gm = bm + m, gk = k0 + kk;
      float v = 0.f;
      if (gm < M && gk < K) {
        v = A[(size_t)gm * K + gk];
        if (A2) v += A2[(size_t)gm * K + gk];
      }
      sA[kk][m] = v;
    }
#pragma unroll
    for (int t = 0; t < 4; ++t) {
      int i = tid + t * 256;
      int kk = i >> 6, n = i & 63;
      int gk = k0 + kk, gn = bn + n;
      sB[kk][n] = (gk < K && gn < N) ? B[(size_t)gk * N + gn] : 0.f;
    }
    __syncthreads();
#pragma unroll
    for (int kk = 0; kk < 16; ++kk) {
      float a[4], b[4];
#pragma unroll
      for (int i = 0; i < 4; ++i) a[i] = sA[kk][ty + 16 * i];
#pragma unroll
      for (int j = 0; j < 4; ++j) b[j] = sB[kk][tx + 16 * j];
#pragma unroll
      for (int i = 0; i < 4; ++i)
#pragma unroll
        for (int j = 0; j < 4; ++j) acc[i][j] = fmaf(a[i], b[j], acc[i][j]);
    }
    __syncthreads();
  }
#pragma unroll
  for (int i = 0; i < 4; ++i) {
    int gm = bm + ty + 16 * i;
    if (gm >= M) continue;
    float rs = rscale ? rscale[gm] : 1.0f;
#pragma unroll
    for (int j = 0; j < 4; ++j) {
      int gn = bn + tx + 16 * j;
      if (gn >= N) continue;
      float v = acc[i][j];
      if (bias) v += bias[gn];
      if (scale) v = v * scale[gn] + shift[gn];
      v *= rs;
      if (ACT == 1) v = fmaxf(v, 0.f);
      if (ACT == 2) v = sspf(v);
      if (Cin) v += Cin[(size_t)gm * ldc + gn];
      Cout[(size_t)gm * ldc + gn] = v;
    }
  }
}

// ---------------- bf16 MFMA GEMM: 128x128 block, 4 waves, BK=32 ----------------
// A f32 [M,K] (+A2), Wt bf16 [Np,Kp] pre-transposed.  M must be a multiple of 128.
// C = act((A[+A2])@B + bias [*scale+shift]) [+Cin], f32 out.

__device__ __forceinline__ float4 ld4g(const float* __restrict__ row, int k, int K) {
  if (k + 3 < K) return *(const float4*)(row + k);
  float4 r;
  r.x = (k + 0 < K) ? row[k + 0] : 0.f;
  r.y = (k + 1 < K) ? row[k + 1] : 0.f;
  r.z = (k + 2 < K) ? row[k + 2] : 0.f;
  r.w = (k + 3 < K) ? row[k + 3] : 0.f;
  return r;
}

template <int ACT>
__global__ __launch_bounds__(256) void k_mgemm(
    const float* __restrict__ A, const float* __restrict__ A2, const short* __restrict__ Wt,
    const float* __restrict__ bias, const float* __restrict__ scale,
    const float* __restrict__ shift, const float* __restrict__ Cin, float* __restrict__ Cout,
    int M, int N, int K, int Kp, int ldc) {
  __shared__ short sA[128 * 32];  // [row][32] bf16, 16B-slot XOR swizzled
  const int tid = threadIdx.x;
  const int lane = tid & 63;
  const int w = tid >> 6;
  const int wm = w >> 1, wn = w & 1;
  const int bm = blockIdx.y * 128, bn = blockIdx.x * 128;

  f32x4 acc[4][4] = {};

  // staging coords: thread t -> row r=t>>1, k-offset (t&1)*16
  const int sr = tid >> 1;
  const int sk = (tid & 1) * 16;
  const float* Arow = A + (size_t)(bm + sr) * K;
  const float* A2row = A2 ? A2 + (size_t)(bm + sr) * K : nullptr;
  const int ssw = (sr + (sr >> 2)) & 3;
  bf16x8* sAv = (bf16x8*)sA;

  // fragment read coords
  const int frow = wm * 64 + (lane & 15);
  const int fslot = lane >> 4;
  // B pointer: row n = bn + wn*64 + (lane&15), k = (lane>>4)*8
  const short* Bbase = Wt + (size_t)(bn + wn * 64 + (lane & 15)) * Kp + (fslot * 8);

  for (int k0 = 0; k0 < Kp; k0 += 32) {
    __syncthreads();
    // stage A (f32 -> bf16) with K-guard zero fill
    {
      short v[16];
#pragma unroll
      for (int q = 0; q < 4; ++q) {
        float4 a = ld4g(Arow, k0 + sk + 4 * q, K);
        if (A2row) {
          float4 b = ld4g(A2row, k0 + sk + 4 * q, K);
          a.x += b.x; a.y += b.y; a.z += b.z; a.w += b.w;
        }
        v[4 * q + 0] = f2b(a.x);
        v[4 * q + 1] = f2b(a.y);
        v[4 * q + 2] = f2b(a.z);
        v[4 * q + 3] = f2b(a.w);
      }
      bf16x8 p0, p1;
#pragma unroll
      for (int j = 0; j < 8; ++j) { p0[j] = v[j]; p1[j] = v[8 + j]; }
      int s0 = (sk >> 3);  // slot index 0..3
      sAv[sr * 4 + ((s0 + 0) ^ ssw)] = p0;
      sAv[sr * 4 + ((s0 + 1) ^ ssw)] = p1;
    }
    __syncthreads();

    bf16x8 af[4], bf[4];
#pragma unroll
    for (int mf = 0; mf < 4; ++mf) {
      int r = frow + mf * 16;
      af[mf] = sAv[r * 4 + (fslot ^ ((r + (r >> 2)) & 3))];
    }
#pragma unroll
    for (int nf = 0; nf < 4; ++nf)
      bf[nf] = *(const bf16x8*)(Bbase + (size_t)nf * 16 * Kp + k0);
#pragma unroll
    for (int mf = 0; mf < 4; ++mf)
#pragma unroll
      for (int nf = 0; nf < 4; ++nf)
        acc[mf][nf] = __builtin_amdgcn_mfma_f32_16x16x32_bf16(af[mf], bf[nf], acc[mf][nf], 0, 0, 0);
  }

  // epilogue
  const int colbase = bn + wn * 64 + (lane & 15);
  const int rowbase = bm + wm * 64 + ((lane >> 4) << 2);
#pragma unroll
  for (int nf = 0; nf < 4; ++nf) {
    int col = colbase + nf * 16;
    if (col >= N) continue;
    float bi = bias ? bias[col] : 0.f;
    float sc = scale ? scale[col] : 1.f;
    float sh = shift ? shift[col] : 0.f;
#pragma unroll
    for (int mf = 0; mf < 4; ++mf) {
      f32x4 v = acc[mf][nf];
#pragma unroll
      for (int j = 0; j < 4; ++j) {
        int row = rowbase + mf * 16 + j;
        float x = v[j] + bi;
        if (scale) x = x * sc + sh;
        if (ACT == 1) x = fmaxf(x, 0.f);
        if (ACT == 2) x = sspf(x);
        if (Cin) x += Cin[(size_t)row * ldc + col];
        Cout[(size_t)row * ldc + col] = x;
      }
    }
  }
}

// ---------------- host ----------------

static inline void run_gemm(hipStream_t st, const float* A, const float* A2, const float* B,
                            const float* bias, const float* scale, const float* shift,
                            const float* rscale, const float* Cin, float* Cout, int M, int N,
                            int K, int ldc, int act) {
  dim3 grid((N + 63) / 64, (M + 63) / 64);
  if (act == 0)
    k_gemm<0><<<grid, 256, 0, st>>>(A, A2, B, bias, scale, shift, rscale, Cin, Cout, M, N, K, ldc);
  else if (act == 1)
    k_gemm<1><<<grid, 256, 0, st>>>(A, A2, B, bias, scale, shift, rscale, Cin, Cout, M, N, K, ldc);
  else
    k_gemm<2><<<grid, 256, 0, st>>>(A, A2, B, bias, scale, shift, rscale, Cin, Cout, M, N, K, ldc);
}

static inline void run_mgemm(hipStream_t st, const float* A, const float* A2, const short* Wt,
                             const float* bias, const float* scale, const float* shift,
                             const float* Cin, float* Cout, int M, int N, int K, int Kp, int ldc,
                             int act) {
  dim3 grid((N + 127) / 128, M / 128);
  if (act == 0)
    k_mgemm<0><<<grid, 256, 0, st>>>(A, A2, Wt, bias, scale, shift, Cin, Cout, M, N, K, Kp, ldc);
  else if (act == 1)
    k_mgemm<1><<<grid, 256, 0, st>>>(A, A2, Wt, bias, scale, shift, Cin, Cout, M, N, K, Kp, ldc);
  else
    k_mgemm<2><<<grid, 256, 0, st>>>(A, A2, Wt, bias, scale, shift, Cin, Cout, M, N, K, Kp, ldc);
}

extern "C" void kernel_launch(void* const* d_in, const int* in_sizes, int n_in, void* d_out,
                              int out_size, void* d_ws, size_t ws_size, hipStream_t stream) {
  const int* x2d = (const int*)d_in[0];
  const int* ei2 = (const int*)d_in[1];
  const int* ea2 = (const int*)d_in[2];
  const int* batch = (const int*)d_in[3];
  const int* z = (const int*)d_in[4];
  const float* pos = (const float*)d_in[5];
  const int* ei3 = (const int*)d_in[6];
  const float* atom_emb1 = (const float*)d_in[7];
  const float* atom_emb2 = (const float*)d_in[8];
  const float* vn_init = (const float*)d_in[9];
  const float* gin_W1 = (const float*)d_in[10];
  const float* gin_b1 = (const float*)d_in[11];
  const float* gin_W2 = (const float*)d_in[12];
  const float* gin_b2 = (const float*)d_in[13];
  const float* gin_bond1 = (const float*)d_in[14];
  const float* gin_bond2 = (const float*)d_in[15];
  const float* gin_gamma = (const float*)d_in[16];
  const float* gin_beta = (const float*)d_in[17];
  const float* vn_W1 = (const float*)d_in[18];
  const float* vn_b1 = (const float*)d_in[19];
  const float* vn_W2 = (const float*)d_in[20];
  const float* vn_b2 = (const float*)d_in[21];
  const float* sch_emb = (const float*)d_in[22];
  const float* s_mW1 = (const float*)d_in[23];
  const float* s_mb1 = (const float*)d_in[24];
  const float* s_mW2 = (const float*)d_in[25];
  const float* s_mb2 = (const float*)d_in[26];
  const float* s_lin1W = (const float*)d_in[27];
  const float* s_lin2W = (const float*)d_in[28];
  const float* s_lin2b = (const float*)d_in[29];
  const float* s_linW = (const float*)d_in[30];
  const float* s_linb = (const float*)d_in[31];
  const float* p2W = (const float*)d_in[32];
  const float* p2b = (const float*)d_in[33];
  const float* p3W = (const float*)d_in[34];
  const float* p3b = (const float*)d_in[35];
  const float* gW1 = (const float*)d_in[36];
  const float* gb1 = (const float*)d_in[37];
  const float* gW2 = (const float*)d_in[38];
  const float* gb2 = (const float*)d_in[39];
  const float* cW1 = (const float*)d_in[40];
  const float* cb1 = (const float*)d_in[41];
  const float* cW2 = (const float*)d_in[42];
  const float* cb2 = (const float*)d_in[43];

  float* ws = (float*)d_ws;
  // GIN arena [0, 19660800)
  float* h = ws;              // 16384*300
  float* agg = ws + 4915200;  // 16384*300
  float* y1 = ws + 9830400;   // 16384*600 -> ends 19660800
  // SchNet phase aliases onto GIN arena
  float* d3 = ws;              // 393216
  float* rbs = ws + 400000;    // 5121*50
  float* Cs = ws + 700000;     // 5121
  float* t1t = ws + 710000;    // 5121*128
  float* ftab = ws + 1400000;  // 5121*128
  float* hs = ws + 2100000;    // 16384*128
  float* x1 = ws + 4200000;    // 16384*128
  float* agg3 = ws + 6300000;  // 16384*128
  float* sx2 = ws + 8400000;   // 16384*128 -> ends 10497152
  // bf16 transposed weights (gap region, untouched by both phases)
  short* W1t = (short*)(ws + 20000000);  // 5*640*320 shorts = 512000 floats
  short* W2t = (short*)(ws + 20600000);  // 5*384*608 shorts = 583680 floats
  short* s1t = (short*)(ws + 21200000);  // 6*128*128 shorts
  short* s2t = (short*)(ws + 21300000);
  short* s3t = (short*)(ws + 21400000);  // ends ~21449152
  // persistent tail
  float* counts = ws + 28442624;  // 512
  float* vn = ws + 28443136;      // 512*300
  float* vnsum = ws + 28596736;   // 512*300
  float* vnh = ws + 28750336;     // 512*600
  float* h2d = ws + 29057536;     // 512*300
  float* h3d = ws + 29211136;     // 512*128
  float* hcat = ws + 29276672;    // 512*600
  float* gh = ws + 29583872;      // 512*128
  float* gbuf = ws + 29649408;    // 512
  float* hf = ws + 29649920;      // 512*300
  float* c1 = ws + 29803520;      // 512*150

  // ---- weight prep (bf16 transpose+pad) ----
  k_prepw<<<(5 * 640 * 320 + 255) / 256, 256, 0, stream>>>(gin_W1, W1t, 300, 600, 320, 640, 5);
  k_prepw<<<(5 * 384 * 608 + 255) / 256, 256, 0, stream>>>(gin_W2, W2t, 600, 300, 608, 384, 5);
  k_prepw<<<(6 * 128 * 128 + 255) / 256, 256, 0, stream>>>(s_lin1W, s1t, 128, 128, 128, 128, 6);
  k_prepw<<<(6 * 128 * 128 + 255) / 256, 256, 0, stream>>>(s_lin2W, s2t, 128, 128, 128, 128, 6);
  k_prepw<<<(6 * 128 * 128 + 255) / 256, 256, 0, stream>>>(s_linW, s3t, 128, 128, 128, 128, 6);

  hipMemsetAsync(counts, 0, 512 * sizeof(float), stream);
  k_counts<<<(NN + 255) / 256, 256, 0, stream>>>(batch, counts);

  // ---- GIN ----
  k_hinit<<<(NN * DEMB + 255) / 256, 256, 0, stream>>>(x2d, atom_emb1, atom_emb2, h);
  k_vninit<<<(NG * DEMB + 255) / 256, 256, 0, stream>>>(vn_init, vn);
  for (int l = 0; l < 5; ++l) {
    k_addvn<<<(NN * DEMB + 255) / 256, 256, 0, stream>>>(h, vn, batch);
    hipMemsetAsync(agg, 0, (size_t)NN * DEMB * sizeof(float), stream);
    k_gin_edge<<<(NE2 * 75 + 255) / 256, 256, 0, stream>>>(
        h, ei2, ea2, gin_bond1 + l * 6 * DEMB, gin_bond2 + l * 3 * DEMB, agg);
    run_mgemm(stream, h, agg, W1t + (size_t)l * 640 * 320, gin_b1 + l * 600, nullptr, nullptr,
              nullptr, y1, NN, 600, 300, 320, 600, 1);
    run_mgemm(stream, y1, nullptr, W2t + (size_t)l * 384 * 608, gin_b2 + l * 300,
              gin_gamma + l * 300, gin_beta + l * 300, nullptr, h, NN, 300, 600, 608, 300,
              (l < 4) ? 1 : 0);
    if (l < 4) {
      hipMemsetAsync(vnsum, 0, (size_t)NG * DEMB * sizeof(float), stream);
      k_segsum<<<(NN * DEMB + 255) / 256, 256, 0, stream>>>(h, batch, vnsum, NN, DEMB);
      run_gemm(stream, vnsum, vn, vn_W1 + (size_t)l * 180000, vn_b1 + l * 600, nullptr, nullptr,
               nullptr, nullptr, vnh, NG, 600, 300, 600, 1);
      run_gemm(stream, vnh, nullptr, vn_W2 + (size_t)l * 180000, vn_b2 + l * 300, nullptr, nullptr,
               nullptr, nullptr, vn, NG, 300, 600, 300, 1);
    }
  }
  hipMemsetAsync(h2d, 0, (size_t)NG * DEMB * sizeof(float), stream);
  k_segsum<<<(NN * DEMB + 255) / 256, 256, 0, stream>>>(h, batch, h2d, NN, DEMB);
  k_div<<<(NG * DEMB + 255) / 256, 256, 0, stream>>>(h2d, counts, NG, DEMB);

  // ---- SchNet ----
  k_dist<<<(NE3 + 255) / 256, 256, 0, stream>>>(ei3, pos, d3);
  k_rbs<<<(TROWS * NRBF + 255) / 256, 256, 0, stream>>>(rbs, Cs);
  k_hsinit<<<(NN * DSCH + 255) / 256, 256, 0, stream>>>(z, sch_emb, hs);
  for (int l = 0; l < 6; ++l) {
    run_gemm(stream, rbs, nullptr, s_mW1 + (size_t)l * 6400, s_mb1 + l * 128, nullptr, nullptr,
             nullptr, nullptr, t1t, TROWS, 128, 50, 128, 2);
    run_gemm(stream, t1t, nullptr, s_mW2 + (size_t)l * 16384, s_mb2 + l * 128, nullptr, nullptr,
             Cs, nullptr, ftab, TROWS, 128, 128, 128, 0);
    run_mgemm(stream, hs, nullptr, s1t + (size_t)l * 16384, nullptr, nullptr, nullptr, nullptr, x1,
              NN, 128, 128, 128, 128, 0);
    hipMemsetAsync(agg3, 0, (size_t)NN * DSCH * sizeof(float), stream);
    k_conv_tab<<<NE3 / 4, 256, 0, stream>>>(d3, ftab, x1, ei3, ei3 + NE3, agg3);
    run_mgemm(stream, agg3, nullptr, s2t + (size_t)l * 16384, s_lin2b + l * 128, nullptr, nullptr,
              nullptr, sx2, NN, 128, 128, 128, 128, 2);
    run_mgemm(stream, sx2, nullptr, s3t + (size_t)l * 16384, s_linb + l * 128, nullptr, nullptr,
              hs, hs, NN, 128, 128, 128, 128, 0);
  }
  hipMemsetAsync(h3d, 0, (size_t)NG * DSCH * sizeof(float), stream);
  k_segsum<<<(NN * DSCH + 255) / 256, 256, 0, stream>>>(hs, batch, h3d, NN, DSCH);
  k_div<<<(NG * DSCH + 255) / 256, 256, 0, stream>>>(h3d, counts, NG, DSCH);

  // ---- fusion + classifier ----
  run_gemm(stream, h2d, nullptr, p2W, p2b, nullptr, nullptr, nullptr, nullptr, hcat, NG, 300, 300,
           600, 0);
  run_gemm(stream, h3d, nullptr, p3W, p3b, nullptr, nullptr, nullptr, nullptr, hcat + 300, NG, 300,
           128, 600, 0);
  run_gemm(stream, hcat, nullptr, gW1, gb1, nullptr, nullptr, nullptr, nullptr, gh, NG, 128, 600,
           128, 1);
  k_gate<<<2, 256, 0, stream>>>(gh, gW2, gb2, gbuf);
  k_hf<<<(NG * DEMB + 255) / 256, 256, 0, stream>>>(gbuf, hcat, hf);
  run_gemm(stream, hf, nullptr, cW1, cb1, nullptr, nullptr, nullptr, nullptr, c1, NG, 150, 300, 150,
           1);
  run_gemm(stream, c1, nullptr, cW2, cb2, nullptr, nullptr, nullptr, nullptr, (float*)d_out, NG, 12,
           150, 12, 0);
}

// Round 4
// 3261.480 us; speedup vs baseline: 3.0570x; 1.8473x over previous
//
#include <hip/hip_runtime.h>
#include <hip/hip_bf16.h>
#include <math.h>

#define NN 16384
#define NG 512
#define NE2 65536
#define NE3 393216
#define DEMB 300
#define DSCH 128
#define NRBF 50
#define NTAB 5120
#define TROWS 5121
#define DMAX 25.0f

typedef __attribute__((ext_vector_type(8))) short bf16x8;
typedef __attribute__((ext_vector_type(4))) float f32x4;

__device__ __forceinline__ float sspf(float x) {
  float sp = log1pf(expf(-fabsf(x))) + fmaxf(x, 0.f);
  return sp - 0.69314718055994530942f;
}

__device__ __forceinline__ short f2b(float f) {
  union { float f; unsigned u; } v;
  v.f = f;
  unsigned r = v.u + 0x7FFF + ((v.u >> 16) & 1);  // RNE
  return (short)(r >> 16);
}

// ---------------- CSR build: histogram / scan / scatter ----------------

__global__ void k_hist(const int* __restrict__ keys, int* __restrict__ cnt, int n) {
  int i = blockIdx.x * blockDim.x + threadIdx.x;
  if (i < n) atomicAdd(&cnt[keys[i]], 1);
}

// exclusive scan of cnt[n] -> off[n+1]; single block of 1024 threads
__global__ __launch_bounds__(1024) void k_scan(const int* __restrict__ cnt, int* __restrict__ off,
                                               int n) {
  __shared__ int part[1024];
  int tid = threadIdx.x;
  int per = (n + 1023) / 1024;
  int base = tid * per;
  int sum = 0;
  for (int i = 0; i < per; ++i) {
    int idx = base + i;
    if (idx < n) sum += cnt[idx];
  }
  part[tid] = sum;
  __syncthreads();
  for (int d = 1; d < 1024; d <<= 1) {
    int v = (tid >= d) ? part[tid - d] : 0;
    __syncthreads();
    part[tid] += v;
    __syncthreads();
  }
  int run = (tid == 0) ? 0 : part[tid - 1];
  for (int i = 0; i < per; ++i) {
    int idx = base + i;
    if (idx < n) {
      off[idx] = run;
      run += cnt[idx];
    }
  }
  if (tid == 0) off[n] = part[1023];
}

__global__ void k_scatter2(const int* __restrict__ ei2, const int* __restrict__ ea2,
                           const int* __restrict__ off2, int* __restrict__ cur2,
                           int* __restrict__ s2s, int* __restrict__ ec2s) {
  int e = blockIdx.x * blockDim.x + threadIdx.x;
  if (e >= NE2) return;
  int d = ei2[NE2 + e];
  int p = atomicAdd(&cur2[d], 1);
  int j = off2[d] + p;
  s2s[j] = ei2[e];
  ec2s[j] = ea2[2 * e] * 4 + ea2[2 * e + 1];
}

__global__ void k_scatter3(const int* __restrict__ ei3, const float* __restrict__ pos,
                           const int* __restrict__ off3, int* __restrict__ cur3,
                           int* __restrict__ s3s, int* __restrict__ id3s,
                           float* __restrict__ fr3s) {
  int e = blockIdx.x * blockDim.x + threadIdx.x;
  if (e >= NE3) return;
  int s = ei3[e], d = ei3[NE3 + e];
  float dx = pos[3 * d] - pos[3 * s];
  float dy = pos[3 * d + 1] - pos[3 * s + 1];
  float dz = pos[3 * d + 2] - pos[3 * s + 2];
  float dist = sqrtf(dx * dx + dy * dy + dz * dz);
  float u = fminf(dist * ((float)NTAB / DMAX), (float)NTAB - 0.001f);
  int idx = (int)u;
  int p = atomicAdd(&cur3[d], 1);
  int j = off3[d] + p;
  s3s[j] = s;
  id3s[j] = idx;
  fr3s[j] = u - (float)idx;
}

// ---------------- small elementwise kernels ----------------

__global__ void k_hinit(const int* __restrict__ x2d, const float* __restrict__ e1,
                        const float* __restrict__ e2, float* __restrict__ h) {
  int i = blockIdx.x * blockDim.x + threadIdx.x;
  if (i >= NN * DEMB) return;
  int n = i / DEMB, c = i - n * DEMB;
  h[i] = e1[x2d[2 * n] * DEMB + c] + e2[x2d[2 * n + 1] * DEMB + c];
}

__global__ void k_vninit(const float* __restrict__ vni, float* __restrict__ vn) {
  int i = blockIdx.x * blockDim.x + threadIdx.x;
  if (i >= NG * DEMB) return;
  vn[i] = vni[i % DEMB];
}

__global__ void k_addvn(float* __restrict__ h, const float* __restrict__ vn,
                        const int* __restrict__ batch) {
  int i = blockIdx.x * blockDim.x + threadIdx.x;
  if (i >= NN * DEMB) return;
  int n = i / DEMB, c = i - n * DEMB;
  h[i] += vn[batch[n] * DEMB + c];
}

__global__ void k_rbs(float* __restrict__ rbs, float* __restrict__ Cs) {
  int i = blockIdx.x * blockDim.x + threadIdx.x;
  if (i >= TROWS * NRBF) return;
  int j = i / NRBF, k = i - j * NRBF;
  float dj = (float)j * (DMAX / (float)NTAB);
  const float step = 10.0f / 49.0f;
  const float coeff = -0.5f / (step * step);
  float t = dj - (float)k * step;
  rbs[i] = expf(coeff * t * t);
  if (k == 0) Cs[j] = 0.5f * (cosf(dj * (3.14159265358979323846f / 10.0f)) + 1.0f);
}

__global__ void k_hsinit(const int* __restrict__ z, const float* __restrict__ emb,
                         float* __restrict__ hs) {
  int i = blockIdx.x * blockDim.x + threadIdx.x;
  if (i >= NN * DSCH) return;
  hs[i] = emb[z[i >> 7] * DSCH + (i & 127)];
}

__global__ void k_gate(const float* __restrict__ gh, const float* __restrict__ gW2,
                       const float* __restrict__ gb2, float* __restrict__ g) {
  int m = blockIdx.x * blockDim.x + threadIdx.x;
  if (m >= NG) return;
  float acc = gb2[0];
  for (int k = 0; k < 128; ++k) acc += gh[m * 128 + k] * gW2[k];
  g[m] = 1.0f / (1.0f + expf(-acc));
}

__global__ void k_hf(const float* __restrict__ g, const float* __restrict__ hcat,
                     float* __restrict__ hf) {
  int i = blockIdx.x * blockDim.x + threadIdx.x;
  if (i >= NG * DEMB) return;
  int m = i / DEMB, c = i - m * DEMB;
  float gg = g[m];
  hf[i] = gg * hcat[m * 600 + c] + (1.0f - gg) * hcat[m * 600 + 300 + c];
}

// ---------------- gather aggregations (one wave per destination) ----------------

// GIN: agg[d] = sum_{e: dst=d} relu(h_in[src_e] + bond1[a0_e] + bond2[a1_e])
__global__ __launch_bounds__(256) void k_gin_gather(
    const float* __restrict__ h, const int* __restrict__ off2, const int* __restrict__ s2s,
    const int* __restrict__ ec2s, const float* __restrict__ bond1, const float* __restrict__ bond2,
    float* __restrict__ agg) {
  __shared__ float sb[9 * DEMB];  // 6 rows bond1 + 3 rows bond2
  int tid = threadIdx.x;
  for (int i = tid; i < 6 * DEMB; i += 256) sb[i] = bond1[i];
  for (int i = tid; i < 3 * DEMB; i += 256) sb[6 * DEMB + i] = bond2[i];
  __syncthreads();
  int d = blockIdx.x * 4 + (tid >> 6);
  int lane = tid & 63;
  int j0 = off2[d], j1 = off2[d + 1];
  float acc[5] = {};
  for (int j = j0; j < j1; ++j) {
    int s = s2s[j], ec = ec2s[j];
    const float* hr = h + (size_t)s * DEMB;
    const float* b1 = sb + (ec >> 2) * DEMB;
    const float* b2 = sb + 6 * DEMB + (ec & 3) * DEMB;
#pragma unroll
    for (int q = 0; q < 5; ++q) {
      int col = lane + 64 * q;
      if (col < DEMB) acc[q] += fmaxf(hr[col] + b1[col] + b2[col], 0.f);
    }
  }
  float* outr = agg + (size_t)d * DEMB;
#pragma unroll
  for (int q = 0; q < 5; ++q) {
    int col = lane + 64 * q;
    if (col < DEMB) outr[col] = acc[q];
  }
}

// CFConv: agg3[d] = sum_{e: dst=d} lerp(ftab,idx_e,fr_e) * x1[src_e]
__global__ __launch_bounds__(256) void k_conv_gather(
    const float* __restrict__ ftab, const float* __restrict__ x1, const int* __restrict__ off3,
    const int* __restrict__ s3s, const int* __restrict__ id3s, const float* __restrict__ fr3s,
    float* __restrict__ agg3) {
  int tid = threadIdx.x;
  int d = blockIdx.x * 4 + (tid >> 6);
  int lane = tid & 63;
  int j0 = off3[d], j1 = off3[d + 1];
  float a0 = 0.f, a1 = 0.f;
  for (int j = j0; j < j1; ++j) {
    int s = s3s[j], idx = id3s[j];
    float fr = fr3s[j];
    float2 t0 = ((const float2*)(ftab + (size_t)idx * 128))[lane];
    float2 t1 = ((const float2*)(ftab + (size_t)(idx + 1) * 128))[lane];
    float2 xv = ((const float2*)(x1 + (size_t)s * 128))[lane];
    a0 += (t0.x + fr * (t1.x - t0.x)) * xv.x;
    a1 += (t0.y + fr * (t1.y - t0.y)) * xv.y;
  }
  ((float2*)(agg3 + (size_t)d * 128))[lane] = make_float2(a0, a1);
}

// pooled segment sum/mean over sorted batch ranges; one wave per graph
template <int W, int MEAN>
__global__ __launch_bounds__(256) void k_pool(const float* __restrict__ x,
                                              const int* __restrict__ goff,
                                              float* __restrict__ out) {
  int g = blockIdx.x * 4 + (threadIdx.x >> 6);
  int lane = threadIdx.x & 63;
  if (g >= NG) return;
  int r0 = goff[g], r1 = goff[g + 1];
  constexpr int NQ = (W + 63) / 64;
  float acc[NQ] = {};
  for (int r = r0; r < r1; ++r) {
    const float* row = x + (size_t)r * W;
#pragma unroll
    for (int q = 0; q < NQ; ++q) {
      int col = lane + 64 * q;
      if ((W % 64 == 0) || col < W) acc[q] += row[col];
    }
  }
  float s = MEAN ? (1.0f / fmaxf((float)(r1 - r0), 1.0f)) : 1.0f;
#pragma unroll
  for (int q = 0; q < NQ; ++q) {
    int col = lane + 64 * q;
    if ((W % 64 == 0) || col < W) out[(size_t)g * W + col] = acc[q] * s;
  }
}

// ---------------- weight prep: W[l][K][N] f32 -> Wt[l][Np][Kp] bf16 (transposed, padded)
__global__ void k_prepw(const float* __restrict__ W, short* __restrict__ Wt, int K, int N, int Kp,
                        int Np, int L) {
  int i = blockIdx.x * blockDim.x + threadIdx.x;
  int per = Np * Kp;
  if (i >= L * per) return;
  int l = i / per, r = i - l * per;
  int n = r / Kp, k = r - n * Kp;
  float v = (n < N && k < K) ? W[(size_t)l * K * N + (size_t)k * N + n] : 0.f;
  Wt[i] = f2b(v);
}

// ---------------- generic fp32 GEMM (64x64 tile) — small matrices only ----------------
template <int ACT>  // 0 none, 1 relu, 2 ssp
__global__ __launch_bounds__(256) void k_gemm(
    const float* __restrict__ A, const float* __restrict__ A2, const float* __restrict__ B,
    const float* __restrict__ bias, const float* __restrict__ scale,
    const float* __restrict__ shift, const float* __restrict__ rscale,
    const float* __restrict__ Cin, float* __restrict__ Cout, int M, int N, int K, int ldc) {
  __shared__ float sA[16][65];
  __shared__ float sB[16][64];
  int tid = threadIdx.x;
  int tx = tid & 15, ty = tid >> 4;
  int bm = blockIdx.y * 64, bn = blockIdx.x * 64;
  float acc[4][4] = {};
  for (int k0 = 0; k0 < K; k0 += 16) {
#pragma unroll
    for (int t = 0; t < 4; ++t) {
      int i = tid + t * 256;
      int m = i >> 4, kk = i & 15;
      int gm = bm + m, gk = k0 + kk;
      float v = 0.f;
      if (gm < M && gk < K) {
        v = A[(size_t)gm * K + gk];
        if (A2) v += A2[(size_t)gm * K + gk];
      }
      sA[kk][m] = v;
    }
#pragma unroll
    for (int t = 0; t < 4; ++t) {
      int i = tid + t * 256;
      int kk = i >> 6, n = i & 63;
      int gk = k0 + kk, gn = bn + n;
      sB[kk][n] = (gk < K && gn < N) ? B[(size_t)gk * N + gn] : 0.f;
    }
    __syncthreads();
#pragma unroll
    for (int kk = 0; kk < 16; ++kk) {
      float a[4], b[4];
#pragma unroll
      for (int i = 0; i < 4; ++i) a[i] = sA[kk][ty + 16 * i];
#pragma unroll
      for (int j = 0; j < 4; ++j) b[j] = sB[kk][tx + 16 * j];
#pragma unroll
      for (int i = 0; i < 4; ++i)
#pragma unroll
        for (int j = 0; j < 4; ++j) acc[i][j] = fmaf(a[i], b[j], acc[i][j]);
    }
    __syncthreads();
  }
#pragma unroll
  for (int i = 0; i < 4; ++i) {
    int gm = bm + ty + 16 * i;
    if (gm >= M) continue;
    float rs = rscale ? rscale[gm] : 1.0f;
#pragma unroll
    for (int j = 0; j < 4; ++j) {
      int gn = bn + tx + 16 * j;
      if (gn >= N) continue;
      float v = acc[i][j];
      if (bias) v += bias[gn];
      if (scale) v = v * scale[gn] + shift[gn];
      v *= rs;
      if (ACT == 1) v = fmaxf(v, 0.f);
      if (ACT == 2) v = sspf(v);
      if (Cin) v += Cin[(size_t)gm * ldc + gn];
      Cout[(size_t)gm * ldc + gn] = v;
    }
  }
}

// ---------------- bf16 MFMA GEMM: 128x128 block, 4 waves, BK=32 ----------------

__device__ __forceinline__ float4 ld4g(const float* __restrict__ row, int k, int K) {
  if (k + 3 < K) return *(const float4*)(row + k);
  float4 r;
  r.x = (k + 0 < K) ? row[k + 0] : 0.f;
  r.y = (k + 1 < K) ? row[k + 1] : 0.f;
  r.z = (k + 2 < K) ? row[k + 2] : 0.f;
  r.w = (k + 3 < K) ? row[k + 3] : 0.f;
  return r;
}

template <int ACT>
__global__ __launch_bounds__(256) void k_mgemm(
    const float* __restrict__ A, const float* __restrict__ A2, const short* __restrict__ Wt,
    const float* __restrict__ bias, const float* __restrict__ scale,
    const float* __restrict__ shift, const float* __restrict__ Cin, float* __restrict__ Cout,
    int M, int N, int K, int Kp, int ldc) {
  __shared__ short sA[128 * 32];
  const int tid = threadIdx.x;
  const int lane = tid & 63;
  const int w = tid >> 6;
  const int wm = w >> 1, wn = w & 1;
  const int bm = blockIdx.y * 128, bn = blockIdx.x * 128;

  f32x4 acc[4][4] = {};

  const int sr = tid >> 1;
  const int sk = (tid & 1) * 16;
  const float* Arow = A + (size_t)(bm + sr) * K;
  const float* A2row = A2 ? A2 + (size_t)(bm + sr) * K : nullptr;
  const int ssw = (sr + (sr >> 2)) & 3;
  bf16x8* sAv = (bf16x8*)sA;

  const int frow = wm * 64 + (lane & 15);
  const int fslot = lane >> 4;
  const short* Bbase = Wt + (size_t)(bn + wn * 64 + (lane & 15)) * Kp + (fslot * 8);

  for (int k0 = 0; k0 < Kp; k0 += 32) {
    __syncthreads();
    {
      short v[16];
#pragma unroll
      for (int q = 0; q < 4; ++q) {
        float4 a = ld4g(Arow, k0 + sk + 4 * q, K);
        if (A2row) {
          float4 b = ld4g(A2row, k0 + sk + 4 * q, K);
          a.x += b.x; a.y += b.y; a.z += b.z; a.w += b.w;
        }
        v[4 * q + 0] = f2b(a.x);
        v[4 * q + 1] = f2b(a.y);
        v[4 * q + 2] = f2b(a.z);
        v[4 * q + 3] = f2b(a.w);
      }
      bf16x8 p0, p1;
#pragma unroll
      for (int j = 0; j < 8; ++j) { p0[j] = v[j]; p1[j] = v[8 + j]; }
      int s0 = (sk >> 3);
      sAv[sr * 4 + ((s0 + 0) ^ ssw)] = p0;
      sAv[sr * 4 + ((s0 + 1) ^ ssw)] = p1;
    }
    __syncthreads();

    bf16x8 af[4], bfr[4];
#pragma unroll
    for (int mf = 0; mf < 4; ++mf) {
      int r = frow + mf * 16;
      af[mf] = sAv[r * 4 + (fslot ^ ((r + (r >> 2)) & 3))];
    }
#pragma unroll
    for (int nf = 0; nf < 4; ++nf)
      bfr[nf] = *(const bf16x8*)(Bbase + (size_t)nf * 16 * Kp + k0);
#pragma unroll
    for (int mf = 0; mf < 4; ++mf)
#pragma unroll
      for (int nf = 0; nf < 4; ++nf)
        acc[mf][nf] =
            __builtin_amdgcn_mfma_f32_16x16x32_bf16(af[mf], bfr[nf], acc[mf][nf], 0, 0, 0);
  }

  const int colbase = bn + wn * 64 + (lane & 15);
  const int rowbase = bm + wm * 64 + ((lane >> 4) << 2);
#pragma unroll
  for (int nf = 0; nf < 4; ++nf) {
    int col = colbase + nf * 16;
    if (col >= N) continue;
    float bi = bias ? bias[col] : 0.f;
    float sc = scale ? scale[col] : 1.f;
    float sh = shift ? shift[col] : 0.f;
#pragma unroll
    for (int mf = 0; mf < 4; ++mf) {
      f32x4 v = acc[mf][nf];
#pragma unroll
      for (int j = 0; j < 4; ++j) {
        int row = rowbase + mf * 16 + j;
        float x = v[j] + bi;
        if (scale) x = x * sc + sh;
        if (ACT == 1) x = fmaxf(x, 0.f);
        if (ACT == 2) x = sspf(x);
        if (Cin) x += Cin[(size_t)row * ldc + col];
        Cout[(size_t)row * ldc + col] = x;
      }
    }
  }
}

// ---------------- host ----------------

static inline void run_gemm(hipStream_t st, const float* A, const float* A2, const float* B,
                            const float* bias, const float* scale, const float* shift,
                            const float* rscale, const float* Cin, float* Cout, int M, int N,
                            int K, int ldc, int act) {
  dim3 grid((N + 63) / 64, (M + 63) / 64);
  if (act == 0)
    k_gemm<0><<<grid, 256, 0, st>>>(A, A2, B, bias, scale, shift, rscale, Cin, Cout, M, N, K, ldc);
  else if (act == 1)
    k_gemm<1><<<grid, 256, 0, st>>>(A, A2, B, bias, scale, shift, rscale, Cin, Cout, M, N, K, ldc);
  else
    k_gemm<2><<<grid, 256, 0, st>>>(A, A2, B, bias, scale, shift, rscale, Cin, Cout, M, N, K, ldc);
}

static inline void run_mgemm(hipStream_t st, const float* A, const float* A2, const short* Wt,
                             const float* bias, const float* scale, const float* shift,
                             const float* Cin, float* Cout, int M, int N, int K, int Kp, int ldc,
                             int act) {
  dim3 grid((N + 127) / 128, M / 128);
  if (act == 0)
    k_mgemm<0><<<grid, 256, 0, st>>>(A, A2, Wt, bias, scale, shift, Cin, Cout, M, N, K, Kp, ldc);
  else if (act == 1)
    k_mgemm<1><<<grid, 256, 0, st>>>(A, A2, Wt, bias, scale, shift, Cin, Cout, M, N, K, Kp, ldc);
  else
    k_mgemm<2><<<grid, 256, 0, st>>>(A, A2, Wt, bias, scale, shift, Cin, Cout, M, N, K, Kp, ldc);
}

extern "C" void kernel_launch(void* const* d_in, const int* in_sizes, int n_in, void* d_out,
                              int out_size, void* d_ws, size_t ws_size, hipStream_t stream) {
  const int* x2d = (const int*)d_in[0];
  const int* ei2 = (const int*)d_in[1];
  const int* ea2 = (const int*)d_in[2];
  const int* batch = (const int*)d_in[3];
  const int* z = (const int*)d_in[4];
  const float* pos = (const float*)d_in[5];
  const int* ei3 = (const int*)d_in[6];
  const float* atom_emb1 = (const float*)d_in[7];
  const float* atom_emb2 = (const float*)d_in[8];
  const float* vn_init = (const float*)d_in[9];
  const float* gin_W1 = (const float*)d_in[10];
  const float* gin_b1 = (const float*)d_in[11];
  const float* gin_W2 = (const float*)d_in[12];
  const float* gin_b2 = (const float*)d_in[13];
  const float* gin_bond1 = (const float*)d_in[14];
  const float* gin_bond2 = (const float*)d_in[15];
  const float* gin_gamma = (const float*)d_in[16];
  const float* gin_beta = (const float*)d_in[17];
  const float* vn_W1 = (const float*)d_in[18];
  const float* vn_b1 = (const float*)d_in[19];
  const float* vn_W2 = (const float*)d_in[20];
  const float* vn_b2 = (const float*)d_in[21];
  const float* sch_emb = (const float*)d_in[22];
  const float* s_mW1 = (const float*)d_in[23];
  const float* s_mb1 = (const float*)d_in[24];
  const float* s_mW2 = (const float*)d_in[25];
  const float* s_mb2 = (const float*)d_in[26];
  const float* s_lin1W = (const float*)d_in[27];
  const float* s_lin2W = (const float*)d_in[28];
  const float* s_lin2b = (const float*)d_in[29];
  const float* s_linW = (const float*)d_in[30];
  const float* s_linb = (const float*)d_in[31];
  const float* p2W = (const float*)d_in[32];
  const float* p2b = (const float*)d_in[33];
  const float* p3W = (const float*)d_in[34];
  const float* p3b = (const float*)d_in[35];
  const float* gW1 = (const float*)d_in[36];
  const float* gb1 = (const float*)d_in[37];
  const float* gW2 = (const float*)d_in[38];
  const float* gb2 = (const float*)d_in[39];
  const float* cW1 = (const float*)d_in[40];
  const float* cb1 = (const float*)d_in[41];
  const float* cW2 = (const float*)d_in[42];
  const float* cb2 = (const float*)d_in[43];

  float* ws = (float*)d_ws;
  // GIN arena [0, 19660800)
  float* h = ws;              // 16384*300
  float* agg = ws + 4915200;  // 16384*300
  float* y1 = ws + 9830400;   // 16384*600 -> ends 19660800
  // SchNet aliases onto GIN arena
  float* rbs = ws + 400000;    // 5121*50
  float* Cs = ws + 700000;     // 5121
  float* t1t = ws + 710000;    // 5121*128
  float* ftab = ws + 1400000;  // 5121*128
  float* hs = ws + 2100000;    // 16384*128
  float* x1 = ws + 4200000;    // 16384*128
  float* agg3 = ws + 6300000;  // 16384*128
  float* sx2 = ws + 8400000;   // 16384*128 -> ends 10497152
  // bf16 transposed weights
  short* W1t = (short*)(ws + 20000000);
  short* W2t = (short*)(ws + 20600000);
  short* s1t = (short*)(ws + 21200000);
  short* s2t = (short*)(ws + 21300000);
  short* s3t = (short*)(ws + 21400000);
  // CSR region (ints) at float offset 22,000,000
  int* I = (int*)(ws + 22000000);
  int* cnt2 = I + 0;              // 16384
  int* cnt3 = I + 16384;          // 16384
  int* cntg = I + 32768;          // 512
  int* cur2 = I + 33280;          // 16384
  int* cur3 = I + 49664;          // 16384 -> zero region = 66048 ints
  int* off2 = I + 70000;          // 16385
  int* off3 = I + 90000;          // 16385
  int* goff = I + 110000;         // 513
  int* s2s = I + 120000;          // 65536
  int* ec2s = I + 190000;         // 65536
  int* s3s = I + 260000;          // 393216
  int* id3s = I + 660000;         // 393216
  float* fr3s = (float*)(I + 1060000);  // 393216 -> ends 23.46M floats
  // persistent tail
  float* vn = ws + 28443136;
  float* vnsum = ws + 28596736;
  float* vnh = ws + 28750336;
  float* h2d = ws + 29057536;
  float* h3d = ws + 29211136;
  float* hcat = ws + 29276672;
  float* gh = ws + 29583872;
  float* gbuf = ws + 29649408;
  float* hf = ws + 29649920;
  float* c1 = ws + 29803520;

  // ---- weight prep ----
  k_prepw<<<(5 * 640 * 320 + 255) / 256, 256, 0, stream>>>(gin_W1, W1t, 300, 600, 320, 640, 5);
  k_prepw<<<(5 * 384 * 608 + 255) / 256, 256, 0, stream>>>(gin_W2, W2t, 600, 300, 608, 384, 5);
  k_prepw<<<(6 * 128 * 128 + 255) / 256, 256, 0, stream>>>(s_lin1W, s1t, 128, 128, 128, 128, 6);
  k_prepw<<<(6 * 128 * 128 + 255) / 256, 256, 0, stream>>>(s_lin2W, s2t, 128, 128, 128, 128, 6);
  k_prepw<<<(6 * 128 * 128 + 255) / 256, 256, 0, stream>>>(s_linW, s3t, 128, 128, 128, 128, 6);

  // ---- CSR build (once; edge structure is layer-invariant) ----
  hipMemsetAsync(I, 0, 66048 * sizeof(int), stream);
  k_hist<<<(NE2 + 255) / 256, 256, 0, stream>>>(ei2 + NE2, cnt2, NE2);
  k_hist<<<(NE3 + 255) / 256, 256, 0, stream>>>(ei3 + NE3, cnt3, NE3);
  k_hist<<<(NN + 255) / 256, 256, 0, stream>>>(batch, cntg, NN);
  k_scan<<<1, 1024, 0, stream>>>(cnt2, off2, 16384);
  k_scan<<<1, 1024, 0, stream>>>(cnt3, off3, 16384);
  k_scan<<<1, 1024, 0, stream>>>(cntg, goff, 512);
  k_scatter2<<<(NE2 + 255) / 256, 256, 0, stream>>>(ei2, ea2, off2, cur2, s2s, ec2s);
  k_scatter3<<<(NE3 + 255) / 256, 256, 0, stream>>>(ei3, pos, off3, cur3, s3s, id3s, fr3s);

  // ---- GIN ----
  k_hinit<<<(NN * DEMB + 255) / 256, 256, 0, stream>>>(x2d, atom_emb1, atom_emb2, h);
  k_vninit<<<(NG * DEMB + 255) / 256, 256, 0, stream>>>(vn_init, vn);
  for (int l = 0; l < 5; ++l) {
    k_addvn<<<(NN * DEMB + 255) / 256, 256, 0, stream>>>(h, vn, batch);
    k_gin_gather<<<NN / 4, 256, 0, stream>>>(h, off2, s2s, ec2s, gin_bond1 + l * 6 * DEMB,
                                             gin_bond2 + l * 3 * DEMB, agg);
    run_mgemm(stream, h, agg, W1t + (size_t)l * 640 * 320, gin_b1 + l * 600, nullptr, nullptr,
              nullptr, y1, NN, 600, 300, 320, 600, 1);
    run_mgemm(stream, y1, nullptr, W2t + (size_t)l * 384 * 608, gin_b2 + l * 300,
              gin_gamma + l * 300, gin_beta + l * 300, nullptr, h, NN, 300, 600, 608, 300,
              (l < 4) ? 1 : 0);
    if (l < 4) {
      k_pool<DEMB, 0><<<NG / 4, 256, 0, stream>>>(h, goff, vnsum);
      run_gemm(stream, vnsum, vn, vn_W1 + (size_t)l * 180000, vn_b1 + l * 600, nullptr, nullptr,
               nullptr, nullptr, vnh, NG, 600, 300, 600, 1);
      run_gemm(stream, vnh, nullptr, vn_W2 + (size_t)l * 180000, vn_b2 + l * 300, nullptr, nullptr,
               nullptr, nullptr, vn, NG, 300, 600, 300, 1);
    }
  }
  k_pool<DEMB, 1><<<NG / 4, 256, 0, stream>>>(h, goff, h2d);

  // ---- SchNet ----
  k_rbs<<<(TROWS * NRBF + 255) / 256, 256, 0, stream>>>(rbs, Cs);
  k_hsinit<<<(NN * DSCH + 255) / 256, 256, 0, stream>>>(z, sch_emb, hs);
  for (int l = 0; l < 6; ++l) {
    run_gemm(stream, rbs, nullptr, s_mW1 + (size_t)l * 6400, s_mb1 + l * 128, nullptr, nullptr,
             nullptr, nullptr, t1t, TROWS, 128, 50, 128, 2);
    run_gemm(stream, t1t, nullptr, s_mW2 + (size_t)l * 16384, s_mb2 + l * 128, nullptr, nullptr,
             Cs, nullptr, ftab, TROWS, 128, 128, 128, 0);
    run_mgemm(stream, hs, nullptr, s1t + (size_t)l * 16384, nullptr, nullptr, nullptr, nullptr, x1,
              NN, 128, 128, 128, 128, 0);
    k_conv_gather<<<NN / 4, 256, 0, stream>>>(ftab, x1, off3, s3s, id3s, fr3s, agg3);
    run_mgemm(stream, agg3, nullptr, s2t + (size_t)l * 16384, s_lin2b + l * 128, nullptr, nullptr,
              nullptr, sx2, NN, 128, 128, 128, 128, 2);
    run_mgemm(stream, sx2, nullptr, s3t + (size_t)l * 16384, s_linb + l * 128, nullptr, nullptr,
              hs, hs, NN, 128, 128, 128, 128, 0);
  }
  k_pool<DSCH, 1><<<NG / 4, 256, 0, stream>>>(hs, goff, h3d);

  // ---- fusion + classifier ----
  run_gemm(stream, h2d, nullptr, p2W, p2b, nullptr, nullptr, nullptr, nullptr, hcat, NG, 300, 300,
           600, 0);
  run_gemm(stream, h3d, nullptr, p3W, p3b, nullptr, nullptr, nullptr, nullptr, hcat + 300, NG, 300,
           128, 600, 0);
  run_gemm(stream, hcat, nullptr, gW1, gb1, nullptr, nullptr, nullptr, nullptr, gh, NG, 128, 600,
           128, 1);
  k_gate<<<2, 256, 0, stream>>>(gh, gW2, gb2, gbuf);
  k_hf<<<(NG * DEMB + 255) / 256, 256, 0, stream>>>(gbuf, hcat, hf);
  run_gemm(stream, hf, nullptr, cW1, cb1, nullptr, nullptr, nullptr, nullptr, c1, NG, 150, 300, 150,
           1);
  run_gemm(stream, c1, nullptr, cW2, cb2, nullptr, nullptr, nullptr, nullptr, (float*)d_out, NG, 12,
           150, 12, 0);
}

// Round 5
// 2643.135 us; speedup vs baseline: 3.7722x; 1.2339x over previous
//
#include <hip/hip_runtime.h>
#include <hip/hip_bf16.h>
#include <math.h>

#define NN 16384
#define NG 512
#define NE2 65536
#define NE3 393216
#define DEMB 300
#define DSCH 128
#define NRBF 50
#define NTAB 5120
#define TROWS 5121
#define DMAX 25.0f
#define GPG 2

typedef __attribute__((ext_vector_type(8))) short bf16x8;
typedef __attribute__((ext_vector_type(4))) float f32x4;

__device__ __forceinline__ float sspf(float x) {
  float sp = log1pf(expf(-fabsf(x))) + fmaxf(x, 0.f);
  return sp - 0.69314718055994530942f;
}

__device__ __forceinline__ short f2b(float f) {
  union { float f; unsigned u; } v;
  v.f = f;
  unsigned r = v.u + 0x7FFF + ((v.u >> 16) & 1);  // RNE
  return (short)(r >> 16);
}

// ---------------- CSR build: histogram / scan / scatter ----------------

__global__ void k_hist(const int* __restrict__ keys, int* __restrict__ cnt, int n) {
  int i = blockIdx.x * blockDim.x + threadIdx.x;
  if (i < n) atomicAdd(&cnt[keys[i]], 1);
}

__global__ __launch_bounds__(1024) void k_scan(const int* __restrict__ cnt, int* __restrict__ off,
                                               int n) {
  __shared__ int part[1024];
  int tid = threadIdx.x;
  int per = (n + 1023) / 1024;
  int base = tid * per;
  int sum = 0;
  for (int i = 0; i < per; ++i) {
    int idx = base + i;
    if (idx < n) sum += cnt[idx];
  }
  part[tid] = sum;
  __syncthreads();
  for (int d = 1; d < 1024; d <<= 1) {
    int v = (tid >= d) ? part[tid - d] : 0;
    __syncthreads();
    part[tid] += v;
    __syncthreads();
  }
  int run = (tid == 0) ? 0 : part[tid - 1];
  for (int i = 0; i < per; ++i) {
    int idx = base + i;
    if (idx < n) {
      off[idx] = run;
      run += cnt[idx];
    }
  }
  if (tid == 0) off[n] = part[1023];
}

__global__ void k_scatter2(const int* __restrict__ ei2, const int* __restrict__ ea2,
                           const int* __restrict__ off2, int* __restrict__ cur2,
                           int* __restrict__ s2s, int* __restrict__ ec2s) {
  int e = blockIdx.x * blockDim.x + threadIdx.x;
  if (e >= NE2) return;
  int d = ei2[NE2 + e];
  int p = atomicAdd(&cur2[d], 1);
  int j = off2[d] + p;
  s2s[j] = ei2[e];
  ec2s[j] = ea2[2 * e] * 4 + ea2[2 * e + 1];
}

__global__ void k_scatter3(const int* __restrict__ ei3, const float* __restrict__ pos,
                           const int* __restrict__ off3, int* __restrict__ cur3,
                           int* __restrict__ s3s, int* __restrict__ id3s,
                           float* __restrict__ fr3s) {
  int e = blockIdx.x * blockDim.x + threadIdx.x;
  if (e >= NE3) return;
  int s = ei3[e], d = ei3[NE3 + e];
  float dx = pos[3 * d] - pos[3 * s];
  float dy = pos[3 * d + 1] - pos[3 * s + 1];
  float dz = pos[3 * d + 2] - pos[3 * s + 2];
  float dist = sqrtf(dx * dx + dy * dy + dz * dz);
  float u = fminf(dist * ((float)NTAB / DMAX), (float)NTAB - 0.001f);
  int idx = (int)u;
  int p = atomicAdd(&cur3[d], 1);
  int j = off3[d] + p;
  s3s[j] = s;
  id3s[j] = idx;
  fr3s[j] = u - (float)idx;
}

// ---------------- small elementwise kernels ----------------

__global__ void k_hinit(const int* __restrict__ x2d, const float* __restrict__ e1,
                        const float* __restrict__ e2, float* __restrict__ h) {
  int i = blockIdx.x * blockDim.x + threadIdx.x;
  if (i >= NN * DEMB) return;
  int n = i / DEMB, c = i - n * DEMB;
  h[i] = e1[x2d[2 * n] * DEMB + c] + e2[x2d[2 * n + 1] * DEMB + c];
}

__global__ void k_vninit(const float* __restrict__ vni, float* __restrict__ vn) {
  int i = blockIdx.x * blockDim.x + threadIdx.x;
  if (i >= NG * DEMB) return;
  vn[i] = vni[i % DEMB];
}

__global__ void k_addvn(float* __restrict__ h, const float* __restrict__ vn,
                        const int* __restrict__ batch) {
  int i = blockIdx.x * blockDim.x + threadIdx.x;
  if (i >= NN * DEMB) return;
  int n = i / DEMB, c = i - n * DEMB;
  h[i] += vn[batch[n] * DEMB + c];
}

__global__ void k_rbs(float* __restrict__ rbs, float* __restrict__ Cs) {
  int i = blockIdx.x * blockDim.x + threadIdx.x;
  if (i >= TROWS * NRBF) return;
  int j = i / NRBF, k = i - j * NRBF;
  float dj = (float)j * (DMAX / (float)NTAB);
  const float step = 10.0f / 49.0f;
  const float coeff = -0.5f / (step * step);
  float t = dj - (float)k * step;
  rbs[i] = expf(coeff * t * t);
  if (k == 0) Cs[j] = 0.5f * (cosf(dj * (3.14159265358979323846f / 10.0f)) + 1.0f);
}

__global__ void k_hsinit(const int* __restrict__ z, const float* __restrict__ emb,
                         float* __restrict__ hs) {
  int i = blockIdx.x * blockDim.x + threadIdx.x;
  if (i >= NN * DSCH) return;
  hs[i] = emb[z[i >> 7] * DSCH + (i & 127)];
}

__global__ void k_gate(const float* __restrict__ gh, const float* __restrict__ gW2,
                       const float* __restrict__ gb2, float* __restrict__ g) {
  int m = blockIdx.x * blockDim.x + threadIdx.x;
  if (m >= NG) return;
  float acc = gb2[0];
  for (int k = 0; k < 128; ++k) acc += gh[m * 128 + k] * gW2[k];
  g[m] = 1.0f / (1.0f + expf(-acc));
}

__global__ void k_hf(const float* __restrict__ g, const float* __restrict__ hcat,
                     float* __restrict__ hf) {
  int i = blockIdx.x * blockDim.x + threadIdx.x;
  if (i >= NG * DEMB) return;
  int m = i / DEMB, c = i - m * DEMB;
  float gg = g[m];
  hf[i] = gg * hcat[m * 600 + c] + (1.0f - gg) * hcat[m * 600 + 300 + c];
}

// ---------------- fused virtual-node MLP (per-graph GEMV, W L2-resident) ----------------
// vn = relu(relu((vnsum+vn)@W1+b1)@W2+b2); one block handles GPG graphs.
__global__ __launch_bounds__(256) void k_vnmlp(const float* __restrict__ vnsum,
                                               float* __restrict__ vn,
                                               const float* __restrict__ W1,
                                               const float* __restrict__ b1,
                                               const float* __restrict__ W2,
                                               const float* __restrict__ b2) {
  __shared__ float sx[GPG][DEMB];
  __shared__ float sh[GPG][2 * DEMB];
  int tid = threadIdx.x;
  int g0 = blockIdx.x * GPG;
  for (int i = tid; i < GPG * DEMB; i += 256) {
    int g = i / DEMB, c = i - g * DEMB;
    sx[g][c] = vnsum[(size_t)(g0 + g) * DEMB + c] + vn[(size_t)(g0 + g) * DEMB + c];
  }
  __syncthreads();
  // stage 1: h = relu(x @ W1 + b1); W1 [300][600] row-major, coalesced across threads
  {
    float acc0[GPG] = {}, acc1[GPG] = {}, acc2[GPG] = {};
    for (int k = 0; k < DEMB; ++k) {
      float w0 = W1[k * 600 + tid];
      float w1 = W1[k * 600 + tid + 256];
      float w2 = (tid < 88) ? W1[k * 600 + tid + 512] : 0.f;
#pragma unroll
      for (int g = 0; g < GPG; ++g) {
        float xv = sx[g][k];
        acc0[g] = fmaf(w0, xv, acc0[g]);
        acc1[g] = fmaf(w1, xv, acc1[g]);
        acc2[g] = fmaf(w2, xv, acc2[g]);
      }
    }
#pragma unroll
    for (int g = 0; g < GPG; ++g) {
      sh[g][tid] = fmaxf(acc0[g] + b1[tid], 0.f);
      sh[g][tid + 256] = fmaxf(acc1[g] + b1[tid + 256], 0.f);
      if (tid < 88) sh[g][tid + 512] = fmaxf(acc2[g] + b1[tid + 512], 0.f);
    }
  }
  __syncthreads();
  // stage 2: vn = relu(h @ W2 + b2); W2 [600][300]
  {
    float acc0[GPG] = {}, acc1[GPG] = {};
    for (int k = 0; k < 2 * DEMB; ++k) {
      float w0 = (tid < 300) ? W2[k * 300 + tid] : 0.f;
      float w1 = (tid < 44) ? W2[k * 300 + tid + 256] : 0.f;
#pragma unroll
      for (int g = 0; g < GPG; ++g) {
        float hv = sh[g][k];
        acc0[g] = fmaf(w0, hv, acc0[g]);
        acc1[g] = fmaf(w1, hv, acc1[g]);
      }
    }
#pragma unroll
    for (int g = 0; g < GPG; ++g) {
      if (tid < 300) vn[(size_t)(g0 + g) * DEMB + tid] = fmaxf(acc0[g] + b2[tid], 0.f);
      if (tid < 44)
        vn[(size_t)(g0 + g) * DEMB + tid + 256] = fmaxf(acc1[g] + b2[tid + 256], 0.f);
    }
  }
}

// ---------------- gather aggregations (one wave per destination) ----------------

__global__ __launch_bounds__(256) void k_gin_gather(
    const float* __restrict__ h, const int* __restrict__ off2, const int* __restrict__ s2s,
    const int* __restrict__ ec2s, const float* __restrict__ bond1, const float* __restrict__ bond2,
    float* __restrict__ agg) {
  __shared__ float sb[9 * DEMB];
  int tid = threadIdx.x;
  for (int i = tid; i < 6 * DEMB; i += 256) sb[i] = bond1[i];
  for (int i = tid; i < 3 * DEMB; i += 256) sb[6 * DEMB + i] = bond2[i];
  __syncthreads();
  int d = blockIdx.x * 4 + (tid >> 6);
  int lane = tid & 63;
  int j0 = off2[d], j1 = off2[d + 1];
  float acc[5] = {};
  for (int j = j0; j < j1; ++j) {
    int s = s2s[j], ec = ec2s[j];
    const float* hr = h + (size_t)s * DEMB;
    const float* b1 = sb + (ec >> 2) * DEMB;
    const float* b2 = sb + 6 * DEMB + (ec & 3) * DEMB;
#pragma unroll
    for (int q = 0; q < 5; ++q) {
      int col = lane + 64 * q;
      if (col < DEMB) acc[q] += fmaxf(hr[col] + b1[col] + b2[col], 0.f);
    }
  }
  float* outr = agg + (size_t)d * DEMB;
#pragma unroll
  for (int q = 0; q < 5; ++q) {
    int col = lane + 64 * q;
    if (col < DEMB) outr[col] = acc[q];
  }
}

__global__ __launch_bounds__(256) void k_conv_gather(
    const float* __restrict__ ftab, const float* __restrict__ x1, const int* __restrict__ off3,
    const int* __restrict__ s3s, const int* __restrict__ id3s, const float* __restrict__ fr3s,
    float* __restrict__ agg3) {
  int tid = threadIdx.x;
  int d = blockIdx.x * 4 + (tid >> 6);
  int lane = tid & 63;
  int j0 = off3[d], j1 = off3[d + 1];
  float a0 = 0.f, a1 = 0.f;
  for (int j = j0; j < j1; ++j) {
    int s = s3s[j], idx = id3s[j];
    float fr = fr3s[j];
    float2 t0 = ((const float2*)(ftab + (size_t)idx * 128))[lane];
    float2 t1 = ((const float2*)(ftab + (size_t)(idx + 1) * 128))[lane];
    float2 xv = ((const float2*)(x1 + (size_t)s * 128))[lane];
    a0 += (t0.x + fr * (t1.x - t0.x)) * xv.x;
    a1 += (t0.y + fr * (t1.y - t0.y)) * xv.y;
  }
  ((float2*)(agg3 + (size_t)d * 128))[lane] = make_float2(a0, a1);
}

template <int W, int MEAN>
__global__ __launch_bounds__(256) void k_pool(const float* __restrict__ x,
                                              const int* __restrict__ goff,
                                              float* __restrict__ out) {
  int g = blockIdx.x * 4 + (threadIdx.x >> 6);
  int lane = threadIdx.x & 63;
  if (g >= NG) return;
  int r0 = goff[g], r1 = goff[g + 1];
  constexpr int NQ = (W + 63) / 64;
  float acc[NQ] = {};
  for (int r = r0; r < r1; ++r) {
    const float* row = x + (size_t)r * W;
#pragma unroll
    for (int q = 0; q < NQ; ++q) {
      int col = lane + 64 * q;
      if ((W % 64 == 0) || col < W) acc[q] += row[col];
    }
  }
  float s = MEAN ? (1.0f / fmaxf((float)(r1 - r0), 1.0f)) : 1.0f;
#pragma unroll
  for (int q = 0; q < NQ; ++q) {
    int col = lane + 64 * q;
    if ((W % 64 == 0) || col < W) out[(size_t)g * W + col] = acc[q] * s;
  }
}

// ---------------- weight prep ----------------
__global__ void k_prepw(const float* __restrict__ W, short* __restrict__ Wt, int K, int N, int Kp,
                        int Np, int L) {
  int i = blockIdx.x * blockDim.x + threadIdx.x;
  int per = Np * Kp;
  if (i >= L * per) return;
  int l = i / per, r = i - l * per;
  int n = r / Kp, k = r - n * Kp;
  float v = (n < N && k < K) ? W[(size_t)l * K * N + (size_t)k * N + n] : 0.f;
  Wt[i] = f2b(v);
}

// ---------------- generic fp32 GEMM (64x64 tile) — small matrices only ----------------
template <int ACT>  // 0 none, 1 relu, 2 ssp
__global__ __launch_bounds__(256) void k_gemm(
    const float* __restrict__ A, const float* __restrict__ A2, const float* __restrict__ B,
    const float* __restrict__ bias, const float* __restrict__ scale,
    const float* __restrict__ shift, const float* __restrict__ rscale,
    const float* __restrict__ Cin, float* __restrict__ Cout, int M, int N, int K, int ldc) {
  __shared__ float sA[16][65];
  __shared__ float sB[16][64];
  int tid = threadIdx.x;
  int tx = tid & 15, ty = tid >> 4;
  int bm = blockIdx.y * 64, bn = blockIdx.x * 64;
  float acc[4][4] = {};
  for (int k0 = 0; k0 < K; k0 += 16) {
#pragma unroll
    for (int t = 0; t < 4; ++t) {
      int i = tid + t * 256;
      int m = i >> 4, kk = i & 15;
      int gm = bm + m, gk = k0 + kk;
      float v = 0.f;
      if (gm < M && gk < K) {
        v = A[(size_t)gm * K + gk];
        if (A2) v += A2[(size_t)gm * K + gk];
      }
      sA[kk][m] = v;
    }
#pragma unroll
    for (int t = 0; t < 4; ++t) {
      int i = tid + t * 256;
      int kk = i >> 6, n = i & 63;
      int gk = k0 + kk, gn = bn + n;
      sB[kk][n] = (gk < K && gn < N) ? B[(size_t)gk * N + gn] : 0.f;
    }
    __syncthreads();
#pragma unroll
    for (int kk = 0; kk < 16; ++kk) {
      float a[4], b[4];
#pragma unroll
      for (int i = 0; i < 4; ++i) a[i] = sA[kk][ty + 16 * i];
#pragma unroll
      for (int j = 0; j < 4; ++j) b[j] = sB[kk][tx + 16 * j];
#pragma unroll
      for (int i = 0; i < 4; ++i)
#pragma unroll
        for (int j = 0; j < 4; ++j) acc[i][j] = fmaf(a[i], b[j], acc[i][j]);
    }
    __syncthreads();
  }
#pragma unroll
  for (int i = 0; i < 4; ++i) {
    int gm = bm + ty + 16 * i;
    if (gm >= M) continue;
    float rs = rscale ? rscale[gm] : 1.0f;
#pragma unroll
    for (int j = 0; j < 4; ++j) {
      int gn = bn + tx + 16 * j;
      if (gn >= N) continue;
      float v = acc[i][j];
      if (bias) v += bias[gn];
      if (scale) v = v * scale[gn] + shift[gn];
      v *= rs;
      if (ACT == 1) v = fmaxf(v, 0.f);
      if (ACT == 2) v = sspf(v);
      if (Cin) v += Cin[(size_t)gm * ldc + gn];
      Cout[(size_t)gm * ldc + gn] = v;
    }
  }
}

// ---------------- z-batched fp32 GEMM (64x64 tile): C_z = act(A_z @ B_z + bias_z) [*rscale] ----
template <int ACT>
__global__ __launch_bounds__(256) void k_gemmz(
    const float* __restrict__ A, const float* __restrict__ B, const float* __restrict__ bias,
    const float* __restrict__ rscale, float* __restrict__ Cout, int M, int N, int K, int ldc,
    long strideA, long strideB, long strideBias, long strideC) {
  A += (size_t)blockIdx.z * strideA;
  B += (size_t)blockIdx.z * strideB;
  bias += (size_t)blockIdx.z * strideBias;
  Cout += (size_t)blockIdx.z * strideC;
  __shared__ float sA[16][65];
  __shared__ float sB[16][64];
  int tid = threadIdx.x;
  int tx = tid & 15, ty = tid >> 4;
  int bm = blockIdx.y * 64, bn = blockIdx.x * 64;
  float acc[4][4] = {};
  for (int k0 = 0; k0 < K; k0 += 16) {
#pragma unroll
    for (int t = 0; t < 4; ++t) {
      int i = tid + t * 256;
      int m = i >> 4, kk = i & 15;
      int gm = bm + m, gk = k0 + kk;
      sA[kk][m] = (gm < M && gk < K) ? A[(size_t)gm * K + gk] : 0.f;
    }
#pragma unroll
    for (int t = 0; t < 4; ++t) {
      int i = tid + t * 256;
      int kk = i >> 6, n = i & 63;
      int gk = k0 + kk, gn = bn + n;
      sB[kk][n] = (gk < K && gn < N) ? B[(size_t)gk * N + gn] : 0.f;
    }
    __syncthreads();
#pragma unroll
    for (int kk = 0; kk < 16; ++kk) {
      float a[4], b[4];
#pragma unroll
      for (int i = 0; i < 4; ++i) a[i] = sA[kk][ty + 16 * i];
#pragma unroll
      for (int j = 0; j < 4; ++j) b[j] = sB[kk][tx + 16 * j];
#pragma unroll
      for (int i = 0; i < 4; ++i)
#pragma unroll
        for (int j = 0; j < 4; ++j) acc[i][j] = fmaf(a[i], b[j], acc[i][j]);
    }
    __syncthreads();
  }
#pragma unroll
  for (int i = 0; i < 4; ++i) {
    int gm = bm + ty + 16 * i;
    if (gm >= M) continue;
    float rs = rscale ? rscale[gm] : 1.0f;
#pragma unroll
    for (int j = 0; j < 4; ++j) {
      int gn = bn + tx + 16 * j;
      if (gn >= N) continue;
      float v = acc[i][j] + bias[gn];
      if (ACT == 1) v = fmaxf(v, 0.f);
      if (ACT == 2) v = sspf(v);
      Cout[(size_t)gm * ldc + gn] = v * rs;
    }
  }
}

// ---------------- bf16 MFMA GEMM: 128x128 block, 4 waves, BK=32 ----------------

__device__ __forceinline__ float4 ld4g(const float* __restrict__ row, int k, int K) {
  if (k + 3 < K) return *(const float4*)(row + k);
  float4 r;
  r.x = (k + 0 < K) ? row[k + 0] : 0.f;
  r.y = (k + 1 < K) ? row[k + 1] : 0.f;
  r.z = (k + 2 < K) ? row[k + 2] : 0.f;
  r.w = (k + 3 < K) ? row[k + 3] : 0.f;
  return r;
}

template <int ACT>
__global__ __launch_bounds__(256) void k_mgemm(
    const float* __restrict__ A, const float* __restrict__ A2, const short* __restrict__ Wt,
    const float* __restrict__ bias, const float* __restrict__ scale,
    const float* __restrict__ shift, const float* __restrict__ Cin, float* __restrict__ Cout,
    int M, int N, int K, int Kp, int ldc) {
  __shared__ short sA[128 * 32];
  const int tid = threadIdx.x;
  const int lane = tid & 63;
  const int w = tid >> 6;
  const int wm = w >> 1, wn = w & 1;
  const int bm = blockIdx.y * 128, bn = blockIdx.x * 128;

  f32x4 acc[4][4] = {};

  const int sr = tid >> 1;
  const int sk = (tid & 1) * 16;
  const float* Arow = A + (size_t)(bm + sr) * K;
  const float* A2row = A2 ? A2 + (size_t)(bm + sr) * K : nullptr;
  const int ssw = (sr + (sr >> 2)) & 3;
  bf16x8* sAv = (bf16x8*)sA;

  const int frow = wm * 64 + (lane & 15);
  const int fslot = lane >> 4;
  const short* Bbase = Wt + (size_t)(bn + wn * 64 + (lane & 15)) * Kp + (fslot * 8);

  for (int k0 = 0; k0 < Kp; k0 += 32) {
    __syncthreads();
    {
      short v[16];
#pragma unroll
      for (int q = 0; q < 4; ++q) {
        float4 a = ld4g(Arow, k0 + sk + 4 * q, K);
        if (A2row) {
          float4 b = ld4g(A2row, k0 + sk + 4 * q, K);
          a.x += b.x; a.y += b.y; a.z += b.z; a.w += b.w;
        }
        v[4 * q + 0] = f2b(a.x);
        v[4 * q + 1] = f2b(a.y);
        v[4 * q + 2] = f2b(a.z);
        v[4 * q + 3] = f2b(a.w);
      }
      bf16x8 p0, p1;
#pragma unroll
      for (int j = 0; j < 8; ++j) { p0[j] = v[j]; p1[j] = v[8 + j]; }
      int s0 = (sk >> 3);
      sAv[sr * 4 + ((s0 + 0) ^ ssw)] = p0;
      sAv[sr * 4 + ((s0 + 1) ^ ssw)] = p1;
    }
    __syncthreads();

    bf16x8 af[4], bfr[4];
#pragma unroll
    for (int mf = 0; mf < 4; ++mf) {
      int r = frow + mf * 16;
      af[mf] = sAv[r * 4 + (fslot ^ ((r + (r >> 2)) & 3))];
    }
#pragma unroll
    for (int nf = 0; nf < 4; ++nf)
      bfr[nf] = *(const bf16x8*)(Bbase + (size_t)nf * 16 * Kp + k0);
#pragma unroll
    for (int mf = 0; mf < 4; ++mf)
#pragma unroll
      for (int nf = 0; nf < 4; ++nf)
        acc[mf][nf] =
            __builtin_amdgcn_mfma_f32_16x16x32_bf16(af[mf], bfr[nf], acc[mf][nf], 0, 0, 0);
  }

  const int colbase = bn + wn * 64 + (lane & 15);
  const int rowbase = bm + wm * 64 + ((lane >> 4) << 2);
#pragma unroll
  for (int nf = 0; nf < 4; ++nf) {
    int col = colbase + nf * 16;
    if (col >= N) continue;
    float bi = bias ? bias[col] : 0.f;
    float sc = scale ? scale[col] : 1.f;
    float sh = shift ? shift[col] : 0.f;
#pragma unroll
    for (int mf = 0; mf < 4; ++mf) {
      f32x4 v = acc[mf][nf];
#pragma unroll
      for (int j = 0; j < 4; ++j) {
        int row = rowbase + mf * 16 + j;
        float x = v[j] + bi;
        if (scale) x = x * sc + sh;
        if (ACT == 1) x = fmaxf(x, 0.f);
        if (ACT == 2) x = sspf(x);
        if (Cin) x += Cin[(size_t)row * ldc + col];
        Cout[(size_t)row * ldc + col] = x;
      }
    }
  }
}

// ---------------- host ----------------

static inline void run_gemm(hipStream_t st, const float* A, const float* A2, const float* B,
                            const float* bias, const float* scale, const float* shift,
                            const float* rscale, const float* Cin, float* Cout, int M, int N,
                            int K, int ldc, int act) {
  dim3 grid((N + 63) / 64, (M + 63) / 64);
  if (act == 0)
    k_gemm<0><<<grid, 256, 0, st>>>(A, A2, B, bias, scale, shift, rscale, Cin, Cout, M, N, K, ldc);
  else if (act == 1)
    k_gemm<1><<<grid, 256, 0, st>>>(A, A2, B, bias, scale, shift, rscale, Cin, Cout, M, N, K, ldc);
  else
    k_gemm<2><<<grid, 256, 0, st>>>(A, A2, B, bias, scale, shift, rscale, Cin, Cout, M, N, K, ldc);
}

static inline void run_mgemm(hipStream_t st, const float* A, const float* A2, const short* Wt,
                             const float* bias, const float* scale, const float* shift,
                             const float* Cin, float* Cout, int M, int N, int K, int Kp, int ldc,
                             int act) {
  dim3 grid((N + 127) / 128, M / 128);
  if (act == 0)
    k_mgemm<0><<<grid, 256, 0, st>>>(A, A2, Wt, bias, scale, shift, Cin, Cout, M, N, K, Kp, ldc);
  else if (act == 1)
    k_mgemm<1><<<grid, 256, 0, st>>>(A, A2, Wt, bias, scale, shift, Cin, Cout, M, N, K, Kp, ldc);
  else
    k_mgemm<2><<<grid, 256, 0, st>>>(A, A2, Wt, bias, scale, shift, Cin, Cout, M, N, K, Kp, ldc);
}

extern "C" void kernel_launch(void* const* d_in, const int* in_sizes, int n_in, void* d_out,
                              int out_size, void* d_ws, size_t ws_size, hipStream_t stream) {
  const int* x2d = (const int*)d_in[0];
  const int* ei2 = (const int*)d_in[1];
  const int* ea2 = (const int*)d_in[2];
  const int* batch = (const int*)d_in[3];
  const int* z = (const int*)d_in[4];
  const float* pos = (const float*)d_in[5];
  const int* ei3 = (const int*)d_in[6];
  const float* atom_emb1 = (const float*)d_in[7];
  const float* atom_emb2 = (const float*)d_in[8];
  const float* vn_init = (const float*)d_in[9];
  const float* gin_W1 = (const float*)d_in[10];
  const float* gin_b1 = (const float*)d_in[11];
  const float* gin_W2 = (const float*)d_in[12];
  const float* gin_b2 = (const float*)d_in[13];
  const float* gin_bond1 = (const float*)d_in[14];
  const float* gin_bond2 = (const float*)d_in[15];
  const float* gin_gamma = (const float*)d_in[16];
  const float* gin_beta = (const float*)d_in[17];
  const float* vn_W1 = (const float*)d_in[18];
  const float* vn_b1 = (const float*)d_in[19];
  const float* vn_W2 = (const float*)d_in[20];
  const float* vn_b2 = (const float*)d_in[21];
  const float* sch_emb = (const float*)d_in[22];
  const float* s_mW1 = (const float*)d_in[23];
  const float* s_mb1 = (const float*)d_in[24];
  const float* s_mW2 = (const float*)d_in[25];
  const float* s_mb2 = (const float*)d_in[26];
  const float* s_lin1W = (const float*)d_in[27];
  const float* s_lin2W = (const float*)d_in[28];
  const float* s_lin2b = (const float*)d_in[29];
  const float* s_linW = (const float*)d_in[30];
  const float* s_linb = (const float*)d_in[31];
  const float* p2W = (const float*)d_in[32];
  const float* p2b = (const float*)d_in[33];
  const float* p3W = (const float*)d_in[34];
  const float* p3b = (const float*)d_in[35];
  const float* gW1 = (const float*)d_in[36];
  const float* gb1 = (const float*)d_in[37];
  const float* gW2 = (const float*)d_in[38];
  const float* gb2 = (const float*)d_in[39];
  const float* cW1 = (const float*)d_in[40];
  const float* cb1 = (const float*)d_in[41];
  const float* cW2 = (const float*)d_in[42];
  const float* cb2 = (const float*)d_in[43];

  float* ws = (float*)d_ws;
  // GIN arena [0, 19660800)
  float* h = ws;              // 16384*300
  float* agg = ws + 4915200;  // 16384*300
  float* y1 = ws + 9830400;   // 16384*600 -> ends 19660800
  // SchNet aliases onto GIN arena (GIN fully done before SchNet writes these)
  float* rbs = ws + 400000;       // 5121*50
  float* Cs = ws + 700000;        // 5121
  float* t1all = ws + 800000;     // 6*5121*128 = 3932928 -> ends 4732928
  float* ftab_all = ws + 4800000; // 3932928 -> ends 8732928
  float* hs = ws + 8800000;       // 16384*128 -> ends 10897152
  float* x1 = ws + 11000000;      // -> 13097152
  float* agg3 = ws + 13200000;    // -> 15297152
  float* sx2 = ws + 15400000;     // -> 17497152 < 19660800
  // bf16 transposed weights
  short* W1t = (short*)(ws + 20000000);
  short* W2t = (short*)(ws + 20600000);
  short* s1t = (short*)(ws + 21200000);
  short* s2t = (short*)(ws + 21300000);
  short* s3t = (short*)(ws + 21400000);
  // CSR region
  int* I = (int*)(ws + 22000000);
  int* cnt2 = I + 0;
  int* cnt3 = I + 16384;
  int* cntg = I + 32768;
  int* cur2 = I + 33280;
  int* cur3 = I + 49664;  // zero region = 66048 ints
  int* off2 = I + 70000;
  int* off3 = I + 90000;
  int* goff = I + 110000;
  int* s2s = I + 120000;
  int* ec2s = I + 190000;
  int* s3s = I + 260000;
  int* id3s = I + 660000;
  float* fr3s = (float*)(I + 1060000);
  // persistent tail
  float* vn = ws + 28443136;
  float* vnsum = ws + 28596736;
  float* h2d = ws + 29057536;
  float* h3d = ws + 29211136;
  float* hcat = ws + 29276672;
  float* gh = ws + 29583872;
  float* gbuf = ws + 29649408;
  float* hf = ws + 29649920;
  float* c1 = ws + 29803520;

  // ---- weight prep ----
  k_prepw<<<(5 * 640 * 320 + 255) / 256, 256, 0, stream>>>(gin_W1, W1t, 300, 600, 320, 640, 5);
  k_prepw<<<(5 * 384 * 608 + 255) / 256, 256, 0, stream>>>(gin_W2, W2t, 600, 300, 608, 384, 5);
  k_prepw<<<(6 * 128 * 128 + 255) / 256, 256, 0, stream>>>(s_lin1W, s1t, 128, 128, 128, 128, 6);
  k_prepw<<<(6 * 128 * 128 + 255) / 256, 256, 0, stream>>>(s_lin2W, s2t, 128, 128, 128, 128, 6);
  k_prepw<<<(6 * 128 * 128 + 255) / 256, 256, 0, stream>>>(s_linW, s3t, 128, 128, 128, 128, 6);

  // ---- CSR build ----
  hipMemsetAsync(I, 0, 66048 * sizeof(int), stream);
  k_hist<<<(NE2 + 255) / 256, 256, 0, stream>>>(ei2 + NE2, cnt2, NE2);
  k_hist<<<(NE3 + 255) / 256, 256, 0, stream>>>(ei3 + NE3, cnt3, NE3);
  k_hist<<<(NN + 255) / 256, 256, 0, stream>>>(batch, cntg, NN);
  k_scan<<<1, 1024, 0, stream>>>(cnt2, off2, 16384);
  k_scan<<<1, 1024, 0, stream>>>(cnt3, off3, 16384);
  k_scan<<<1, 1024, 0, stream>>>(cntg, goff, 512);
  k_scatter2<<<(NE2 + 255) / 256, 256, 0, stream>>>(ei2, ea2, off2, cur2, s2s, ec2s);
  k_scatter3<<<(NE3 + 255) / 256, 256, 0, stream>>>(ei3, pos, off3, cur3, s3s, id3s, fr3s);

  // ---- GIN ----
  k_hinit<<<(NN * DEMB + 255) / 256, 256, 0, stream>>>(x2d, atom_emb1, atom_emb2, h);
  k_vninit<<<(NG * DEMB + 255) / 256, 256, 0, stream>>>(vn_init, vn);
  for (int l = 0; l < 5; ++l) {
    k_addvn<<<(NN * DEMB + 255) / 256, 256, 0, stream>>>(h, vn, batch);
    k_gin_gather<<<NN / 4, 256, 0, stream>>>(h, off2, s2s, ec2s, gin_bond1 + l * 6 * DEMB,
                                             gin_bond2 + l * 3 * DEMB, agg);
    run_mgemm(stream, h, agg, W1t + (size_t)l * 640 * 320, gin_b1 + l * 600, nullptr, nullptr,
              nullptr, y1, NN, 600, 300, 320, 600, 1);
    run_mgemm(stream, y1, nullptr, W2t + (size_t)l * 384 * 608, gin_b2 + l * 300,
              gin_gamma + l * 300, gin_beta + l * 300, nullptr, h, NN, 300, 600, 608, 300,
              (l < 4) ? 1 : 0);
    if (l < 4) {
      k_pool<DEMB, 0><<<NG / 4, 256, 0, stream>>>(h, goff, vnsum);
      k_vnmlp<<<NG / GPG, 256, 0, stream>>>(vnsum, vn, vn_W1 + (size_t)l * 180000,
                                            vn_b1 + l * 600, vn_W2 + (size_t)l * 180000,
                                            vn_b2 + l * 300);
    }
  }
  k_pool<DEMB, 1><<<NG / 4, 256, 0, stream>>>(h, goff, h2d);

  // ---- SchNet ----
  k_rbs<<<(TROWS * NRBF + 255) / 256, 256, 0, stream>>>(rbs, Cs);
  k_hsinit<<<(NN * DSCH + 255) / 256, 256, 0, stream>>>(z, sch_emb, hs);
  // batched filter-table build across all 6 layers
  {
    dim3 ga(2, (TROWS + 63) / 64, 6);
    k_gemmz<2><<<ga, 256, 0, stream>>>(rbs, s_mW1, s_mb1, nullptr, t1all, TROWS, 128, 50, 128,
                                       0L, 50L * 128, 128L, (long)TROWS * 128);
    k_gemmz<0><<<ga, 256, 0, stream>>>(t1all, s_mW2, s_mb2, Cs, ftab_all, TROWS, 128, 128, 128,
                                       (long)TROWS * 128, 128L * 128, 128L, (long)TROWS * 128);
  }
  for (int l = 0; l < 6; ++l) {
    run_mgemm(stream, hs, nullptr, s1t + (size_t)l * 16384, nullptr, nullptr, nullptr, nullptr, x1,
              NN, 128, 128, 128, 128, 0);
    k_conv_gather<<<NN / 4, 256, 0, stream>>>(ftab_all + (size_t)l * TROWS * 128, x1, off3, s3s,
                                              id3s, fr3s, agg3);
    run_mgemm(stream, agg3, nullptr, s2t + (size_t)l * 16384, s_lin2b + l * 128, nullptr, nullptr,
              nullptr, sx2, NN, 128, 128, 128, 128, 2);
    run_mgemm(stream, sx2, nullptr, s3t + (size_t)l * 16384, s_linb + l * 128, nullptr, nullptr,
              hs, hs, NN, 128, 128, 128, 128, 0);
  }
  k_pool<DSCH, 1><<<NG / 4, 256, 0, stream>>>(hs, goff, h3d);

  // ---- fusion + classifier ----
  run_gemm(stream, h2d, nullptr, p2W, p2b, nullptr, nullptr, nullptr, nullptr, hcat, NG, 300, 300,
           600, 0);
  run_gemm(stream, h3d, nullptr, p3W, p3b, nullptr, nullptr, nullptr, nullptr, hcat + 300, NG, 300,
           128, 600, 0);
  run_gemm(stream, hcat, nullptr, gW1, gb1, nullptr, nullptr, nullptr, nullptr, gh, NG, 128, 600,
           128, 1);
  k_gate<<<2, 256, 0, stream>>>(gh, gW2, gb2, gbuf);
  k_hf<<<(NG * DEMB + 255) / 256, 256, 0, stream>>>(gbuf, hcat, hf);
  run_gemm(stream, hf, nullptr, cW1, cb1, nullptr, nullptr, nullptr, nullptr, c1, NG, 150, 300, 150,
           1);
  run_gemm(stream, c1, nullptr, cW2, cb2, nullptr, nullptr, nullptr, nullptr, (float*)d_out, NG, 12,
           150, 12, 0);
}

// Round 6
// 2479.455 us; speedup vs baseline: 4.0212x; 1.0660x over previous
//
#include <hip/hip_runtime.h>
#include <hip/hip_bf16.h>
#include <math.h>

#define NN 16384
#define NG 512
#define NE2 65536
#define NE3 393216
#define DEMB 300
#define DSCH 128
#define NRBF 50
#define NTAB 5120
#define TROWS 5121
#define DMAX 25.0f
#define GPG 2

typedef __attribute__((ext_vector_type(8))) short bf16x8;
typedef __attribute__((ext_vector_type(4))) float f32x4;

__device__ __forceinline__ float sspf(float x) {
  float sp = log1pf(expf(-fabsf(x))) + fmaxf(x, 0.f);
  return sp - 0.69314718055994530942f;
}

__device__ __forceinline__ short f2b(float f) {
  union { float f; unsigned u; } v;
  v.f = f;
  unsigned r = v.u + 0x7FFF + ((v.u >> 16) & 1);  // RNE
  return (short)(r >> 16);
}

// ---------------- CSR build: histogram / scan / scatter ----------------

__global__ void k_hist(const int* __restrict__ keys, int* __restrict__ cnt, int n) {
  int i = blockIdx.x * blockDim.x + threadIdx.x;
  if (i < n) atomicAdd(&cnt[keys[i]], 1);
}

__global__ __launch_bounds__(1024) void k_scan(const int* __restrict__ cnt, int* __restrict__ off,
                                               int n) {
  __shared__ int part[1024];
  int tid = threadIdx.x;
  int per = (n + 1023) / 1024;
  int base = tid * per;
  int sum = 0;
  for (int i = 0; i < per; ++i) {
    int idx = base + i;
    if (idx < n) sum += cnt[idx];
  }
  part[tid] = sum;
  __syncthreads();
  for (int d = 1; d < 1024; d <<= 1) {
    int v = (tid >= d) ? part[tid - d] : 0;
    __syncthreads();
    part[tid] += v;
    __syncthreads();
  }
  int run = (tid == 0) ? 0 : part[tid - 1];
  for (int i = 0; i < per; ++i) {
    int idx = base + i;
    if (idx < n) {
      off[idx] = run;
      run += cnt[idx];
    }
  }
  if (tid == 0) off[n] = part[1023];
}

__global__ void k_scatter2(const int* __restrict__ ei2, const int* __restrict__ ea2,
                           const int* __restrict__ off2, int* __restrict__ cur2,
                           int* __restrict__ s2s, int* __restrict__ ec2s) {
  int e = blockIdx.x * blockDim.x + threadIdx.x;
  if (e >= NE2) return;
  int d = ei2[NE2 + e];
  int p = atomicAdd(&cur2[d], 1);
  int j = off2[d] + p;
  s2s[j] = ei2[e];
  ec2s[j] = ea2[2 * e] * 4 + ea2[2 * e + 1];
}

__global__ void k_scatter3(const int* __restrict__ ei3, const float* __restrict__ pos,
                           const int* __restrict__ off3, int* __restrict__ cur3,
                           int* __restrict__ s3s, int* __restrict__ id3s,
                           float* __restrict__ fr3s) {
  int e = blockIdx.x * blockDim.x + threadIdx.x;
  if (e >= NE3) return;
  int s = ei3[e], d = ei3[NE3 + e];
  float dx = pos[3 * d] - pos[3 * s];
  float dy = pos[3 * d + 1] - pos[3 * s + 1];
  float dz = pos[3 * d + 2] - pos[3 * s + 2];
  float dist = sqrtf(dx * dx + dy * dy + dz * dz);
  float u = fminf(dist * ((float)NTAB / DMAX), (float)NTAB - 0.001f);
  int idx = (int)u;
  int p = atomicAdd(&cur3[d], 1);
  int j = off3[d] + p;
  s3s[j] = s;
  id3s[j] = idx;
  fr3s[j] = u - (float)idx;
}

// ---------------- small elementwise kernels ----------------

__global__ void k_hinit(const int* __restrict__ x2d, const float* __restrict__ e1,
                        const float* __restrict__ e2, float* __restrict__ h) {
  int i = blockIdx.x * blockDim.x + threadIdx.x;
  if (i >= NN * DEMB) return;
  int n = i / DEMB, c = i - n * DEMB;
  h[i] = e1[x2d[2 * n] * DEMB + c] + e2[x2d[2 * n + 1] * DEMB + c];
}

__global__ void k_vninit(const float* __restrict__ vni, float* __restrict__ vn) {
  int i = blockIdx.x * blockDim.x + threadIdx.x;
  if (i >= NG * DEMB) return;
  vn[i] = vni[i % DEMB];
}

__global__ void k_addvn(float* __restrict__ h, const float* __restrict__ vn,
                        const int* __restrict__ batch) {
  int i = blockIdx.x * blockDim.x + threadIdx.x;
  if (i >= NN * DEMB) return;
  int n = i / DEMB, c = i - n * DEMB;
  h[i] += vn[batch[n] * DEMB + c];
}

__global__ void k_rbs(float* __restrict__ rbs, float* __restrict__ Cs) {
  int i = blockIdx.x * blockDim.x + threadIdx.x;
  if (i >= TROWS * NRBF) return;
  int j = i / NRBF, k = i - j * NRBF;
  float dj = (float)j * (DMAX / (float)NTAB);
  const float step = 10.0f / 49.0f;
  const float coeff = -0.5f / (step * step);
  float t = dj - (float)k * step;
  rbs[i] = expf(coeff * t * t);
  if (k == 0) Cs[j] = 0.5f * (cosf(dj * (3.14159265358979323846f / 10.0f)) + 1.0f);
}

__global__ void k_hsinit(const int* __restrict__ z, const float* __restrict__ emb,
                         float* __restrict__ hs) {
  int i = blockIdx.x * blockDim.x + threadIdx.x;
  if (i >= NN * DSCH) return;
  hs[i] = emb[z[i >> 7] * DSCH + (i & 127)];
}

// ---------------- fused virtual-node MLP ----------------
__global__ __launch_bounds__(256) void k_vnmlp(const float* __restrict__ vnsum,
                                               float* __restrict__ vn,
                                               const float* __restrict__ W1,
                                               const float* __restrict__ b1,
                                               const float* __restrict__ W2,
                                               const float* __restrict__ b2) {
  __shared__ float sx[GPG][DEMB];
  __shared__ float sh[GPG][2 * DEMB];
  int tid = threadIdx.x;
  int g0 = blockIdx.x * GPG;
  for (int i = tid; i < GPG * DEMB; i += 256) {
    int g = i / DEMB, c = i - g * DEMB;
    sx[g][c] = vnsum[(size_t)(g0 + g) * DEMB + c] + vn[(size_t)(g0 + g) * DEMB + c];
  }
  __syncthreads();
  {
    float acc0[GPG] = {}, acc1[GPG] = {}, acc2[GPG] = {};
    for (int k = 0; k < DEMB; ++k) {
      float w0 = W1[k * 600 + tid];
      float w1 = W1[k * 600 + tid + 256];
      float w2 = (tid < 88) ? W1[k * 600 + tid + 512] : 0.f;
#pragma unroll
      for (int g = 0; g < GPG; ++g) {
        float xv = sx[g][k];
        acc0[g] = fmaf(w0, xv, acc0[g]);
        acc1[g] = fmaf(w1, xv, acc1[g]);
        acc2[g] = fmaf(w2, xv, acc2[g]);
      }
    }
#pragma unroll
    for (int g = 0; g < GPG; ++g) {
      sh[g][tid] = fmaxf(acc0[g] + b1[tid], 0.f);
      sh[g][tid + 256] = fmaxf(acc1[g] + b1[tid + 256], 0.f);
      if (tid < 88) sh[g][tid + 512] = fmaxf(acc2[g] + b1[tid + 512], 0.f);
    }
  }
  __syncthreads();
  {
    float acc0[GPG] = {}, acc1[GPG] = {};
    for (int k = 0; k < 2 * DEMB; ++k) {
      float w0 = (tid < 300) ? W2[k * 300 + tid] : 0.f;
      float w1 = (tid < 44) ? W2[k * 300 + tid + 256] : 0.f;
#pragma unroll
      for (int g = 0; g < GPG; ++g) {
        float hv = sh[g][k];
        acc0[g] = fmaf(w0, hv, acc0[g]);
        acc1[g] = fmaf(w1, hv, acc1[g]);
      }
    }
#pragma unroll
    for (int g = 0; g < GPG; ++g) {
      if (tid < 300) vn[(size_t)(g0 + g) * DEMB + tid] = fmaxf(acc0[g] + b2[tid], 0.f);
      if (tid < 44)
        vn[(size_t)(g0 + g) * DEMB + tid + 256] = fmaxf(acc1[g] + b2[tid + 256], 0.f);
    }
  }
}

// ---------------- fused head: pool(hs) + projections + gate + classifier ----------------
// one block per graph
__global__ __launch_bounds__(256) void k_head(
    const float* __restrict__ h2d, const float* __restrict__ hs, const int* __restrict__ goff,
    const float* __restrict__ p2W, const float* __restrict__ p2b, const float* __restrict__ p3W,
    const float* __restrict__ p3b, const float* __restrict__ gW1, const float* __restrict__ gb1,
    const float* __restrict__ gW2, const float* __restrict__ gb2, const float* __restrict__ cW1,
    const float* __restrict__ cb1, const float* __restrict__ cW2, const float* __restrict__ cb2,
    float* __restrict__ out) {
  __shared__ float sx[DEMB];   // h2d row, later hf
  __shared__ float sy[DSCH];   // pooled hs row
  __shared__ float h2p[DEMB];
  __shared__ float h3p[DEMB];
  __shared__ float ghl[DSCH];
  __shared__ float c1l[152];
  __shared__ float gshare;
  int g = blockIdx.x;
  int tid = threadIdx.x;
  int r0 = goff[g], r1 = goff[g + 1];
  float inv = 1.0f / fmaxf((float)(r1 - r0), 1.0f);
  // load h2d row; pool hs
  {
    sx[tid] = h2d[(size_t)g * DEMB + tid];
    if (tid < 44) sx[tid + 256] = h2d[(size_t)g * DEMB + tid + 256];
    if (tid < DSCH) {
      float b0 = 0.f;
      for (int r = r0; r < r1; ++r) b0 += hs[(size_t)r * DSCH + tid];
      sy[tid] = b0 * inv;
    }
  }
  __syncthreads();
  // h2p = sx @ p2W + p2b ; h3p = sy @ p3W + p3b  (both [*,300])
  {
    float a0 = 0.f, a1 = 0.f, b0 = 0.f, b1 = 0.f;
    for (int k = 0; k < DEMB; ++k) {
      float xv = sx[k];
      a0 = fmaf(xv, p2W[k * 300 + tid], a0);
      if (tid < 44) a1 = fmaf(xv, p2W[k * 300 + tid + 256], a1);
    }
    for (int k = 0; k < DSCH; ++k) {
      float yv = sy[k];
      b0 = fmaf(yv, p3W[k * 300 + tid], b0);
      if (tid < 44) b1 = fmaf(yv, p3W[k * 300 + tid + 256], b1);
    }
    h2p[tid] = a0 + p2b[tid];
    h3p[tid] = b0 + p3b[tid];
    if (tid < 44) {
      h2p[tid + 256] = a1 + p2b[tid + 256];
      h3p[tid + 256] = b1 + p3b[tid + 256];
    }
  }
  __syncthreads();
  // gate hidden: ghl = relu(concat(h2p,h3p) @ gW1 + gb1)
  if (tid < DSCH) {
    float a = gb1[tid];
    for (int k = 0; k < DEMB; ++k) a = fmaf(h2p[k], gW1[k * 128 + tid], a);
    for (int k = 0; k < DEMB; ++k) a = fmaf(h3p[k], gW1[(DEMB + k) * 128 + tid], a);
    ghl[tid] = fmaxf(a, 0.f);
  }
  __syncthreads();
  if (tid == 0) {
    float a = gb2[0];
    for (int k = 0; k < DSCH; ++k) a += ghl[k] * gW2[k];
    gshare = 1.0f / (1.0f + expf(-a));
  }
  __syncthreads();
  // hf = g*h2p + (1-g)*h3p -> sx
  {
    float gg = gshare;
    sx[tid] = gg * h2p[tid] + (1.0f - gg) * h3p[tid];
    if (tid < 44) sx[tid + 256] = gg * h2p[tid + 256] + (1.0f - gg) * h3p[tid + 256];
  }
  __syncthreads();
  // c1 = relu(hf @ cW1 + cb1)  [150]
  if (tid < 150) {
    float a = cb1[tid];
    for (int k = 0; k < DEMB; ++k) a = fmaf(sx[k], cW1[k * 150 + tid], a);
    c1l[tid] = fmaxf(a, 0.f);
  }
  __syncthreads();
  // out = c1 @ cW2 + cb2  [12]
  if (tid < 12) {
    float a = cb2[tid];
    for (int k = 0; k < 150; ++k) a = fmaf(c1l[k], cW2[k * 12 + tid], a);
    out[(size_t)g * 12 + tid] = a;
  }
}

// ---------------- gather aggregations (one wave per destination) ----------------

__global__ __launch_bounds__(256) void k_gin_gather(
    const float* __restrict__ h, const int* __restrict__ off2, const int* __restrict__ s2s,
    const int* __restrict__ ec2s, const float* __restrict__ bond1, const float* __restrict__ bond2,
    float* __restrict__ agg) {
  __shared__ float sb[9 * DEMB];
  int tid = threadIdx.x;
  for (int i = tid; i < 6 * DEMB; i += 256) sb[i] = bond1[i];
  for (int i = tid; i < 3 * DEMB; i += 256) sb[6 * DEMB + i] = bond2[i];
  __syncthreads();
  int d = blockIdx.x * 4 + (tid >> 6);
  int lane = tid & 63;
  int j0 = off2[d], j1 = off2[d + 1];
  float acc[5] = {};
  for (int j = j0; j < j1; ++j) {
    int s = s2s[j], ec = ec2s[j];
    const float* hr = h + (size_t)s * DEMB;
    const float* b1 = sb + (ec >> 2) * DEMB;
    const float* b2 = sb + 6 * DEMB + (ec & 3) * DEMB;
#pragma unroll
    for (int q = 0; q < 5; ++q) {
      int col = lane + 64 * q;
      if (col < DEMB) acc[q] += fmaxf(hr[col] + b1[col] + b2[col], 0.f);
    }
  }
  float* outr = agg + (size_t)d * DEMB;
#pragma unroll
  for (int q = 0; q < 5; ++q) {
    int col = lane + 64 * q;
    if (col < DEMB) outr[col] = acc[q];
  }
}

__global__ __launch_bounds__(256) void k_conv_gather(
    const float* __restrict__ ftab, const float* __restrict__ x1, const int* __restrict__ off3,
    const int* __restrict__ s3s, const int* __restrict__ id3s, const float* __restrict__ fr3s,
    float* __restrict__ agg3) {
  int tid = threadIdx.x;
  int d = blockIdx.x * 4 + (tid >> 6);
  int lane = tid & 63;
  int j0 = off3[d], j1 = off3[d + 1];
  float a0 = 0.f, a1 = 0.f;
  for (int j = j0; j < j1; ++j) {
    int s = s3s[j], idx = id3s[j];
    float fr = fr3s[j];
    float2 t0 = ((const float2*)(ftab + (size_t)idx * 128))[lane];
    float2 t1 = ((const float2*)(ftab + (size_t)(idx + 1) * 128))[lane];
    float2 xv = ((const float2*)(x1 + (size_t)s * 128))[lane];
    a0 += (t0.x + fr * (t1.x - t0.x)) * xv.x;
    a1 += (t0.y + fr * (t1.y - t0.y)) * xv.y;
  }
  ((float2*)(agg3 + (size_t)d * 128))[lane] = make_float2(a0, a1);
}

template <int W, int MEAN>
__global__ __launch_bounds__(256) void k_pool(const float* __restrict__ x,
                                              const int* __restrict__ goff,
                                              float* __restrict__ out) {
  int g = blockIdx.x * 4 + (threadIdx.x >> 6);
  int lane = threadIdx.x & 63;
  if (g >= NG) return;
  int r0 = goff[g], r1 = goff[g + 1];
  constexpr int NQ = (W + 63) / 64;
  float acc[NQ] = {};
  for (int r = r0; r < r1; ++r) {
    const float* row = x + (size_t)r * W;
#pragma unroll
    for (int q = 0; q < NQ; ++q) {
      int col = lane + 64 * q;
      if ((W % 64 == 0) || col < W) acc[q] += row[col];
    }
  }
  float s = MEAN ? (1.0f / fmaxf((float)(r1 - r0), 1.0f)) : 1.0f;
#pragma unroll
  for (int q = 0; q < NQ; ++q) {
    int col = lane + 64 * q;
    if ((W % 64 == 0) || col < W) out[(size_t)g * W + col] = acc[q] * s;
  }
}

// ---------------- weight prep ----------------
__global__ void k_prepw(const float* __restrict__ W, short* __restrict__ Wt, int K, int N, int Kp,
                        int Np, int L) {
  int i = blockIdx.x * blockDim.x + threadIdx.x;
  int per = Np * Kp;
  if (i >= L * per) return;
  int l = i / per, r = i - l * per;
  int n = r / Kp, k = r - n * Kp;
  float v = (n < N && k < K) ? W[(size_t)l * K * N + (size_t)k * N + n] : 0.f;
  Wt[i] = f2b(v);
}

// ---------------- z-batched fp32 GEMM (64x64 tile) ----------------
template <int ACT>
__global__ __launch_bounds__(256) void k_gemmz(
    const float* __restrict__ A, const float* __restrict__ B, const float* __restrict__ bias,
    const float* __restrict__ rscale, float* __restrict__ Cout, int M, int N, int K, int ldc,
    long strideA, long strideB, long strideBias, long strideC) {
  A += (size_t)blockIdx.z * strideA;
  B += (size_t)blockIdx.z * strideB;
  bias += (size_t)blockIdx.z * strideBias;
  Cout += (size_t)blockIdx.z * strideC;
  __shared__ float sA[16][65];
  __shared__ float sB[16][64];
  int tid = threadIdx.x;
  int tx = tid & 15, ty = tid >> 4;
  int bm = blockIdx.y * 64, bn = blockIdx.x * 64;
  float acc[4][4] = {};
  for (int k0 = 0; k0 < K; k0 += 16) {
#pragma unroll
    for (int t = 0; t < 4; ++t) {
      int i = tid + t * 256;
      int m = i >> 4, kk = i & 15;
      int gm = bm + m, gk = k0 + kk;
      sA[kk][m] = (gm < M && gk < K) ? A[(size_t)gm * K + gk] : 0.f;
    }
#pragma unroll
    for (int t = 0; t < 4; ++t) {
      int i = tid + t * 256;
      int kk = i >> 6, n = i & 63;
      int gk = k0 + kk, gn = bn + n;
      sB[kk][n] = (gk < K && gn < N) ? B[(size_t)gk * N + gn] : 0.f;
    }
    __syncthreads();
#pragma unroll
    for (int kk = 0; kk < 16; ++kk) {
      float a[4], b[4];
#pragma unroll
      for (int i = 0; i < 4; ++i) a[i] = sA[kk][ty + 16 * i];
#pragma unroll
      for (int j = 0; j < 4; ++j) b[j] = sB[kk][tx + 16 * j];
#pragma unroll
      for (int i = 0; i < 4; ++i)
#pragma unroll
        for (int j = 0; j < 4; ++j) acc[i][j] = fmaf(a[i], b[j], acc[i][j]);
    }
    __syncthreads();
  }
#pragma unroll
  for (int i = 0; i < 4; ++i) {
    int gm = bm + ty + 16 * i;
    if (gm >= M) continue;
    float rs = rscale ? rscale[gm] : 1.0f;
#pragma unroll
    for (int j = 0; j < 4; ++j) {
      int gn = bn + tx + 16 * j;
      if (gn >= N) continue;
      float v = acc[i][j] + bias[gn];
      if (ACT == 1) v = fmaxf(v, 0.f);
      if (ACT == 2) v = sspf(v);
      Cout[(size_t)gm * ldc + gn] = v * rs;
    }
  }
}

// ---------------- bf16 MFMA GEMM: 128x128 block, 4 waves, BK=32 ----------------

__device__ __forceinline__ float4 ld4g(const float* __restrict__ row, int k, int K) {
  if (k + 3 < K) return *(const float4*)(row + k);
  float4 r;
  r.x = (k + 0 < K) ? row[k + 0] : 0.f;
  r.y = (k + 1 < K) ? row[k + 1] : 0.f;
  r.z = (k + 2 < K) ? row[k + 2] : 0.f;
  r.w = (k + 3 < K) ? row[k + 3] : 0.f;
  return r;
}

template <int ACT>
__global__ __launch_bounds__(256) void k_mgemm(
    const float* __restrict__ A, const float* __restrict__ A2, const short* __restrict__ Wt,
    const float* __restrict__ bias, const float* __restrict__ scale,
    const float* __restrict__ shift, const float* __restrict__ Cin, float* __restrict__ Cout,
    int M, int N, int K, int Kp, int ldc) {
  __shared__ short sA[128 * 32];
  const int tid = threadIdx.x;
  const int lane = tid & 63;
  const int w = tid >> 6;
  const int wm = w >> 1, wn = w & 1;
  const int bm = blockIdx.y * 128, bn = blockIdx.x * 128;

  f32x4 acc[4][4] = {};

  const int sr = tid >> 1;
  const int sk = (tid & 1) * 16;
  const float* Arow = A + (size_t)(bm + sr) * K;
  const float* A2row = A2 ? A2 + (size_t)(bm + sr) * K : nullptr;
  const int ssw = (sr + (sr >> 2)) & 3;
  bf16x8* sAv = (bf16x8*)sA;

  const int frow = wm * 64 + (lane & 15);
  const int fslot = lane >> 4;
  const short* Bbase = Wt + (size_t)(bn + wn * 64 + (lane & 15)) * Kp + (fslot * 8);

  for (int k0 = 0; k0 < Kp; k0 += 32) {
    __syncthreads();
    {
      short v[16];
#pragma unroll
      for (int q = 0; q < 4; ++q) {
        float4 a = ld4g(Arow, k0 + sk + 4 * q, K);
        if (A2row) {
          float4 b = ld4g(A2row, k0 + sk + 4 * q, K);
          a.x += b.x; a.y += b.y; a.z += b.z; a.w += b.w;
        }
        v[4 * q + 0] = f2b(a.x);
        v[4 * q + 1] = f2b(a.y);
        v[4 * q + 2] = f2b(a.z);
        v[4 * q + 3] = f2b(a.w);
      }
      bf16x8 p0, p1;
#pragma unroll
      for (int j = 0; j < 8; ++j) { p0[j] = v[j]; p1[j] = v[8 + j]; }
      int s0 = (sk >> 3);
      sAv[sr * 4 + ((s0 + 0) ^ ssw)] = p0;
      sAv[sr * 4 + ((s0 + 1) ^ ssw)] = p1;
    }
    __syncthreads();

    bf16x8 af[4], bfr[4];
#pragma unroll
    for (int mf = 0; mf < 4; ++mf) {
      int r = frow + mf * 16;
      af[mf] = sAv[r * 4 + (fslot ^ ((r + (r >> 2)) & 3))];
    }
#pragma unroll
    for (int nf = 0; nf < 4; ++nf)
      bfr[nf] = *(const bf16x8*)(Bbase + (size_t)nf * 16 * Kp + k0);
#pragma unroll
    for (int mf = 0; mf < 4; ++mf)
#pragma unroll
      for (int nf = 0; nf < 4; ++nf)
        acc[mf][nf] =
            __builtin_amdgcn_mfma_f32_16x16x32_bf16(af[mf], bfr[nf], acc[mf][nf], 0, 0, 0);
  }

  const int colbase = bn + wn * 64 + (lane & 15);
  const int rowbase = bm + wm * 64 + ((lane >> 4) << 2);
#pragma unroll
  for (int nf = 0; nf < 4; ++nf) {
    int col = colbase + nf * 16;
    if (col >= N) continue;
    float bi = bias ? bias[col] : 0.f;
    float sc = scale ? scale[col] : 1.f;
    float sh = shift ? shift[col] : 0.f;
#pragma unroll
    for (int mf = 0; mf < 4; ++mf) {
      f32x4 v = acc[mf][nf];
#pragma unroll
      for (int j = 0; j < 4; ++j) {
        int row = rowbase + mf * 16 + j;
        float x = v[j] + bi;
        if (scale) x = x * sc + sh;
        if (ACT == 1) x = fmaxf(x, 0.f);
        if (ACT == 2) x = sspf(x);
        if (Cin) x += Cin[(size_t)row * ldc + col];
        Cout[(size_t)row * ldc + col] = x;
      }
    }
  }
}

// ---------------- host ----------------

static inline void run_mgemm(hipStream_t st, const float* A, const float* A2, const short* Wt,
                             const float* bias, const float* scale, const float* shift,
                             const float* Cin, float* Cout, int M, int N, int K, int Kp, int ldc,
                             int act) {
  dim3 grid((N + 127) / 128, M / 128);
  if (act == 0)
    k_mgemm<0><<<grid, 256, 0, st>>>(A, A2, Wt, bias, scale, shift, Cin, Cout, M, N, K, Kp, ldc);
  else if (act == 1)
    k_mgemm<1><<<grid, 256, 0, st>>>(A, A2, Wt, bias, scale, shift, Cin, Cout, M, N, K, Kp, ldc);
  else
    k_mgemm<2><<<grid, 256, 0, st>>>(A, A2, Wt, bias, scale, shift, Cin, Cout, M, N, K, Kp, ldc);
}

extern "C" void kernel_launch(void* const* d_in, const int* in_sizes, int n_in, void* d_out,
                              int out_size, void* d_ws, size_t ws_size, hipStream_t stream) {
  const int* x2d = (const int*)d_in[0];
  const int* ei2 = (const int*)d_in[1];
  const int* ea2 = (const int*)d_in[2];
  const int* batch = (const int*)d_in[3];
  const int* z = (const int*)d_in[4];
  const float* pos = (const float*)d_in[5];
  const int* ei3 = (const int*)d_in[6];
  const float* atom_emb1 = (const float*)d_in[7];
  const float* atom_emb2 = (const float*)d_in[8];
  const float* vn_init = (const float*)d_in[9];
  const float* gin_W1 = (const float*)d_in[10];
  const float* gin_b1 = (const float*)d_in[11];
  const float* gin_W2 = (const float*)d_in[12];
  const float* gin_b2 = (const float*)d_in[13];
  const float* gin_bond1 = (const float*)d_in[14];
  const float* gin_bond2 = (const float*)d_in[15];
  const float* gin_gamma = (const float*)d_in[16];
  const float* gin_beta = (const float*)d_in[17];
  const float* vn_W1 = (const float*)d_in[18];
  const float* vn_b1 = (const float*)d_in[19];
  const float* vn_W2 = (const float*)d_in[20];
  const float* vn_b2 = (const float*)d_in[21];
  const float* sch_emb = (const float*)d_in[22];
  const float* s_mW1 = (const float*)d_in[23];
  const float* s_mb1 = (const float*)d_in[24];
  const float* s_mW2 = (const float*)d_in[25];
  const float* s_mb2 = (const float*)d_in[26];
  const float* s_lin1W = (const float*)d_in[27];
  const float* s_lin2W = (const float*)d_in[28];
  const float* s_lin2b = (const float*)d_in[29];
  const float* s_linW = (const float*)d_in[30];
  const float* s_linb = (const float*)d_in[31];
  const float* p2W = (const float*)d_in[32];
  const float* p2b = (const float*)d_in[33];
  const float* p3W = (const float*)d_in[34];
  const float* p3b = (const float*)d_in[35];
  const float* gW1 = (const float*)d_in[36];
  const float* gb1 = (const float*)d_in[37];
  const float* gW2 = (const float*)d_in[38];
  const float* gb2 = (const float*)d_in[39];
  const float* cW1 = (const float*)d_in[40];
  const float* cb1 = (const float*)d_in[41];
  const float* cW2 = (const float*)d_in[42];
  const float* cb2 = (const float*)d_in[43];

  float* ws = (float*)d_ws;
  // GIN arena [0, 19660800)
  float* h = ws;              // 16384*300
  float* agg = ws + 4915200;  // 16384*300
  float* y1 = ws + 9830400;   // 16384*600 -> ends 19660800
  // SchNet aliases onto GIN arena (GIN fully done & h2d extracted before these are written)
  float* rbs = ws + 400000;
  float* Cs = ws + 700000;
  float* t1all = ws + 800000;      // 6*5121*128
  float* ftab_all = ws + 4800000;  // 6*5121*128
  float* hs = ws + 8800000;        // 16384*128
  float* x1 = ws + 11000000;
  float* agg3 = ws + 13200000;
  float* sx2 = ws + 15400000;
  // bf16 transposed weights
  short* W1t = (short*)(ws + 20000000);
  short* W2t = (short*)(ws + 20600000);
  short* s1t = (short*)(ws + 21200000);
  short* s2t = (short*)(ws + 21300000);
  short* s3t = (short*)(ws + 21400000);
  // CSR region
  int* I = (int*)(ws + 22000000);
  int* cnt2 = I + 0;
  int* cnt3 = I + 16384;
  int* cntg = I + 32768;
  int* cur2 = I + 33280;
  int* cur3 = I + 49664;  // zero region = 66048 ints
  int* off2 = I + 70000;
  int* off3 = I + 90000;
  int* goff = I + 110000;
  int* s2s = I + 120000;
  int* ec2s = I + 190000;
  int* s3s = I + 260000;
  int* id3s = I + 660000;
  float* fr3s = (float*)(I + 1060000);
  // persistent tail
  float* vn = ws + 28443136;
  float* vnsum = ws + 28596736;
  float* h2d = ws + 29057536;

  // ---- weight prep ----
  k_prepw<<<(5 * 640 * 320 + 255) / 256, 256, 0, stream>>>(gin_W1, W1t, 300, 600, 320, 640, 5);
  k_prepw<<<(5 * 384 * 608 + 255) / 256, 256, 0, stream>>>(gin_W2, W2t, 600, 300, 608, 384, 5);
  k_prepw<<<(6 * 128 * 128 + 255) / 256, 256, 0, stream>>>(s_lin1W, s1t, 128, 128, 128, 128, 6);
  k_prepw<<<(6 * 128 * 128 + 255) / 256, 256, 0, stream>>>(s_lin2W, s2t, 128, 128, 128, 128, 6);
  k_prepw<<<(6 * 128 * 128 + 255) / 256, 256, 0, stream>>>(s_linW, s3t, 128, 128, 128, 128, 6);

  // ---- CSR build ----
  hipMemsetAsync(I, 0, 66048 * sizeof(int), stream);
  k_hist<<<(NE2 + 255) / 256, 256, 0, stream>>>(ei2 + NE2, cnt2, NE2);
  k_hist<<<(NE3 + 255) / 256, 256, 0, stream>>>(ei3 + NE3, cnt3, NE3);
  k_hist<<<(NN + 255) / 256, 256, 0, stream>>>(batch, cntg, NN);
  k_scan<<<1, 1024, 0, stream>>>(cnt2, off2, 16384);
  k_scan<<<1, 1024, 0, stream>>>(cnt3, off3, 16384);
  k_scan<<<1, 1024, 0, stream>>>(cntg, goff, 512);
  k_scatter2<<<(NE2 + 255) / 256, 256, 0, stream>>>(ei2, ea2, off2, cur2, s2s, ec2s);
  k_scatter3<<<(NE3 + 255) / 256, 256, 0, stream>>>(ei3, pos, off3, cur3, s3s, id3s, fr3s);

  // ---- GIN ----
  k_hinit<<<(NN * DEMB + 255) / 256, 256, 0, stream>>>(x2d, atom_emb1, atom_emb2, h);
  k_vninit<<<(NG * DEMB + 255) / 256, 256, 0, stream>>>(vn_init, vn);
  for (int l = 0; l < 5; ++l) {
    k_addvn<<<(NN * DEMB + 255) / 256, 256, 0, stream>>>(h, vn, batch);
    k_gin_gather<<<NN / 4, 256, 0, stream>>>(h, off2, s2s, ec2s, gin_bond1 + l * 6 * DEMB,
                                             gin_bond2 + l * 3 * DEMB, agg);
    run_mgemm(stream, h, agg, W1t + (size_t)l * 640 * 320, gin_b1 + l * 600, nullptr, nullptr,
              nullptr, y1, NN, 600, 300, 320, 600, 1);
    run_mgemm(stream, y1, nullptr, W2t + (size_t)l * 384 * 608, gin_b2 + l * 300,
              gin_gamma + l * 300, gin_beta + l * 300, nullptr, h, NN, 300, 600, 608, 300,
              (l < 4) ? 1 : 0);
    if (l < 4) {
      k_pool<DEMB, 0><<<NG / 4, 256, 0, stream>>>(h, goff, vnsum);
      k_vnmlp<<<NG / GPG, 256, 0, stream>>>(vnsum, vn, vn_W1 + (size_t)l * 180000,
                                            vn_b1 + l * 600, vn_W2 + (size_t)l * 180000,
                                            vn_b2 + l * 300);
    }
  }
  k_pool<DEMB, 1><<<NG / 4, 256, 0, stream>>>(h, goff, h2d);  // must run before SchNet clobbers h

  // ---- SchNet ----
  k_rbs<<<(TROWS * NRBF + 255) / 256, 256, 0, stream>>>(rbs, Cs);
  k_hsinit<<<(NN * DSCH + 255) / 256, 256, 0, stream>>>(z, sch_emb, hs);
  {
    dim3 ga(2, (TROWS + 63) / 64, 6);
    k_gemmz<2><<<ga, 256, 0, stream>>>(rbs, s_mW1, s_mb1, nullptr, t1all, TROWS, 128, 50, 128,
                                       0L, 50L * 128, 128L, (long)TROWS * 128);
    k_gemmz<0><<<ga, 256, 0, stream>>>(t1all, s_mW2, s_mb2, Cs, ftab_all, TROWS, 128, 128, 128,
                                       (long)TROWS * 128, 128L * 128, 128L, (long)TROWS * 128);
  }
  for (int l = 0; l < 6; ++l) {
    run_mgemm(stream, hs, nullptr, s1t + (size_t)l * 16384, nullptr, nullptr, nullptr, nullptr, x1,
              NN, 128, 128, 128, 128, 0);
    k_conv_gather<<<NN / 4, 256, 0, stream>>>(ftab_all + (size_t)l * TROWS * 128, x1, off3, s3s,
                                              id3s, fr3s, agg3);
    run_mgemm(stream, agg3, nullptr, s2t + (size_t)l * 16384, s_lin2b + l * 128, nullptr, nullptr,
              nullptr, sx2, NN, 128, 128, 128, 128, 2);
    run_mgemm(stream, sx2, nullptr, s3t + (size_t)l * 16384, s_linb + l * 128, nullptr, nullptr,
              hs, hs, NN, 128, 128, 128, 128, 0);
  }

  // ---- fused head ----
  k_head<<<NG, 256, 0, stream>>>(h2d, hs, goff, p2W, p2b, p3W, p3b, gW1, gb1, gW2, gb2, cW1, cb1,
                                 cW2, cb2, (float*)d_out);
}

// Round 7
// 1980.068 us; speedup vs baseline: 5.0354x; 1.2522x over previous
//
#include <hip/hip_runtime.h>
#include <hip/hip_bf16.h>
#include <math.h>

#define NN 16384
#define NG 512
#define NE2 65536
#define NE3 393216
#define DEMB 300
#define DSCH 128
#define NRBF 50
#define NTAB 5120
#define TROWS 5121
#define DMAX 25.0f
#define GPG 2

typedef __attribute__((ext_vector_type(8))) short bf16x8;
typedef __attribute__((ext_vector_type(4))) float f32x4;

__device__ __forceinline__ float sspf(float x) {
  float sp = log1pf(expf(-fabsf(x))) + fmaxf(x, 0.f);
  return sp - 0.69314718055994530942f;
}

__device__ __forceinline__ short f2b(float f) {
  union { float f; unsigned u; } v;
  v.f = f;
  unsigned r = v.u + 0x7FFF + ((v.u >> 16) & 1);  // RNE
  return (short)(r >> 16);
}

// ---------------- CSR build ----------------

__global__ void k_hist(const int* __restrict__ keys, int* __restrict__ cnt, int n) {
  int i = blockIdx.x * blockDim.x + threadIdx.x;
  if (i < n) atomicAdd(&cnt[keys[i]], 1);
}

__global__ __launch_bounds__(1024) void k_scan(const int* __restrict__ cnt, int* __restrict__ off,
                                               int n) {
  __shared__ int part[1024];
  int tid = threadIdx.x;
  int per = (n + 1023) / 1024;
  int base = tid * per;
  int sum = 0;
  for (int i = 0; i < per; ++i) {
    int idx = base + i;
    if (idx < n) sum += cnt[idx];
  }
  part[tid] = sum;
  __syncthreads();
  for (int d = 1; d < 1024; d <<= 1) {
    int v = (tid >= d) ? part[tid - d] : 0;
    __syncthreads();
    part[tid] += v;
    __syncthreads();
  }
  int run = (tid == 0) ? 0 : part[tid - 1];
  for (int i = 0; i < per; ++i) {
    int idx = base + i;
    if (idx < n) {
      off[idx] = run;
      run += cnt[idx];
    }
  }
  if (tid == 0) off[n] = part[1023];
}

__global__ void k_scatter2(const int* __restrict__ ei2, const int* __restrict__ ea2,
                           const int* __restrict__ off2, int* __restrict__ cur2,
                           int* __restrict__ s2s, int* __restrict__ ec2s) {
  int e = blockIdx.x * blockDim.x + threadIdx.x;
  if (e >= NE2) return;
  int d = ei2[NE2 + e];
  int p = atomicAdd(&cur2[d], 1);
  int j = off2[d] + p;
  s2s[j] = ei2[e];
  ec2s[j] = ea2[2 * e] * 4 + ea2[2 * e + 1];
}

__global__ void k_scatter3(const int* __restrict__ ei3, const float* __restrict__ pos,
                           const int* __restrict__ off3, int* __restrict__ cur3,
                           int* __restrict__ s3s, int* __restrict__ id3s,
                           float* __restrict__ fr3s) {
  int e = blockIdx.x * blockDim.x + threadIdx.x;
  if (e >= NE3) return;
  int s = ei3[e], d = ei3[NE3 + e];
  float dx = pos[3 * d] - pos[3 * s];
  float dy = pos[3 * d + 1] - pos[3 * s + 1];
  float dz = pos[3 * d + 2] - pos[3 * s + 2];
  float dist = sqrtf(dx * dx + dy * dy + dz * dz);
  float u = fminf(dist * ((float)NTAB / DMAX), (float)NTAB - 0.001f);
  int idx = (int)u;
  int p = atomicAdd(&cur3[d], 1);
  int j = off3[d] + p;
  s3s[j] = s;
  id3s[j] = idx;
  fr3s[j] = u - (float)idx;
}

// ---------------- small elementwise kernels ----------------

__global__ void k_hinit(const int* __restrict__ x2d, const float* __restrict__ e1,
                        const float* __restrict__ e2, float* __restrict__ h) {
  int i = blockIdx.x * blockDim.x + threadIdx.x;
  if (i >= NN * DEMB) return;
  int n = i / DEMB, c = i - n * DEMB;
  h[i] = e1[x2d[2 * n] * DEMB + c] + e2[x2d[2 * n + 1] * DEMB + c];
}

__global__ void k_vninit(const float* __restrict__ vni, float* __restrict__ vn) {
  int i = blockIdx.x * blockDim.x + threadIdx.x;
  if (i >= NG * DEMB) return;
  vn[i] = vni[i % DEMB];
}

__global__ void k_rbs(float* __restrict__ rbs, float* __restrict__ Cs) {
  int i = blockIdx.x * blockDim.x + threadIdx.x;
  if (i >= TROWS * NRBF) return;
  int j = i / NRBF, k = i - j * NRBF;
  float dj = (float)j * (DMAX / (float)NTAB);
  const float step = 10.0f / 49.0f;
  const float coeff = -0.5f / (step * step);
  float t = dj - (float)k * step;
  rbs[i] = expf(coeff * t * t);
  if (k == 0) Cs[j] = 0.5f * (cosf(dj * (3.14159265358979323846f / 10.0f)) + 1.0f);
}

__global__ void k_hsinit2(const int* __restrict__ z, const float* __restrict__ emb,
                          float* __restrict__ hs, short* __restrict__ hsb) {
  int i = blockIdx.x * blockDim.x + threadIdx.x;
  if (i >= NN * DSCH) return;
  float v = emb[z[i >> 7] * DSCH + (i & 127)];
  hs[i] = v;
  hsb[i] = f2b(v);
}

// ---------------- fused virtual-node MLP ----------------
__global__ __launch_bounds__(256) void k_vnmlp(const float* __restrict__ vnsum,
                                               float* __restrict__ vn,
                                               const float* __restrict__ W1,
                                               const float* __restrict__ b1,
                                               const float* __restrict__ W2,
                                               const float* __restrict__ b2) {
  __shared__ float sx[GPG][DEMB];
  __shared__ float sh[GPG][2 * DEMB];
  int tid = threadIdx.x;
  int g0 = blockIdx.x * GPG;
  for (int i = tid; i < GPG * DEMB; i += 256) {
    int g = i / DEMB, c = i - g * DEMB;
    sx[g][c] = vnsum[(size_t)(g0 + g) * DEMB + c] + vn[(size_t)(g0 + g) * DEMB + c];
  }
  __syncthreads();
  {
    float acc0[GPG] = {}, acc1[GPG] = {}, acc2[GPG] = {};
    for (int k = 0; k < DEMB; ++k) {
      float w0 = W1[k * 600 + tid];
      float w1 = W1[k * 600 + tid + 256];
      float w2 = (tid < 88) ? W1[k * 600 + tid + 512] : 0.f;
#pragma unroll
      for (int g = 0; g < GPG; ++g) {
        float xv = sx[g][k];
        acc0[g] = fmaf(w0, xv, acc0[g]);
        acc1[g] = fmaf(w1, xv, acc1[g]);
        acc2[g] = fmaf(w2, xv, acc2[g]);
      }
    }
#pragma unroll
    for (int g = 0; g < GPG; ++g) {
      sh[g][tid] = fmaxf(acc0[g] + b1[tid], 0.f);
      sh[g][tid + 256] = fmaxf(acc1[g] + b1[tid + 256], 0.f);
      if (tid < 88) sh[g][tid + 512] = fmaxf(acc2[g] + b1[tid + 512], 0.f);
    }
  }
  __syncthreads();
  {
    float acc0[GPG] = {}, acc1[GPG] = {};
    for (int k = 0; k < 2 * DEMB; ++k) {
      float w0 = (tid < 300) ? W2[k * 300 + tid] : 0.f;
      float w1 = (tid < 44) ? W2[k * 300 + tid + 256] : 0.f;
#pragma unroll
      for (int g = 0; g < GPG; ++g) {
        float hv = sh[g][k];
        acc0[g] = fmaf(w0, hv, acc0[g]);
        acc1[g] = fmaf(w1, hv, acc1[g]);
      }
    }
#pragma unroll
    for (int g = 0; g < GPG; ++g) {
      if (tid < 300) vn[(size_t)(g0 + g) * DEMB + tid] = fmaxf(acc0[g] + b2[tid], 0.f);
      if (tid < 44)
        vn[(size_t)(g0 + g) * DEMB + tid + 256] = fmaxf(acc1[g] + b2[tid + 256], 0.f);
    }
  }
}

// ---------------- fused head v2: k-split GEMVs with transposed weights ----------------
__global__ __launch_bounds__(256) void k_head2(
    const float* __restrict__ h2d, const float* __restrict__ hs, const int* __restrict__ goff,
    const float* __restrict__ p2Wt, const float* __restrict__ p2b,
    const float* __restrict__ p3Wt, const float* __restrict__ p3b,
    const float* __restrict__ gW1t, const float* __restrict__ gb1,
    const float* __restrict__ gW2, const float* __restrict__ gb2,
    const float* __restrict__ cW1t, const float* __restrict__ cb1,
    const float* __restrict__ cW2t, const float* __restrict__ cb2, float* __restrict__ out) {
  __shared__ float sx[DEMB], sy[DSCH], h2p[DEMB], h3p[DEMB], ghl[DSCH], c1l[150];
  __shared__ float pa[2][128], pb[2][128];
  __shared__ float gshare;
  int g = blockIdx.x, tid = threadIdx.x;
  int half = tid >> 7, o7 = tid & 127;
  int r0 = goff[g], r1 = goff[g + 1];
  float inv = 1.0f / fmaxf((float)(r1 - r0), 1.0f);
  for (int i = tid; i < DEMB; i += 256) sx[i] = h2d[(size_t)g * DEMB + i];
  {
    float a = 0.f;
    for (int r = r0 + half; r < r1; r += 2) a += hs[(size_t)r * DSCH + o7];
    pa[half][o7] = a;
  }
  __syncthreads();
  if (half == 0) sy[o7] = (pa[0][o7] + pa[1][o7]) * inv;
  __syncthreads();
  // h2p = sx@p2W+b, h3p = sy@p3W+b (outputs 300, 2-way k-split)
  for (int ob = 0; ob < DEMB; ob += 128) {
    int o = ob + o7;
    float a = 0.f, b = 0.f;
    if (o < DEMB) {
      const float* wr = p2Wt + (size_t)o * DEMB;
      for (int k = half * 150; k < half * 150 + 150; ++k) a = fmaf(sx[k], wr[k], a);
      const float* w3 = p3Wt + (size_t)o * DSCH;
      for (int k = half * 64; k < half * 64 + 64; ++k) b = fmaf(sy[k], w3[k], b);
    }
    pa[half][o7] = a;
    pb[half][o7] = b;
    __syncthreads();
    if (half == 0 && o < DEMB) {
      h2p[o] = pa[0][o7] + pa[1][o7] + p2b[o];
      h3p[o] = pb[0][o7] + pb[1][o7] + p3b[o];
    }
    __syncthreads();
  }
  // gate hidden (128 outputs, K=600 split: half0 h2p, half1 h3p)
  {
    float a = 0.f;
    const float* wr = gW1t + (size_t)o7 * 600;
    if (half == 0) {
      for (int k = 0; k < 300; ++k) a = fmaf(h2p[k], wr[k], a);
    } else {
      for (int k = 0; k < 300; ++k) a = fmaf(h3p[k], wr[300 + k], a);
    }
    pa[half][o7] = a;
    __syncthreads();
    if (half == 0) ghl[o7] = fmaxf(pa[0][o7] + pa[1][o7] + gb1[o7], 0.f);
    __syncthreads();
  }
  // gate scalar
  if (tid < 128) pa[0][tid] = ghl[tid] * gW2[tid];
  __syncthreads();
  for (int s = 64; s > 0; s >>= 1) {
    if (tid < s) pa[0][tid] += pa[0][tid + s];
    __syncthreads();
  }
  if (tid == 0) gshare = 1.0f / (1.0f + expf(-(pa[0][0] + gb2[0])));
  __syncthreads();
  float gg = gshare;
  for (int i = tid; i < DEMB; i += 256) sx[i] = gg * h2p[i] + (1.0f - gg) * h3p[i];
  __syncthreads();
  // c1 = relu(hf@cW1+b) (150 outputs)
  for (int ob = 0; ob < 150; ob += 128) {
    int o = ob + o7;
    float a = 0.f;
    if (o < 150) {
      const float* wr = cW1t + (size_t)o * DEMB;
      for (int k = half * 150; k < half * 150 + 150; ++k) a = fmaf(sx[k], wr[k], a);
    }
    pa[half][o7] = a;
    __syncthreads();
    if (half == 0 && o < 150) c1l[o] = fmaxf(pa[0][o7] + pa[1][o7] + cb1[o], 0.f);
    __syncthreads();
  }
  if (tid < 12) {
    float a = cb2[tid];
    const float* wr = cW2t + (size_t)tid * 150;
    for (int k = 0; k < 150; ++k) a = fmaf(c1l[k], wr[k], a);
    out[(size_t)g * 12 + tid] = a;
  }
}

// ---------------- gather aggregations ----------------

// GIN: aggb[d] = bf16( h[d]+vn[b[d]] + sum_e relu(h[s]+vn[b[s]]+eemb) ), padded to 320
__global__ __launch_bounds__(256) void k_gin_gather2(
    const float* __restrict__ h, const float* __restrict__ vn, const int* __restrict__ batch,
    const int* __restrict__ off2, const int* __restrict__ s2s, const int* __restrict__ ec2s,
    const float* __restrict__ bond1, const float* __restrict__ bond2, short* __restrict__ aggb) {
  __shared__ float sb[9 * DEMB];
  int tid = threadIdx.x;
  for (int i = tid; i < 6 * DEMB; i += 256) sb[i] = bond1[i];
  for (int i = tid; i < 3 * DEMB; i += 256) sb[6 * DEMB + i] = bond2[i];
  __syncthreads();
  int d = blockIdx.x * 4 + (tid >> 6);
  int lane = tid & 63;
  int j0 = off2[d], j1 = off2[d + 1];
  const float* hd = h + (size_t)d * DEMB;
  const float* vd = vn + (size_t)batch[d] * DEMB;
  float acc[5];
#pragma unroll
  for (int q = 0; q < 5; ++q) {
    int col = lane + 64 * q;
    acc[q] = (col < DEMB) ? hd[col] + vd[col] : 0.f;
  }
  for (int j = j0; j < j1; ++j) {
    int s = s2s[j], ec = ec2s[j];
    const float* hr = h + (size_t)s * DEMB;
    const float* vr = vn + (size_t)batch[s] * DEMB;
    const float* b1 = sb + (ec >> 2) * DEMB;
    const float* b2 = sb + 6 * DEMB + (ec & 3) * DEMB;
#pragma unroll
    for (int q = 0; q < 5; ++q) {
      int col = lane + 64 * q;
      if (col < DEMB) acc[q] += fmaxf(hr[col] + vr[col] + b1[col] + b2[col], 0.f);
    }
  }
  short* outr = aggb + (size_t)d * 320;
#pragma unroll
  for (int q = 0; q < 5; ++q) {
    int col = lane + 64 * q;
    outr[col] = (col < DEMB) ? f2b(acc[q]) : (short)0;
  }
}

// CFConv: agg3b[d] = bf16( sum_e lerp(ftab)*x1[src] )
__global__ __launch_bounds__(256) void k_conv_gather2(
    const float* __restrict__ ftab, const float* __restrict__ x1, const int* __restrict__ off3,
    const int* __restrict__ s3s, const int* __restrict__ id3s, const float* __restrict__ fr3s,
    short* __restrict__ agg3b) {
  int tid = threadIdx.x;
  int d = blockIdx.x * 4 + (tid >> 6);
  int lane = tid & 63;
  int j0 = off3[d], j1 = off3[d + 1];
  float a0 = 0.f, a1 = 0.f;
  for (int j = j0; j < j1; ++j) {
    int s = s3s[j], idx = id3s[j];
    float fr = fr3s[j];
    float2 t0 = ((const float2*)(ftab + (size_t)idx * 128))[lane];
    float2 t1 = ((const float2*)(ftab + (size_t)(idx + 1) * 128))[lane];
    float2 xv = ((const float2*)(x1 + (size_t)s * 128))[lane];
    a0 += (t0.x + fr * (t1.x - t0.x)) * xv.x;
    a1 += (t0.y + fr * (t1.y - t0.y)) * xv.y;
  }
  unsigned pack = ((unsigned)(unsigned short)f2b(a1) << 16) | (unsigned short)f2b(a0);
  ((unsigned*)(agg3b + (size_t)d * 128))[lane] = pack;
}

template <int W, int MEAN>
__global__ __launch_bounds__(256) void k_pool(const float* __restrict__ x,
                                              const int* __restrict__ goff,
                                              float* __restrict__ out) {
  int g = blockIdx.x * 4 + (threadIdx.x >> 6);
  int lane = threadIdx.x & 63;
  if (g >= NG) return;
  int r0 = goff[g], r1 = goff[g + 1];
  constexpr int NQ = (W + 63) / 64;
  float acc[NQ] = {};
  for (int r = r0; r < r1; ++r) {
    const float* row = x + (size_t)r * W;
#pragma unroll
    for (int q = 0; q < NQ; ++q) {
      int col = lane + 64 * q;
      if ((W % 64 == 0) || col < W) acc[q] += row[col];
    }
  }
  float s = MEAN ? (1.0f / fmaxf((float)(r1 - r0), 1.0f)) : 1.0f;
#pragma unroll
  for (int q = 0; q < NQ; ++q) {
    int col = lane + 64 * q;
    if ((W % 64 == 0) || col < W) out[(size_t)g * W + col] = acc[q] * s;
  }
}

// ---------------- weight prep ----------------
// W[l][K][N] f32 -> Wt[l][Np][Kp] bf16 (transposed, padded)
__global__ void k_prepw(const float* __restrict__ W, short* __restrict__ Wt, int K, int N, int Kp,
                        int Np, int L) {
  int i = blockIdx.x * blockDim.x + threadIdx.x;
  int per = Np * Kp;
  if (i >= L * per) return;
  int l = i / per, r = i - l * per;
  int n = r / Kp, k = r - n * Kp;
  float v = (n < N && k < K) ? W[(size_t)l * K * N + (size_t)k * N + n] : 0.f;
  Wt[i] = f2b(v);
}

// f32 transpose: W[K][N] -> Wt[N][K]
__global__ void k_prepwt(const float* __restrict__ W, float* __restrict__ Wt, int K, int N) {
  int i = blockIdx.x * blockDim.x + threadIdx.x;
  if (i >= N * K) return;
  int n = i / K, k = i - n * K;
  Wt[i] = W[(size_t)k * N + n];
}

// ---------------- z-batched fp32 GEMM (64x64 tile) ----------------
template <int ACT>
__global__ __launch_bounds__(256) void k_gemmz(
    const float* __restrict__ A, const float* __restrict__ B, const float* __restrict__ bias,
    const float* __restrict__ rscale, float* __restrict__ Cout, int M, int N, int K, int ldc,
    long strideA, long strideB, long strideBias, long strideC) {
  A += (size_t)blockIdx.z * strideA;
  B += (size_t)blockIdx.z * strideB;
  bias += (size_t)blockIdx.z * strideBias;
  Cout += (size_t)blockIdx.z * strideC;
  __shared__ float sA[16][65];
  __shared__ float sB[16][64];
  int tid = threadIdx.x;
  int tx = tid & 15, ty = tid >> 4;
  int bm = blockIdx.y * 64, bn = blockIdx.x * 64;
  float acc[4][4] = {};
  for (int k0 = 0; k0 < K; k0 += 16) {
#pragma unroll
    for (int t = 0; t < 4; ++t) {
      int i = tid + t * 256;
      int m = i >> 4, kk = i & 15;
      int gm = bm + m, gk = k0 + kk;
      sA[kk][m] = (gm < M && gk < K) ? A[(size_t)gm * K + gk] : 0.f;
    }
#pragma unroll
    for (int t = 0; t < 4; ++t) {
      int i = tid + t * 256;
      int kk = i >> 6, n = i & 63;
      int gk = k0 + kk, gn = bn + n;
      sB[kk][n] = (gk < K && gn < N) ? B[(size_t)gk * N + gn] : 0.f;
    }
    __syncthreads();
#pragma unroll
    for (int kk = 0; kk < 16; ++kk) {
      float a[4], b[4];
#pragma unroll
      for (int i = 0; i < 4; ++i) a[i] = sA[kk][ty + 16 * i];
#pragma unroll
      for (int j = 0; j < 4; ++j) b[j] = sB[kk][tx + 16 * j];
#pragma unroll
      for (int i = 0; i < 4; ++i)
#pragma unroll
        for (int j = 0; j < 4; ++j) acc[i][j] = fmaf(a[i], b[j], acc[i][j]);
    }
    __syncthreads();
  }
#pragma unroll
  for (int i = 0; i < 4; ++i) {
    int gm = bm + ty + 16 * i;
    if (gm >= M) continue;
    float rs = rscale ? rscale[gm] : 1.0f;
#pragma unroll
    for (int j = 0; j < 4; ++j) {
      int gn = bn + tx + 16 * j;
      if (gn >= N) continue;
      float v = acc[i][j] + bias[gn];
      if (ACT == 1) v = fmaxf(v, 0.f);
      if (ACT == 2) v = sspf(v);
      Cout[(size_t)gm * ldc + gn] = v * rs;
    }
  }
}

// ---------------- bf16 MFMA GEMM with bf16-native A ----------------
// Ab: bf16 [M][Kp] (zero-padded). Wt: bf16 [Np][Kp]. Outputs: f32 Cout and/or bf16 Coutb.
template <int ACT>
__global__ __launch_bounds__(256) void k_mgemm_bf(
    const short* __restrict__ Ab, const short* __restrict__ Wt, const float* __restrict__ bias,
    const float* __restrict__ scale, const float* __restrict__ shift,
    const float* __restrict__ Cin, float* __restrict__ Cout, short* __restrict__ Coutb,
    int M, int N, int Kp, int ldc, int ldcb, int Nb) {
  __shared__ short sA[128 * 32];
  const int tid = threadIdx.x;
  const int lane = tid & 63;
  const int w = tid >> 6;
  const int wm = w >> 1, wn = w & 1;
  const int bm = blockIdx.y * 128, bn = blockIdx.x * 128;

  f32x4 acc[4][4] = {};

  const int sr = tid >> 1;
  const int sk = (tid & 1) * 16;
  const short* Arow = Ab + (size_t)(bm + sr) * Kp + sk;
  const int ssw = (sr + (sr >> 2)) & 3;
  const int s0 = (sk >> 3);
  bf16x8* sAv = (bf16x8*)sA;

  const int frow = wm * 64 + (lane & 15);
  const int fslot = lane >> 4;
  const short* Bbase = Wt + (size_t)(bn + wn * 64 + (lane & 15)) * Kp + (fslot * 8);

  for (int k0 = 0; k0 < Kp; k0 += 32) {
    __syncthreads();
    {
      bf16x8 p0 = *(const bf16x8*)(Arow + k0);
      bf16x8 p1 = *(const bf16x8*)(Arow + k0 + 8);
      sAv[sr * 4 + ((s0 + 0) ^ ssw)] = p0;
      sAv[sr * 4 + ((s0 + 1) ^ ssw)] = p1;
    }
    __syncthreads();

    bf16x8 af[4], bfr[4];
#pragma unroll
    for (int mf = 0; mf < 4; ++mf) {
      int r = frow + mf * 16;
      af[mf] = sAv[r * 4 + (fslot ^ ((r + (r >> 2)) & 3))];
    }
#pragma unroll
    for (int nf = 0; nf < 4; ++nf) bfr[nf] = *(const bf16x8*)(Bbase + (size_t)nf * 16 * Kp + k0);
#pragma unroll
    for (int mf = 0; mf < 4; ++mf)
#pragma unroll
      for (int nf = 0; nf < 4; ++nf)
        acc[mf][nf] =
            __builtin_amdgcn_mfma_f32_16x16x32_bf16(af[mf], bfr[nf], acc[mf][nf], 0, 0, 0);
  }

  const int colbase = bn + wn * 64 + (lane & 15);
  const int rowbase = bm + wm * 64 + ((lane >> 4) << 2);
#pragma unroll
  for (int nf = 0; nf < 4; ++nf) {
    int col = colbase + nf * 16;
    bool cv = col < N;
    float bi = (bias && cv) ? bias[col] : 0.f;
    float sc = (scale && cv) ? scale[col] : 1.f;
    float sh = (shift && cv) ? shift[col] : 0.f;
#pragma unroll
    for (int mf = 0; mf < 4; ++mf) {
      f32x4 v = acc[mf][nf];
#pragma unroll
      for (int j = 0; j < 4; ++j) {
        int row = rowbase + mf * 16 + j;
        float x = v[j] + bi;
        if (scale) x = x * sc + sh;
        if (ACT == 1) x = fmaxf(x, 0.f);
        if (ACT == 2) x = sspf(x);
        if (Cin && cv) x += Cin[(size_t)row * ldc + col];
        if (Cout && cv) Cout[(size_t)row * ldc + col] = x;
        if (Coutb && col < Nb) Coutb[(size_t)row * ldcb + col] = cv ? f2b(x) : (short)0;
      }
    }
  }
}

// ---------------- host ----------------

static inline void run_mgemm_bf(hipStream_t st, const short* Ab, const short* Wt,
                                const float* bias, const float* scale, const float* shift,
                                const float* Cin, float* Cout, short* Coutb, int M, int N, int Kp,
                                int ldc, int ldcb, int Nb, int act) {
  dim3 grid((N + 127) / 128, M / 128);
  if (act == 0)
    k_mgemm_bf<0><<<grid, 256, 0, st>>>(Ab, Wt, bias, scale, shift, Cin, Cout, Coutb, M, N, Kp,
                                        ldc, ldcb, Nb);
  else if (act == 1)
    k_mgemm_bf<1><<<grid, 256, 0, st>>>(Ab, Wt, bias, scale, shift, Cin, Cout, Coutb, M, N, Kp,
                                        ldc, ldcb, Nb);
  else
    k_mgemm_bf<2><<<grid, 256, 0, st>>>(Ab, Wt, bias, scale, shift, Cin, Cout, Coutb, M, N, Kp,
                                        ldc, ldcb, Nb);
}

extern "C" void kernel_launch(void* const* d_in, const int* in_sizes, int n_in, void* d_out,
                              int out_size, void* d_ws, size_t ws_size, hipStream_t stream) {
  const int* x2d = (const int*)d_in[0];
  const int* ei2 = (const int*)d_in[1];
  const int* ea2 = (const int*)d_in[2];
  const int* batch = (const int*)d_in[3];
  const int* z = (const int*)d_in[4];
  const float* pos = (const float*)d_in[5];
  const int* ei3 = (const int*)d_in[6];
  const float* atom_emb1 = (const float*)d_in[7];
  const float* atom_emb2 = (const float*)d_in[8];
  const float* vn_init = (const float*)d_in[9];
  const float* gin_W1 = (const float*)d_in[10];
  const float* gin_b1 = (const float*)d_in[11];
  const float* gin_W2 = (const float*)d_in[12];
  const float* gin_b2 = (const float*)d_in[13];
  const float* gin_bond1 = (const float*)d_in[14];
  const float* gin_bond2 = (const float*)d_in[15];
  const float* gin_gamma = (const float*)d_in[16];
  const float* gin_beta = (const float*)d_in[17];
  const float* vn_W1 = (const float*)d_in[18];
  const float* vn_b1 = (const float*)d_in[19];
  const float* vn_W2 = (const float*)d_in[20];
  const float* vn_b2 = (const float*)d_in[21];
  const float* sch_emb = (const float*)d_in[22];
  const float* s_mW1 = (const float*)d_in[23];
  const float* s_mb1 = (const float*)d_in[24];
  const float* s_mW2 = (const float*)d_in[25];
  const float* s_mb2 = (const float*)d_in[26];
  const float* s_lin1W = (const float*)d_in[27];
  const float* s_lin2W = (const float*)d_in[28];
  const float* s_lin2b = (const float*)d_in[29];
  const float* s_linW = (const float*)d_in[30];
  const float* s_linb = (const float*)d_in[31];
  const float* p2W = (const float*)d_in[32];
  const float* p2b = (const float*)d_in[33];
  const float* p3W = (const float*)d_in[34];
  const float* p3b = (const float*)d_in[35];
  const float* gW1 = (const float*)d_in[36];
  const float* gb1 = (const float*)d_in[37];
  const float* gW2 = (const float*)d_in[38];
  const float* gb2 = (const float*)d_in[39];
  const float* cW1 = (const float*)d_in[40];
  const float* cb1 = (const float*)d_in[41];
  const float* cW2 = (const float*)d_in[42];
  const float* cb2 = (const float*)d_in[43];

  float* ws = (float*)d_ws;
  // GIN phase
  float* h = ws;                           // [0, 4.92M)
  short* aggb = (short*)(ws + 5000000);    // 16384*320 shorts -> 2.62M floats
  short* y1b = (short*)(ws + 7700000);     // 16384*608 shorts -> 4.98M floats, ends 12.69M
  // SchNet phase (aliases GIN region; GIN dead by then)
  float* rbs = ws + 400000;
  float* Cs = ws + 700000;
  float* t1all = ws + 800000;              // 6*5121*128 -> ends 4.73M
  float* ftab_all = ws + 4800000;          // -> ends 8.74M
  float* hs = ws + 8800000;                // 16384*128 -> ends 10.9M
  float* x1 = ws + 11000000;               // -> 13.1M
  short* agg3b = (short*)(ws + 13200000);  // 2M shorts -> 1.05M floats
  short* sx2b = (short*)(ws + 14300000);
  short* hsb = (short*)(ws + 15400000);    // ends 16.45M
  // bf16 transposed weights
  short* W1t = (short*)(ws + 20000000);
  short* W2t = (short*)(ws + 20600000);
  short* s1t = (short*)(ws + 21200000);
  short* s2t = (short*)(ws + 21300000);
  short* s3t = (short*)(ws + 21400000);
  // head transposed f32 weights
  float* p2Wt = ws + 21500000;  // 90000
  float* p3Wt = ws + 21600000;  // 38400
  float* gW1t = ws + 21650000;  // 76800
  float* cW1t = ws + 21730000;  // 45000
  float* cW2t = ws + 21780000;  // 1800
  // CSR region
  int* I = (int*)(ws + 22000000);
  int* cnt2 = I + 0;
  int* cnt3 = I + 16384;
  int* cntg = I + 32768;
  int* cur2 = I + 33280;
  int* cur3 = I + 49664;  // zero region = 66048 ints
  int* off2 = I + 70000;
  int* off3 = I + 90000;
  int* goff = I + 110000;
  int* s2s = I + 120000;
  int* ec2s = I + 190000;
  int* s3s = I + 260000;
  int* id3s = I + 660000;
  float* fr3s = (float*)(I + 1060000);
  // persistent tail
  float* vn = ws + 28443136;
  float* vnsum = ws + 28596736;
  float* h2d = ws + 29057536;

  // ---- weight prep ----
  k_prepw<<<(5 * 640 * 320 + 255) / 256, 256, 0, stream>>>(gin_W1, W1t, 300, 600, 320, 640, 5);
  k_prepw<<<(5 * 384 * 608 + 255) / 256, 256, 0, stream>>>(gin_W2, W2t, 600, 300, 608, 384, 5);
  k_prepw<<<(6 * 128 * 128 + 255) / 256, 256, 0, stream>>>(s_lin1W, s1t, 128, 128, 128, 128, 6);
  k_prepw<<<(6 * 128 * 128 + 255) / 256, 256, 0, stream>>>(s_lin2W, s2t, 128, 128, 128, 128, 6);
  k_prepw<<<(6 * 128 * 128 + 255) / 256, 256, 0, stream>>>(s_linW, s3t, 128, 128, 128, 128, 6);
  k_prepwt<<<(300 * 300 + 255) / 256, 256, 0, stream>>>(p2W, p2Wt, 300, 300);
  k_prepwt<<<(300 * 128 + 255) / 256, 256, 0, stream>>>(p3W, p3Wt, 128, 300);
  k_prepwt<<<(128 * 600 + 255) / 256, 256, 0, stream>>>(gW1, gW1t, 600, 128);
  k_prepwt<<<(150 * 300 + 255) / 256, 256, 0, stream>>>(cW1, cW1t, 300, 150);
  k_prepwt<<<(12 * 150 + 255) / 256, 256, 0, stream>>>(cW2, cW2t, 150, 12);

  // ---- CSR build ----
  hipMemsetAsync(I, 0, 66048 * sizeof(int), stream);
  k_hist<<<(NE2 + 255) / 256, 256, 0, stream>>>(ei2 + NE2, cnt2, NE2);
  k_hist<<<(NE3 + 255) / 256, 256, 0, stream>>>(ei3 + NE3, cnt3, NE3);
  k_hist<<<(NN + 255) / 256, 256, 0, stream>>>(batch, cntg, NN);
  k_scan<<<1, 1024, 0, stream>>>(cnt2, off2, 16384);
  k_scan<<<1, 1024, 0, stream>>>(cnt3, off3, 16384);
  k_scan<<<1, 1024, 0, stream>>>(cntg, goff, 512);
  k_scatter2<<<(NE2 + 255) / 256, 256, 0, stream>>>(ei2, ea2, off2, cur2, s2s, ec2s);
  k_scatter3<<<(NE3 + 255) / 256, 256, 0, stream>>>(ei3, pos, off3, cur3, s3s, id3s, fr3s);

  // ---- GIN ----
  k_hinit<<<(NN * DEMB + 255) / 256, 256, 0, stream>>>(x2d, atom_emb1, atom_emb2, h);
  k_vninit<<<(NG * DEMB + 255) / 256, 256, 0, stream>>>(vn_init, vn);
  for (int l = 0; l < 5; ++l) {
    k_gin_gather2<<<NN / 4, 256, 0, stream>>>(h, vn, batch, off2, s2s, ec2s,
                                              gin_bond1 + l * 6 * DEMB, gin_bond2 + l * 3 * DEMB,
                                              aggb);
    // y1b = bf16(relu(aggb @ W1 + b1)), padded to 608
    run_mgemm_bf(stream, aggb, W1t + (size_t)l * 640 * 320, gin_b1 + l * 600, nullptr, nullptr,
                 nullptr, nullptr, y1b, NN, 600, 320, 0, 608, 608, 1);
    // h = [relu] BN(y1b @ W2 + b2)
    run_mgemm_bf(stream, y1b, W2t + (size_t)l * 384 * 608, gin_b2 + l * 300, gin_gamma + l * 300,
                 gin_beta + l * 300, nullptr, h, nullptr, NN, 300, 608, 300, 0, 300,
                 (l < 4) ? 1 : 0);
    if (l < 4) {
      k_pool<DEMB, 0><<<NG / 4, 256, 0, stream>>>(h, goff, vnsum);
      k_vnmlp<<<NG / GPG, 256, 0, stream>>>(vnsum, vn, vn_W1 + (size_t)l * 180000,
                                            vn_b1 + l * 600, vn_W2 + (size_t)l * 180000,
                                            vn_b2 + l * 300);
    }
  }
  k_pool<DEMB, 1><<<NG / 4, 256, 0, stream>>>(h, goff, h2d);  // before SchNet clobbers h

  // ---- SchNet ----
  k_rbs<<<(TROWS * NRBF + 255) / 256, 256, 0, stream>>>(rbs, Cs);
  k_hsinit2<<<(NN * DSCH + 255) / 256, 256, 0, stream>>>(z, sch_emb, hs, hsb);
  {
    dim3 ga(2, (TROWS + 63) / 64, 6);
    k_gemmz<2><<<ga, 256, 0, stream>>>(rbs, s_mW1, s_mb1, nullptr, t1all, TROWS, 128, 50, 128, 0L,
                                       50L * 128, 128L, (long)TROWS * 128);
    k_gemmz<0><<<ga, 256, 0, stream>>>(t1all, s_mW2, s_mb2, Cs, ftab_all, TROWS, 128, 128, 128,
                                       (long)TROWS * 128, 128L * 128, 128L, (long)TROWS * 128);
  }
  for (int l = 0; l < 6; ++l) {
    // x1 = hsb @ lin1W (f32 out)
    run_mgemm_bf(stream, hsb, s1t + (size_t)l * 16384, nullptr, nullptr, nullptr, nullptr, x1,
                 nullptr, NN, 128, 128, 128, 0, 128, 0);
    k_conv_gather2<<<NN / 4, 256, 0, stream>>>(ftab_all + (size_t)l * TROWS * 128, x1, off3, s3s,
                                               id3s, fr3s, agg3b);
    // sx2b = bf16(ssp(agg3b @ lin2W + b))
    run_mgemm_bf(stream, agg3b, s2t + (size_t)l * 16384, s_lin2b + l * 128, nullptr, nullptr,
                 nullptr, nullptr, sx2b, NN, 128, 128, 0, 128, 128, 2);
    // hs += sx2b @ linW + b (dual-write f32 + bf16)
    run_mgemm_bf(stream, sx2b, s3t + (size_t)l * 16384, s_linb + l * 128, nullptr, nullptr, hs,
                 hs, hsb, NN, 128, 128, 128, 128, 128, 0);
  }

  // ---- fused head ----
  k_head2<<<NG, 256, 0, stream>>>(h2d, hs, goff, p2Wt, p2b, p3Wt, p3b, gW1t, gb1, gW2, gb2, cW1t,
                                  cb1, cW2t, cb2, (float*)d_out);
}

// Round 8
// 1786.196 us; speedup vs baseline: 5.5819x; 1.1085x over previous
//
#include <hip/hip_runtime.h>
#include <hip/hip_bf16.h>
#include <math.h>

#define NN 16384
#define NG 512
#define NE2 65536
#define NE3 393216
#define DEMB 300
#define DSCH 128
#define NRBF 50
#define NTAB 5120
#define TROWS 5121
#define DMAX 25.0f

typedef __attribute__((ext_vector_type(8))) short bf16x8;
typedef __attribute__((ext_vector_type(4))) float f32x4;

__device__ __forceinline__ float sspf(float x) {
  float sp = log1pf(expf(-fabsf(x))) + fmaxf(x, 0.f);
  return sp - 0.69314718055994530942f;
}

__device__ __forceinline__ short f2b(float f) {
  union { float f; unsigned u; } v;
  v.f = f;
  unsigned r = v.u + 0x7FFF + ((v.u >> 16) & 1);  // RNE
  return (short)(r >> 16);
}

__device__ __forceinline__ float b2f(unsigned short b) {
  union { unsigned u; float f; } v;
  v.u = ((unsigned)b) << 16;
  return v.f;
}

// ---------------- CSR build ----------------

__global__ void k_hist(const int* __restrict__ keys, int* __restrict__ cnt, int n) {
  int i = blockIdx.x * blockDim.x + threadIdx.x;
  if (i < n) atomicAdd(&cnt[keys[i]], 1);
}

__global__ __launch_bounds__(1024) void k_scan(const int* __restrict__ cnt, int* __restrict__ off,
                                               int n) {
  __shared__ int part[1024];
  int tid = threadIdx.x;
  int per = (n + 1023) / 1024;
  int base = tid * per;
  int sum = 0;
  for (int i = 0; i < per; ++i) {
    int idx = base + i;
    if (idx < n) sum += cnt[idx];
  }
  part[tid] = sum;
  __syncthreads();
  for (int d = 1; d < 1024; d <<= 1) {
    int v = (tid >= d) ? part[tid - d] : 0;
    __syncthreads();
    part[tid] += v;
    __syncthreads();
  }
  int run = (tid == 0) ? 0 : part[tid - 1];
  for (int i = 0; i < per; ++i) {
    int idx = base + i;
    if (idx < n) {
      off[idx] = run;
      run += cnt[idx];
    }
  }
  if (tid == 0) off[n] = part[1023];
}

__global__ void k_scatter2(const int* __restrict__ ei2, const int* __restrict__ ea2,
                           const int* __restrict__ off2, int* __restrict__ cur2,
                           int* __restrict__ s2s, int* __restrict__ ec2s) {
  int e = blockIdx.x * blockDim.x + threadIdx.x;
  if (e >= NE2) return;
  int d = ei2[NE2 + e];
  int p = atomicAdd(&cur2[d], 1);
  int j = off2[d] + p;
  s2s[j] = ei2[e];
  ec2s[j] = ea2[2 * e] * 4 + ea2[2 * e + 1];
}

__global__ void k_scatter3(const int* __restrict__ ei3, const float* __restrict__ pos,
                           const int* __restrict__ off3, int* __restrict__ cur3,
                           int* __restrict__ s3s, int* __restrict__ id3s,
                           float* __restrict__ fr3s) {
  int e = blockIdx.x * blockDim.x + threadIdx.x;
  if (e >= NE3) return;
  int s = ei3[e], d = ei3[NE3 + e];
  float dx = pos[3 * d] - pos[3 * s];
  float dy = pos[3 * d + 1] - pos[3 * s + 1];
  float dz = pos[3 * d + 2] - pos[3 * s + 2];
  float dist = sqrtf(dx * dx + dy * dy + dz * dz);
  float u = fminf(dist * ((float)NTAB / DMAX), (float)NTAB - 0.001f);
  int idx = (int)u;
  int p = atomicAdd(&cur3[d], 1);
  int j = off3[d] + p;
  s3s[j] = s;
  id3s[j] = idx;
  fr3s[j] = u - (float)idx;
}

// ---------------- small elementwise kernels ----------------

__global__ void k_hinit(const int* __restrict__ x2d, const float* __restrict__ e1,
                        const float* __restrict__ e2, float* __restrict__ h) {
  int i = blockIdx.x * blockDim.x + threadIdx.x;
  if (i >= NN * DEMB) return;
  int n = i / DEMB, c = i - n * DEMB;
  h[i] = e1[x2d[2 * n] * DEMB + c] + e2[x2d[2 * n + 1] * DEMB + c];
}

__global__ void k_vninit(const float* __restrict__ vni, float* __restrict__ vn) {
  int i = blockIdx.x * blockDim.x + threadIdx.x;
  if (i >= NG * DEMB) return;
  vn[i] = vni[i % DEMB];
}

__global__ void k_rbs(float* __restrict__ rbs, float* __restrict__ Cs) {
  int i = blockIdx.x * blockDim.x + threadIdx.x;
  if (i >= TROWS * NRBF) return;
  int j = i / NRBF, k = i - j * NRBF;
  float dj = (float)j * (DMAX / (float)NTAB);
  const float step = 10.0f / 49.0f;
  const float coeff = -0.5f / (step * step);
  float t = dj - (float)k * step;
  rbs[i] = expf(coeff * t * t);
  if (k == 0) Cs[j] = 0.5f * (cosf(dj * (3.14159265358979323846f / 10.0f)) + 1.0f);
}

__global__ void k_hsinit2(const int* __restrict__ z, const float* __restrict__ emb,
                          float* __restrict__ hs, short* __restrict__ hsb) {
  int i = blockIdx.x * blockDim.x + threadIdx.x;
  if (i >= NN * DSCH) return;
  float v = emb[z[i >> 7] * DSCH + (i & 127)];
  hs[i] = v;
  hsb[i] = f2b(v);
}

// vn-MLP input prep: ab[g][320] = bf16(vnsum[g] + vn[g]) padded
__global__ void k_prepvn(const float* __restrict__ vnsum, const float* __restrict__ vn,
                         short* __restrict__ ab) {
  int i = blockIdx.x * blockDim.x + threadIdx.x;
  if (i >= NG * 320) return;
  int g = i / 320, c = i - g * 320;
  ab[i] = (c < DEMB) ? f2b(vnsum[(size_t)g * DEMB + c] + vn[(size_t)g * DEMB + c]) : (short)0;
}

// ---------------- fused head v2 ----------------
__global__ __launch_bounds__(256) void k_head2(
    const float* __restrict__ h2d, const float* __restrict__ hs, const int* __restrict__ goff,
    const float* __restrict__ p2Wt, const float* __restrict__ p2b,
    const float* __restrict__ p3Wt, const float* __restrict__ p3b,
    const float* __restrict__ gW1t, const float* __restrict__ gb1,
    const float* __restrict__ gW2, const float* __restrict__ gb2,
    const float* __restrict__ cW1t, const float* __restrict__ cb1,
    const float* __restrict__ cW2t, const float* __restrict__ cb2, float* __restrict__ out) {
  __shared__ float sx[DEMB], sy[DSCH], h2p[DEMB], h3p[DEMB], ghl[DSCH], c1l[150];
  __shared__ float pa[2][128], pb[2][128];
  __shared__ float gshare;
  int g = blockIdx.x, tid = threadIdx.x;
  int half = tid >> 7, o7 = tid & 127;
  int r0 = goff[g], r1 = goff[g + 1];
  float inv = 1.0f / fmaxf((float)(r1 - r0), 1.0f);
  for (int i = tid; i < DEMB; i += 256) sx[i] = h2d[(size_t)g * DEMB + i];
  {
    float a = 0.f;
    for (int r = r0 + half; r < r1; r += 2) a += hs[(size_t)r * DSCH + o7];
    pa[half][o7] = a;
  }
  __syncthreads();
  if (half == 0) sy[o7] = (pa[0][o7] + pa[1][o7]) * inv;
  __syncthreads();
  for (int ob = 0; ob < DEMB; ob += 128) {
    int o = ob + o7;
    float a = 0.f, b = 0.f;
    if (o < DEMB) {
      const float* wr = p2Wt + (size_t)o * DEMB;
      for (int k = half * 150; k < half * 150 + 150; ++k) a = fmaf(sx[k], wr[k], a);
      const float* w3 = p3Wt + (size_t)o * DSCH;
      for (int k = half * 64; k < half * 64 + 64; ++k) b = fmaf(sy[k], w3[k], b);
    }
    pa[half][o7] = a;
    pb[half][o7] = b;
    __syncthreads();
    if (half == 0 && o < DEMB) {
      h2p[o] = pa[0][o7] + pa[1][o7] + p2b[o];
      h3p[o] = pb[0][o7] + pb[1][o7] + p3b[o];
    }
    __syncthreads();
  }
  {
    float a = 0.f;
    const float* wr = gW1t + (size_t)o7 * 600;
    if (half == 0) {
      for (int k = 0; k < 300; ++k) a = fmaf(h2p[k], wr[k], a);
    } else {
      for (int k = 0; k < 300; ++k) a = fmaf(h3p[k], wr[300 + k], a);
    }
    pa[half][o7] = a;
    __syncthreads();
    if (half == 0) ghl[o7] = fmaxf(pa[0][o7] + pa[1][o7] + gb1[o7], 0.f);
    __syncthreads();
  }
  if (tid < 128) pa[0][tid] = ghl[tid] * gW2[tid];
  __syncthreads();
  for (int s = 64; s > 0; s >>= 1) {
    if (tid < s) pa[0][tid] += pa[0][tid + s];
    __syncthreads();
  }
  if (tid == 0) gshare = 1.0f / (1.0f + expf(-(pa[0][0] + gb2[0])));
  __syncthreads();
  float gg = gshare;
  for (int i = tid; i < DEMB; i += 256) sx[i] = gg * h2p[i] + (1.0f - gg) * h3p[i];
  __syncthreads();
  for (int ob = 0; ob < 150; ob += 128) {
    int o = ob + o7;
    float a = 0.f;
    if (o < 150) {
      const float* wr = cW1t + (size_t)o * DEMB;
      for (int k = half * 150; k < half * 150 + 150; ++k) a = fmaf(sx[k], wr[k], a);
    }
    pa[half][o7] = a;
    __syncthreads();
    if (half == 0 && o < 150) c1l[o] = fmaxf(pa[0][o7] + pa[1][o7] + cb1[o], 0.f);
    __syncthreads();
  }
  if (tid < 12) {
    float a = cb2[tid];
    const float* wr = cW2t + (size_t)tid * 150;
    for (int k = 0; k < 150; ++k) a = fmaf(c1l[k], wr[k], a);
    out[(size_t)g * 12 + tid] = a;
  }
}

// ---------------- gather aggregations ----------------

__global__ __launch_bounds__(256) void k_gin_gather2(
    const float* __restrict__ h, const float* __restrict__ vn, const int* __restrict__ batch,
    const int* __restrict__ off2, const int* __restrict__ s2s, const int* __restrict__ ec2s,
    const float* __restrict__ bond1, const float* __restrict__ bond2, short* __restrict__ aggb) {
  __shared__ float sb[9 * DEMB];
  int tid = threadIdx.x;
  for (int i = tid; i < 6 * DEMB; i += 256) sb[i] = bond1[i];
  for (int i = tid; i < 3 * DEMB; i += 256) sb[6 * DEMB + i] = bond2[i];
  __syncthreads();
  int d = blockIdx.x * 4 + (tid >> 6);
  int lane = tid & 63;
  int j0 = off2[d], j1 = off2[d + 1];
  const float* hd = h + (size_t)d * DEMB;
  const float* vd = vn + (size_t)batch[d] * DEMB;
  float acc[5];
#pragma unroll
  for (int q = 0; q < 5; ++q) {
    int col = lane + 64 * q;
    acc[q] = (col < DEMB) ? hd[col] + vd[col] : 0.f;
  }
  for (int j = j0; j < j1; ++j) {
    int s = s2s[j], ec = ec2s[j];
    const float* hr = h + (size_t)s * DEMB;
    const float* vr = vn + (size_t)batch[s] * DEMB;
    const float* b1 = sb + (ec >> 2) * DEMB;
    const float* b2 = sb + 6 * DEMB + (ec & 3) * DEMB;
#pragma unroll
    for (int q = 0; q < 5; ++q) {
      int col = lane + 64 * q;
      if (col < DEMB) acc[q] += fmaxf(hr[col] + vr[col] + b1[col] + b2[col], 0.f);
    }
  }
  short* outr = aggb + (size_t)d * 320;
#pragma unroll
  for (int q = 0; q < 5; ++q) {
    int col = lane + 64 * q;
    outr[col] = (col < DEMB) ? f2b(acc[q]) : (short)0;
  }
}

// CFConv with bf16 x1: agg3b[d] = bf16( sum_e lerp(ftab)*x1b[src] )
__global__ __launch_bounds__(256) void k_conv_gather3(
    const float* __restrict__ ftab, const short* __restrict__ x1b, const int* __restrict__ off3,
    const int* __restrict__ s3s, const int* __restrict__ id3s, const float* __restrict__ fr3s,
    short* __restrict__ agg3b) {
  int tid = threadIdx.x;
  int d = blockIdx.x * 4 + (tid >> 6);
  int lane = tid & 63;
  int j0 = off3[d], j1 = off3[d + 1];
  float a0 = 0.f, a1 = 0.f;
  for (int j = j0; j < j1; ++j) {
    int s = s3s[j], idx = id3s[j];
    float fr = fr3s[j];
    float2 t0 = ((const float2*)(ftab + (size_t)idx * 128))[lane];
    float2 t1 = ((const float2*)(ftab + (size_t)(idx + 1) * 128))[lane];
    unsigned xv = ((const unsigned*)(x1b + (size_t)s * 128))[lane];
    a0 += (t0.x + fr * (t1.x - t0.x)) * b2f((unsigned short)(xv & 0xFFFF));
    a1 += (t0.y + fr * (t1.y - t0.y)) * b2f((unsigned short)(xv >> 16));
  }
  unsigned pack = ((unsigned)(unsigned short)f2b(a1) << 16) | (unsigned short)f2b(a0);
  ((unsigned*)(agg3b + (size_t)d * 128))[lane] = pack;
}

template <int W, int MEAN>
__global__ __launch_bounds__(256) void k_pool(const float* __restrict__ x,
                                              const int* __restrict__ goff,
                                              float* __restrict__ out) {
  int g = blockIdx.x * 4 + (threadIdx.x >> 6);
  int lane = threadIdx.x & 63;
  if (g >= NG) return;
  int r0 = goff[g], r1 = goff[g + 1];
  constexpr int NQ = (W + 63) / 64;
  float acc[NQ] = {};
  for (int r = r0; r < r1; ++r) {
    const float* row = x + (size_t)r * W;
#pragma unroll
    for (int q = 0; q < NQ; ++q) {
      int col = lane + 64 * q;
      if ((W % 64 == 0) || col < W) acc[q] += row[col];
    }
  }
  float s = MEAN ? (1.0f / fmaxf((float)(r1 - r0), 1.0f)) : 1.0f;
#pragma unroll
  for (int q = 0; q < NQ; ++q) {
    int col = lane + 64 * q;
    if ((W % 64 == 0) || col < W) out[(size_t)g * W + col] = acc[q] * s;
  }
}

// ---------------- weight prep ----------------
__global__ void k_prepw(const float* __restrict__ W, short* __restrict__ Wt, int K, int N, int Kp,
                        int Np, int L) {
  int i = blockIdx.x * blockDim.x + threadIdx.x;
  int per = Np * Kp;
  if (i >= L * per) return;
  int l = i / per, r = i - l * per;
  int n = r / Kp, k = r - n * Kp;
  float v = (n < N && k < K) ? W[(size_t)l * K * N + (size_t)k * N + n] : 0.f;
  Wt[i] = f2b(v);
}

__global__ void k_prepwt(const float* __restrict__ W, float* __restrict__ Wt, int K, int N) {
  int i = blockIdx.x * blockDim.x + threadIdx.x;
  if (i >= N * K) return;
  int n = i / K, k = i - n * K;
  Wt[i] = W[(size_t)k * N + n];
}

// ---------------- z-batched fp32 GEMM (64x64 tile) ----------------
template <int ACT>
__global__ __launch_bounds__(256) void k_gemmz(
    const float* __restrict__ A, const float* __restrict__ B, const float* __restrict__ bias,
    const float* __restrict__ rscale, float* __restrict__ Cout, int M, int N, int K, int ldc,
    long strideA, long strideB, long strideBias, long strideC) {
  A += (size_t)blockIdx.z * strideA;
  B += (size_t)blockIdx.z * strideB;
  bias += (size_t)blockIdx.z * strideBias;
  Cout += (size_t)blockIdx.z * strideC;
  __shared__ float sA[16][65];
  __shared__ float sB[16][64];
  int tid = threadIdx.x;
  int tx = tid & 15, ty = tid >> 4;
  int bm = blockIdx.y * 64, bn = blockIdx.x * 64;
  float acc[4][4] = {};
  for (int k0 = 0; k0 < K; k0 += 16) {
#pragma unroll
    for (int t = 0; t < 4; ++t) {
      int i = tid + t * 256;
      int m = i >> 4, kk = i & 15;
      int gm = bm + m, gk = k0 + kk;
      sA[kk][m] = (gm < M && gk < K) ? A[(size_t)gm * K + gk] : 0.f;
    }
#pragma unroll
    for (int t = 0; t < 4; ++t) {
      int i = tid + t * 256;
      int kk = i >> 6, n = i & 63;
      int gk = k0 + kk, gn = bn + n;
      sB[kk][n] = (gk < K && gn < N) ? B[(size_t)gk * N + gn] : 0.f;
    }
    __syncthreads();
#pragma unroll
    for (int kk = 0; kk < 16; ++kk) {
      float a[4], b[4];
#pragma unroll
      for (int i = 0; i < 4; ++i) a[i] = sA[kk][ty + 16 * i];
#pragma unroll
      for (int j = 0; j < 4; ++j) b[j] = sB[kk][tx + 16 * j];
#pragma unroll
      for (int i = 0; i < 4; ++i)
#pragma unroll
        for (int j = 0; j < 4; ++j) acc[i][j] = fmaf(a[i], b[j], acc[i][j]);
    }
    __syncthreads();
  }
#pragma unroll
  for (int i = 0; i < 4; ++i) {
    int gm = bm + ty + 16 * i;
    if (gm >= M) continue;
    float rs = rscale ? rscale[gm] : 1.0f;
#pragma unroll
    for (int j = 0; j < 4; ++j) {
      int gn = bn + tx + 16 * j;
      if (gn >= N) continue;
      float v = acc[i][j] + bias[gn];
      if (ACT == 1) v = fmaxf(v, 0.f);
      if (ACT == 2) v = sspf(v);
      Cout[(size_t)gm * ldc + gn] = v * rs;
    }
  }
}

// ---------------- bf16 MFMA GEMM with bf16-native A ----------------
template <int ACT>
__global__ __launch_bounds__(256) void k_mgemm_bf(
    const short* __restrict__ Ab, const short* __restrict__ Wt, const float* __restrict__ bias,
    const float* __restrict__ scale, const float* __restrict__ shift,
    const float* __restrict__ Cin, float* __restrict__ Cout, short* __restrict__ Coutb,
    int M, int N, int Kp, int ldc, int ldcb, int Nb) {
  __shared__ short sA[128 * 32];
  const int tid = threadIdx.x;
  const int lane = tid & 63;
  const int w = tid >> 6;
  const int wm = w >> 1, wn = w & 1;
  const int bm = blockIdx.y * 128, bn = blockIdx.x * 128;

  f32x4 acc[4][4] = {};

  const int sr = tid >> 1;
  const int sk = (tid & 1) * 16;
  const short* Arow = Ab + (size_t)(bm + sr) * Kp + sk;
  const int ssw = (sr + (sr >> 2)) & 3;
  const int s0 = (sk >> 3);
  bf16x8* sAv = (bf16x8*)sA;

  const int frow = wm * 64 + (lane & 15);
  const int fslot = lane >> 4;
  const short* Bbase = Wt + (size_t)(bn + wn * 64 + (lane & 15)) * Kp + (fslot * 8);

  for (int k0 = 0; k0 < Kp; k0 += 32) {
    __syncthreads();
    {
      bf16x8 p0 = *(const bf16x8*)(Arow + k0);
      bf16x8 p1 = *(const bf16x8*)(Arow + k0 + 8);
      sAv[sr * 4 + ((s0 + 0) ^ ssw)] = p0;
      sAv[sr * 4 + ((s0 + 1) ^ ssw)] = p1;
    }
    __syncthreads();

    bf16x8 af[4], bfr[4];
#pragma unroll
    for (int mf = 0; mf < 4; ++mf) {
      int r = frow + mf * 16;
      af[mf] = sAv[r * 4 + (fslot ^ ((r + (r >> 2)) & 3))];
    }
#pragma unroll
    for (int nf = 0; nf < 4; ++nf) bfr[nf] = *(const bf16x8*)(Bbase + (size_t)nf * 16 * Kp + k0);
#pragma unroll
    for (int mf = 0; mf < 4; ++mf)
#pragma unroll
      for (int nf = 0; nf < 4; ++nf)
        acc[mf][nf] =
            __builtin_amdgcn_mfma_f32_16x16x32_bf16(af[mf], bfr[nf], acc[mf][nf], 0, 0, 0);
  }

  const int colbase = bn + wn * 64 + (lane & 15);
  const int rowbase = bm + wm * 64 + ((lane >> 4) << 2);
#pragma unroll
  for (int nf = 0; nf < 4; ++nf) {
    int col = colbase + nf * 16;
    bool cv = col < N;
    float bi = (bias && cv) ? bias[col] : 0.f;
    float sc = (scale && cv) ? scale[col] : 1.f;
    float sh = (shift && cv) ? shift[col] : 0.f;
#pragma unroll
    for (int mf = 0; mf < 4; ++mf) {
      f32x4 v = acc[mf][nf];
#pragma unroll
      for (int j = 0; j < 4; ++j) {
        int row = rowbase + mf * 16 + j;
        float x = v[j] + bi;
        if (scale) x = x * sc + sh;
        if (ACT == 1) x = fmaxf(x, 0.f);
        if (ACT == 2) x = sspf(x);
        if (Cin && cv) x += Cin[(size_t)row * ldc + col];
        if (Cout && cv) Cout[(size_t)row * ldc + col] = x;
        if (Coutb && col < Nb) Coutb[(size_t)row * ldcb + col] = cv ? f2b(x) : (short)0;
      }
    }
  }
}

// ---------------- host ----------------

static inline void run_mgemm_bf(hipStream_t st, const short* Ab, const short* Wt,
                                const float* bias, const float* scale, const float* shift,
                                const float* Cin, float* Cout, short* Coutb, int M, int N, int Kp,
                                int ldc, int ldcb, int Nb, int act) {
  dim3 grid((N + 127) / 128, M / 128);
  if (act == 0)
    k_mgemm_bf<0><<<grid, 256, 0, st>>>(Ab, Wt, bias, scale, shift, Cin, Cout, Coutb, M, N, Kp,
                                        ldc, ldcb, Nb);
  else if (act == 1)
    k_mgemm_bf<1><<<grid, 256, 0, st>>>(Ab, Wt, bias, scale, shift, Cin, Cout, Coutb, M, N, Kp,
                                        ldc, ldcb, Nb);
  else
    k_mgemm_bf<2><<<grid, 256, 0, st>>>(Ab, Wt, bias, scale, shift, Cin, Cout, Coutb, M, N, Kp,
                                        ldc, ldcb, Nb);
}

extern "C" void kernel_launch(void* const* d_in, const int* in_sizes, int n_in, void* d_out,
                              int out_size, void* d_ws, size_t ws_size, hipStream_t stream) {
  const int* x2d = (const int*)d_in[0];
  const int* ei2 = (const int*)d_in[1];
  const int* ea2 = (const int*)d_in[2];
  const int* batch = (const int*)d_in[3];
  const int* z = (const int*)d_in[4];
  const float* pos = (const float*)d_in[5];
  const int* ei3 = (const int*)d_in[6];
  const float* atom_emb1 = (const float*)d_in[7];
  const float* atom_emb2 = (const float*)d_in[8];
  const float* vn_init = (const float*)d_in[9];
  const float* gin_W1 = (const float*)d_in[10];
  const float* gin_b1 = (const float*)d_in[11];
  const float* gin_W2 = (const float*)d_in[12];
  const float* gin_b2 = (const float*)d_in[13];
  const float* gin_bond1 = (const float*)d_in[14];
  const float* gin_bond2 = (const float*)d_in[15];
  const float* gin_gamma = (const float*)d_in[16];
  const float* gin_beta = (const float*)d_in[17];
  const float* vn_W1 = (const float*)d_in[18];
  const float* vn_b1 = (const float*)d_in[19];
  const float* vn_W2 = (const float*)d_in[20];
  const float* vn_b2 = (const float*)d_in[21];
  const float* sch_emb = (const float*)d_in[22];
  const float* s_mW1 = (const float*)d_in[23];
  const float* s_mb1 = (const float*)d_in[24];
  const float* s_mW2 = (const float*)d_in[25];
  const float* s_mb2 = (const float*)d_in[26];
  const float* s_lin1W = (const float*)d_in[27];
  const float* s_lin2W = (const float*)d_in[28];
  const float* s_lin2b = (const float*)d_in[29];
  const float* s_linW = (const float*)d_in[30];
  const float* s_linb = (const float*)d_in[31];
  const float* p2W = (const float*)d_in[32];
  const float* p2b = (const float*)d_in[33];
  const float* p3W = (const float*)d_in[34];
  const float* p3b = (const float*)d_in[35];
  const float* gW1 = (const float*)d_in[36];
  const float* gb1 = (const float*)d_in[37];
  const float* gW2 = (const float*)d_in[38];
  const float* gb2 = (const float*)d_in[39];
  const float* cW1 = (const float*)d_in[40];
  const float* cb1 = (const float*)d_in[41];
  const float* cW2 = (const float*)d_in[42];
  const float* cb2 = (const float*)d_in[43];

  float* ws = (float*)d_ws;
  // GIN phase
  float* h = ws;                           // [0, 4.92M)
  short* aggb = (short*)(ws + 5000000);    // 16384*320 shorts
  short* y1b = (short*)(ws + 7700000);     // 16384*608 shorts
  // SchNet phase (aliases GIN region)
  float* rbs = ws + 400000;
  float* Cs = ws + 700000;
  float* t1all = ws + 800000;              // 6*5121*128
  float* ftab_all = ws + 4800000;
  float* hs = ws + 8800000;                // 16384*128
  short* x1b = (short*)(ws + 11000000);    // 16384*128 shorts
  short* agg3b = (short*)(ws + 13200000);
  short* sx2b = (short*)(ws + 14300000);
  short* hsb = (short*)(ws + 15400000);
  // bf16 transposed weights
  short* W1t = (short*)(ws + 20000000);
  short* W2t = (short*)(ws + 20600000);
  short* s1t = (short*)(ws + 21200000);
  short* s2t = (short*)(ws + 21300000);
  short* s3t = (short*)(ws + 21400000);
  // head transposed f32 weights
  float* p2Wt = ws + 21500000;
  float* p3Wt = ws + 21600000;
  float* gW1t = ws + 21650000;
  float* cW1t = ws + 21730000;
  float* cW2t = ws + 21780000;
  // CSR region
  int* I = (int*)(ws + 22000000);
  int* cnt2 = I + 0;
  int* cnt3 = I + 16384;
  int* cntg = I + 32768;
  int* cur2 = I + 33280;
  int* cur3 = I + 49664;  // zero region = 66048 ints
  int* off2 = I + 70000;
  int* off3 = I + 90000;
  int* goff = I + 110000;
  int* s2s = I + 120000;
  int* ec2s = I + 190000;
  int* s3s = I + 260000;
  int* id3s = I + 660000;
  float* fr3s = (float*)(I + 1060000);     // ends ws+23453216
  // vn-MLP bf16 weights + buffers
  short* vnW1t = (short*)(ws + 23500000);  // 4*640*320 shorts = 409600 fl
  short* vnW2t = (short*)(ws + 24000000);  // 4*384*608 shorts = 466944 fl
  short* vnab = (short*)(ws + 24500000);   // 512*320 shorts
  short* vnhb = (short*)(ws + 24600000);   // 512*608 shorts -> ends ~24.76M
  // persistent tail
  float* vn = ws + 28443136;
  float* vnsum = ws + 28596736;
  float* h2d = ws + 29057536;

  // ---- weight prep ----
  k_prepw<<<(5 * 640 * 320 + 255) / 256, 256, 0, stream>>>(gin_W1, W1t, 300, 600, 320, 640, 5);
  k_prepw<<<(5 * 384 * 608 + 255) / 256, 256, 0, stream>>>(gin_W2, W2t, 600, 300, 608, 384, 5);
  k_prepw<<<(6 * 128 * 128 + 255) / 256, 256, 0, stream>>>(s_lin1W, s1t, 128, 128, 128, 128, 6);
  k_prepw<<<(6 * 128 * 128 + 255) / 256, 256, 0, stream>>>(s_lin2W, s2t, 128, 128, 128, 128, 6);
  k_prepw<<<(6 * 128 * 128 + 255) / 256, 256, 0, stream>>>(s_linW, s3t, 128, 128, 128, 128, 6);
  k_prepw<<<(4 * 640 * 320 + 255) / 256, 256, 0, stream>>>(vn_W1, vnW1t, 300, 600, 320, 640, 4);
  k_prepw<<<(4 * 384 * 608 + 255) / 256, 256, 0, stream>>>(vn_W2, vnW2t, 600, 300, 608, 384, 4);
  k_prepwt<<<(300 * 300 + 255) / 256, 256, 0, stream>>>(p2W, p2Wt, 300, 300);
  k_prepwt<<<(300 * 128 + 255) / 256, 256, 0, stream>>>(p3W, p3Wt, 128, 300);
  k_prepwt<<<(128 * 600 + 255) / 256, 256, 0, stream>>>(gW1, gW1t, 600, 128);
  k_prepwt<<<(150 * 300 + 255) / 256, 256, 0, stream>>>(cW1, cW1t, 300, 150);
  k_prepwt<<<(12 * 150 + 255) / 256, 256, 0, stream>>>(cW2, cW2t, 150, 12);

  // ---- CSR build ----
  hipMemsetAsync(I, 0, 66048 * sizeof(int), stream);
  k_hist<<<(NE2 + 255) / 256, 256, 0, stream>>>(ei2 + NE2, cnt2, NE2);
  k_hist<<<(NE3 + 255) / 256, 256, 0, stream>>>(ei3 + NE3, cnt3, NE3);
  k_hist<<<(NN + 255) / 256, 256, 0, stream>>>(batch, cntg, NN);
  k_scan<<<1, 1024, 0, stream>>>(cnt2, off2, 16384);
  k_scan<<<1, 1024, 0, stream>>>(cnt3, off3, 16384);
  k_scan<<<1, 1024, 0, stream>>>(cntg, goff, 512);
  k_scatter2<<<(NE2 + 255) / 256, 256, 0, stream>>>(ei2, ea2, off2, cur2, s2s, ec2s);
  k_scatter3<<<(NE3 + 255) / 256, 256, 0, stream>>>(ei3, pos, off3, cur3, s3s, id3s, fr3s);

  // ---- GIN ----
  k_hinit<<<(NN * DEMB + 255) / 256, 256, 0, stream>>>(x2d, atom_emb1, atom_emb2, h);
  k_vninit<<<(NG * DEMB + 255) / 256, 256, 0, stream>>>(vn_init, vn);
  for (int l = 0; l < 5; ++l) {
    k_gin_gather2<<<NN / 4, 256, 0, stream>>>(h, vn, batch, off2, s2s, ec2s,
                                              gin_bond1 + l * 6 * DEMB, gin_bond2 + l * 3 * DEMB,
                                              aggb);
    run_mgemm_bf(stream, aggb, W1t + (size_t)l * 640 * 320, gin_b1 + l * 600, nullptr, nullptr,
                 nullptr, nullptr, y1b, NN, 600, 320, 0, 608, 608, 1);
    run_mgemm_bf(stream, y1b, W2t + (size_t)l * 384 * 608, gin_b2 + l * 300, gin_gamma + l * 300,
                 gin_beta + l * 300, nullptr, h, nullptr, NN, 300, 608, 300, 0, 300,
                 (l < 4) ? 1 : 0);
    if (l < 4) {
      k_pool<DEMB, 0><<<NG / 4, 256, 0, stream>>>(h, goff, vnsum);
      k_prepvn<<<(NG * 320 + 255) / 256, 256, 0, stream>>>(vnsum, vn, vnab);
      // vnhb = bf16(relu(vnab @ vnW1 + b1))
      run_mgemm_bf(stream, vnab, vnW1t + (size_t)l * 640 * 320, vn_b1 + l * 600, nullptr, nullptr,
                   nullptr, nullptr, vnhb, NG, 600, 320, 0, 608, 608, 1);
      // vn = relu(vnhb @ vnW2 + b2)  (f32)
      run_mgemm_bf(stream, vnhb, vnW2t + (size_t)l * 384 * 608, vn_b2 + l * 300, nullptr, nullptr,
                   nullptr, vn, nullptr, NG, 300, 608, 300, 0, 300, 1);
    }
  }
  k_pool<DEMB, 1><<<NG / 4, 256, 0, stream>>>(h, goff, h2d);  // before SchNet clobbers h

  // ---- SchNet ----
  k_rbs<<<(TROWS * NRBF + 255) / 256, 256, 0, stream>>>(rbs, Cs);
  k_hsinit2<<<(NN * DSCH + 255) / 256, 256, 0, stream>>>(z, sch_emb, hs, hsb);
  {
    dim3 ga(2, (TROWS + 63) / 64, 6);
    k_gemmz<2><<<ga, 256, 0, stream>>>(rbs, s_mW1, s_mb1, nullptr, t1all, TROWS, 128, 50, 128, 0L,
                                       50L * 128, 128L, (long)TROWS * 128);
    k_gemmz<0><<<ga, 256, 0, stream>>>(t1all, s_mW2, s_mb2, Cs, ftab_all, TROWS, 128, 128, 128,
                                       (long)TROWS * 128, 128L * 128, 128L, (long)TROWS * 128);
  }
  for (int l = 0; l < 6; ++l) {
    // x1b = bf16(hsb @ lin1W)
    run_mgemm_bf(stream, hsb, s1t + (size_t)l * 16384, nullptr, nullptr, nullptr, nullptr,
                 nullptr, x1b, NN, 128, 128, 0, 128, 128, 0);
    k_conv_gather3<<<NN / 4, 256, 0, stream>>>(ftab_all + (size_t)l * TROWS * 128, x1b, off3, s3s,
                                               id3s, fr3s, agg3b);
    run_mgemm_bf(stream, agg3b, s2t + (size_t)l * 16384, s_lin2b + l * 128, nullptr, nullptr,
                 nullptr, nullptr, sx2b, NN, 128, 128, 0, 128, 128, 2);
    run_mgemm_bf(stream, sx2b, s3t + (size_t)l * 16384, s_linb + l * 128, nullptr, nullptr, hs,
                 hs, hsb, NN, 128, 128, 128, 128, 128, 0);
  }

  // ---- fused head ----
  k_head2<<<NG, 256, 0, stream>>>(h2d, hs, goff, p2Wt, p2b, p3Wt, p3b, gW1t, gb1, gW2, gb2, cW1t,
                                  cb1, cW2t, cb2, (float*)d_out);
}

// Round 9
// 1753.640 us; speedup vs baseline: 5.6856x; 1.0186x over previous
//
#include <hip/hip_runtime.h>
#include <hip/hip_bf16.h>
#include <math.h>

#define NN 16384
#define NG 512
#define NE2 65536
#define NE3 393216
#define DEMB 300
#define DSCH 128
#define NRBF 50
#define NTAB 5120
#define TROWS 5121
#define DMAX 25.0f

typedef __attribute__((ext_vector_type(8))) short bf16x8;
typedef __attribute__((ext_vector_type(4))) float f32x4;

__device__ __forceinline__ float sspf(float x) {
  float sp = log1pf(expf(-fabsf(x))) + fmaxf(x, 0.f);
  return sp - 0.69314718055994530942f;
}

__device__ __forceinline__ short f2b(float f) {
  union { float f; unsigned u; } v;
  v.f = f;
  unsigned r = v.u + 0x7FFF + ((v.u >> 16) & 1);  // RNE
  return (short)(r >> 16);
}

__device__ __forceinline__ float b2f(unsigned short b) {
  union { unsigned u; float f; } v;
  v.u = ((unsigned)b) << 16;
  return v.f;
}

// ---------------- CSR build ----------------

__global__ void k_hist(const int* __restrict__ keys, int* __restrict__ cnt, int n) {
  int i = blockIdx.x * blockDim.x + threadIdx.x;
  if (i < n) atomicAdd(&cnt[keys[i]], 1);
}

__global__ __launch_bounds__(1024) void k_scan(const int* __restrict__ cnt, int* __restrict__ off,
                                               int n) {
  __shared__ int part[1024];
  int tid = threadIdx.x;
  int per = (n + 1023) / 1024;
  int base = tid * per;
  int sum = 0;
  for (int i = 0; i < per; ++i) {
    int idx = base + i;
    if (idx < n) sum += cnt[idx];
  }
  part[tid] = sum;
  __syncthreads();
  for (int d = 1; d < 1024; d <<= 1) {
    int v = (tid >= d) ? part[tid - d] : 0;
    __syncthreads();
    part[tid] += v;
    __syncthreads();
  }
  int run = (tid == 0) ? 0 : part[tid - 1];
  for (int i = 0; i < per; ++i) {
    int idx = base + i;
    if (idx < n) {
      off[idx] = run;
      run += cnt[idx];
    }
  }
  if (tid == 0) off[n] = part[1023];
}

__global__ void k_scatter2(const int* __restrict__ ei2, const int* __restrict__ ea2,
                           const int* __restrict__ off2, int* __restrict__ cur2,
                           int* __restrict__ s2s, int* __restrict__ ec2s) {
  int e = blockIdx.x * blockDim.x + threadIdx.x;
  if (e >= NE2) return;
  int d = ei2[NE2 + e];
  int p = atomicAdd(&cur2[d], 1);
  int j = off2[d] + p;
  s2s[j] = ei2[e];
  ec2s[j] = ea2[2 * e] * 4 + ea2[2 * e + 1];
}

__global__ void k_scatter3(const int* __restrict__ ei3, const float* __restrict__ pos,
                           const int* __restrict__ off3, int* __restrict__ cur3,
                           int* __restrict__ s3s, int* __restrict__ id3s,
                           float* __restrict__ fr3s) {
  int e = blockIdx.x * blockDim.x + threadIdx.x;
  if (e >= NE3) return;
  int s = ei3[e], d = ei3[NE3 + e];
  float dx = pos[3 * d] - pos[3 * s];
  float dy = pos[3 * d + 1] - pos[3 * s + 1];
  float dz = pos[3 * d + 2] - pos[3 * s + 2];
  float dist = sqrtf(dx * dx + dy * dy + dz * dz);
  float u = fminf(dist * ((float)NTAB / DMAX), (float)NTAB - 0.001f);
  int idx = (int)u;
  int p = atomicAdd(&cur3[d], 1);
  int j = off3[d] + p;
  s3s[j] = s;
  id3s[j] = idx;
  fr3s[j] = u - (float)idx;
}

// ---------------- small elementwise kernels ----------------

__global__ void k_hinit2(const int* __restrict__ x2d, const float* __restrict__ e1,
                         const float* __restrict__ e2, short* __restrict__ hb) {
  int i = blockIdx.x * blockDim.x + threadIdx.x;
  if (i >= NN * DEMB) return;
  int n = i / DEMB, c = i - n * DEMB;
  hb[i] = f2b(e1[x2d[2 * n] * DEMB + c] + e2[x2d[2 * n + 1] * DEMB + c]);
}

__global__ void k_vninit2(const float* __restrict__ vni, float* __restrict__ vn,
                          short* __restrict__ vnb) {
  int i = blockIdx.x * blockDim.x + threadIdx.x;
  if (i >= NG * DEMB) return;
  float v = vni[i % DEMB];
  vn[i] = v;
  vnb[i] = f2b(v);
}

__global__ void k_rbs(float* __restrict__ rbs, float* __restrict__ Cs) {
  int i = blockIdx.x * blockDim.x + threadIdx.x;
  if (i >= TROWS * NRBF) return;
  int j = i / NRBF, k = i - j * NRBF;
  float dj = (float)j * (DMAX / (float)NTAB);
  const float step = 10.0f / 49.0f;
  const float coeff = -0.5f / (step * step);
  float t = dj - (float)k * step;
  rbs[i] = expf(coeff * t * t);
  if (k == 0) Cs[j] = 0.5f * (cosf(dj * (3.14159265358979323846f / 10.0f)) + 1.0f);
}

__global__ void k_hsinit2(const int* __restrict__ z, const float* __restrict__ emb,
                          float* __restrict__ hs, short* __restrict__ hsb) {
  int i = blockIdx.x * blockDim.x + threadIdx.x;
  if (i >= NN * DSCH) return;
  float v = emb[z[i >> 7] * DSCH + (i & 127)];
  hs[i] = v;
  hsb[i] = f2b(v);
}

// ---------------- fused head v2 (pools bf16 hsb) ----------------
__global__ __launch_bounds__(256) void k_head2(
    const float* __restrict__ h2d, const short* __restrict__ hsb, const int* __restrict__ goff,
    const float* __restrict__ p2Wt, const float* __restrict__ p2b,
    const float* __restrict__ p3Wt, const float* __restrict__ p3b,
    const float* __restrict__ gW1t, const float* __restrict__ gb1,
    const float* __restrict__ gW2, const float* __restrict__ gb2,
    const float* __restrict__ cW1t, const float* __restrict__ cb1,
    const float* __restrict__ cW2t, const float* __restrict__ cb2, float* __restrict__ out) {
  __shared__ float sx[DEMB], sy[DSCH], h2p[DEMB], h3p[DEMB], ghl[DSCH], c1l[150];
  __shared__ float pa[2][128], pb[2][128];
  __shared__ float gshare;
  int g = blockIdx.x, tid = threadIdx.x;
  int half = tid >> 7, o7 = tid & 127;
  int r0 = goff[g], r1 = goff[g + 1];
  float inv = 1.0f / fmaxf((float)(r1 - r0), 1.0f);
  for (int i = tid; i < DEMB; i += 256) sx[i] = h2d[(size_t)g * DEMB + i];
  {
    float a = 0.f;
    for (int r = r0 + half; r < r1; r += 2) a += b2f(((const unsigned short*)hsb)[(size_t)r * DSCH + o7]);
    pa[half][o7] = a;
  }
  __syncthreads();
  if (half == 0) sy[o7] = (pa[0][o7] + pa[1][o7]) * inv;
  __syncthreads();
  for (int ob = 0; ob < DEMB; ob += 128) {
    int o = ob + o7;
    float a = 0.f, b = 0.f;
    if (o < DEMB) {
      const float* wr = p2Wt + (size_t)o * DEMB;
      for (int k = half * 150; k < half * 150 + 150; ++k) a = fmaf(sx[k], wr[k], a);
      const float* w3 = p3Wt + (size_t)o * DSCH;
      for (int k = half * 64; k < half * 64 + 64; ++k) b = fmaf(sy[k], w3[k], b);
    }
    pa[half][o7] = a;
    pb[half][o7] = b;
    __syncthreads();
    if (half == 0 && o < DEMB) {
      h2p[o] = pa[0][o7] + pa[1][o7] + p2b[o];
      h3p[o] = pb[0][o7] + pb[1][o7] + p3b[o];
    }
    __syncthreads();
  }
  {
    float a = 0.f;
    const float* wr = gW1t + (size_t)o7 * 600;
    if (half == 0) {
      for (int k = 0; k < 300; ++k) a = fmaf(h2p[k], wr[k], a);
    } else {
      for (int k = 0; k < 300; ++k) a = fmaf(h3p[k], wr[300 + k], a);
    }
    pa[half][o7] = a;
    __syncthreads();
    if (half == 0) ghl[o7] = fmaxf(pa[0][o7] + pa[1][o7] + gb1[o7], 0.f);
    __syncthreads();
  }
  if (tid < 128) pa[0][tid] = ghl[tid] * gW2[tid];
  __syncthreads();
  for (int s = 64; s > 0; s >>= 1) {
    if (tid < s) pa[0][tid] += pa[0][tid + s];
    __syncthreads();
  }
  if (tid == 0) gshare = 1.0f / (1.0f + expf(-(pa[0][0] + gb2[0])));
  __syncthreads();
  float gg = gshare;
  for (int i = tid; i < DEMB; i += 256) sx[i] = gg * h2p[i] + (1.0f - gg) * h3p[i];
  __syncthreads();
  for (int ob = 0; ob < 150; ob += 128) {
    int o = ob + o7;
    float a = 0.f;
    if (o < 150) {
      const float* wr = cW1t + (size_t)o * DEMB;
      for (int k = half * 150; k < half * 150 + 150; ++k) a = fmaf(sx[k], wr[k], a);
    }
    pa[half][o7] = a;
    __syncthreads();
    if (half == 0 && o < 150) c1l[o] = fmaxf(pa[0][o7] + pa[1][o7] + cb1[o], 0.f);
    __syncthreads();
  }
  if (tid < 12) {
    float a = cb2[tid];
    const float* wr = cW2t + (size_t)tid * 150;
    for (int k = 0; k < 150; ++k) a = fmaf(c1l[k], wr[k], a);
    out[(size_t)g * 12 + tid] = a;
  }
}

// ---------------- gather aggregations (bf16 node state) ----------------

__global__ __launch_bounds__(256) void k_gin_gather2b(
    const short* __restrict__ hb, const short* __restrict__ vnb, const int* __restrict__ batch,
    const int* __restrict__ off2, const int* __restrict__ s2s, const int* __restrict__ ec2s,
    const float* __restrict__ bond1, const float* __restrict__ bond2, short* __restrict__ aggb) {
  __shared__ float sb[9 * DEMB];
  int tid = threadIdx.x;
  for (int i = tid; i < 6 * DEMB; i += 256) sb[i] = bond1[i];
  for (int i = tid; i < 3 * DEMB; i += 256) sb[6 * DEMB + i] = bond2[i];
  __syncthreads();
  int d = blockIdx.x * 4 + (tid >> 6);
  int lane = tid & 63;
  int j0 = off2[d], j1 = off2[d + 1];
  const unsigned short* hd = (const unsigned short*)hb + (size_t)d * DEMB;
  const unsigned short* vd = (const unsigned short*)vnb + (size_t)batch[d] * DEMB;
  float acc[5];
#pragma unroll
  for (int q = 0; q < 5; ++q) {
    int col = lane + 64 * q;
    acc[q] = (col < DEMB) ? b2f(hd[col]) + b2f(vd[col]) : 0.f;
  }
  for (int j = j0; j < j1; ++j) {
    int s = s2s[j], ec = ec2s[j];
    const unsigned short* hr = (const unsigned short*)hb + (size_t)s * DEMB;
    const unsigned short* vr = (const unsigned short*)vnb + (size_t)batch[s] * DEMB;
    const float* b1 = sb + (ec >> 2) * DEMB;
    const float* b2 = sb + 6 * DEMB + (ec & 3) * DEMB;
#pragma unroll
    for (int q = 0; q < 5; ++q) {
      int col = lane + 64 * q;
      if (col < DEMB) acc[q] += fmaxf(b2f(hr[col]) + b2f(vr[col]) + b1[col] + b2[col], 0.f);
    }
  }
  short* outr = aggb + (size_t)d * 320;
#pragma unroll
  for (int q = 0; q < 5; ++q) {
    int col = lane + 64 * q;
    outr[col] = (col < DEMB) ? f2b(acc[q]) : (short)0;
  }
}

__global__ __launch_bounds__(256) void k_conv_gather3(
    const float* __restrict__ ftab, const short* __restrict__ x1b, const int* __restrict__ off3,
    const int* __restrict__ s3s, const int* __restrict__ id3s, const float* __restrict__ fr3s,
    short* __restrict__ agg3b) {
  int tid = threadIdx.x;
  int d = blockIdx.x * 4 + (tid >> 6);
  int lane = tid & 63;
  int j0 = off3[d], j1 = off3[d + 1];
  float a0 = 0.f, a1 = 0.f;
  for (int j = j0; j < j1; ++j) {
    int s = s3s[j], idx = id3s[j];
    float fr = fr3s[j];
    float2 t0 = ((const float2*)(ftab + (size_t)idx * 128))[lane];
    float2 t1 = ((const float2*)(ftab + (size_t)(idx + 1) * 128))[lane];
    unsigned xv = ((const unsigned*)(x1b + (size_t)s * 128))[lane];
    a0 += (t0.x + fr * (t1.x - t0.x)) * b2f((unsigned short)(xv & 0xFFFF));
    a1 += (t0.y + fr * (t1.y - t0.y)) * b2f((unsigned short)(xv >> 16));
  }
  unsigned pack = ((unsigned)(unsigned short)f2b(a1) << 16) | (unsigned short)f2b(a0);
  ((unsigned*)(agg3b + (size_t)d * 128))[lane] = pack;
}

// pool bf16 rows -> f32 out (mean)
__global__ __launch_bounds__(256) void k_poolb300(const short* __restrict__ xb,
                                                  const int* __restrict__ goff,
                                                  float* __restrict__ out) {
  int g = blockIdx.x * 4 + (threadIdx.x >> 6);
  int lane = threadIdx.x & 63;
  if (g >= NG) return;
  int r0 = goff[g], r1 = goff[g + 1];
  float acc[5] = {};
  for (int r = r0; r < r1; ++r) {
    const unsigned short* row = (const unsigned short*)xb + (size_t)r * DEMB;
#pragma unroll
    for (int q = 0; q < 5; ++q) {
      int col = lane + 64 * q;
      if (col < DEMB) acc[q] += b2f(row[col]);
    }
  }
  float s = 1.0f / fmaxf((float)(r1 - r0), 1.0f);
#pragma unroll
  for (int q = 0; q < 5; ++q) {
    int col = lane + 64 * q;
    if (col < DEMB) out[(size_t)g * DEMB + col] = acc[q] * s;
  }
}

// fused: vnab[g][320] = bf16( sum_rows(hb) + vn[g] ), padded
__global__ __launch_bounds__(256) void k_poolvn(const short* __restrict__ hb,
                                                const int* __restrict__ goff,
                                                const float* __restrict__ vn,
                                                short* __restrict__ vnab) {
  int g = blockIdx.x * 4 + (threadIdx.x >> 6);
  int lane = threadIdx.x & 63;
  if (g >= NG) return;
  int r0 = goff[g], r1 = goff[g + 1];
  float acc[5] = {};
  for (int r = r0; r < r1; ++r) {
    const unsigned short* row = (const unsigned short*)hb + (size_t)r * DEMB;
#pragma unroll
    for (int q = 0; q < 5; ++q) {
      int col = lane + 64 * q;
      if (col < DEMB) acc[q] += b2f(row[col]);
    }
  }
  short* outr = vnab + (size_t)g * 320;
#pragma unroll
  for (int q = 0; q < 5; ++q) {
    int col = lane + 64 * q;
    if (col < 320)
      outr[col] = (col < DEMB) ? f2b(acc[q] + vn[(size_t)g * DEMB + col]) : (short)0;
  }
}

// ---------------- weight prep ----------------
__global__ void k_prepw(const float* __restrict__ W, short* __restrict__ Wt, int K, int N, int Kp,
                        int Np, int L) {
  int i = blockIdx.x * blockDim.x + threadIdx.x;
  int per = Np * Kp;
  if (i >= L * per) return;
  int l = i / per, r = i - l * per;
  int n = r / Kp, k = r - n * Kp;
  float v = (n < N && k < K) ? W[(size_t)l * K * N + (size_t)k * N + n] : 0.f;
  Wt[i] = f2b(v);
}

__global__ void k_prepwt(const float* __restrict__ W, float* __restrict__ Wt, int K, int N) {
  int i = blockIdx.x * blockDim.x + threadIdx.x;
  if (i >= N * K) return;
  int n = i / K, k = i - n * K;
  Wt[i] = W[(size_t)k * N + n];
}

// ---------------- z-batched fp32 GEMM (64x64 tile) ----------------
template <int ACT>
__global__ __launch_bounds__(256) void k_gemmz(
    const float* __restrict__ A, const float* __restrict__ B, const float* __restrict__ bias,
    const float* __restrict__ rscale, float* __restrict__ Cout, int M, int N, int K, int ldc,
    long strideA, long strideB, long strideBias, long strideC) {
  A += (size_t)blockIdx.z * strideA;
  B += (size_t)blockIdx.z * strideB;
  bias += (size_t)blockIdx.z * strideBias;
  Cout += (size_t)blockIdx.z * strideC;
  __shared__ float sA[16][65];
  __shared__ float sB[16][64];
  int tid = threadIdx.x;
  int tx = tid & 15, ty = tid >> 4;
  int bm = blockIdx.y * 64, bn = blockIdx.x * 64;
  float acc[4][4] = {};
  for (int k0 = 0; k0 < K; k0 += 16) {
#pragma unroll
    for (int t = 0; t < 4; ++t) {
      int i = tid + t * 256;
      int m = i >> 4, kk = i & 15;
      int gm = bm + m, gk = k0 + kk;
      sA[kk][m] = (gm < M && gk < K) ? A[(size_t)gm * K + gk] : 0.f;
    }
#pragma unroll
    for (int t = 0; t < 4; ++t) {
      int i = tid + t * 256;
      int kk = i >> 6, n = i & 63;
      int gk = k0 + kk, gn = bn + n;
      sB[kk][n] = (gk < K && gn < N) ? B[(size_t)gk * N + gn] : 0.f;
    }
    __syncthreads();
#pragma unroll
    for (int kk = 0; kk < 16; ++kk) {
      float a[4], b[4];
#pragma unroll
      for (int i = 0; i < 4; ++i) a[i] = sA[kk][ty + 16 * i];
#pragma unroll
      for (int j = 0; j < 4; ++j) b[j] = sB[kk][tx + 16 * j];
#pragma unroll
      for (int i = 0; i < 4; ++i)
#pragma unroll
        for (int j = 0; j < 4; ++j) acc[i][j] = fmaf(a[i], b[j], acc[i][j]);
    }
    __syncthreads();
  }
#pragma unroll
  for (int i = 0; i < 4; ++i) {
    int gm = bm + ty + 16 * i;
    if (gm >= M) continue;
    float rs = rscale ? rscale[gm] : 1.0f;
#pragma unroll
    for (int j = 0; j < 4; ++j) {
      int gn = bn + tx + 16 * j;
      if (gn >= N) continue;
      float v = acc[i][j] + bias[gn];
      if (ACT == 1) v = fmaxf(v, 0.f);
      if (ACT == 2) v = sspf(v);
      Cout[(size_t)gm * ldc + gn] = v * rs;
    }
  }
}

// ---------------- bf16 MFMA GEMM with bf16-native A ----------------
template <int ACT>
__global__ __launch_bounds__(256) void k_mgemm_bf(
    const short* __restrict__ Ab, const short* __restrict__ Wt, const float* __restrict__ bias,
    const float* __restrict__ scale, const float* __restrict__ shift,
    const float* __restrict__ Cin, float* __restrict__ Cout, short* __restrict__ Coutb,
    int M, int N, int Kp, int ldc, int ldcb, int Nb) {
  __shared__ short sA[128 * 32];
  const int tid = threadIdx.x;
  const int lane = tid & 63;
  const int w = tid >> 6;
  const int wm = w >> 1, wn = w & 1;
  const int bm = blockIdx.y * 128, bn = blockIdx.x * 128;

  f32x4 acc[4][4] = {};

  const int sr = tid >> 1;
  const int sk = (tid & 1) * 16;
  const short* Arow = Ab + (size_t)(bm + sr) * Kp + sk;
  const int ssw = (sr + (sr >> 2)) & 3;
  const int s0 = (sk >> 3);
  bf16x8* sAv = (bf16x8*)sA;

  const int frow = wm * 64 + (lane & 15);
  const int fslot = lane >> 4;
  const short* Bbase = Wt + (size_t)(bn + wn * 64 + (lane & 15)) * Kp + (fslot * 8);

  for (int k0 = 0; k0 < Kp; k0 += 32) {
    __syncthreads();
    {
      bf16x8 p0 = *(const bf16x8*)(Arow + k0);
      bf16x8 p1 = *(const bf16x8*)(Arow + k0 + 8);
      sAv[sr * 4 + ((s0 + 0) ^ ssw)] = p0;
      sAv[sr * 4 + ((s0 + 1) ^ ssw)] = p1;
    }
    __syncthreads();

    bf16x8 af[4], bfr[4];
#pragma unroll
    for (int mf = 0; mf < 4; ++mf) {
      int r = frow + mf * 16;
      af[mf] = sAv[r * 4 + (fslot ^ ((r + (r >> 2)) & 3))];
    }
#pragma unroll
    for (int nf = 0; nf < 4; ++nf) bfr[nf] = *(const bf16x8*)(Bbase + (size_t)nf * 16 * Kp + k0);
#pragma unroll
    for (int mf = 0; mf < 4; ++mf)
#pragma unroll
      for (int nf = 0; nf < 4; ++nf)
        acc[mf][nf] =
            __builtin_amdgcn_mfma_f32_16x16x32_bf16(af[mf], bfr[nf], acc[mf][nf], 0, 0, 0);
  }

  const int colbase = bn + wn * 64 + (lane & 15);
  const int rowbase = bm + wm * 64 + ((lane >> 4) << 2);
#pragma unroll
  for (int nf = 0; nf < 4; ++nf) {
    int col = colbase + nf * 16;
    bool cv = col < N;
    float bi = (bias && cv) ? bias[col] : 0.f;
    float sc = (scale && cv) ? scale[col] : 1.f;
    float sh = (shift && cv) ? shift[col] : 0.f;
#pragma unroll
    for (int mf = 0; mf < 4; ++mf) {
      f32x4 v = acc[mf][nf];
#pragma unroll
      for (int j = 0; j < 4; ++j) {
        int row = rowbase + mf * 16 + j;
        float x = v[j] + bi;
        if (scale) x = x * sc + sh;
        if (ACT == 1) x = fmaxf(x, 0.f);
        if (ACT == 2) x = sspf(x);
        if (Cin && cv) x += Cin[(size_t)row * ldc + col];
        if (Cout && cv) Cout[(size_t)row * ldc + col] = x;
        if (Coutb && col < Nb) Coutb[(size_t)row * ldcb + col] = cv ? f2b(x) : (short)0;
      }
    }
  }
}

// ---------------- host ----------------

static inline void run_mgemm_bf(hipStream_t st, const short* Ab, const short* Wt,
                                const float* bias, const float* scale, const float* shift,
                                const float* Cin, float* Cout, short* Coutb, int M, int N, int Kp,
                                int ldc, int ldcb, int Nb, int act) {
  dim3 grid((N + 127) / 128, M / 128);
  if (act == 0)
    k_mgemm_bf<0><<<grid, 256, 0, st>>>(Ab, Wt, bias, scale, shift, Cin, Cout, Coutb, M, N, Kp,
                                        ldc, ldcb, Nb);
  else if (act == 1)
    k_mgemm_bf<1><<<grid, 256, 0, st>>>(Ab, Wt, bias, scale, shift, Cin, Cout, Coutb, M, N, Kp,
                                        ldc, ldcb, Nb);
  else
    k_mgemm_bf<2><<<grid, 256, 0, st>>>(Ab, Wt, bias, scale, shift, Cin, Cout, Coutb, M, N, Kp,
                                        ldc, ldcb, Nb);
}

extern "C" void kernel_launch(void* const* d_in, const int* in_sizes, int n_in, void* d_out,
                              int out_size, void* d_ws, size_t ws_size, hipStream_t stream) {
  const int* x2d = (const int*)d_in[0];
  const int* ei2 = (const int*)d_in[1];
  const int* ea2 = (const int*)d_in[2];
  const int* batch = (const int*)d_in[3];
  const int* z = (const int*)d_in[4];
  const float* pos = (const float*)d_in[5];
  const int* ei3 = (const int*)d_in[6];
  const float* atom_emb1 = (const float*)d_in[7];
  const float* atom_emb2 = (const float*)d_in[8];
  const float* vn_init = (const float*)d_in[9];
  const float* gin_W1 = (const float*)d_in[10];
  const float* gin_b1 = (const float*)d_in[11];
  const float* gin_W2 = (const float*)d_in[12];
  const float* gin_b2 = (const float*)d_in[13];
  const float* gin_bond1 = (const float*)d_in[14];
  const float* gin_bond2 = (const float*)d_in[15];
  const float* gin_gamma = (const float*)d_in[16];
  const float* gin_beta = (const float*)d_in[17];
  const float* vn_W1 = (const float*)d_in[18];
  const float* vn_b1 = (const float*)d_in[19];
  const float* vn_W2 = (const float*)d_in[20];
  const float* vn_b2 = (const float*)d_in[21];
  const float* sch_emb = (const float*)d_in[22];
  const float* s_mW1 = (const float*)d_in[23];
  const float* s_mb1 = (const float*)d_in[24];
  const float* s_mW2 = (const float*)d_in[25];
  const float* s_mb2 = (const float*)d_in[26];
  const float* s_lin1W = (const float*)d_in[27];
  const float* s_lin2W = (const float*)d_in[28];
  const float* s_lin2b = (const float*)d_in[29];
  const float* s_linW = (const float*)d_in[30];
  const float* s_linb = (const float*)d_in[31];
  const float* p2W = (const float*)d_in[32];
  const float* p2b = (const float*)d_in[33];
  const float* p3W = (const float*)d_in[34];
  const float* p3b = (const float*)d_in[35];
  const float* gW1 = (const float*)d_in[36];
  const float* gb1 = (const float*)d_in[37];
  const float* gW2 = (const float*)d_in[38];
  const float* gb2 = (const float*)d_in[39];
  const float* cW1 = (const float*)d_in[40];
  const float* cb1 = (const float*)d_in[41];
  const float* cW2 = (const float*)d_in[42];
  const float* cb2 = (const float*)d_in[43];

  float* ws = (float*)d_ws;
  // GIN phase
  short* hb = (short*)ws;                  // 16384*300 shorts -> 2.458M floats
  short* aggb = (short*)(ws + 5000000);    // 16384*320 shorts
  short* y1b = (short*)(ws + 7700000);     // 16384*608 shorts
  // SchNet phase (aliases GIN region; hb dead after h2d pool)
  float* rbs = ws + 400000;
  float* Cs = ws + 700000;
  float* t1all = ws + 800000;              // 6*5121*128
  float* ftab_all = ws + 4800000;
  float* hs = ws + 8800000;                // 16384*128
  short* x1b = (short*)(ws + 11000000);
  short* agg3b = (short*)(ws + 13200000);
  short* sx2b = (short*)(ws + 14300000);
  short* hsb = (short*)(ws + 15400000);
  // bf16 transposed weights
  short* W1t = (short*)(ws + 20000000);
  short* W2t = (short*)(ws + 20600000);
  short* s1t = (short*)(ws + 21200000);
  short* s2t = (short*)(ws + 21300000);
  short* s3t = (short*)(ws + 21400000);
  // head transposed f32 weights
  float* p2Wt = ws + 21500000;
  float* p3Wt = ws + 21600000;
  float* gW1t = ws + 21650000;
  float* cW1t = ws + 21730000;
  float* cW2t = ws + 21780000;
  // CSR region
  int* I = (int*)(ws + 22000000);
  int* cnt2 = I + 0;
  int* cnt3 = I + 16384;
  int* cntg = I + 32768;
  int* cur2 = I + 33280;
  int* cur3 = I + 49664;  // zero region = 66048 ints
  int* off2 = I + 70000;
  int* off3 = I + 90000;
  int* goff = I + 110000;
  int* s2s = I + 120000;
  int* ec2s = I + 190000;
  int* s3s = I + 260000;
  int* id3s = I + 660000;
  float* fr3s = (float*)(I + 1060000);
  // vn-MLP bf16 weights + buffers
  short* vnW1t = (short*)(ws + 23500000);
  short* vnW2t = (short*)(ws + 24000000);
  short* vnab = (short*)(ws + 24500000);   // 512*320 shorts
  short* vnhb = (short*)(ws + 24600000);   // 512*608 shorts
  short* vnb = (short*)(ws + 24800000);    // 512*300 shorts
  // persistent tail
  float* vn = ws + 28443136;
  float* h2d = ws + 29057536;

  // ---- weight prep ----
  k_prepw<<<(5 * 640 * 320 + 255) / 256, 256, 0, stream>>>(gin_W1, W1t, 300, 600, 320, 640, 5);
  k_prepw<<<(5 * 384 * 608 + 255) / 256, 256, 0, stream>>>(gin_W2, W2t, 600, 300, 608, 384, 5);
  k_prepw<<<(6 * 128 * 128 + 255) / 256, 256, 0, stream>>>(s_lin1W, s1t, 128, 128, 128, 128, 6);
  k_prepw<<<(6 * 128 * 128 + 255) / 256, 256, 0, stream>>>(s_lin2W, s2t, 128, 128, 128, 128, 6);
  k_prepw<<<(6 * 128 * 128 + 255) / 256, 256, 0, stream>>>(s_linW, s3t, 128, 128, 128, 128, 6);
  k_prepw<<<(4 * 640 * 320 + 255) / 256, 256, 0, stream>>>(vn_W1, vnW1t, 300, 600, 320, 640, 4);
  k_prepw<<<(4 * 384 * 608 + 255) / 256, 256, 0, stream>>>(vn_W2, vnW2t, 600, 300, 608, 384, 4);
  k_prepwt<<<(300 * 300 + 255) / 256, 256, 0, stream>>>(p2W, p2Wt, 300, 300);
  k_prepwt<<<(300 * 128 + 255) / 256, 256, 0, stream>>>(p3W, p3Wt, 128, 300);
  k_prepwt<<<(128 * 600 + 255) / 256, 256, 0, stream>>>(gW1, gW1t, 600, 128);
  k_prepwt<<<(150 * 300 + 255) / 256, 256, 0, stream>>>(cW1, cW1t, 300, 150);
  k_prepwt<<<(12 * 150 + 255) / 256, 256, 0, stream>>>(cW2, cW2t, 150, 12);

  // ---- CSR build ----
  hipMemsetAsync(I, 0, 66048 * sizeof(int), stream);
  k_hist<<<(NE2 + 255) / 256, 256, 0, stream>>>(ei2 + NE2, cnt2, NE2);
  k_hist<<<(NE3 + 255) / 256, 256, 0, stream>>>(ei3 + NE3, cnt3, NE3);
  k_hist<<<(NN + 255) / 256, 256, 0, stream>>>(batch, cntg, NN);
  k_scan<<<1, 1024, 0, stream>>>(cnt2, off2, 16384);
  k_scan<<<1, 1024, 0, stream>>>(cnt3, off3, 16384);
  k_scan<<<1, 1024, 0, stream>>>(cntg, goff, 512);
  k_scatter2<<<(NE2 + 255) / 256, 256, 0, stream>>>(ei2, ea2, off2, cur2, s2s, ec2s);
  k_scatter3<<<(NE3 + 255) / 256, 256, 0, stream>>>(ei3, pos, off3, cur3, s3s, id3s, fr3s);

  // ---- GIN (node state carried in bf16 hb) ----
  k_hinit2<<<(NN * DEMB + 255) / 256, 256, 0, stream>>>(x2d, atom_emb1, atom_emb2, hb);
  k_vninit2<<<(NG * DEMB + 255) / 256, 256, 0, stream>>>(vn_init, vn, vnb);
  for (int l = 0; l < 5; ++l) {
    k_gin_gather2b<<<NN / 4, 256, 0, stream>>>(hb, vnb, batch, off2, s2s, ec2s,
                                               gin_bond1 + l * 6 * DEMB,
                                               gin_bond2 + l * 3 * DEMB, aggb);
    run_mgemm_bf(stream, aggb, W1t + (size_t)l * 640 * 320, gin_b1 + l * 600, nullptr, nullptr,
                 nullptr, nullptr, y1b, NN, 600, 320, 0, 608, 608, 1);
    // hb = bf16([relu] BN(y1b @ W2 + b2))
    run_mgemm_bf(stream, y1b, W2t + (size_t)l * 384 * 608, gin_b2 + l * 300, gin_gamma + l * 300,
                 gin_beta + l * 300, nullptr, nullptr, hb, NN, 300, 608, 0, 300, 300,
                 (l < 4) ? 1 : 0);
    if (l < 4) {
      k_poolvn<<<NG / 4, 256, 0, stream>>>(hb, goff, vn, vnab);
      run_mgemm_bf(stream, vnab, vnW1t + (size_t)l * 640 * 320, vn_b1 + l * 600, nullptr, nullptr,
                   nullptr, nullptr, vnhb, NG, 600, 320, 0, 608, 608, 1);
      // vn (f32) + vnb (bf16)
      run_mgemm_bf(stream, vnhb, vnW2t + (size_t)l * 384 * 608, vn_b2 + l * 300, nullptr, nullptr,
                   nullptr, vn, vnb, NG, 300, 608, 300, 300, 300, 1);
    }
  }
  k_poolb300<<<NG / 4, 256, 0, stream>>>(hb, goff, h2d);  // before SchNet clobbers hb region

  // ---- SchNet ----
  k_rbs<<<(TROWS * NRBF + 255) / 256, 256, 0, stream>>>(rbs, Cs);
  k_hsinit2<<<(NN * DSCH + 255) / 256, 256, 0, stream>>>(z, sch_emb, hs, hsb);
  {
    dim3 ga(2, (TROWS + 63) / 64, 6);
    k_gemmz<2><<<ga, 256, 0, stream>>>(rbs, s_mW1, s_mb1, nullptr, t1all, TROWS, 128, 50, 128, 0L,
                                       50L * 128, 128L, (long)TROWS * 128);
    k_gemmz<0><<<ga, 256, 0, stream>>>(t1all, s_mW2, s_mb2, Cs, ftab_all, TROWS, 128, 128, 128,
                                       (long)TROWS * 128, 128L * 128, 128L, (long)TROWS * 128);
  }
  for (int l = 0; l < 6; ++l) {
    run_mgemm_bf(stream, hsb, s1t + (size_t)l * 16384, nullptr, nullptr, nullptr, nullptr,
                 nullptr, x1b, NN, 128, 128, 0, 128, 128, 0);
    k_conv_gather3<<<NN / 4, 256, 0, stream>>>(ftab_all + (size_t)l * TROWS * 128, x1b, off3, s3s,
                                               id3s, fr3s, agg3b);
    run_mgemm_bf(stream, agg3b, s2t + (size_t)l * 16384, s_lin2b + l * 128, nullptr, nullptr,
                 nullptr, nullptr, sx2b, NN, 128, 128, 0, 128, 128, 2);
    run_mgemm_bf(stream, sx2b, s3t + (size_t)l * 16384, s_linb + l * 128, nullptr, nullptr, hs,
                 hs, hsb, NN, 128, 128, 128, 128, 128, 0);
  }

  // ---- fused head ----
  k_head2<<<NG, 256, 0, stream>>>(h2d, hsb, goff, p2Wt, p2b, p3Wt, p3b, gW1t, gb1, gW2, gb2, cW1t,
                                  cb1, cW2t, cb2, (float*)d_out);
}

// Round 10
// 1556.938 us; speedup vs baseline: 6.4039x; 1.1263x over previous
//
#include <hip/hip_runtime.h>
#include <hip/hip_bf16.h>
#include <math.h>

#define NN 16384
#define NG 512
#define NE2 65536
#define NE3 393216
#define DEMB 300
#define DSCH 128
#define NRBF 50
#define NTAB 5120
#define TROWS 5121
#define DMAX 25.0f

typedef __attribute__((ext_vector_type(8))) short bf16x8;
typedef __attribute__((ext_vector_type(4))) float f32x4;

__device__ __forceinline__ float sspf(float x) {
  float sp = log1pf(expf(-fabsf(x))) + fmaxf(x, 0.f);
  return sp - 0.69314718055994530942f;
}

__device__ __forceinline__ short f2b(float f) {
  union { float f; unsigned u; } v;
  v.f = f;
  unsigned r = v.u + 0x7FFF + ((v.u >> 16) & 1);  // RNE
  return (short)(r >> 16);
}

__device__ __forceinline__ float b2f(unsigned short b) {
  union { unsigned u; float f; } v;
  v.u = ((unsigned)b) << 16;
  return v.f;
}

// ---------------- CSR build ----------------

__global__ void k_hist(const int* __restrict__ keys, int* __restrict__ cnt, int n) {
  int i = blockIdx.x * blockDim.x + threadIdx.x;
  if (i < n) atomicAdd(&cnt[keys[i]], 1);
}

__global__ __launch_bounds__(1024) void k_scan(const int* __restrict__ cnt, int* __restrict__ off,
                                               int n) {
  __shared__ int part[1024];
  int tid = threadIdx.x;
  int per = (n + 1023) / 1024;
  int base = tid * per;
  int sum = 0;
  for (int i = 0; i < per; ++i) {
    int idx = base + i;
    if (idx < n) sum += cnt[idx];
  }
  part[tid] = sum;
  __syncthreads();
  for (int d = 1; d < 1024; d <<= 1) {
    int v = (tid >= d) ? part[tid - d] : 0;
    __syncthreads();
    part[tid] += v;
    __syncthreads();
  }
  int run = (tid == 0) ? 0 : part[tid - 1];
  for (int i = 0; i < per; ++i) {
    int idx = base + i;
    if (idx < n) {
      off[idx] = run;
      run += cnt[idx];
    }
  }
  if (tid == 0) off[n] = part[1023];
}

__global__ void k_scatter2(const int* __restrict__ ei2, const int* __restrict__ ea2,
                           const int* __restrict__ off2, int* __restrict__ cur2,
                           int* __restrict__ s2s, int* __restrict__ ec2s) {
  int e = blockIdx.x * blockDim.x + threadIdx.x;
  if (e >= NE2) return;
  int d = ei2[NE2 + e];
  int p = atomicAdd(&cur2[d], 1);
  int j = off2[d] + p;
  s2s[j] = ei2[e];
  ec2s[j] = ea2[2 * e] * 4 + ea2[2 * e + 1];
}

__global__ void k_scatter3(const int* __restrict__ ei3, const float* __restrict__ pos,
                           const int* __restrict__ off3, int* __restrict__ cur3,
                           int* __restrict__ s3s, int* __restrict__ id3s,
                           float* __restrict__ fr3s) {
  int e = blockIdx.x * blockDim.x + threadIdx.x;
  if (e >= NE3) return;
  int s = ei3[e], d = ei3[NE3 + e];
  float dx = pos[3 * d] - pos[3 * s];
  float dy = pos[3 * d + 1] - pos[3 * s + 1];
  float dz = pos[3 * d + 2] - pos[3 * s + 2];
  float dist = sqrtf(dx * dx + dy * dy + dz * dz);
  float u = fminf(dist * ((float)NTAB / DMAX), (float)NTAB - 0.001f);
  int idx = (int)u;
  int p = atomicAdd(&cur3[d], 1);
  int j = off3[d] + p;
  s3s[j] = s;
  id3s[j] = idx;
  fr3s[j] = u - (float)idx;
}

// ---------------- small elementwise kernels ----------------

__global__ void k_hinit2(const int* __restrict__ x2d, const float* __restrict__ e1,
                         const float* __restrict__ e2, short* __restrict__ hb) {
  int i = blockIdx.x * blockDim.x + threadIdx.x;
  if (i >= NN * DEMB) return;
  int n = i / DEMB, c = i - n * DEMB;
  hb[i] = f2b(e1[x2d[2 * n] * DEMB + c] + e2[x2d[2 * n + 1] * DEMB + c]);
}

__global__ void k_vninit2(const float* __restrict__ vni, float* __restrict__ vn,
                          short* __restrict__ vnb) {
  int i = blockIdx.x * blockDim.x + threadIdx.x;
  if (i >= NG * DEMB) return;
  float v = vni[i % DEMB];
  vn[i] = v;
  vnb[i] = f2b(v);
}

// hvb[n] = bf16(hb[n] + vnb[batch[n]])
__global__ void k_addvnb(const short* __restrict__ hb, const short* __restrict__ vnb,
                         const int* __restrict__ batch, short* __restrict__ hvb) {
  int i = blockIdx.x * blockDim.x + threadIdx.x;
  if (i >= NN * DEMB) return;
  int n = i / DEMB, c = i - n * DEMB;
  hvb[i] = f2b(b2f(((const unsigned short*)hb)[i]) +
               b2f(((const unsigned short*)vnb)[batch[n] * DEMB + c]));
}

__global__ void k_rbs(float* __restrict__ rbs, float* __restrict__ Cs) {
  int i = blockIdx.x * blockDim.x + threadIdx.x;
  if (i >= TROWS * NRBF) return;
  int j = i / NRBF, k = i - j * NRBF;
  float dj = (float)j * (DMAX / (float)NTAB);
  const float step = 10.0f / 49.0f;
  const float coeff = -0.5f / (step * step);
  float t = dj - (float)k * step;
  rbs[i] = expf(coeff * t * t);
  if (k == 0) Cs[j] = 0.5f * (cosf(dj * (3.14159265358979323846f / 10.0f)) + 1.0f);
}

__global__ void k_hsinit2(const int* __restrict__ z, const float* __restrict__ emb,
                          float* __restrict__ hs, short* __restrict__ hsb) {
  int i = blockIdx.x * blockDim.x + threadIdx.x;
  if (i >= NN * DSCH) return;
  float v = emb[z[i >> 7] * DSCH + (i & 127)];
  hs[i] = v;
  hsb[i] = f2b(v);
}

// ---------------- fused head v3 (h3d precomputed) ----------------
__global__ __launch_bounds__(256) void k_head3(
    const float* __restrict__ h2d, const float* __restrict__ h3d,
    const float* __restrict__ p2Wt, const float* __restrict__ p2b,
    const float* __restrict__ p3Wt, const float* __restrict__ p3b,
    const float* __restrict__ gW1t, const float* __restrict__ gb1,
    const float* __restrict__ gW2, const float* __restrict__ gb2,
    const float* __restrict__ cW1t, const float* __restrict__ cb1,
    const float* __restrict__ cW2t, const float* __restrict__ cb2, float* __restrict__ out) {
  __shared__ float sx[DEMB], sy[DSCH], h2p[DEMB], h3p[DEMB], ghl[DSCH], c1l[150];
  __shared__ float pa[2][128], pb[2][128];
  __shared__ float gshare;
  int g = blockIdx.x, tid = threadIdx.x;
  int half = tid >> 7, o7 = tid & 127;
  for (int i = tid; i < DEMB; i += 256) sx[i] = h2d[(size_t)g * DEMB + i];
  if (tid < DSCH) sy[tid] = h3d[(size_t)g * DSCH + tid];
  __syncthreads();
  for (int ob = 0; ob < DEMB; ob += 128) {
    int o = ob + o7;
    float a = 0.f, b = 0.f;
    if (o < DEMB) {
      const float* wr = p2Wt + (size_t)o * DEMB;
      for (int k = half * 150; k < half * 150 + 150; ++k) a = fmaf(sx[k], wr[k], a);
      const float* w3 = p3Wt + (size_t)o * DSCH;
      for (int k = half * 64; k < half * 64 + 64; ++k) b = fmaf(sy[k], w3[k], b);
    }
    pa[half][o7] = a;
    pb[half][o7] = b;
    __syncthreads();
    if (half == 0 && o < DEMB) {
      h2p[o] = pa[0][o7] + pa[1][o7] + p2b[o];
      h3p[o] = pb[0][o7] + pb[1][o7] + p3b[o];
    }
    __syncthreads();
  }
  {
    float a = 0.f;
    const float* wr = gW1t + (size_t)o7 * 600;
    if (half == 0) {
      for (int k = 0; k < 300; ++k) a = fmaf(h2p[k], wr[k], a);
    } else {
      for (int k = 0; k < 300; ++k) a = fmaf(h3p[k], wr[300 + k], a);
    }
    pa[half][o7] = a;
    __syncthreads();
    if (half == 0) ghl[o7] = fmaxf(pa[0][o7] + pa[1][o7] + gb1[o7], 0.f);
    __syncthreads();
  }
  if (tid < 128) pa[0][tid] = ghl[tid] * gW2[tid];
  __syncthreads();
  for (int s = 64; s > 0; s >>= 1) {
    if (tid < s) pa[0][tid] += pa[0][tid + s];
    __syncthreads();
  }
  if (tid == 0) gshare = 1.0f / (1.0f + expf(-(pa[0][0] + gb2[0])));
  __syncthreads();
  float gg = gshare;
  for (int i = tid; i < DEMB; i += 256) sx[i] = gg * h2p[i] + (1.0f - gg) * h3p[i];
  __syncthreads();
  for (int ob = 0; ob < 150; ob += 128) {
    int o = ob + o7;
    float a = 0.f;
    if (o < 150) {
      const float* wr = cW1t + (size_t)o * DEMB;
      for (int k = half * 150; k < half * 150 + 150; ++k) a = fmaf(sx[k], wr[k], a);
    }
    pa[half][o7] = a;
    __syncthreads();
    if (half == 0 && o < 150) c1l[o] = fmaxf(pa[0][o7] + pa[1][o7] + cb1[o], 0.f);
    __syncthreads();
  }
  if (tid < 12) {
    float a = cb2[tid];
    const float* wr = cW2t + (size_t)tid * 150;
    for (int k = 0; k < 150; ++k) a = fmaf(c1l[k], wr[k], a);
    out[(size_t)g * 12 + tid] = a;
  }
}

// ---------------- gather aggregations ----------------

// GIN with pre-added hvb: aggb[d] = bf16( hvb[d] + sum_e relu(hvb[src] + eemb) )
__global__ __launch_bounds__(256) void k_gin_gather3(
    const short* __restrict__ hvb, const int* __restrict__ off2, const int* __restrict__ s2s,
    const int* __restrict__ ec2s, const float* __restrict__ bond1, const float* __restrict__ bond2,
    short* __restrict__ aggb) {
  __shared__ float sb[9 * DEMB];
  int tid = threadIdx.x;
  for (int i = tid; i < 6 * DEMB; i += 256) sb[i] = bond1[i];
  for (int i = tid; i < 3 * DEMB; i += 256) sb[6 * DEMB + i] = bond2[i];
  __syncthreads();
  int d = blockIdx.x * 4 + (tid >> 6);
  int lane = tid & 63;
  int j0 = off2[d], j1 = off2[d + 1];
  const unsigned short* hd = (const unsigned short*)hvb + (size_t)d * DEMB;
  float acc[5];
#pragma unroll
  for (int q = 0; q < 5; ++q) {
    int col = lane + 64 * q;
    acc[q] = (col < DEMB) ? b2f(hd[col]) : 0.f;
  }
  for (int j = j0; j < j1; ++j) {
    int s = s2s[j], ec = ec2s[j];
    const unsigned short* hr = (const unsigned short*)hvb + (size_t)s * DEMB;
    const float* b1 = sb + (ec >> 2) * DEMB;
    const float* b2 = sb + 6 * DEMB + (ec & 3) * DEMB;
#pragma unroll
    for (int q = 0; q < 5; ++q) {
      int col = lane + 64 * q;
      if (col < DEMB) acc[q] += fmaxf(b2f(hr[col]) + b1[col] + b2[col], 0.f);
    }
  }
  short* outr = aggb + (size_t)d * 320;
#pragma unroll
  for (int q = 0; q < 5; ++q) {
    int col = lane + 64 * q;
    outr[col] = (col < DEMB) ? f2b(acc[q]) : (short)0;
  }
}

// CFConv with bf16 table + bf16 x1
__global__ __launch_bounds__(256) void k_conv_gather4(
    const short* __restrict__ ftabb, const short* __restrict__ x1b, const int* __restrict__ off3,
    const int* __restrict__ s3s, const int* __restrict__ id3s, const float* __restrict__ fr3s,
    short* __restrict__ agg3b) {
  int tid = threadIdx.x;
  int d = blockIdx.x * 4 + (tid >> 6);
  int lane = tid & 63;
  int j0 = off3[d], j1 = off3[d + 1];
  float a0 = 0.f, a1 = 0.f;
  for (int j = j0; j < j1; ++j) {
    int s = s3s[j], idx = id3s[j];
    float fr = fr3s[j];
    unsigned t0 = ((const unsigned*)(ftabb + (size_t)idx * 128))[lane];
    unsigned t1 = ((const unsigned*)(ftabb + (size_t)(idx + 1) * 128))[lane];
    unsigned xv = ((const unsigned*)(x1b + (size_t)s * 128))[lane];
    float t0a = b2f((unsigned short)(t0 & 0xFFFF)), t0b = b2f((unsigned short)(t0 >> 16));
    float t1a = b2f((unsigned short)(t1 & 0xFFFF)), t1b = b2f((unsigned short)(t1 >> 16));
    a0 += (t0a + fr * (t1a - t0a)) * b2f((unsigned short)(xv & 0xFFFF));
    a1 += (t0b + fr * (t1b - t0b)) * b2f((unsigned short)(xv >> 16));
  }
  unsigned pack = ((unsigned)(unsigned short)f2b(a1) << 16) | (unsigned short)f2b(a0);
  ((unsigned*)(agg3b + (size_t)d * 128))[lane] = pack;
}

// pool bf16 rows [*,300] -> f32 mean
__global__ __launch_bounds__(256) void k_poolb300(const short* __restrict__ xb,
                                                  const int* __restrict__ goff,
                                                  float* __restrict__ out) {
  int g = blockIdx.x * 4 + (threadIdx.x >> 6);
  int lane = threadIdx.x & 63;
  if (g >= NG) return;
  int r0 = goff[g], r1 = goff[g + 1];
  float acc[5] = {};
  for (int r = r0; r < r1; ++r) {
    const unsigned short* row = (const unsigned short*)xb + (size_t)r * DEMB;
#pragma unroll
    for (int q = 0; q < 5; ++q) {
      int col = lane + 64 * q;
      if (col < DEMB) acc[q] += b2f(row[col]);
    }
  }
  float s = 1.0f / fmaxf((float)(r1 - r0), 1.0f);
#pragma unroll
  for (int q = 0; q < 5; ++q) {
    int col = lane + 64 * q;
    if (col < DEMB) out[(size_t)g * DEMB + col] = acc[q] * s;
  }
}

// pool bf16 rows [*,128] -> f32 mean (one wave per graph)
__global__ __launch_bounds__(256) void k_poolb128(const short* __restrict__ xb,
                                                  const int* __restrict__ goff,
                                                  float* __restrict__ out) {
  int g = blockIdx.x * 4 + (threadIdx.x >> 6);
  int lane = threadIdx.x & 63;
  if (g >= NG) return;
  int r0 = goff[g], r1 = goff[g + 1];
  float a0 = 0.f, a1 = 0.f;
  for (int r = r0; r < r1; ++r) {
    unsigned v = ((const unsigned*)(xb + (size_t)r * DSCH))[lane];
    a0 += b2f((unsigned short)(v & 0xFFFF));
    a1 += b2f((unsigned short)(v >> 16));
  }
  float s = 1.0f / fmaxf((float)(r1 - r0), 1.0f);
  out[(size_t)g * DSCH + lane * 2] = a0 * s;
  out[(size_t)g * DSCH + lane * 2 + 1] = a1 * s;
}

// fused: vnab[g][320] = bf16( sum_rows(hb) + vn[g] )
__global__ __launch_bounds__(256) void k_poolvn(const short* __restrict__ hb,
                                                const int* __restrict__ goff,
                                                const float* __restrict__ vn,
                                                short* __restrict__ vnab) {
  int g = blockIdx.x * 4 + (threadIdx.x >> 6);
  int lane = threadIdx.x & 63;
  if (g >= NG) return;
  int r0 = goff[g], r1 = goff[g + 1];
  float acc[5] = {};
  for (int r = r0; r < r1; ++r) {
    const unsigned short* row = (const unsigned short*)hb + (size_t)r * DEMB;
#pragma unroll
    for (int q = 0; q < 5; ++q) {
      int col = lane + 64 * q;
      if (col < DEMB) acc[q] += b2f(row[col]);
    }
  }
  short* outr = vnab + (size_t)g * 320;
#pragma unroll
  for (int q = 0; q < 5; ++q) {
    int col = lane + 64 * q;
    if (col < 320)
      outr[col] = (col < DEMB) ? f2b(acc[q] + vn[(size_t)g * DEMB + col]) : (short)0;
  }
}

// ---------------- weight prep ----------------
__global__ void k_prepw(const float* __restrict__ W, short* __restrict__ Wt, int K, int N, int Kp,
                        int Np, int L) {
  int i = blockIdx.x * blockDim.x + threadIdx.x;
  int per = Np * Kp;
  if (i >= L * per) return;
  int l = i / per, r = i - l * per;
  int n = r / Kp, k = r - n * Kp;
  float v = (n < N && k < K) ? W[(size_t)l * K * N + (size_t)k * N + n] : 0.f;
  Wt[i] = f2b(v);
}

__global__ void k_prepwt(const float* __restrict__ W, float* __restrict__ Wt, int K, int N) {
  int i = blockIdx.x * blockDim.x + threadIdx.x;
  if (i >= N * K) return;
  int n = i / K, k = i - n * K;
  Wt[i] = W[(size_t)k * N + n];
}

// ---------------- z-batched fp32 GEMM; optional bf16 output ----------------
template <int ACT>
__global__ __launch_bounds__(256) void k_gemmz(
    const float* __restrict__ A, const float* __restrict__ B, const float* __restrict__ bias,
    const float* __restrict__ rscale, float* __restrict__ Cout, short* __restrict__ Coutb,
    int M, int N, int K, int ldc, long strideA, long strideB, long strideBias, long strideC) {
  A += (size_t)blockIdx.z * strideA;
  B += (size_t)blockIdx.z * strideB;
  bias += (size_t)blockIdx.z * strideBias;
  __shared__ float sA[16][65];
  __shared__ float sB[16][64];
  int tid = threadIdx.x;
  int tx = tid & 15, ty = tid >> 4;
  int bm = blockIdx.y * 64, bn = blockIdx.x * 64;
  float acc[4][4] = {};
  for (int k0 = 0; k0 < K; k0 += 16) {
#pragma unroll
    for (int t = 0; t < 4; ++t) {
      int i = tid + t * 256;
      int m = i >> 4, kk = i & 15;
      int gm = bm + m, gk = k0 + kk;
      sA[kk][m] = (gm < M && gk < K) ? A[(size_t)gm * K + gk] : 0.f;
    }
#pragma unroll
    for (int t = 0; t < 4; ++t) {
      int i = tid + t * 256;
      int kk = i >> 6, n = i & 63;
      int gk = k0 + kk, gn = bn + n;
      sB[kk][n] = (gk < K && gn < N) ? B[(size_t)gk * N + gn] : 0.f;
    }
    __syncthreads();
#pragma unroll
    for (int kk = 0; kk < 16; ++kk) {
      float a[4], b[4];
#pragma unroll
      for (int i = 0; i < 4; ++i) a[i] = sA[kk][ty + 16 * i];
#pragma unroll
      for (int j = 0; j < 4; ++j) b[j] = sB[kk][tx + 16 * j];
#pragma unroll
      for (int i = 0; i < 4; ++i)
#pragma unroll
        for (int j = 0; j < 4; ++j) acc[i][j] = fmaf(a[i], b[j], acc[i][j]);
    }
    __syncthreads();
  }
#pragma unroll
  for (int i = 0; i < 4; ++i) {
    int gm = bm + ty + 16 * i;
    if (gm >= M) continue;
    float rs = rscale ? rscale[gm] : 1.0f;
#pragma unroll
    for (int j = 0; j < 4; ++j) {
      int gn = bn + tx + 16 * j;
      if (gn >= N) continue;
      float v = acc[i][j] + bias[gn];
      if (ACT == 1) v = fmaxf(v, 0.f);
      if (ACT == 2) v = sspf(v);
      v *= rs;
      if (Cout) Cout[(size_t)blockIdx.z * strideC + (size_t)gm * ldc + gn] = v;
      if (Coutb) Coutb[(size_t)blockIdx.z * strideC + (size_t)gm * ldc + gn] = f2b(v);
    }
  }
}

// ---------------- bf16 MFMA GEMM, 128x128 tile ----------------
template <int ACT>
__global__ __launch_bounds__(256) void k_mgemm_bf(
    const short* __restrict__ Ab, const short* __restrict__ Wt, const float* __restrict__ bias,
    const float* __restrict__ scale, const float* __restrict__ shift,
    const float* __restrict__ Cin, float* __restrict__ Cout, short* __restrict__ Coutb,
    int M, int N, int Kp, int ldc, int ldcb, int Nb) {
  __shared__ short sA[128 * 32];
  const int tid = threadIdx.x;
  const int lane = tid & 63;
  const int w = tid >> 6;
  const int wm = w >> 1, wn = w & 1;
  const int bm = blockIdx.y * 128, bn = blockIdx.x * 128;

  f32x4 acc[4][4] = {};

  const int sr = tid >> 1;
  const int sk = (tid & 1) * 16;
  const short* Arow = Ab + (size_t)(bm + sr) * Kp + sk;
  const int ssw = (sr + (sr >> 2)) & 3;
  const int s0 = (sk >> 3);
  bf16x8* sAv = (bf16x8*)sA;

  const int frow = wm * 64 + (lane & 15);
  const int fslot = lane >> 4;
  const short* Bbase = Wt + (size_t)(bn + wn * 64 + (lane & 15)) * Kp + (fslot * 8);

  for (int k0 = 0; k0 < Kp; k0 += 32) {
    __syncthreads();
    {
      bf16x8 p0 = *(const bf16x8*)(Arow + k0);
      bf16x8 p1 = *(const bf16x8*)(Arow + k0 + 8);
      sAv[sr * 4 + ((s0 + 0) ^ ssw)] = p0;
      sAv[sr * 4 + ((s0 + 1) ^ ssw)] = p1;
    }
    __syncthreads();

    bf16x8 af[4], bfr[4];
#pragma unroll
    for (int mf = 0; mf < 4; ++mf) {
      int r = frow + mf * 16;
      af[mf] = sAv[r * 4 + (fslot ^ ((r + (r >> 2)) & 3))];
    }
#pragma unroll
    for (int nf = 0; nf < 4; ++nf) bfr[nf] = *(const bf16x8*)(Bbase + (size_t)nf * 16 * Kp + k0);
#pragma unroll
    for (int mf = 0; mf < 4; ++mf)
#pragma unroll
      for (int nf = 0; nf < 4; ++nf)
        acc[mf][nf] =
            __builtin_amdgcn_mfma_f32_16x16x32_bf16(af[mf], bfr[nf], acc[mf][nf], 0, 0, 0);
  }

  const int colbase = bn + wn * 64 + (lane & 15);
  const int rowbase = bm + wm * 64 + ((lane >> 4) << 2);
#pragma unroll
  for (int nf = 0; nf < 4; ++nf) {
    int col = colbase + nf * 16;
    bool cv = col < N;
    float bi = (bias && cv) ? bias[col] : 0.f;
    float sc = (scale && cv) ? scale[col] : 1.f;
    float sh = (shift && cv) ? shift[col] : 0.f;
#pragma unroll
    for (int mf = 0; mf < 4; ++mf) {
      f32x4 v = acc[mf][nf];
#pragma unroll
      for (int j = 0; j < 4; ++j) {
        int row = rowbase + mf * 16 + j;
        float x = v[j] + bi;
        if (scale) x = x * sc + sh;
        if (ACT == 1) x = fmaxf(x, 0.f);
        if (ACT == 2) x = sspf(x);
        if (Cin && cv) x += Cin[(size_t)row * ldc + col];
        if (Cout && cv) Cout[(size_t)row * ldc + col] = x;
        if (Coutb && col < Nb) Coutb[(size_t)row * ldcb + col] = cv ? f2b(x) : (short)0;
      }
    }
  }
}

// ---------------- bf16 MFMA GEMM, 64x128 tile (4 waves = 1x4 col groups) ----------------
template <int ACT>
__global__ __launch_bounds__(256) void k_mgemm_bf64(
    const short* __restrict__ Ab, const short* __restrict__ Wt, const float* __restrict__ bias,
    const float* __restrict__ scale, const float* __restrict__ shift,
    const float* __restrict__ Cin, float* __restrict__ Cout, short* __restrict__ Coutb,
    int M, int N, int Kp, int ldc, int ldcb, int Nb) {
  __shared__ short sA[64 * 32];
  const int tid = threadIdx.x;
  const int lane = tid & 63;
  const int w = tid >> 6;  // col group 0..3
  const int bm = blockIdx.y * 64, bn = blockIdx.x * 128;

  f32x4 acc[4][2] = {};

  const int sr = tid >> 2;
  const int sk = (tid & 3) * 8;
  const short* Arow = Ab + (size_t)(bm + sr) * Kp + sk;
  const int ssw = (sr + (sr >> 2)) & 3;
  const int s0 = tid & 3;
  bf16x8* sAv = (bf16x8*)sA;

  const int frow = lane & 15;
  const int fslot = lane >> 4;
  const short* Bbase = Wt + (size_t)(bn + w * 32 + (lane & 15)) * Kp + (fslot * 8);

  for (int k0 = 0; k0 < Kp; k0 += 32) {
    __syncthreads();
    sAv[sr * 4 + (s0 ^ ssw)] = *(const bf16x8*)(Arow + k0);
    __syncthreads();

    bf16x8 af[4], bfr[2];
#pragma unroll
    for (int mf = 0; mf < 4; ++mf) {
      int r = frow + mf * 16;
      af[mf] = sAv[r * 4 + (fslot ^ ((r + (r >> 2)) & 3))];
    }
#pragma unroll
    for (int nf = 0; nf < 2; ++nf) bfr[nf] = *(const bf16x8*)(Bbase + (size_t)nf * 16 * Kp + k0);
#pragma unroll
    for (int mf = 0; mf < 4; ++mf)
#pragma unroll
      for (int nf = 0; nf < 2; ++nf)
        acc[mf][nf] =
            __builtin_amdgcn_mfma_f32_16x16x32_bf16(af[mf], bfr[nf], acc[mf][nf], 0, 0, 0);
  }

  const int colbase = bn + w * 32 + (lane & 15);
  const int rowbase = bm + ((lane >> 4) << 2);
#pragma unroll
  for (int nf = 0; nf < 2; ++nf) {
    int col = colbase + nf * 16;
    bool cv = col < N;
    float bi = (bias && cv) ? bias[col] : 0.f;
    float sc = (scale && cv) ? scale[col] : 1.f;
    float sh = (shift && cv) ? shift[col] : 0.f;
#pragma unroll
    for (int mf = 0; mf < 4; ++mf) {
      f32x4 v = acc[mf][nf];
#pragma unroll
      for (int j = 0; j < 4; ++j) {
        int row = rowbase + mf * 16 + j;
        float x = v[j] + bi;
        if (scale) x = x * sc + sh;
        if (ACT == 1) x = fmaxf(x, 0.f);
        if (ACT == 2) x = sspf(x);
        if (Cin && cv) x += Cin[(size_t)row * ldc + col];
        if (Cout && cv) Cout[(size_t)row * ldc + col] = x;
        if (Coutb && col < Nb) Coutb[(size_t)row * ldcb + col] = cv ? f2b(x) : (short)0;
      }
    }
  }
}

// ---------------- host ----------------

static inline void run_mgemm_bf(hipStream_t st, const short* Ab, const short* Wt,
                                const float* bias, const float* scale, const float* shift,
                                const float* Cin, float* Cout, short* Coutb, int M, int N, int Kp,
                                int ldc, int ldcb, int Nb, int act) {
  dim3 grid((N + 127) / 128, M / 128);
  if (act == 0)
    k_mgemm_bf<0><<<grid, 256, 0, st>>>(Ab, Wt, bias, scale, shift, Cin, Cout, Coutb, M, N, Kp,
                                        ldc, ldcb, Nb);
  else if (act == 1)
    k_mgemm_bf<1><<<grid, 256, 0, st>>>(Ab, Wt, bias, scale, shift, Cin, Cout, Coutb, M, N, Kp,
                                        ldc, ldcb, Nb);
  else
    k_mgemm_bf<2><<<grid, 256, 0, st>>>(Ab, Wt, bias, scale, shift, Cin, Cout, Coutb, M, N, Kp,
                                        ldc, ldcb, Nb);
}

static inline void run_mgemm_bf64(hipStream_t st, const short* Ab, const short* Wt,
                                  const float* bias, const float* scale, const float* shift,
                                  const float* Cin, float* Cout, short* Coutb, int M, int N,
                                  int Kp, int ldc, int ldcb, int Nb, int act) {
  dim3 grid((N + 127) / 128, M / 64);
  if (act == 0)
    k_mgemm_bf64<0><<<grid, 256, 0, st>>>(Ab, Wt, bias, scale, shift, Cin, Cout, Coutb, M, N, Kp,
                                          ldc, ldcb, Nb);
  else if (act == 1)
    k_mgemm_bf64<1><<<grid, 256, 0, st>>>(Ab, Wt, bias, scale, shift, Cin, Cout, Coutb, M, N, Kp,
                                          ldc, ldcb, Nb);
  else
    k_mgemm_bf64<2><<<grid, 256, 0, st>>>(Ab, Wt, bias, scale, shift, Cin, Cout, Coutb, M, N, Kp,
                                          ldc, ldcb, Nb);
}

extern "C" void kernel_launch(void* const* d_in, const int* in_sizes, int n_in, void* d_out,
                              int out_size, void* d_ws, size_t ws_size, hipStream_t stream) {
  const int* x2d = (const int*)d_in[0];
  const int* ei2 = (const int*)d_in[1];
  const int* ea2 = (const int*)d_in[2];
  const int* batch = (const int*)d_in[3];
  const int* z = (const int*)d_in[4];
  const float* pos = (const float*)d_in[5];
  const int* ei3 = (const int*)d_in[6];
  const float* atom_emb1 = (const float*)d_in[7];
  const float* atom_emb2 = (const float*)d_in[8];
  const float* vn_init = (const float*)d_in[9];
  const float* gin_W1 = (const float*)d_in[10];
  const float* gin_b1 = (const float*)d_in[11];
  const float* gin_W2 = (const float*)d_in[12];
  const float* gin_b2 = (const float*)d_in[13];
  const float* gin_bond1 = (const float*)d_in[14];
  const float* gin_bond2 = (const float*)d_in[15];
  const float* gin_gamma = (const float*)d_in[16];
  const float* gin_beta = (const float*)d_in[17];
  const float* vn_W1 = (const float*)d_in[18];
  const float* vn_b1 = (const float*)d_in[19];
  const float* vn_W2 = (const float*)d_in[20];
  const float* vn_b2 = (const float*)d_in[21];
  const float* sch_emb = (const float*)d_in[22];
  const float* s_mW1 = (const float*)d_in[23];
  const float* s_mb1 = (const float*)d_in[24];
  const float* s_mW2 = (const float*)d_in[25];
  const float* s_mb2 = (const float*)d_in[26];
  const float* s_lin1W = (const float*)d_in[27];
  const float* s_lin2W = (const float*)d_in[28];
  const float* s_lin2b = (const float*)d_in[29];
  const float* s_linW = (const float*)d_in[30];
  const float* s_linb = (const float*)d_in[31];
  const float* p2W = (const float*)d_in[32];
  const float* p2b = (const float*)d_in[33];
  const float* p3W = (const float*)d_in[34];
  const float* p3b = (const float*)d_in[35];
  const float* gW1 = (const float*)d_in[36];
  const float* gb1 = (const float*)d_in[37];
  const float* gW2 = (const float*)d_in[38];
  const float* gb2 = (const float*)d_in[39];
  const float* cW1 = (const float*)d_in[40];
  const float* cb1 = (const float*)d_in[41];
  const float* cW2 = (const float*)d_in[42];
  const float* cb2 = (const float*)d_in[43];

  float* ws = (float*)d_ws;
  // GIN phase
  short* hb = (short*)ws;                  // 16384*300 shorts -> [0, 2.458M fl)
  short* hvb = (short*)(ws + 2500000);     // 16384*300 shorts -> [2.5M, 4.958M)
  short* aggb = (short*)(ws + 5000000);    // 16384*320 shorts
  short* y1b = (short*)(ws + 7700000);     // 16384*608 shorts
  // SchNet phase (aliases GIN region; GIN dead when written)
  float* rbs = ws + 400000;
  float* Cs = ws + 700000;
  float* t1all = ws + 800000;              // 6*5121*128 f32 -> ends 4.733M
  short* ftabb = (short*)(ws + 4800000);   // 6*5121*128 shorts -> ends 6.77M
  float* hs = ws + 8800000;                // 16384*128 f32
  short* x1b = (short*)(ws + 11000000);
  short* agg3b = (short*)(ws + 13200000);
  short* hsb = (short*)(ws + 15400000);
  // bf16 transposed weights
  short* W1t = (short*)(ws + 20000000);
  short* W2t = (short*)(ws + 20600000);
  short* s1t = (short*)(ws + 21200000);
  short* s2t = (short*)(ws + 21300000);
  short* s3t = (short*)(ws + 21400000);
  // head transposed f32 weights
  float* p2Wt = ws + 21500000;
  float* p3Wt = ws + 21600000;
  float* gW1t = ws + 21650000;
  float* cW1t = ws + 21730000;
  float* cW2t = ws + 21780000;
  // CSR region
  int* I = (int*)(ws + 22000000);
  int* cnt2 = I + 0;
  int* cnt3 = I + 16384;
  int* cntg = I + 32768;
  int* cur2 = I + 33280;
  int* cur3 = I + 49664;  // zero region = 66048 ints
  int* off2 = I + 70000;
  int* off3 = I + 90000;
  int* goff = I + 110000;
  int* s2s = I + 120000;
  int* ec2s = I + 190000;
  int* s3s = I + 260000;
  int* id3s = I + 660000;
  float* fr3s = (float*)(I + 1060000);
  // vn-MLP bf16 weights + buffers
  short* vnW1t = (short*)(ws + 23500000);
  short* vnW2t = (short*)(ws + 24000000);
  short* vnab = (short*)(ws + 24500000);
  short* vnhb = (short*)(ws + 24600000);
  short* vnb = (short*)(ws + 24800000);
  // persistent tail
  float* vn = ws + 28443136;
  float* h2d = ws + 29057536;
  float* h3d = ws + 29211136;

  // ---- weight prep ----
  k_prepw<<<(5 * 640 * 320 + 255) / 256, 256, 0, stream>>>(gin_W1, W1t, 300, 600, 320, 640, 5);
  k_prepw<<<(5 * 384 * 608 + 255) / 256, 256, 0, stream>>>(gin_W2, W2t, 600, 300, 608, 384, 5);
  k_prepw<<<(6 * 128 * 128 + 255) / 256, 256, 0, stream>>>(s_lin1W, s1t, 128, 128, 128, 128, 6);
  k_prepw<<<(6 * 128 * 128 + 255) / 256, 256, 0, stream>>>(s_lin2W, s2t, 128, 128, 128, 128, 6);
  k_prepw<<<(6 * 128 * 128 + 255) / 256, 256, 0, stream>>>(s_linW, s3t, 128, 128, 128, 128, 6);
  k_prepw<<<(4 * 640 * 320 + 255) / 256, 256, 0, stream>>>(vn_W1, vnW1t, 300, 600, 320, 640, 4);
  k_prepw<<<(4 * 384 * 608 + 255) / 256, 256, 0, stream>>>(vn_W2, vnW2t, 600, 300, 608, 384, 4);
  k_prepwt<<<(300 * 300 + 255) / 256, 256, 0, stream>>>(p2W, p2Wt, 300, 300);
  k_prepwt<<<(300 * 128 + 255) / 256, 256, 0, stream>>>(p3W, p3Wt, 128, 300);
  k_prepwt<<<(128 * 600 + 255) / 256, 256, 0, stream>>>(gW1, gW1t, 600, 128);
  k_prepwt<<<(150 * 300 + 255) / 256, 256, 0, stream>>>(cW1, cW1t, 300, 150);
  k_prepwt<<<(12 * 150 + 255) / 256, 256, 0, stream>>>(cW2, cW2t, 150, 12);

  // ---- CSR build ----
  hipMemsetAsync(I, 0, 66048 * sizeof(int), stream);
  k_hist<<<(NE2 + 255) / 256, 256, 0, stream>>>(ei2 + NE2, cnt2, NE2);
  k_hist<<<(NE3 + 255) / 256, 256, 0, stream>>>(ei3 + NE3, cnt3, NE3);
  k_hist<<<(NN + 255) / 256, 256, 0, stream>>>(batch, cntg, NN);
  k_scan<<<1, 1024, 0, stream>>>(cnt2, off2, 16384);
  k_scan<<<1, 1024, 0, stream>>>(cnt3, off3, 16384);
  k_scan<<<1, 1024, 0, stream>>>(cntg, goff, 512);
  k_scatter2<<<(NE2 + 255) / 256, 256, 0, stream>>>(ei2, ea2, off2, cur2, s2s, ec2s);
  k_scatter3<<<(NE3 + 255) / 256, 256, 0, stream>>>(ei3, pos, off3, cur3, s3s, id3s, fr3s);

  // ---- GIN ----
  k_hinit2<<<(NN * DEMB + 255) / 256, 256, 0, stream>>>(x2d, atom_emb1, atom_emb2, hb);
  k_vninit2<<<(NG * DEMB + 255) / 256, 256, 0, stream>>>(vn_init, vn, vnb);
  for (int l = 0; l < 5; ++l) {
    k_addvnb<<<(NN * DEMB + 255) / 256, 256, 0, stream>>>(hb, vnb, batch, hvb);
    k_gin_gather3<<<NN / 4, 256, 0, stream>>>(hvb, off2, s2s, ec2s, gin_bond1 + l * 6 * DEMB,
                                              gin_bond2 + l * 3 * DEMB, aggb);
    run_mgemm_bf(stream, aggb, W1t + (size_t)l * 640 * 320, gin_b1 + l * 600, nullptr, nullptr,
                 nullptr, nullptr, y1b, NN, 600, 320, 0, 608, 608, 1);
    run_mgemm_bf(stream, y1b, W2t + (size_t)l * 384 * 608, gin_b2 + l * 300, gin_gamma + l * 300,
                 gin_beta + l * 300, nullptr, nullptr, hb, NN, 300, 608, 0, 300, 300,
                 (l < 4) ? 1 : 0);
    if (l < 4) {
      k_poolvn<<<NG / 4, 256, 0, stream>>>(hb, goff, vn, vnab);
      run_mgemm_bf64(stream, vnab, vnW1t + (size_t)l * 640 * 320, vn_b1 + l * 600, nullptr,
                     nullptr, nullptr, nullptr, vnhb, NG, 600, 320, 0, 608, 608, 1);
      run_mgemm_bf64(stream, vnhb, vnW2t + (size_t)l * 384 * 608, vn_b2 + l * 300, nullptr,
                     nullptr, nullptr, vn, vnb, NG, 300, 608, 300, 300, 300, 1);
    }
  }
  k_poolb300<<<NG / 4, 256, 0, stream>>>(hb, goff, h2d);  // before SchNet clobbers hb region

  // ---- SchNet ----
  k_rbs<<<(TROWS * NRBF + 255) / 256, 256, 0, stream>>>(rbs, Cs);
  k_hsinit2<<<(NN * DSCH + 255) / 256, 256, 0, stream>>>(z, sch_emb, hs, hsb);
  {
    dim3 ga(2, (TROWS + 63) / 64, 6);
    k_gemmz<2><<<ga, 256, 0, stream>>>(rbs, s_mW1, s_mb1, nullptr, t1all, nullptr, TROWS, 128, 50,
                                       128, 0L, 50L * 128, 128L, (long)TROWS * 128);
    k_gemmz<0><<<ga, 256, 0, stream>>>(t1all, s_mW2, s_mb2, Cs, nullptr, ftabb, TROWS, 128, 128,
                                       128, (long)TROWS * 128, 128L * 128, 128L,
                                       (long)TROWS * 128);
  }
  for (int l = 0; l < 6; ++l) {
    run_mgemm_bf64(stream, hsb, s1t + (size_t)l * 16384, nullptr, nullptr, nullptr, nullptr,
                   nullptr, x1b, NN, 128, 128, 0, 128, 128, 0);
    k_conv_gather4<<<NN / 4, 256, 0, stream>>>(ftabb + (size_t)l * TROWS * 128, x1b, off3, s3s,
                                               id3s, fr3s, agg3b);
    run_mgemm_bf64(stream, agg3b, s2t + (size_t)l * 16384, s_lin2b + l * 128, nullptr, nullptr,
                   nullptr, nullptr, x1b, NN, 128, 128, 0, 128, 128, 2);
    run_mgemm_bf64(stream, x1b, s3t + (size_t)l * 16384, s_linb + l * 128, nullptr, nullptr, hs,
                   hs, hsb, NN, 128, 128, 128, 128, 128, 0);
  }
  k_poolb128<<<NG / 4, 256, 0, stream>>>(hsb, goff, h3d);

  // ---- fused head ----
  k_head3<<<NG, 256, 0, stream>>>(h2d, h3d, p2Wt, p2b, p3Wt, p3b, gW1t, gb1, gW2, gb2, cW1t, cb1,
                                  cW2t, cb2, (float*)d_out);
}

// Round 11
// 1439.340 us; speedup vs baseline: 6.9271x; 1.0817x over previous
//
#include <hip/hip_runtime.h>
#include <hip/hip_bf16.h>
#include <math.h>

#define NN 16384
#define NG 512
#define NE2 65536
#define NE3 393216
#define DEMB 300
#define DSCH 128
#define NRBF 50
#define NTAB 5120
#define TROWS 5121
#define DMAX 25.0f

typedef __attribute__((ext_vector_type(8))) short bf16x8;
typedef __attribute__((ext_vector_type(4))) float f32x4;

__device__ __forceinline__ float sspf(float x) {
  float sp = log1pf(expf(-fabsf(x))) + fmaxf(x, 0.f);
  return sp - 0.69314718055994530942f;
}

__device__ __forceinline__ short f2b(float f) {
  union { float f; unsigned u; } v;
  v.f = f;
  unsigned r = v.u + 0x7FFF + ((v.u >> 16) & 1);  // RNE
  return (short)(r >> 16);
}

__device__ __forceinline__ float b2f(unsigned short b) {
  union { unsigned u; float f; } v;
  v.u = ((unsigned)b) << 16;
  return v.f;
}

// ---------------- CSR build (consolidated) ----------------

__global__ void k_hist3(const int* __restrict__ ei2, const int* __restrict__ ei3,
                        const int* __restrict__ batch, int* __restrict__ cnt2,
                        int* __restrict__ cnt3, int* __restrict__ cntg) {
  int i = blockIdx.x * blockDim.x + threadIdx.x;
  if (i < NE2) {
    atomicAdd(&cnt2[ei2[NE2 + i]], 1);
  } else if (i < NE2 + NE3) {
    atomicAdd(&cnt3[ei3[NE3 + (i - NE2)]], 1);
  } else if (i < NE2 + NE3 + NN) {
    atomicAdd(&cntg[batch[i - NE2 - NE3]], 1);
  }
}

__global__ __launch_bounds__(1024) void k_scan3(const int* __restrict__ c0, int* __restrict__ o0,
                                                int n0, const int* __restrict__ c1,
                                                int* __restrict__ o1, int n1,
                                                const int* __restrict__ c2, int* __restrict__ o2,
                                                int n2) {
  const int* cnt = (blockIdx.x == 0) ? c0 : (blockIdx.x == 1) ? c1 : c2;
  int* off = (blockIdx.x == 0) ? o0 : (blockIdx.x == 1) ? o1 : o2;
  int n = (blockIdx.x == 0) ? n0 : (blockIdx.x == 1) ? n1 : n2;
  __shared__ int part[1024];
  int tid = threadIdx.x;
  int per = (n + 1023) / 1024;
  int base = tid * per;
  int sum = 0;
  for (int i = 0; i < per; ++i) {
    int idx = base + i;
    if (idx < n) sum += cnt[idx];
  }
  part[tid] = sum;
  __syncthreads();
  for (int d = 1; d < 1024; d <<= 1) {
    int v = (tid >= d) ? part[tid - d] : 0;
    __syncthreads();
    part[tid] += v;
    __syncthreads();
  }
  int run = (tid == 0) ? 0 : part[tid - 1];
  for (int i = 0; i < per; ++i) {
    int idx = base + i;
    if (idx < n) {
      off[idx] = run;
      run += cnt[idx];
    }
  }
  if (tid == 0) off[n] = part[1023];
}

__global__ void k_scatterB(const int* __restrict__ ei2, const int* __restrict__ ea2,
                           const int* __restrict__ batch, const int* __restrict__ off2,
                           int* __restrict__ cur2, int* __restrict__ s2s, int* __restrict__ ec2s,
                           int* __restrict__ b2s, const int* __restrict__ ei3,
                           const float* __restrict__ pos, const int* __restrict__ off3,
                           int* __restrict__ cur3, int* __restrict__ s3s, int* __restrict__ id3s,
                           float* __restrict__ fr3s) {
  int i = blockIdx.x * blockDim.x + threadIdx.x;
  if (i < NE2) {
    int e = i;
    int s = ei2[e], d = ei2[NE2 + e];
    int p = atomicAdd(&cur2[d], 1);
    int j = off2[d] + p;
    s2s[j] = s;
    ec2s[j] = ea2[2 * e] * 4 + ea2[2 * e + 1];
    b2s[j] = batch[s];
  } else if (i < NE2 + NE3) {
    int e = i - NE2;
    int s = ei3[e], d = ei3[NE3 + e];
    float dx = pos[3 * d] - pos[3 * s];
    float dy = pos[3 * d + 1] - pos[3 * s + 1];
    float dz = pos[3 * d + 2] - pos[3 * s + 2];
    float dist = sqrtf(dx * dx + dy * dy + dz * dz);
    float u = fminf(dist * ((float)NTAB / DMAX), (float)NTAB - 0.001f);
    int idx = (int)u;
    int p = atomicAdd(&cur3[d], 1);
    int j = off3[d] + p;
    s3s[j] = s;
    id3s[j] = idx;
    fr3s[j] = u - (float)idx;
  }
}

// ---------------- consolidated init kernels ----------------

__global__ void k_init_gin(const int* __restrict__ x2d, const float* __restrict__ e1,
                           const float* __restrict__ e2, short* __restrict__ hb,
                           const float* __restrict__ vni, float* __restrict__ vn,
                           short* __restrict__ vnb) {
  int i = blockIdx.x * blockDim.x + threadIdx.x;
  if (i < NN * DEMB) {
    int n = i / DEMB, c = i - n * DEMB;
    hb[i] = f2b(e1[x2d[2 * n] * DEMB + c] + e2[x2d[2 * n + 1] * DEMB + c]);
  } else if (i < NN * DEMB + NG * DEMB) {
    int j = i - NN * DEMB;
    float v = vni[j % DEMB];
    vn[j] = v;
    vnb[j] = f2b(v);
  }
}

__global__ void k_init_sch(float* __restrict__ rbs, float* __restrict__ Cs,
                           const int* __restrict__ z, const float* __restrict__ emb,
                           float* __restrict__ hs, short* __restrict__ hsb) {
  int i = blockIdx.x * blockDim.x + threadIdx.x;
  if (i < TROWS * NRBF) {
    int j = i / NRBF, k = i - j * NRBF;
    float dj = (float)j * (DMAX / (float)NTAB);
    const float step = 10.0f / 49.0f;
    const float coeff = -0.5f / (step * step);
    float t = dj - (float)k * step;
    rbs[i] = expf(coeff * t * t);
    if (k == 0) Cs[j] = 0.5f * (cosf(dj * (3.14159265358979323846f / 10.0f)) + 1.0f);
  } else if (i < TROWS * NRBF + NN * DSCH) {
    int j = i - TROWS * NRBF;
    float v = emb[z[j >> 7] * DSCH + (j & 127)];
    hs[j] = v;
    hsb[j] = f2b(v);
  }
}

// ---------------- fused head v4: k-major weights, coalesced lane->output ----------------
__global__ __launch_bounds__(256) void k_head4(
    const float* __restrict__ h2d, const float* __restrict__ h3d, const float* __restrict__ p2W,
    const float* __restrict__ p2b, const float* __restrict__ p3W, const float* __restrict__ p3b,
    const float* __restrict__ gW1, const float* __restrict__ gb1, const float* __restrict__ gW2,
    const float* __restrict__ gb2, const float* __restrict__ cW1, const float* __restrict__ cb1,
    const float* __restrict__ cW2, const float* __restrict__ cb2, float* __restrict__ out) {
  __shared__ float sx[DEMB], sy[DSCH], h2p[DEMB], h3p[DEMB], ghl[DSCH], c1l[150];
  __shared__ float pa[2][128], pb[2][128];
  __shared__ float gshare;
  int g = blockIdx.x, tid = threadIdx.x;
  int half = tid >> 7, o7 = tid & 127;
  for (int i = tid; i < DEMB; i += 256) sx[i] = h2d[(size_t)g * DEMB + i];
  if (tid < DSCH) sy[tid] = h3d[(size_t)g * DSCH + tid];
  __syncthreads();
  // h2p = sx@p2W+b (K=300 2-way split), h3p = sy@p3W+b (K=128 2-way split); coalesced W reads
  for (int ob = 0; ob < DEMB; ob += 128) {
    int o = ob + o7;
    float a = 0.f, b = 0.f;
    if (o < DEMB) {
      for (int k = half * 150; k < half * 150 + 150; ++k) a = fmaf(sx[k], p2W[k * 300 + o], a);
      for (int k = half * 64; k < half * 64 + 64; ++k) b = fmaf(sy[k], p3W[k * 300 + o], b);
    }
    pa[half][o7] = a;
    pb[half][o7] = b;
    __syncthreads();
    if (half == 0 && o < DEMB) {
      h2p[o] = pa[0][o7] + pa[1][o7] + p2b[o];
      h3p[o] = pb[0][o7] + pb[1][o7] + p3b[o];
    }
    __syncthreads();
  }
  // gate hidden: 128 outputs, K=600 (half0: h2p rows 0..299; half1: h3p rows 300..599)
  {
    float a = 0.f;
    if (half == 0) {
      for (int k = 0; k < 300; ++k) a = fmaf(h2p[k], gW1[k * 128 + o7], a);
    } else {
      for (int k = 0; k < 300; ++k) a = fmaf(h3p[k], gW1[(300 + k) * 128 + o7], a);
    }
    pa[half][o7] = a;
    __syncthreads();
    if (half == 0) ghl[o7] = fmaxf(pa[0][o7] + pa[1][o7] + gb1[o7], 0.f);
    __syncthreads();
  }
  if (tid < 128) pa[0][tid] = ghl[tid] * gW2[tid];
  __syncthreads();
  for (int s = 64; s > 0; s >>= 1) {
    if (tid < s) pa[0][tid] += pa[0][tid + s];
    __syncthreads();
  }
  if (tid == 0) gshare = 1.0f / (1.0f + expf(-(pa[0][0] + gb2[0])));
  __syncthreads();
  float gg = gshare;
  for (int i = tid; i < DEMB; i += 256) sx[i] = gg * h2p[i] + (1.0f - gg) * h3p[i];
  __syncthreads();
  // c1 = relu(hf@cW1+b), 150 outputs, K=300 2-way split
  for (int ob = 0; ob < 150; ob += 128) {
    int o = ob + o7;
    float a = 0.f;
    if (o < 150) {
      for (int k = half * 150; k < half * 150 + 150; ++k) a = fmaf(sx[k], cW1[k * 150 + o], a);
    }
    pa[half][o7] = a;
    __syncthreads();
    if (half == 0 && o < 150) c1l[o] = fmaxf(pa[0][o7] + pa[1][o7] + cb1[o], 0.f);
    __syncthreads();
  }
  if (tid < 12) {
    float a = cb2[tid];
    for (int k = 0; k < 150; ++k) a = fmaf(c1l[k], cW2[k * 12 + tid], a);
    out[(size_t)g * 12 + tid] = a;
  }
}

// ---------------- gather aggregations ----------------

// GIN: aggb[d] = bf16( (hb[d]+vnb[batch[d]]) + sum_e relu(hb[s]+vnb[b2s]+eemb) )
__global__ __launch_bounds__(256) void k_gin_gather4(
    const short* __restrict__ hb, const short* __restrict__ vnb, const int* __restrict__ batch,
    const int* __restrict__ off2, const int* __restrict__ s2s, const int* __restrict__ ec2s,
    const int* __restrict__ b2s, const float* __restrict__ bond1,
    const float* __restrict__ bond2, short* __restrict__ aggb) {
  __shared__ float sb[9 * DEMB];
  int tid = threadIdx.x;
  for (int i = tid; i < 6 * DEMB; i += 256) sb[i] = bond1[i];
  for (int i = tid; i < 3 * DEMB; i += 256) sb[6 * DEMB + i] = bond2[i];
  __syncthreads();
  int d = blockIdx.x * 4 + (tid >> 6);
  int lane = tid & 63;
  int j0 = off2[d], j1 = off2[d + 1];
  const unsigned short* hd = (const unsigned short*)hb + (size_t)d * DEMB;
  const unsigned short* vd = (const unsigned short*)vnb + (size_t)batch[d] * DEMB;
  float acc[5];
#pragma unroll
  for (int q = 0; q < 5; ++q) {
    int col = lane + 64 * q;
    acc[q] = (col < DEMB) ? b2f(hd[col]) + b2f(vd[col]) : 0.f;
  }
  for (int j = j0; j < j1; ++j) {
    int s = s2s[j], ec = ec2s[j], bs = b2s[j];
    const unsigned short* hr = (const unsigned short*)hb + (size_t)s * DEMB;
    const unsigned short* vr = (const unsigned short*)vnb + (size_t)bs * DEMB;
    const float* b1 = sb + (ec >> 2) * DEMB;
    const float* b2 = sb + 6 * DEMB + (ec & 3) * DEMB;
#pragma unroll
    for (int q = 0; q < 5; ++q) {
      int col = lane + 64 * q;
      if (col < DEMB) acc[q] += fmaxf(b2f(hr[col]) + b2f(vr[col]) + b1[col] + b2[col], 0.f);
    }
  }
  short* outr = aggb + (size_t)d * 320;
#pragma unroll
  for (int q = 0; q < 5; ++q) {
    int col = lane + 64 * q;
    outr[col] = (col < DEMB) ? f2b(acc[q]) : (short)0;
  }
}

// CFConv with bf16 table + bf16 x1
__global__ __launch_bounds__(256) void k_conv_gather4(
    const short* __restrict__ ftabb, const short* __restrict__ x1b, const int* __restrict__ off3,
    const int* __restrict__ s3s, const int* __restrict__ id3s, const float* __restrict__ fr3s,
    short* __restrict__ agg3b) {
  int tid = threadIdx.x;
  int d = blockIdx.x * 4 + (tid >> 6);
  int lane = tid & 63;
  int j0 = off3[d], j1 = off3[d + 1];
  float a0 = 0.f, a1 = 0.f;
  for (int j = j0; j < j1; ++j) {
    int s = s3s[j], idx = id3s[j];
    float fr = fr3s[j];
    unsigned t0 = ((const unsigned*)(ftabb + (size_t)idx * 128))[lane];
    unsigned t1 = ((const unsigned*)(ftabb + (size_t)(idx + 1) * 128))[lane];
    unsigned xv = ((const unsigned*)(x1b + (size_t)s * 128))[lane];
    float t0a = b2f((unsigned short)(t0 & 0xFFFF)), t0b = b2f((unsigned short)(t0 >> 16));
    float t1a = b2f((unsigned short)(t1 & 0xFFFF)), t1b = b2f((unsigned short)(t1 >> 16));
    a0 += (t0a + fr * (t1a - t0a)) * b2f((unsigned short)(xv & 0xFFFF));
    a1 += (t0b + fr * (t1b - t0b)) * b2f((unsigned short)(xv >> 16));
  }
  unsigned pack = ((unsigned)(unsigned short)f2b(a1) << 16) | (unsigned short)f2b(a0);
  ((unsigned*)(agg3b + (size_t)d * 128))[lane] = pack;
}

// pool bf16 rows [*,300] -> f32 mean
__global__ __launch_bounds__(256) void k_poolb300(const short* __restrict__ xb,
                                                  const int* __restrict__ goff,
                                                  float* __restrict__ out) {
  int g = blockIdx.x * 4 + (threadIdx.x >> 6);
  int lane = threadIdx.x & 63;
  if (g >= NG) return;
  int r0 = goff[g], r1 = goff[g + 1];
  float acc[5] = {};
  for (int r = r0; r < r1; ++r) {
    const unsigned short* row = (const unsigned short*)xb + (size_t)r * DEMB;
#pragma unroll
    for (int q = 0; q < 5; ++q) {
      int col = lane + 64 * q;
      if (col < DEMB) acc[q] += b2f(row[col]);
    }
  }
  float s = 1.0f / fmaxf((float)(r1 - r0), 1.0f);
#pragma unroll
  for (int q = 0; q < 5; ++q) {
    int col = lane + 64 * q;
    if (col < DEMB) out[(size_t)g * DEMB + col] = acc[q] * s;
  }
}

// pool bf16 rows [*,128] -> f32 mean
__global__ __launch_bounds__(256) void k_poolb128(const short* __restrict__ xb,
                                                  const int* __restrict__ goff,
                                                  float* __restrict__ out) {
  int g = blockIdx.x * 4 + (threadIdx.x >> 6);
  int lane = threadIdx.x & 63;
  if (g >= NG) return;
  int r0 = goff[g], r1 = goff[g + 1];
  float a0 = 0.f, a1 = 0.f;
  for (int r = r0; r < r1; ++r) {
    unsigned v = ((const unsigned*)(xb + (size_t)r * DSCH))[lane];
    a0 += b2f((unsigned short)(v & 0xFFFF));
    a1 += b2f((unsigned short)(v >> 16));
  }
  float s = 1.0f / fmaxf((float)(r1 - r0), 1.0f);
  out[(size_t)g * DSCH + lane * 2] = a0 * s;
  out[(size_t)g * DSCH + lane * 2 + 1] = a1 * s;
}

// fused: vnab[g][320] = bf16( sum_rows(hb) + vn[g] )
__global__ __launch_bounds__(256) void k_poolvn(const short* __restrict__ hb,
                                                const int* __restrict__ goff,
                                                const float* __restrict__ vn,
                                                short* __restrict__ vnab) {
  int g = blockIdx.x * 4 + (threadIdx.x >> 6);
  int lane = threadIdx.x & 63;
  if (g >= NG) return;
  int r0 = goff[g], r1 = goff[g + 1];
  float acc[5] = {};
  for (int r = r0; r < r1; ++r) {
    const unsigned short* row = (const unsigned short*)hb + (size_t)r * DEMB;
#pragma unroll
    for (int q = 0; q < 5; ++q) {
      int col = lane + 64 * q;
      if (col < DEMB) acc[q] += b2f(row[col]);
    }
  }
  short* outr = vnab + (size_t)g * 320;
#pragma unroll
  for (int q = 0; q < 5; ++q) {
    int col = lane + 64 * q;
    if (col < 320)
      outr[col] = (col < DEMB) ? f2b(acc[q] + vn[(size_t)g * DEMB + col]) : (short)0;
  }
}

// ---------------- weight prep (consolidated) ----------------
// two sources, same geometry: W[l][K][N] -> Wt[l][Np][Kp] bf16 transposed/padded
__global__ void k_prepw2(const float* __restrict__ Wa, const float* __restrict__ Wb,
                         short* __restrict__ Wta, short* __restrict__ Wtb, int K, int N, int Kp,
                         int Np, int La, int Lb) {
  int i = blockIdx.x * blockDim.x + threadIdx.x;
  int per = Np * Kp;
  if (i >= (La + Lb) * per) return;
  int l = i / per, r = i - l * per;
  int n = r / Kp, k = r - n * Kp;
  const float* W = (l < La) ? Wa : Wb;
  int ll = (l < La) ? l : l - La;
  short* Wt = (l < La) ? Wta : Wtb;
  float v = (n < N && k < K) ? W[(size_t)ll * K * N + (size_t)k * N + n] : 0.f;
  Wt[(size_t)ll * per + r] = f2b(v);
}

// three 6-layer 128x128 weights
__global__ void k_prepw3(const float* __restrict__ W0, const float* __restrict__ W1,
                         const float* __restrict__ W2, short* __restrict__ T0,
                         short* __restrict__ T1, short* __restrict__ T2) {
  int i = blockIdx.x * blockDim.x + threadIdx.x;
  const int per = 6 * 128 * 128;
  if (i >= 3 * per) return;
  int which = i / per, r = i - which * per;
  int l = r / 16384, rr = r - l * 16384;
  int n = rr / 128, k = rr - n * 128;
  const float* W = (which == 0) ? W0 : (which == 1) ? W1 : W2;
  short* T = (which == 0) ? T0 : (which == 1) ? T1 : T2;
  T[r] = f2b(W[(size_t)l * 16384 + (size_t)k * 128 + n]);
}

// ---------------- z-batched fp32 GEMM; optional bf16 output ----------------
template <int ACT>
__global__ __launch_bounds__(256) void k_gemmz(
    const float* __restrict__ A, const float* __restrict__ B, const float* __restrict__ bias,
    const float* __restrict__ rscale, float* __restrict__ Cout, short* __restrict__ Coutb,
    int M, int N, int K, int ldc, long strideA, long strideB, long strideBias, long strideC) {
  A += (size_t)blockIdx.z * strideA;
  B += (size_t)blockIdx.z * strideB;
  bias += (size_t)blockIdx.z * strideBias;
  __shared__ float sA[16][65];
  __shared__ float sB[16][64];
  int tid = threadIdx.x;
  int tx = tid & 15, ty = tid >> 4;
  int bm = blockIdx.y * 64, bn = blockIdx.x * 64;
  float acc[4][4] = {};
  for (int k0 = 0; k0 < K; k0 += 16) {
#pragma unroll
    for (int t = 0; t < 4; ++t) {
      int i = tid + t * 256;
      int m = i >> 4, kk = i & 15;
      int gm = bm + m, gk = k0 + kk;
      sA[kk][m] = (gm < M && gk < K) ? A[(size_t)gm * K + gk] : 0.f;
    }
#pragma unroll
    for (int t = 0; t < 4; ++t) {
      int i = tid + t * 256;
      int kk = i >> 6, n = i & 63;
      int gk = k0 + kk, gn = bn + n;
      sB[kk][n] = (gk < K && gn < N) ? B[(size_t)gk * N + gn] : 0.f;
    }
    __syncthreads();
#pragma unroll
    for (int kk = 0; kk < 16; ++kk) {
      float a[4], b[4];
#pragma unroll
      for (int i = 0; i < 4; ++i) a[i] = sA[kk][ty + 16 * i];
#pragma unroll
      for (int j = 0; j < 4; ++j) b[j] = sB[kk][tx + 16 * j];
#pragma unroll
      for (int i = 0; i < 4; ++i)
#pragma unroll
        for (int j = 0; j < 4; ++j) acc[i][j] = fmaf(a[i], b[j], acc[i][j]);
    }
    __syncthreads();
  }
#pragma unroll
  for (int i = 0; i < 4; ++i) {
    int gm = bm + ty + 16 * i;
    if (gm >= M) continue;
    float rs = rscale ? rscale[gm] : 1.0f;
#pragma unroll
    for (int j = 0; j < 4; ++j) {
      int gn = bn + tx + 16 * j;
      if (gn >= N) continue;
      float v = acc[i][j] + bias[gn];
      if (ACT == 1) v = fmaxf(v, 0.f);
      if (ACT == 2) v = sspf(v);
      v *= rs;
      if (Cout) Cout[(size_t)blockIdx.z * strideC + (size_t)gm * ldc + gn] = v;
      if (Coutb) Coutb[(size_t)blockIdx.z * strideC + (size_t)gm * ldc + gn] = f2b(v);
    }
  }
}

// ---------------- bf16 MFMA GEMM, 128x128 tile ----------------
template <int ACT>
__global__ __launch_bounds__(256) void k_mgemm_bf(
    const short* __restrict__ Ab, const short* __restrict__ Wt, const float* __restrict__ bias,
    const float* __restrict__ scale, const float* __restrict__ shift,
    const float* __restrict__ Cin, float* __restrict__ Cout, short* __restrict__ Coutb,
    int M, int N, int Kp, int ldc, int ldcb, int Nb) {
  __shared__ short sA[128 * 32];
  const int tid = threadIdx.x;
  const int lane = tid & 63;
  const int w = tid >> 6;
  const int wm = w >> 1, wn = w & 1;
  const int bm = blockIdx.y * 128, bn = blockIdx.x * 128;

  f32x4 acc[4][4] = {};

  const int sr = tid >> 1;
  const int sk = (tid & 1) * 16;
  const short* Arow = Ab + (size_t)(bm + sr) * Kp + sk;
  const int ssw = (sr + (sr >> 2)) & 3;
  const int s0 = (sk >> 3);
  bf16x8* sAv = (bf16x8*)sA;

  const int frow = wm * 64 + (lane & 15);
  const int fslot = lane >> 4;
  const short* Bbase = Wt + (size_t)(bn + wn * 64 + (lane & 15)) * Kp + (fslot * 8);

  for (int k0 = 0; k0 < Kp; k0 += 32) {
    __syncthreads();
    {
      bf16x8 p0 = *(const bf16x8*)(Arow + k0);
      bf16x8 p1 = *(const bf16x8*)(Arow + k0 + 8);
      sAv[sr * 4 + ((s0 + 0) ^ ssw)] = p0;
      sAv[sr * 4 + ((s0 + 1) ^ ssw)] = p1;
    }
    __syncthreads();

    bf16x8 af[4], bfr[4];
#pragma unroll
    for (int mf = 0; mf < 4; ++mf) {
      int r = frow + mf * 16;
      af[mf] = sAv[r * 4 + (fslot ^ ((r + (r >> 2)) & 3))];
    }
#pragma unroll
    for (int nf = 0; nf < 4; ++nf) bfr[nf] = *(const bf16x8*)(Bbase + (size_t)nf * 16 * Kp + k0);
#pragma unroll
    for (int mf = 0; mf < 4; ++mf)
#pragma unroll
      for (int nf = 0; nf < 4; ++nf)
        acc[mf][nf] =
            __builtin_amdgcn_mfma_f32_16x16x32_bf16(af[mf], bfr[nf], acc[mf][nf], 0, 0, 0);
  }

  const int colbase = bn + wn * 64 + (lane & 15);
  const int rowbase = bm + wm * 64 + ((lane >> 4) << 2);
#pragma unroll
  for (int nf = 0; nf < 4; ++nf) {
    int col = colbase + nf * 16;
    bool cv = col < N;
    float bi = (bias && cv) ? bias[col] : 0.f;
    float sc = (scale && cv) ? scale[col] : 1.f;
    float sh = (shift && cv) ? shift[col] : 0.f;
#pragma unroll
    for (int mf = 0; mf < 4; ++mf) {
      f32x4 v = acc[mf][nf];
#pragma unroll
      for (int j = 0; j < 4; ++j) {
        int row = rowbase + mf * 16 + j;
        float x = v[j] + bi;
        if (scale) x = x * sc + sh;
        if (ACT == 1) x = fmaxf(x, 0.f);
        if (ACT == 2) x = sspf(x);
        if (Cin && cv) x += Cin[(size_t)row * ldc + col];
        if (Cout && cv) Cout[(size_t)row * ldc + col] = x;
        if (Coutb && col < Nb) Coutb[(size_t)row * ldcb + col] = cv ? f2b(x) : (short)0;
      }
    }
  }
}

// ---------------- bf16 MFMA GEMM, 64x128 tile ----------------
template <int ACT>
__global__ __launch_bounds__(256) void k_mgemm_bf64(
    const short* __restrict__ Ab, const short* __restrict__ Wt, const float* __restrict__ bias,
    const float* __restrict__ scale, const float* __restrict__ shift,
    const float* __restrict__ Cin, float* __restrict__ Cout, short* __restrict__ Coutb,
    int M, int N, int Kp, int ldc, int ldcb, int Nb) {
  __shared__ short sA[64 * 32];
  const int tid = threadIdx.x;
  const int lane = tid & 63;
  const int w = tid >> 6;
  const int bm = blockIdx.y * 64, bn = blockIdx.x * 128;

  f32x4 acc[4][2] = {};

  const int sr = tid >> 2;
  const int sk = (tid & 3) * 8;
  const short* Arow = Ab + (size_t)(bm + sr) * Kp + sk;
  const int ssw = (sr + (sr >> 2)) & 3;
  const int s0 = tid & 3;
  bf16x8* sAv = (bf16x8*)sA;

  const int frow = lane & 15;
  const int fslot = lane >> 4;
  const short* Bbase = Wt + (size_t)(bn + w * 32 + (lane & 15)) * Kp + (fslot * 8);

  for (int k0 = 0; k0 < Kp; k0 += 32) {
    __syncthreads();
    sAv[sr * 4 + (s0 ^ ssw)] = *(const bf16x8*)(Arow + k0);
    __syncthreads();

    bf16x8 af[4], bfr[2];
#pragma unroll
    for (int mf = 0; mf < 4; ++mf) {
      int r = frow + mf * 16;
      af[mf] = sAv[r * 4 + (fslot ^ ((r + (r >> 2)) & 3))];
    }
#pragma unroll
    for (int nf = 0; nf < 2; ++nf) bfr[nf] = *(const bf16x8*)(Bbase + (size_t)nf * 16 * Kp + k0);
#pragma unroll
    for (int mf = 0; mf < 4; ++mf)
#pragma unroll
      for (int nf = 0; nf < 2; ++nf)
        acc[mf][nf] =
            __builtin_amdgcn_mfma_f32_16x16x32_bf16(af[mf], bfr[nf], acc[mf][nf], 0, 0, 0);
  }

  const int colbase = bn + w * 32 + (lane & 15);
  const int rowbase = bm + ((lane >> 4) << 2);
#pragma unroll
  for (int nf = 0; nf < 2; ++nf) {
    int col = colbase + nf * 16;
    bool cv = col < N;
    float bi = (bias && cv) ? bias[col] : 0.f;
    float sc = (scale && cv) ? scale[col] : 1.f;
    float sh = (shift && cv) ? shift[col] : 0.f;
#pragma unroll
    for (int mf = 0; mf < 4; ++mf) {
      f32x4 v = acc[mf][nf];
#pragma unroll
      for (int j = 0; j < 4; ++j) {
        int row = rowbase + mf * 16 + j;
        float x = v[j] + bi;
        if (scale) x = x * sc + sh;
        if (ACT == 1) x = fmaxf(x, 0.f);
        if (ACT == 2) x = sspf(x);
        if (Cin && cv) x += Cin[(size_t)row * ldc + col];
        if (Cout && cv) Cout[(size_t)row * ldc + col] = x;
        if (Coutb && col < Nb) Coutb[(size_t)row * ldcb + col] = cv ? f2b(x) : (short)0;
      }
    }
  }
}

// ---------------- host ----------------

static inline void run_mgemm_bf(hipStream_t st, const short* Ab, const short* Wt,
                                const float* bias, const float* scale, const float* shift,
                                const float* Cin, float* Cout, short* Coutb, int M, int N, int Kp,
                                int ldc, int ldcb, int Nb, int act) {
  dim3 grid((N + 127) / 128, M / 128);
  if (act == 0)
    k_mgemm_bf<0><<<grid, 256, 0, st>>>(Ab, Wt, bias, scale, shift, Cin, Cout, Coutb, M, N, Kp,
                                        ldc, ldcb, Nb);
  else if (act == 1)
    k_mgemm_bf<1><<<grid, 256, 0, st>>>(Ab, Wt, bias, scale, shift, Cin, Cout, Coutb, M, N, Kp,
                                        ldc, ldcb, Nb);
  else
    k_mgemm_bf<2><<<grid, 256, 0, st>>>(Ab, Wt, bias, scale, shift, Cin, Cout, Coutb, M, N, Kp,
                                        ldc, ldcb, Nb);
}

static inline void run_mgemm_bf64(hipStream_t st, const short* Ab, const short* Wt,
                                  const float* bias, const float* scale, const float* shift,
                                  const float* Cin, float* Cout, short* Coutb, int M, int N,
                                  int Kp, int ldc, int ldcb, int Nb, int act) {
  dim3 grid((N + 127) / 128, M / 64);
  if (act == 0)
    k_mgemm_bf64<0><<<grid, 256, 0, st>>>(Ab, Wt, bias, scale, shift, Cin, Cout, Coutb, M, N, Kp,
                                          ldc, ldcb, Nb);
  else if (act == 1)
    k_mgemm_bf64<1><<<grid, 256, 0, st>>>(Ab, Wt, bias, scale, shift, Cin, Cout, Coutb, M, N, Kp,
                                          ldc, ldcb, Nb);
  else
    k_mgemm_bf64<2><<<grid, 256, 0, st>>>(Ab, Wt, bias, scale, shift, Cin, Cout, Coutb, M, N, Kp,
                                          ldc, ldcb, Nb);
}

extern "C" void kernel_launch(void* const* d_in, const int* in_sizes, int n_in, void* d_out,
                              int out_size, void* d_ws, size_t ws_size, hipStream_t stream) {
  const int* x2d = (const int*)d_in[0];
  const int* ei2 = (const int*)d_in[1];
  const int* ea2 = (const int*)d_in[2];
  const int* batch = (const int*)d_in[3];
  const int* z = (const int*)d_in[4];
  const float* pos = (const float*)d_in[5];
  const int* ei3 = (const int*)d_in[6];
  const float* atom_emb1 = (const float*)d_in[7];
  const float* atom_emb2 = (const float*)d_in[8];
  const float* vn_init = (const float*)d_in[9];
  const float* gin_W1 = (const float*)d_in[10];
  const float* gin_b1 = (const float*)d_in[11];
  const float* gin_W2 = (const float*)d_in[12];
  const float* gin_b2 = (const float*)d_in[13];
  const float* gin_bond1 = (const float*)d_in[14];
  const float* gin_bond2 = (const float*)d_in[15];
  const float* gin_gamma = (const float*)d_in[16];
  const float* gin_beta = (const float*)d_in[17];
  const float* vn_W1 = (const float*)d_in[18];
  const float* vn_b1 = (const float*)d_in[19];
  const float* vn_W2 = (const float*)d_in[20];
  const float* vn_b2 = (const float*)d_in[21];
  const float* sch_emb = (const float*)d_in[22];
  const float* s_mW1 = (const float*)d_in[23];
  const float* s_mb1 = (const float*)d_in[24];
  const float* s_mW2 = (const float*)d_in[25];
  const float* s_mb2 = (const float*)d_in[26];
  const float* s_lin1W = (const float*)d_in[27];
  const float* s_lin2W = (const float*)d_in[28];
  const float* s_lin2b = (const float*)d_in[29];
  const float* s_linW = (const float*)d_in[30];
  const float* s_linb = (const float*)d_in[31];
  const float* p2W = (const float*)d_in[32];
  const float* p2b = (const float*)d_in[33];
  const float* p3W = (const float*)d_in[34];
  const float* p3b = (const float*)d_in[35];
  const float* gW1 = (const float*)d_in[36];
  const float* gb1 = (const float*)d_in[37];
  const float* gW2 = (const float*)d_in[38];
  const float* gb2 = (const float*)d_in[39];
  const float* cW1 = (const float*)d_in[40];
  const float* cb1 = (const float*)d_in[41];
  const float* cW2 = (const float*)d_in[42];
  const float* cb2 = (const float*)d_in[43];

  float* ws = (float*)d_ws;
  // GIN phase
  short* hb = (short*)ws;                  // 16384*300 shorts -> [0, 2.458M fl)
  int* b2s = (int*)(ws + 2500000);         // 65536 ints (GIN-phase only)
  short* aggb = (short*)(ws + 5000000);    // 16384*320 shorts
  short* y1b = (short*)(ws + 7700000);     // 16384*608 shorts
  // SchNet phase (aliases GIN region; GIN dead when written)
  float* rbs = ws + 400000;
  float* Cs = ws + 700000;
  float* t1all = ws + 800000;              // 6*5121*128 f32
  short* ftabb = (short*)(ws + 4800000);   // 6*5121*128 shorts
  float* hs = ws + 8800000;                // 16384*128 f32
  short* x1b = (short*)(ws + 11000000);
  short* agg3b = (short*)(ws + 13200000);
  short* hsb = (short*)(ws + 15400000);
  // bf16 transposed weights
  short* W1t = (short*)(ws + 20000000);
  short* W2t = (short*)(ws + 20600000);
  short* s1t = (short*)(ws + 21200000);
  short* s2t = (short*)(ws + 21300000);
  short* s3t = (short*)(ws + 21400000);
  // CSR region
  int* I = (int*)(ws + 22000000);
  int* cnt2 = I + 0;
  int* cnt3 = I + 16384;
  int* cntg = I + 32768;
  int* cur2 = I + 33280;
  int* cur3 = I + 49664;  // zero region = 66048 ints
  int* off2 = I + 70000;
  int* off3 = I + 90000;
  int* goff = I + 110000;
  int* s2s = I + 120000;
  int* ec2s = I + 190000;
  int* s3s = I + 260000;
  int* id3s = I + 660000;
  float* fr3s = (float*)(I + 1060000);
  // vn-MLP bf16 weights + buffers
  short* vnW1t = (short*)(ws + 23500000);
  short* vnW2t = (short*)(ws + 24000000);
  short* vnab = (short*)(ws + 24500000);
  short* vnhb = (short*)(ws + 24600000);
  short* vnb = (short*)(ws + 24800000);
  // persistent tail
  float* vn = ws + 28443136;
  float* h2d = ws + 29057536;
  float* h3d = ws + 29211136;

  // ---- weight prep (3 dispatches) ----
  k_prepw2<<<(9 * 640 * 320 + 255) / 256, 256, 0, stream>>>(gin_W1, vn_W1, W1t, vnW1t, 300, 600,
                                                            320, 640, 5, 4);
  k_prepw2<<<(9 * 384 * 608 + 255) / 256, 256, 0, stream>>>(gin_W2, vn_W2, W2t, vnW2t, 600, 300,
                                                            608, 384, 5, 4);
  k_prepw3<<<(3 * 6 * 16384 + 255) / 256, 256, 0, stream>>>(s_lin1W, s_lin2W, s_linW, s1t, s2t,
                                                            s3t);

  // ---- CSR build (4 dispatches) ----
  hipMemsetAsync(I, 0, 66048 * sizeof(int), stream);
  k_hist3<<<(NE2 + NE3 + NN + 255) / 256, 256, 0, stream>>>(ei2, ei3, batch, cnt2, cnt3, cntg);
  k_scan3<<<3, 1024, 0, stream>>>(cnt2, off2, 16384, cnt3, off3, 16384, cntg, goff, 512);
  k_scatterB<<<(NE2 + NE3 + 255) / 256, 256, 0, stream>>>(ei2, ea2, batch, off2, cur2, s2s, ec2s,
                                                          b2s, ei3, pos, off3, cur3, s3s, id3s,
                                                          fr3s);

  // ---- GIN ----
  k_init_gin<<<(NN * DEMB + NG * DEMB + 255) / 256, 256, 0, stream>>>(x2d, atom_emb1, atom_emb2,
                                                                      hb, vn_init, vn, vnb);
  for (int l = 0; l < 5; ++l) {
    k_gin_gather4<<<NN / 4, 256, 0, stream>>>(hb, vnb, batch, off2, s2s, ec2s, b2s,
                                              gin_bond1 + l * 6 * DEMB, gin_bond2 + l * 3 * DEMB,
                                              aggb);
    run_mgemm_bf(stream, aggb, W1t + (size_t)l * 640 * 320, gin_b1 + l * 600, nullptr, nullptr,
                 nullptr, nullptr, y1b, NN, 600, 320, 0, 608, 608, 1);
    run_mgemm_bf(stream, y1b, W2t + (size_t)l * 384 * 608, gin_b2 + l * 300, gin_gamma + l * 300,
                 gin_beta + l * 300, nullptr, nullptr, hb, NN, 300, 608, 0, 300, 300,
                 (l < 4) ? 1 : 0);
    if (l < 4) {
      k_poolvn<<<NG / 4, 256, 0, stream>>>(hb, goff, vn, vnab);
      run_mgemm_bf64(stream, vnab, vnW1t + (size_t)l * 640 * 320, vn_b1 + l * 600, nullptr,
                     nullptr, nullptr, nullptr, vnhb, NG, 600, 320, 0, 608, 608, 1);
      run_mgemm_bf64(stream, vnhb, vnW2t + (size_t)l * 384 * 608, vn_b2 + l * 300, nullptr,
                     nullptr, nullptr, vn, vnb, NG, 300, 608, 300, 300, 300, 1);
    }
  }
  k_poolb300<<<NG / 4, 256, 0, stream>>>(hb, goff, h2d);  // before SchNet clobbers hb region

  // ---- SchNet ----
  k_init_sch<<<(TROWS * NRBF + NN * DSCH + 255) / 256, 256, 0, stream>>>(rbs, Cs, z, sch_emb, hs,
                                                                         hsb);
  {
    dim3 ga(2, (TROWS + 63) / 64, 6);
    k_gemmz<2><<<ga, 256, 0, stream>>>(rbs, s_mW1, s_mb1, nullptr, t1all, nullptr, TROWS, 128, 50,
                                       128, 0L, 50L * 128, 128L, (long)TROWS * 128);
    k_gemmz<0><<<ga, 256, 0, stream>>>(t1all, s_mW2, s_mb2, Cs, nullptr, ftabb, TROWS, 128, 128,
                                       128, (long)TROWS * 128, 128L * 128, 128L,
                                       (long)TROWS * 128);
  }
  for (int l = 0; l < 6; ++l) {
    run_mgemm_bf64(stream, hsb, s1t + (size_t)l * 16384, nullptr, nullptr, nullptr, nullptr,
                   nullptr, x1b, NN, 128, 128, 0, 128, 128, 0);
    k_conv_gather4<<<NN / 4, 256, 0, stream>>>(ftabb + (size_t)l * TROWS * 128, x1b, off3, s3s,
                                               id3s, fr3s, agg3b);
    run_mgemm_bf64(stream, agg3b, s2t + (size_t)l * 16384, s_lin2b + l * 128, nullptr, nullptr,
                   nullptr, nullptr, x1b, NN, 128, 128, 0, 128, 128, 2);
    run_mgemm_bf64(stream, x1b, s3t + (size_t)l * 16384, s_linb + l * 128, nullptr, nullptr, hs,
                   hs, hsb, NN, 128, 128, 128, 128, 128, 0);
  }
  k_poolb128<<<NG / 4, 256, 0, stream>>>(hsb, goff, h3d);

  // ---- fused head ----
  k_head4<<<NG, 256, 0, stream>>>(h2d, h3d, p2W, p2b, p3W, p3b, gW1, gb1, gW2, gb2, cW1, cb1, cW2,
                                  cb2, (float*)d_out);
}

// Round 12
// 1348.956 us; speedup vs baseline: 7.3912x; 1.0670x over previous
//
#include <hip/hip_runtime.h>
#include <hip/hip_bf16.h>
#include <math.h>

#define NN 16384
#define NG 512
#define NE2 65536
#define NE3 393216
#define DEMB 300
#define DSCH 128
#define NRBF 50
#define NTAB 5120
#define TROWS 5121
#define DMAX 25.0f

typedef __attribute__((ext_vector_type(8))) short bf16x8;
typedef __attribute__((ext_vector_type(4))) float f32x4;

__device__ __forceinline__ float sspf(float x) {
  float sp = log1pf(expf(-fabsf(x))) + fmaxf(x, 0.f);
  return sp - 0.69314718055994530942f;
}

__device__ __forceinline__ short f2b(float f) {
  union { float f; unsigned u; } v;
  v.f = f;
  unsigned r = v.u + 0x7FFF + ((v.u >> 16) & 1);  // RNE
  return (short)(r >> 16);
}

__device__ __forceinline__ float b2f(unsigned short b) {
  union { unsigned u; float f; } v;
  v.u = ((unsigned)b) << 16;
  return v.f;
}

// ---------------- CSR build ----------------

__global__ void k_hist3(const int* __restrict__ ei2, const int* __restrict__ ei3,
                        const int* __restrict__ batch, int* __restrict__ cnt2,
                        int* __restrict__ cnt3, int* __restrict__ cntg) {
  int i = blockIdx.x * blockDim.x + threadIdx.x;
  if (i < NE2) {
    atomicAdd(&cnt2[ei2[NE2 + i]], 1);
  } else if (i < NE2 + NE3) {
    atomicAdd(&cnt3[ei3[NE3 + (i - NE2)]], 1);
  } else if (i < NE2 + NE3 + NN) {
    atomicAdd(&cntg[batch[i - NE2 - NE3]], 1);
  }
}

__global__ __launch_bounds__(1024) void k_scan3(const int* __restrict__ c0, int* __restrict__ o0,
                                                int n0, const int* __restrict__ c1,
                                                int* __restrict__ o1, int n1,
                                                const int* __restrict__ c2, int* __restrict__ o2,
                                                int n2) {
  const int* cnt = (blockIdx.x == 0) ? c0 : (blockIdx.x == 1) ? c1 : c2;
  int* off = (blockIdx.x == 0) ? o0 : (blockIdx.x == 1) ? o1 : o2;
  int n = (blockIdx.x == 0) ? n0 : (blockIdx.x == 1) ? n1 : n2;
  __shared__ int part[1024];
  int tid = threadIdx.x;
  int per = (n + 1023) / 1024;
  int base = tid * per;
  int sum = 0;
  for (int i = 0; i < per; ++i) {
    int idx = base + i;
    if (idx < n) sum += cnt[idx];
  }
  part[tid] = sum;
  __syncthreads();
  for (int d = 1; d < 1024; d <<= 1) {
    int v = (tid >= d) ? part[tid - d] : 0;
    __syncthreads();
    part[tid] += v;
    __syncthreads();
  }
  int run = (tid == 0) ? 0 : part[tid - 1];
  for (int i = 0; i < per; ++i) {
    int idx = base + i;
    if (idx < n) {
      off[idx] = run;
      run += cnt[idx];
    }
  }
  if (tid == 0) off[n] = part[1023];
}

__global__ void k_scatterB(const int* __restrict__ ei2, const int* __restrict__ ea2,
                           const int* __restrict__ batch, const int* __restrict__ off2,
                           int* __restrict__ cur2, int* __restrict__ s2s, int* __restrict__ ec2s,
                           int* __restrict__ b2s, const int* __restrict__ ei3,
                           const float* __restrict__ pos, const int* __restrict__ off3,
                           int* __restrict__ cur3, int* __restrict__ s3s, int* __restrict__ id3s,
                           float* __restrict__ fr3s) {
  int i = blockIdx.x * blockDim.x + threadIdx.x;
  if (i < NE2) {
    int e = i;
    int s = ei2[e], d = ei2[NE2 + e];
    int p = atomicAdd(&cur2[d], 1);
    int j = off2[d] + p;
    s2s[j] = s;
    ec2s[j] = ea2[2 * e] * 4 + ea2[2 * e + 1];
    b2s[j] = batch[s];
  } else if (i < NE2 + NE3) {
    int e = i - NE2;
    int s = ei3[e], d = ei3[NE3 + e];
    float dx = pos[3 * d] - pos[3 * s];
    float dy = pos[3 * d + 1] - pos[3 * s + 1];
    float dz = pos[3 * d + 2] - pos[3 * s + 2];
    float dist = sqrtf(dx * dx + dy * dy + dz * dz);
    float u = fminf(dist * ((float)NTAB / DMAX), (float)NTAB - 0.001f);
    int idx = (int)u;
    int p = atomicAdd(&cur3[d], 1);
    int j = off3[d] + p;
    s3s[j] = s;
    id3s[j] = idx;
    fr3s[j] = u - (float)idx;
  }
}

// ---------------- consolidated init kernels ----------------

__global__ void k_init_gin(const int* __restrict__ x2d, const float* __restrict__ e1,
                           const float* __restrict__ e2, short* __restrict__ hb,
                           const float* __restrict__ vni, float* __restrict__ vn,
                           short* __restrict__ vnb) {
  int i = blockIdx.x * blockDim.x + threadIdx.x;
  if (i < NN * DEMB) {
    int n = i / DEMB, c = i - n * DEMB;
    hb[i] = f2b(e1[x2d[2 * n] * DEMB + c] + e2[x2d[2 * n + 1] * DEMB + c]);
  } else if (i < NN * DEMB + NG * DEMB) {
    int j = i - NN * DEMB;
    float v = vni[j % DEMB];
    vn[j] = v;
    vnb[j] = f2b(v);
  }
}

__global__ void k_init_sch(float* __restrict__ rbs, float* __restrict__ Cs,
                           const int* __restrict__ z, const float* __restrict__ emb,
                           float* __restrict__ hs, short* __restrict__ hsb) {
  int i = blockIdx.x * blockDim.x + threadIdx.x;
  if (i < TROWS * NRBF) {
    int j = i / NRBF, k = i - j * NRBF;
    float dj = (float)j * (DMAX / (float)NTAB);
    const float step = 10.0f / 49.0f;
    const float coeff = -0.5f / (step * step);
    float t = dj - (float)k * step;
    rbs[i] = expf(coeff * t * t);
    if (k == 0) Cs[j] = 0.5f * (cosf(dj * (3.14159265358979323846f / 10.0f)) + 1.0f);
  } else if (i < TROWS * NRBF + NN * DSCH) {
    int j = i - TROWS * NRBF;
    float v = emb[z[j >> 7] * DSCH + (j & 127)];
    hs[j] = v;
    hsb[j] = f2b(v);
  }
}

// ---------------- fused head v5: k-major weights + multi-accumulator ----------------
__global__ __launch_bounds__(256) void k_head5(
    const float* __restrict__ h2d, const float* __restrict__ h3d, const float* __restrict__ p2W,
    const float* __restrict__ p2b, const float* __restrict__ p3W, const float* __restrict__ p3b,
    const float* __restrict__ gW1, const float* __restrict__ gb1, const float* __restrict__ gW2,
    const float* __restrict__ gb2, const float* __restrict__ cW1, const float* __restrict__ cb1,
    const float* __restrict__ cW2, const float* __restrict__ cb2, float* __restrict__ out) {
  __shared__ float sx[DEMB], sy[DSCH], h2p[DEMB], h3p[DEMB], ghl[DSCH], c1l[150];
  __shared__ float pa[2][128], pb[2][128];
  __shared__ float gshare;
  int g = blockIdx.x, tid = threadIdx.x;
  int half = tid >> 7, o7 = tid & 127;
  for (int i = tid; i < DEMB; i += 256) sx[i] = h2d[(size_t)g * DEMB + i];
  if (tid < DSCH) sy[tid] = h3d[(size_t)g * DSCH + tid];
  __syncthreads();
  for (int ob = 0; ob < DEMB; ob += 128) {
    int o = ob + o7;
    float a0 = 0.f, a1 = 0.f, b0 = 0.f, b1 = 0.f;
    if (o < DEMB) {
      int kb = half * 150;
      for (int k = kb; k < kb + 150; k += 2) {
        a0 = fmaf(sx[k], p2W[k * 300 + o], a0);
        a1 = fmaf(sx[k + 1], p2W[(k + 1) * 300 + o], a1);
      }
      int kb3 = half * 64;
      for (int k = kb3; k < kb3 + 64; k += 2) {
        b0 = fmaf(sy[k], p3W[k * 300 + o], b0);
        b1 = fmaf(sy[k + 1], p3W[(k + 1) * 300 + o], b1);
      }
    }
    pa[half][o7] = a0 + a1;
    pb[half][o7] = b0 + b1;
    __syncthreads();
    if (half == 0 && o < DEMB) {
      h2p[o] = pa[0][o7] + pa[1][o7] + p2b[o];
      h3p[o] = pb[0][o7] + pb[1][o7] + p3b[o];
    }
    __syncthreads();
  }
  {
    const float* src = (half == 0) ? h2p : h3p;
    const float* wb = gW1 + (half ? 300 * 128 : 0);
    float a0 = 0.f, a1 = 0.f, a2 = 0.f, a3 = 0.f;
    for (int k = 0; k < 300; k += 4) {
      a0 = fmaf(src[k], wb[k * 128 + o7], a0);
      a1 = fmaf(src[k + 1], wb[(k + 1) * 128 + o7], a1);
      a2 = fmaf(src[k + 2], wb[(k + 2) * 128 + o7], a2);
      a3 = fmaf(src[k + 3], wb[(k + 3) * 128 + o7], a3);
    }
    pa[half][o7] = (a0 + a1) + (a2 + a3);
    __syncthreads();
    if (half == 0) ghl[o7] = fmaxf(pa[0][o7] + pa[1][o7] + gb1[o7], 0.f);
    __syncthreads();
  }
  if (tid < 128) pa[0][tid] = ghl[tid] * gW2[tid];
  __syncthreads();
  for (int s = 64; s > 0; s >>= 1) {
    if (tid < s) pa[0][tid] += pa[0][tid + s];
    __syncthreads();
  }
  if (tid == 0) gshare = 1.0f / (1.0f + expf(-(pa[0][0] + gb2[0])));
  __syncthreads();
  float gg = gshare;
  for (int i = tid; i < DEMB; i += 256) sx[i] = gg * h2p[i] + (1.0f - gg) * h3p[i];
  __syncthreads();
  for (int ob = 0; ob < 150; ob += 128) {
    int o = ob + o7;
    float a0 = 0.f, a1 = 0.f;
    if (o < 150) {
      int kb = half * 150;
      for (int k = kb; k < kb + 150; k += 2) {
        a0 = fmaf(sx[k], cW1[k * 150 + o], a0);
        a1 = fmaf(sx[k + 1], cW1[(k + 1) * 150 + o], a1);
      }
    }
    pa[half][o7] = a0 + a1;
    __syncthreads();
    if (half == 0 && o < 150) c1l[o] = fmaxf(pa[0][o7] + pa[1][o7] + cb1[o], 0.f);
    __syncthreads();
  }
  if (tid < 12) {
    float a = cb2[tid];
    for (int k = 0; k < 150; ++k) a = fmaf(c1l[k], cW2[k * 12 + tid], a);
    out[(size_t)g * 12 + tid] = a;
  }
}

// ---------------- gather aggregations ----------------

__global__ __launch_bounds__(256) void k_gin_gather4(
    const short* __restrict__ hb, const short* __restrict__ vnb, const int* __restrict__ batch,
    const int* __restrict__ off2, const int* __restrict__ s2s, const int* __restrict__ ec2s,
    const int* __restrict__ b2s, const float* __restrict__ bond1,
    const float* __restrict__ bond2, short* __restrict__ aggb) {
  __shared__ float sb[9 * DEMB];
  int tid = threadIdx.x;
  for (int i = tid; i < 6 * DEMB; i += 256) sb[i] = bond1[i];
  for (int i = tid; i < 3 * DEMB; i += 256) sb[6 * DEMB + i] = bond2[i];
  __syncthreads();
  int d = blockIdx.x * 4 + (tid >> 6);
  int lane = tid & 63;
  int j0 = off2[d], j1 = off2[d + 1];
  const unsigned short* hd = (const unsigned short*)hb + (size_t)d * DEMB;
  const unsigned short* vd = (const unsigned short*)vnb + (size_t)batch[d] * DEMB;
  float acc[5];
#pragma unroll
  for (int q = 0; q < 5; ++q) {
    int col = lane + 64 * q;
    acc[q] = (col < DEMB) ? b2f(hd[col]) + b2f(vd[col]) : 0.f;
  }
  for (int j = j0; j < j1; ++j) {
    int s = s2s[j], ec = ec2s[j], bs = b2s[j];
    const unsigned short* hr = (const unsigned short*)hb + (size_t)s * DEMB;
    const unsigned short* vr = (const unsigned short*)vnb + (size_t)bs * DEMB;
    const float* b1 = sb + (ec >> 2) * DEMB;
    const float* b2 = sb + 6 * DEMB + (ec & 3) * DEMB;
#pragma unroll
    for (int q = 0; q < 5; ++q) {
      int col = lane + 64 * q;
      if (col < DEMB) acc[q] += fmaxf(b2f(hr[col]) + b2f(vr[col]) + b1[col] + b2[col], 0.f);
    }
  }
  short* outr = aggb + (size_t)d * 320;
#pragma unroll
  for (int q = 0; q < 5; ++q) {
    int col = lane + 64 * q;
    outr[col] = (col < DEMB) ? f2b(acc[q]) : (short)0;
  }
}

__global__ __launch_bounds__(256) void k_conv_gather4(
    const short* __restrict__ ftabb, const short* __restrict__ x1b, const int* __restrict__ off3,
    const int* __restrict__ s3s, const int* __restrict__ id3s, const float* __restrict__ fr3s,
    short* __restrict__ agg3b) {
  int tid = threadIdx.x;
  int d = blockIdx.x * 4 + (tid >> 6);
  int lane = tid & 63;
  int j0 = off3[d], j1 = off3[d + 1];
  float a0 = 0.f, a1 = 0.f;
  for (int j = j0; j < j1; ++j) {
    int s = s3s[j], idx = id3s[j];
    float fr = fr3s[j];
    unsigned t0 = ((const unsigned*)(ftabb + (size_t)idx * 128))[lane];
    unsigned t1 = ((const unsigned*)(ftabb + (size_t)(idx + 1) * 128))[lane];
    unsigned xv = ((const unsigned*)(x1b + (size_t)s * 128))[lane];
    float t0a = b2f((unsigned short)(t0 & 0xFFFF)), t0b = b2f((unsigned short)(t0 >> 16));
    float t1a = b2f((unsigned short)(t1 & 0xFFFF)), t1b = b2f((unsigned short)(t1 >> 16));
    a0 += (t0a + fr * (t1a - t0a)) * b2f((unsigned short)(xv & 0xFFFF));
    a1 += (t0b + fr * (t1b - t0b)) * b2f((unsigned short)(xv >> 16));
  }
  unsigned pack = ((unsigned)(unsigned short)f2b(a1) << 16) | (unsigned short)f2b(a0);
  ((unsigned*)(agg3b + (size_t)d * 128))[lane] = pack;
}

// pool bf16 rows [*,300] -> f32 mean
__global__ __launch_bounds__(256) void k_poolb300(const short* __restrict__ xb,
                                                  const int* __restrict__ goff,
                                                  float* __restrict__ out) {
  int g = blockIdx.x * 4 + (threadIdx.x >> 6);
  int lane = threadIdx.x & 63;
  if (g >= NG) return;
  int r0 = goff[g], r1 = goff[g + 1];
  float acc[5] = {};
  for (int r = r0; r < r1; ++r) {
    const unsigned short* row = (const unsigned short*)xb + (size_t)r * DEMB;
#pragma unroll
    for (int q = 0; q < 5; ++q) {
      int col = lane + 64 * q;
      if (col < DEMB) acc[q] += b2f(row[col]);
    }
  }
  float s = 1.0f / fmaxf((float)(r1 - r0), 1.0f);
#pragma unroll
  for (int q = 0; q < 5; ++q) {
    int col = lane + 64 * q;
    if (col < DEMB) out[(size_t)g * DEMB + col] = acc[q] * s;
  }
}

// pool bf16 rows [*,128] -> f32 mean
__global__ __launch_bounds__(256) void k_poolb128(const short* __restrict__ xb,
                                                  const int* __restrict__ goff,
                                                  float* __restrict__ out) {
  int g = blockIdx.x * 4 + (threadIdx.x >> 6);
  int lane = threadIdx.x & 63;
  if (g >= NG) return;
  int r0 = goff[g], r1 = goff[g + 1];
  float a0 = 0.f, a1 = 0.f;
  for (int r = r0; r < r1; ++r) {
    unsigned v = ((const unsigned*)(xb + (size_t)r * DSCH))[lane];
    a0 += b2f((unsigned short)(v & 0xFFFF));
    a1 += b2f((unsigned short)(v >> 16));
  }
  float s = 1.0f / fmaxf((float)(r1 - r0), 1.0f);
  out[(size_t)g * DSCH + lane * 2] = a0 * s;
  out[(size_t)g * DSCH + lane * 2 + 1] = a1 * s;
}

// fused: vnab[g][320] = bf16( sum_rows(hb) + vn[g] )
__global__ __launch_bounds__(256) void k_poolvn(const short* __restrict__ hb,
                                                const int* __restrict__ goff,
                                                const float* __restrict__ vn,
                                                short* __restrict__ vnab) {
  int g = blockIdx.x * 4 + (threadIdx.x >> 6);
  int lane = threadIdx.x & 63;
  if (g >= NG) return;
  int r0 = goff[g], r1 = goff[g + 1];
  float acc[5] = {};
  for (int r = r0; r < r1; ++r) {
    const unsigned short* row = (const unsigned short*)hb + (size_t)r * DEMB;
#pragma unroll
    for (int q = 0; q < 5; ++q) {
      int col = lane + 64 * q;
      if (col < DEMB) acc[q] += b2f(row[col]);
    }
  }
  short* outr = vnab + (size_t)g * 320;
#pragma unroll
  for (int q = 0; q < 5; ++q) {
    int col = lane + 64 * q;
    if (col < 320)
      outr[col] = (col < DEMB) ? f2b(acc[q] + vn[(size_t)g * DEMB + col]) : (short)0;
  }
}

// ---------------- weight prep (consolidated) ----------------
__global__ void k_prepw2(const float* __restrict__ Wa, const float* __restrict__ Wb,
                         short* __restrict__ Wta, short* __restrict__ Wtb, int K, int N, int Kp,
                         int Np, int La, int Lb) {
  int i = blockIdx.x * blockDim.x + threadIdx.x;
  int per = Np * Kp;
  if (i >= (La + Lb) * per) return;
  int l = i / per, r = i - l * per;
  int n = r / Kp, k = r - n * Kp;
  const float* W = (l < La) ? Wa : Wb;
  int ll = (l < La) ? l : l - La;
  short* Wt = (l < La) ? Wta : Wtb;
  float v = (n < N && k < K) ? W[(size_t)ll * K * N + (size_t)k * N + n] : 0.f;
  Wt[(size_t)ll * per + r] = f2b(v);
}

__global__ void k_prepw3(const float* __restrict__ W0, const float* __restrict__ W1,
                         const float* __restrict__ W2, short* __restrict__ T0,
                         short* __restrict__ T1, short* __restrict__ T2) {
  int i = blockIdx.x * blockDim.x + threadIdx.x;
  const int per = 6 * 128 * 128;
  if (i >= 3 * per) return;
  int which = i / per, r = i - which * per;
  int l = r / 16384, rr = r - l * 16384;
  int n = rr / 128, k = rr - n * 128;
  const float* W = (which == 0) ? W0 : (which == 1) ? W1 : W2;
  short* T = (which == 0) ? T0 : (which == 1) ? T1 : T2;
  T[r] = f2b(W[(size_t)l * 16384 + (size_t)k * 128 + n]);
}

// ---------------- z-batched fp32 GEMM; optional bf16 output ----------------
template <int ACT>
__global__ __launch_bounds__(256) void k_gemmz(
    const float* __restrict__ A, const float* __restrict__ B, const float* __restrict__ bias,
    const float* __restrict__ rscale, float* __restrict__ Cout, short* __restrict__ Coutb,
    int M, int N, int K, int ldc, long strideA, long strideB, long strideBias, long strideC) {
  A += (size_t)blockIdx.z * strideA;
  B += (size_t)blockIdx.z * strideB;
  bias += (size_t)blockIdx.z * strideBias;
  __shared__ float sA[16][65];
  __shared__ float sB[16][64];
  int tid = threadIdx.x;
  int tx = tid & 15, ty = tid >> 4;
  int bm = blockIdx.y * 64, bn = blockIdx.x * 64;
  float acc[4][4] = {};
  for (int k0 = 0; k0 < K; k0 += 16) {
#pragma unroll
    for (int t = 0; t < 4; ++t) {
      int i = tid + t * 256;
      int m = i >> 4, kk = i & 15;
      int gm = bm + m, gk = k0 + kk;
      sA[kk][m] = (gm < M && gk < K) ? A[(size_t)gm * K + gk] : 0.f;
    }
#pragma unroll
    for (int t = 0; t < 4; ++t) {
      int i = tid + t * 256;
      int kk = i >> 6, n = i & 63;
      int gk = k0 + kk, gn = bn + n;
      sB[kk][n] = (gk < K && gn < N) ? B[(size_t)gk * N + gn] : 0.f;
    }
    __syncthreads();
#pragma unroll
    for (int kk = 0; kk < 16; ++kk) {
      float a[4], b[4];
#pragma unroll
      for (int i = 0; i < 4; ++i) a[i] = sA[kk][ty + 16 * i];
#pragma unroll
      for (int j = 0; j < 4; ++j) b[j] = sB[kk][tx + 16 * j];
#pragma unroll
      for (int i = 0; i < 4; ++i)
#pragma unroll
        for (int j = 0; j < 4; ++j) acc[i][j] = fmaf(a[i], b[j], acc[i][j]);
    }
    __syncthreads();
  }
#pragma unroll
  for (int i = 0; i < 4; ++i) {
    int gm = bm + ty + 16 * i;
    if (gm >= M) continue;
    float rs = rscale ? rscale[gm] : 1.0f;
#pragma unroll
    for (int j = 0; j < 4; ++j) {
      int gn = bn + tx + 16 * j;
      if (gn >= N) continue;
      float v = acc[i][j] + bias[gn];
      if (ACT == 1) v = fmaxf(v, 0.f);
      if (ACT == 2) v = sspf(v);
      v *= rs;
      if (Cout) Cout[(size_t)blockIdx.z * strideC + (size_t)gm * ldc + gn] = v;
      if (Coutb) Coutb[(size_t)blockIdx.z * strideC + (size_t)gm * ldc + gn] = f2b(v);
    }
  }
}

// ---------------- bf16 MFMA GEMM, 128x128 tile ----------------
template <int ACT>
__global__ __launch_bounds__(256) void k_mgemm_bf(
    const short* __restrict__ Ab, const short* __restrict__ Wt, const float* __restrict__ bias,
    const float* __restrict__ scale, const float* __restrict__ shift,
    const float* __restrict__ Cin, float* __restrict__ Cout, short* __restrict__ Coutb,
    int M, int N, int Kp, int ldc, int ldcb, int Nb) {
  __shared__ short sA[128 * 32];
  const int tid = threadIdx.x;
  const int lane = tid & 63;
  const int w = tid >> 6;
  const int wm = w >> 1, wn = w & 1;
  const int bm = blockIdx.y * 128, bn = blockIdx.x * 128;

  f32x4 acc[4][4] = {};

  const int sr = tid >> 1;
  const int sk = (tid & 1) * 16;
  const short* Arow = Ab + (size_t)(bm + sr) * Kp + sk;
  const int ssw = (sr + (sr >> 2)) & 3;
  const int s0 = (sk >> 3);
  bf16x8* sAv = (bf16x8*)sA;

  const int frow = wm * 64 + (lane & 15);
  const int fslot = lane >> 4;
  const short* Bbase = Wt + (size_t)(bn + wn * 64 + (lane & 15)) * Kp + (fslot * 8);

  for (int k0 = 0; k0 < Kp; k0 += 32) {
    __syncthreads();
    {
      bf16x8 p0 = *(const bf16x8*)(Arow + k0);
      bf16x8 p1 = *(const bf16x8*)(Arow + k0 + 8);
      sAv[sr * 4 + ((s0 + 0) ^ ssw)] = p0;
      sAv[sr * 4 + ((s0 + 1) ^ ssw)] = p1;
    }
    __syncthreads();

    bf16x8 af[4], bfr[4];
#pragma unroll
    for (int mf = 0; mf < 4; ++mf) {
      int r = frow + mf * 16;
      af[mf] = sAv[r * 4 + (fslot ^ ((r + (r >> 2)) & 3))];
    }
#pragma unroll
    for (int nf = 0; nf < 4; ++nf) bfr[nf] = *(const bf16x8*)(Bbase + (size_t)nf * 16 * Kp + k0);
#pragma unroll
    for (int mf = 0; mf < 4; ++mf)
#pragma unroll
      for (int nf = 0; nf < 4; ++nf)
        acc[mf][nf] =
            __builtin_amdgcn_mfma_f32_16x16x32_bf16(af[mf], bfr[nf], acc[mf][nf], 0, 0, 0);
  }

  const int colbase = bn + wn * 64 + (lane & 15);
  const int rowbase = bm + wm * 64 + ((lane >> 4) << 2);
#pragma unroll
  for (int nf = 0; nf < 4; ++nf) {
    int col = colbase + nf * 16;
    bool cv = col < N;
    float bi = (bias && cv) ? bias[col] : 0.f;
    float sc = (scale && cv) ? scale[col] : 1.f;
    float sh = (shift && cv) ? shift[col] : 0.f;
#pragma unroll
    for (int mf = 0; mf < 4; ++mf) {
      f32x4 v = acc[mf][nf];
#pragma unroll
      for (int j = 0; j < 4; ++j) {
        int row = rowbase + mf * 16 + j;
        float x = v[j] + bi;
        if (scale) x = x * sc + sh;
        if (ACT == 1) x = fmaxf(x, 0.f);
        if (ACT == 2) x = sspf(x);
        if (Cin && cv) x += Cin[(size_t)row * ldc + col];
        if (Cout && cv) Cout[(size_t)row * ldc + col] = x;
        if (Coutb && col < Nb) Coutb[(size_t)row * ldcb + col] = cv ? f2b(x) : (short)0;
      }
    }
  }
}

// ---------------- bf16 MFMA GEMM, 64x128 tile ----------------
template <int ACT>
__global__ __launch_bounds__(256) void k_mgemm_bf64(
    const short* __restrict__ Ab, const short* __restrict__ Wt, const float* __restrict__ bias,
    const float* __restrict__ scale, const float* __restrict__ shift,
    const float* __restrict__ Cin, float* __restrict__ Cout, short* __restrict__ Coutb,
    int M, int N, int Kp, int ldc, int ldcb, int Nb) {
  __shared__ short sA[64 * 32];
  const int tid = threadIdx.x;
  const int lane = tid & 63;
  const int w = tid >> 6;
  const int bm = blockIdx.y * 64, bn = blockIdx.x * 128;

  f32x4 acc[4][2] = {};

  const int sr = tid >> 2;
  const int sk = (tid & 3) * 8;
  const short* Arow = Ab + (size_t)(bm + sr) * Kp + sk;
  const int ssw = (sr + (sr >> 2)) & 3;
  const int s0 = tid & 3;
  bf16x8* sAv = (bf16x8*)sA;

  const int frow = lane & 15;
  const int fslot = lane >> 4;
  const short* Bbase = Wt + (size_t)(bn + w * 32 + (lane & 15)) * Kp + (fslot * 8);

  for (int k0 = 0; k0 < Kp; k0 += 32) {
    __syncthreads();
    sAv[sr * 4 + (s0 ^ ssw)] = *(const bf16x8*)(Arow + k0);
    __syncthreads();

    bf16x8 af[4], bfr[2];
#pragma unroll
    for (int mf = 0; mf < 4; ++mf) {
      int r = frow + mf * 16;
      af[mf] = sAv[r * 4 + (fslot ^ ((r + (r >> 2)) & 3))];
    }
#pragma unroll
    for (int nf = 0; nf < 2; ++nf) bfr[nf] = *(const bf16x8*)(Bbase + (size_t)nf * 16 * Kp + k0);
#pragma unroll
    for (int mf = 0; mf < 4; ++mf)
#pragma unroll
      for (int nf = 0; nf < 2; ++nf)
        acc[mf][nf] =
            __builtin_amdgcn_mfma_f32_16x16x32_bf16(af[mf], bfr[nf], acc[mf][nf], 0, 0, 0);
  }

  const int colbase = bn + w * 32 + (lane & 15);
  const int rowbase = bm + ((lane >> 4) << 2);
#pragma unroll
  for (int nf = 0; nf < 2; ++nf) {
    int col = colbase + nf * 16;
    bool cv = col < N;
    float bi = (bias && cv) ? bias[col] : 0.f;
    float sc = (scale && cv) ? scale[col] : 1.f;
    float sh = (shift && cv) ? shift[col] : 0.f;
#pragma unroll
    for (int mf = 0; mf < 4; ++mf) {
      f32x4 v = acc[mf][nf];
#pragma unroll
      for (int j = 0; j < 4; ++j) {
        int row = rowbase + mf * 16 + j;
        float x = v[j] + bi;
        if (scale) x = x * sc + sh;
        if (ACT == 1) x = fmaxf(x, 0.f);
        if (ACT == 2) x = sspf(x);
        if (Cin && cv) x += Cin[(size_t)row * ldc + col];
        if (Cout && cv) Cout[(size_t)row * ldc + col] = x;
        if (Coutb && col < Nb) Coutb[(size_t)row * ldcb + col] = cv ? f2b(x) : (short)0;
      }
    }
  }
}

// ---------------- fused SchNet layer: y=ssp(A@W2+b2); hnew=hs+y@W3+b3; x1'=hnew@W1n ----------------
// 64 rows/block, N=128, K=128 for all three GEMMs. Whole A-tile LDS-resident.
template <int LAST>
__global__ __launch_bounds__(256) void k_sch_fused(
    const short* __restrict__ agg3b, const short* __restrict__ W2t, const float* __restrict__ b2,
    const short* __restrict__ W3t, const float* __restrict__ b3, const short* __restrict__ W1n,
    float* __restrict__ hs, short* __restrict__ hsb, short* __restrict__ x1b) {
  __shared__ short sA[64 * 128];
  __shared__ short sY[64 * 128];
  const int tid = threadIdx.x;
  const int lane = tid & 63;
  const int w = tid >> 6;
  const int bm = blockIdx.x * 64;
  bf16x8* sAv = (bf16x8*)sA;
  bf16x8* sYv = (bf16x8*)sY;
  // stage A (agg3b rows) into swizzled slots: slot(row, c, s) = row*16 + c*4 + (s ^ ssw(row))
  {
    int r = tid >> 2, q = tid & 3;
    int ssw = (r + (r >> 2)) & 3;
    const short* Arow = agg3b + (size_t)(bm + r) * 128 + q * 8;
#pragma unroll
    for (int c = 0; c < 4; ++c) sAv[r * 16 + c * 4 + (q ^ ssw)] = *(const bf16x8*)(Arow + c * 32);
  }
  __syncthreads();
  const int frow = lane & 15;
  const int fslot = lane >> 4;
  const int colw = w * 32 + (lane & 15);
  const int rw0 = (lane >> 4) << 2;
  // GEMM1 -> sY
  {
    f32x4 acc[4][2] = {};
    const short* Bbase = W2t + (size_t)colw * 128 + fslot * 8;
#pragma unroll
    for (int c = 0; c < 4; ++c) {
      bf16x8 af[4], bfr[2];
#pragma unroll
      for (int mf = 0; mf < 4; ++mf) {
        int r = frow + mf * 16;
        af[mf] = sAv[r * 16 + c * 4 + (fslot ^ ((r + (r >> 2)) & 3))];
      }
#pragma unroll
      for (int nf = 0; nf < 2; ++nf) bfr[nf] = *(const bf16x8*)(Bbase + nf * 16 * 128 + c * 32);
#pragma unroll
      for (int mf = 0; mf < 4; ++mf)
#pragma unroll
        for (int nf = 0; nf < 2; ++nf)
          acc[mf][nf] =
              __builtin_amdgcn_mfma_f32_16x16x32_bf16(af[mf], bfr[nf], acc[mf][nf], 0, 0, 0);
    }
#pragma unroll
    for (int nf = 0; nf < 2; ++nf) {
      int cl = colw + nf * 16;
      float bi = b2[cl];
#pragma unroll
      for (int mf = 0; mf < 4; ++mf)
#pragma unroll
        for (int j = 0; j < 4; ++j) {
          int rw = rw0 + mf * 16 + j;
          float y = sspf(acc[mf][nf][j] + bi);
          int slot = (cl >> 5) * 4 + (((cl >> 3) & 3) ^ ((rw + (rw >> 2)) & 3));
          sY[rw * 128 + slot * 8 + (cl & 7)] = f2b(y);
        }
    }
  }
  __syncthreads();
  // GEMM2 -> hs (f32), hsb, and sA (bf16, for GEMM3)
  {
    f32x4 acc[4][2] = {};
    const short* Bbase = W3t + (size_t)colw * 128 + fslot * 8;
#pragma unroll
    for (int c = 0; c < 4; ++c) {
      bf16x8 af[4], bfr[2];
#pragma unroll
      for (int mf = 0; mf < 4; ++mf) {
        int r = frow + mf * 16;
        af[mf] = sYv[r * 16 + c * 4 + (fslot ^ ((r + (r >> 2)) & 3))];
      }
#pragma unroll
      for (int nf = 0; nf < 2; ++nf) bfr[nf] = *(const bf16x8*)(Bbase + nf * 16 * 128 + c * 32);
#pragma unroll
      for (int mf = 0; mf < 4; ++mf)
#pragma unroll
        for (int nf = 0; nf < 2; ++nf)
          acc[mf][nf] =
              __builtin_amdgcn_mfma_f32_16x16x32_bf16(af[mf], bfr[nf], acc[mf][nf], 0, 0, 0);
    }
#pragma unroll
    for (int nf = 0; nf < 2; ++nf) {
      int cl = colw + nf * 16;
      float bi = b3[cl];
#pragma unroll
      for (int mf = 0; mf < 4; ++mf)
#pragma unroll
        for (int j = 0; j < 4; ++j) {
          int rw = rw0 + mf * 16 + j;
          size_t gi = (size_t)(bm + rw) * 128 + cl;
          float x = acc[mf][nf][j] + bi + hs[gi];
          hs[gi] = x;
          short xb = f2b(x);
          hsb[gi] = xb;
          int slot = (cl >> 5) * 4 + (((cl >> 3) & 3) ^ ((rw + (rw >> 2)) & 3));
          sA[rw * 128 + slot * 8 + (cl & 7)] = xb;
        }
    }
  }
  if (LAST) return;
  __syncthreads();
  // GEMM3 -> x1b for next layer
  {
    f32x4 acc[4][2] = {};
    const short* Bbase = W1n + (size_t)colw * 128 + fslot * 8;
#pragma unroll
    for (int c = 0; c < 4; ++c) {
      bf16x8 af[4], bfr[2];
#pragma unroll
      for (int mf = 0; mf < 4; ++mf) {
        int r = frow + mf * 16;
        af[mf] = sAv[r * 16 + c * 4 + (fslot ^ ((r + (r >> 2)) & 3))];
      }
#pragma unroll
      for (int nf = 0; nf < 2; ++nf) bfr[nf] = *(const bf16x8*)(Bbase + nf * 16 * 128 + c * 32);
#pragma unroll
      for (int mf = 0; mf < 4; ++mf)
#pragma unroll
        for (int nf = 0; nf < 2; ++nf)
          acc[mf][nf] =
              __builtin_amdgcn_mfma_f32_16x16x32_bf16(af[mf], bfr[nf], acc[mf][nf], 0, 0, 0);
    }
#pragma unroll
    for (int nf = 0; nf < 2; ++nf) {
      int cl = colw + nf * 16;
#pragma unroll
      for (int mf = 0; mf < 4; ++mf)
#pragma unroll
        for (int j = 0; j < 4; ++j) {
          int rw = rw0 + mf * 16 + j;
          x1b[(size_t)(bm + rw) * 128 + cl] = f2b(acc[mf][nf][j]);
        }
    }
  }
}

// ---------------- host ----------------

static inline void run_mgemm_bf(hipStream_t st, const short* Ab, const short* Wt,
                                const float* bias, const float* scale, const float* shift,
                                const float* Cin, float* Cout, short* Coutb, int M, int N, int Kp,
                                int ldc, int ldcb, int Nb, int act) {
  dim3 grid((N + 127) / 128, M / 128);
  if (act == 0)
    k_mgemm_bf<0><<<grid, 256, 0, st>>>(Ab, Wt, bias, scale, shift, Cin, Cout, Coutb, M, N, Kp,
                                        ldc, ldcb, Nb);
  else if (act == 1)
    k_mgemm_bf<1><<<grid, 256, 0, st>>>(Ab, Wt, bias, scale, shift, Cin, Cout, Coutb, M, N, Kp,
                                        ldc, ldcb, Nb);
  else
    k_mgemm_bf<2><<<grid, 256, 0, st>>>(Ab, Wt, bias, scale, shift, Cin, Cout, Coutb, M, N, Kp,
                                        ldc, ldcb, Nb);
}

static inline void run_mgemm_bf64(hipStream_t st, const short* Ab, const short* Wt,
                                  const float* bias, const float* scale, const float* shift,
                                  const float* Cin, float* Cout, short* Coutb, int M, int N,
                                  int Kp, int ldc, int ldcb, int Nb, int act) {
  dim3 grid((N + 127) / 128, M / 64);
  if (act == 0)
    k_mgemm_bf64<0><<<grid, 256, 0, st>>>(Ab, Wt, bias, scale, shift, Cin, Cout, Coutb, M, N, Kp,
                                          ldc, ldcb, Nb);
  else if (act == 1)
    k_mgemm_bf64<1><<<grid, 256, 0, st>>>(Ab, Wt, bias, scale, shift, Cin, Cout, Coutb, M, N, Kp,
                                          ldc, ldcb, Nb);
  else
    k_mgemm_bf64<2><<<grid, 256, 0, st>>>(Ab, Wt, bias, scale, shift, Cin, Cout, Coutb, M, N, Kp,
                                          ldc, ldcb, Nb);
}

extern "C" void kernel_launch(void* const* d_in, const int* in_sizes, int n_in, void* d_out,
                              int out_size, void* d_ws, size_t ws_size, hipStream_t stream) {
  const int* x2d = (const int*)d_in[0];
  const int* ei2 = (const int*)d_in[1];
  const int* ea2 = (const int*)d_in[2];
  const int* batch = (const int*)d_in[3];
  const int* z = (const int*)d_in[4];
  const float* pos = (const float*)d_in[5];
  const int* ei3 = (const int*)d_in[6];
  const float* atom_emb1 = (const float*)d_in[7];
  const float* atom_emb2 = (const float*)d_in[8];
  const float* vn_init = (const float*)d_in[9];
  const float* gin_W1 = (const float*)d_in[10];
  const float* gin_b1 = (const float*)d_in[11];
  const float* gin_W2 = (const float*)d_in[12];
  const float* gin_b2 = (const float*)d_in[13];
  const float* gin_bond1 = (const float*)d_in[14];
  const float* gin_bond2 = (const float*)d_in[15];
  const float* gin_gamma = (const float*)d_in[16];
  const float* gin_beta = (const float*)d_in[17];
  const float* vn_W1 = (const float*)d_in[18];
  const float* vn_b1 = (const float*)d_in[19];
  const float* vn_W2 = (const float*)d_in[20];
  const float* vn_b2 = (const float*)d_in[21];
  const float* sch_emb = (const float*)d_in[22];
  const float* s_mW1 = (const float*)d_in[23];
  const float* s_mb1 = (const float*)d_in[24];
  const float* s_mW2 = (const float*)d_in[25];
  const float* s_mb2 = (const float*)d_in[26];
  const float* s_lin1W = (const float*)d_in[27];
  const float* s_lin2W = (const float*)d_in[28];
  const float* s_lin2b = (const float*)d_in[29];
  const float* s_linW = (const float*)d_in[30];
  const float* s_linb = (const float*)d_in[31];
  const float* p2W = (const float*)d_in[32];
  const float* p2b = (const float*)d_in[33];
  const float* p3W = (const float*)d_in[34];
  const float* p3b = (const float*)d_in[35];
  const float* gW1 = (const float*)d_in[36];
  const float* gb1 = (const float*)d_in[37];
  const float* gW2 = (const float*)d_in[38];
  const float* gb2 = (const float*)d_in[39];
  const float* cW1 = (const float*)d_in[40];
  const float* cb1 = (const float*)d_in[41];
  const float* cW2 = (const float*)d_in[42];
  const float* cb2 = (const float*)d_in[43];

  float* ws = (float*)d_ws;
  // GIN phase
  short* hb = (short*)ws;
  int* b2s = (int*)(ws + 2500000);
  short* aggb = (short*)(ws + 5000000);
  short* y1b = (short*)(ws + 7700000);
  // SchNet phase (aliases GIN region)
  float* rbs = ws + 400000;
  float* Cs = ws + 700000;
  float* t1all = ws + 800000;
  short* ftabb = (short*)(ws + 4800000);
  float* hs = ws + 8800000;
  short* x1b = (short*)(ws + 11000000);
  short* agg3b = (short*)(ws + 13200000);
  short* hsb = (short*)(ws + 15400000);
  // bf16 transposed weights
  short* W1t = (short*)(ws + 20000000);
  short* W2t = (short*)(ws + 20600000);
  short* s1t = (short*)(ws + 21200000);
  short* s2t = (short*)(ws + 21300000);
  short* s3t = (short*)(ws + 21400000);
  // CSR region
  int* I = (int*)(ws + 22000000);
  int* cnt2 = I + 0;
  int* cnt3 = I + 16384;
  int* cntg = I + 32768;
  int* cur2 = I + 33280;
  int* cur3 = I + 49664;  // zero region = 66048 ints
  int* off2 = I + 70000;
  int* off3 = I + 90000;
  int* goff = I + 110000;
  int* s2s = I + 120000;
  int* ec2s = I + 190000;
  int* s3s = I + 260000;
  int* id3s = I + 660000;
  float* fr3s = (float*)(I + 1060000);
  // vn-MLP bf16 weights + buffers
  short* vnW1t = (short*)(ws + 23500000);
  short* vnW2t = (short*)(ws + 24000000);
  short* vnab = (short*)(ws + 24500000);
  short* vnhb = (short*)(ws + 24600000);
  short* vnb = (short*)(ws + 24800000);
  // persistent tail
  float* vn = ws + 28443136;
  float* h2d = ws + 29057536;
  float* h3d = ws + 29211136;

  // ---- weight prep ----
  k_prepw2<<<(9 * 640 * 320 + 255) / 256, 256, 0, stream>>>(gin_W1, vn_W1, W1t, vnW1t, 300, 600,
                                                            320, 640, 5, 4);
  k_prepw2<<<(9 * 384 * 608 + 255) / 256, 256, 0, stream>>>(gin_W2, vn_W2, W2t, vnW2t, 600, 300,
                                                            608, 384, 5, 4);
  k_prepw3<<<(3 * 6 * 16384 + 255) / 256, 256, 0, stream>>>(s_lin1W, s_lin2W, s_linW, s1t, s2t,
                                                            s3t);

  // ---- CSR build ----
  hipMemsetAsync(I, 0, 66048 * sizeof(int), stream);
  k_hist3<<<(NE2 + NE3 + NN + 255) / 256, 256, 0, stream>>>(ei2, ei3, batch, cnt2, cnt3, cntg);
  k_scan3<<<3, 1024, 0, stream>>>(cnt2, off2, 16384, cnt3, off3, 16384, cntg, goff, 512);
  k_scatterB<<<(NE2 + NE3 + 255) / 256, 256, 0, stream>>>(ei2, ea2, batch, off2, cur2, s2s, ec2s,
                                                          b2s, ei3, pos, off3, cur3, s3s, id3s,
                                                          fr3s);

  // ---- GIN ----
  k_init_gin<<<(NN * DEMB + NG * DEMB + 255) / 256, 256, 0, stream>>>(x2d, atom_emb1, atom_emb2,
                                                                      hb, vn_init, vn, vnb);
  for (int l = 0; l < 5; ++l) {
    k_gin_gather4<<<NN / 4, 256, 0, stream>>>(hb, vnb, batch, off2, s2s, ec2s, b2s,
                                              gin_bond1 + l * 6 * DEMB, gin_bond2 + l * 3 * DEMB,
                                              aggb);
    run_mgemm_bf(stream, aggb, W1t + (size_t)l * 640 * 320, gin_b1 + l * 600, nullptr, nullptr,
                 nullptr, nullptr, y1b, NN, 600, 320, 0, 608, 608, 1);
    run_mgemm_bf(stream, y1b, W2t + (size_t)l * 384 * 608, gin_b2 + l * 300, gin_gamma + l * 300,
                 gin_beta + l * 300, nullptr, nullptr, hb, NN, 300, 608, 0, 300, 300,
                 (l < 4) ? 1 : 0);
    if (l < 4) {
      k_poolvn<<<NG / 4, 256, 0, stream>>>(hb, goff, vn, vnab);
      run_mgemm_bf64(stream, vnab, vnW1t + (size_t)l * 640 * 320, vn_b1 + l * 600, nullptr,
                     nullptr, nullptr, nullptr, vnhb, NG, 600, 320, 0, 608, 608, 1);
      run_mgemm_bf64(stream, vnhb, vnW2t + (size_t)l * 384 * 608, vn_b2 + l * 300, nullptr,
                     nullptr, nullptr, vn, vnb, NG, 300, 608, 300, 300, 300, 1);
    }
  }
  k_poolb300<<<NG / 4, 256, 0, stream>>>(hb, goff, h2d);  // before SchNet clobbers hb region

  // ---- SchNet ----
  k_init_sch<<<(TROWS * NRBF + NN * DSCH + 255) / 256, 256, 0, stream>>>(rbs, Cs, z, sch_emb, hs,
                                                                         hsb);
  {
    dim3 ga(2, (TROWS + 63) / 64, 6);
    k_gemmz<2><<<ga, 256, 0, stream>>>(rbs, s_mW1, s_mb1, nullptr, t1all, nullptr, TROWS, 128, 50,
                                       128, 0L, 50L * 128, 128L, (long)TROWS * 128);
    k_gemmz<0><<<ga, 256, 0, stream>>>(t1all, s_mW2, s_mb2, Cs, nullptr, ftabb, TROWS, 128, 128,
                                       128, (long)TROWS * 128, 128L * 128, 128L,
                                       (long)TROWS * 128);
  }
  // x1 for layer 0
  run_mgemm_bf64(stream, hsb, s1t, nullptr, nullptr, nullptr, nullptr, nullptr, x1b, NN, 128, 128,
                 0, 128, 128, 0);
  for (int l = 0; l < 6; ++l) {
    k_conv_gather4<<<NN / 4, 256, 0, stream>>>(ftabb + (size_t)l * TROWS * 128, x1b, off3, s3s,
                                               id3s, fr3s, agg3b);
    if (l < 5)
      k_sch_fused<0><<<NN / 64, 256, 0, stream>>>(agg3b, s2t + (size_t)l * 16384,
                                                  s_lin2b + l * 128, s3t + (size_t)l * 16384,
                                                  s_linb + l * 128, s1t + (size_t)(l + 1) * 16384,
                                                  hs, hsb, x1b);
    else
      k_sch_fused<1><<<NN / 64, 256, 0, stream>>>(agg3b, s2t + (size_t)l * 16384,
                                                  s_lin2b + l * 128, s3t + (size_t)l * 16384,
                                                  s_linb + l * 128, s1t, hs, hsb, x1b);
  }
  k_poolb128<<<NG / 4, 256, 0, stream>>>(hsb, goff, h3d);

  // ---- fused head ----
  k_head5<<<NG, 256, 0, stream>>>(h2d, h3d, p2W, p2b, p3W, p3b, gW1, gb1, gW2, gb2, cW1, cb1, cW2,
                                  cb2, (float*)d_out);
}

// Round 13
// 1317.838 us; speedup vs baseline: 7.5657x; 1.0236x over previous
//
#include <hip/hip_runtime.h>
#include <hip/hip_bf16.h>
#include <math.h>

#define NN 16384
#define NG 512
#define NE2 65536
#define NE3 393216
#define DEMB 300
#define DSCH 128
#define NRBF 50
#define NTAB 5120
#define TROWS 5121
#define DMAX 25.0f

typedef __attribute__((ext_vector_type(8))) short bf16x8;
typedef __attribute__((ext_vector_type(4))) float f32x4;

__device__ __forceinline__ float sspf(float x) {
  float sp = log1pf(expf(-fabsf(x))) + fmaxf(x, 0.f);
  return sp - 0.69314718055994530942f;
}

__device__ __forceinline__ short f2b(float f) {
  union { float f; unsigned u; } v;
  v.f = f;
  unsigned r = v.u + 0x7FFF + ((v.u >> 16) & 1);  // RNE
  return (short)(r >> 16);
}

__device__ __forceinline__ float b2f(unsigned short b) {
  union { unsigned u; float f; } v;
  v.u = ((unsigned)b) << 16;
  return v.f;
}

__device__ __forceinline__ unsigned pk2(float a, float b) {
  return ((unsigned)(unsigned short)f2b(b) << 16) | (unsigned short)f2b(a);
}

// ---------------- CSR build ----------------

__global__ void k_hist3(const int* __restrict__ ei2, const int* __restrict__ ei3,
                        const int* __restrict__ batch, int* __restrict__ cnt2,
                        int* __restrict__ cnt3, int* __restrict__ cntg) {
  int i = blockIdx.x * blockDim.x + threadIdx.x;
  if (i < NE2) {
    atomicAdd(&cnt2[ei2[NE2 + i]], 1);
  } else if (i < NE2 + NE3) {
    atomicAdd(&cnt3[ei3[NE3 + (i - NE2)]], 1);
  } else if (i < NE2 + NE3 + NN) {
    atomicAdd(&cntg[batch[i - NE2 - NE3]], 1);
  }
}

__global__ __launch_bounds__(1024) void k_scan3(const int* __restrict__ c0, int* __restrict__ o0,
                                                int n0, const int* __restrict__ c1,
                                                int* __restrict__ o1, int n1,
                                                const int* __restrict__ c2, int* __restrict__ o2,
                                                int n2) {
  const int* cnt = (blockIdx.x == 0) ? c0 : (blockIdx.x == 1) ? c1 : c2;
  int* off = (blockIdx.x == 0) ? o0 : (blockIdx.x == 1) ? o1 : o2;
  int n = (blockIdx.x == 0) ? n0 : (blockIdx.x == 1) ? n1 : n2;
  __shared__ int part[1024];
  int tid = threadIdx.x;
  int per = (n + 1023) / 1024;
  int base = tid * per;
  int sum = 0;
  for (int i = 0; i < per; ++i) {
    int idx = base + i;
    if (idx < n) sum += cnt[idx];
  }
  part[tid] = sum;
  __syncthreads();
  for (int d = 1; d < 1024; d <<= 1) {
    int v = (tid >= d) ? part[tid - d] : 0;
    __syncthreads();
    part[tid] += v;
    __syncthreads();
  }
  int run = (tid == 0) ? 0 : part[tid - 1];
  for (int i = 0; i < per; ++i) {
    int idx = base + i;
    if (idx < n) {
      off[idx] = run;
      run += cnt[idx];
    }
  }
  if (tid == 0) off[n] = part[1023];
}

__global__ void k_scatterB(const int* __restrict__ ei2, const int* __restrict__ ea2,
                           const int* __restrict__ batch, const int* __restrict__ off2,
                           int* __restrict__ cur2, int* __restrict__ s2s, int* __restrict__ ec2s,
                           int* __restrict__ b2s, const int* __restrict__ ei3,
                           const float* __restrict__ pos, const int* __restrict__ off3,
                           int* __restrict__ cur3, int* __restrict__ s3s, int* __restrict__ id3s,
                           float* __restrict__ fr3s) {
  int i = blockIdx.x * blockDim.x + threadIdx.x;
  if (i < NE2) {
    int e = i;
    int s = ei2[e], d = ei2[NE2 + e];
    int p = atomicAdd(&cur2[d], 1);
    int j = off2[d] + p;
    s2s[j] = s;
    ec2s[j] = ea2[2 * e] * 4 + ea2[2 * e + 1];
    b2s[j] = batch[s];
  } else if (i < NE2 + NE3) {
    int e = i - NE2;
    int s = ei3[e], d = ei3[NE3 + e];
    float dx = pos[3 * d] - pos[3 * s];
    float dy = pos[3 * d + 1] - pos[3 * s + 1];
    float dz = pos[3 * d + 2] - pos[3 * s + 2];
    float dist = sqrtf(dx * dx + dy * dy + dz * dz);
    float u = fminf(dist * ((float)NTAB / DMAX), (float)NTAB - 0.001f);
    int idx = (int)u;
    int p = atomicAdd(&cur3[d], 1);
    int j = off3[d] + p;
    s3s[j] = s;
    id3s[j] = idx;
    fr3s[j] = u - (float)idx;
  }
}

// ---------------- consolidated init kernels ----------------

__global__ void k_init_gin(const int* __restrict__ x2d, const float* __restrict__ e1,
                           const float* __restrict__ e2, short* __restrict__ hb,
                           const float* __restrict__ vni, float* __restrict__ vn,
                           short* __restrict__ vnb) {
  int i = blockIdx.x * blockDim.x + threadIdx.x;
  if (i < NN * DEMB) {
    int n = i / DEMB, c = i - n * DEMB;
    hb[i] = f2b(e1[x2d[2 * n] * DEMB + c] + e2[x2d[2 * n + 1] * DEMB + c]);
  } else if (i < NN * DEMB + NG * DEMB) {
    int j = i - NN * DEMB;
    float v = vni[j % DEMB];
    vn[j] = v;
    vnb[j] = f2b(v);
  }
}

__global__ void k_init_sch(float* __restrict__ rbs, float* __restrict__ Cs,
                           const int* __restrict__ z, const float* __restrict__ emb,
                           float* __restrict__ hs, short* __restrict__ hsb) {
  int i = blockIdx.x * blockDim.x + threadIdx.x;
  if (i < TROWS * NRBF) {
    int j = i / NRBF, k = i - j * NRBF;
    float dj = (float)j * (DMAX / (float)NTAB);
    const float step = 10.0f / 49.0f;
    const float coeff = -0.5f / (step * step);
    float t = dj - (float)k * step;
    rbs[i] = expf(coeff * t * t);
    if (k == 0) Cs[j] = 0.5f * (cosf(dj * (3.14159265358979323846f / 10.0f)) + 1.0f);
  } else if (i < TROWS * NRBF + NN * DSCH) {
    int j = i - TROWS * NRBF;
    float v = emb[z[j >> 7] * DSCH + (j & 127)];
    hs[j] = v;
    hsb[j] = f2b(v);
  }
}

// ---------------- gather aggregations (uint-vectorized) ----------------

// GIN: aggb[d] = bf16( (hb[d]+vnb[b[d]]) + sum_e relu(hb[s]+vnb[b2s]+eemb) ); 4B/lane loads
__global__ __launch_bounds__(256) void k_gin_gather5(
    const short* __restrict__ hb, const short* __restrict__ vnb, const int* __restrict__ batch,
    const int* __restrict__ off2, const int* __restrict__ s2s, const int* __restrict__ ec2s,
    const int* __restrict__ b2s, const float* __restrict__ bond1,
    const float* __restrict__ bond2, short* __restrict__ aggb) {
  __shared__ unsigned sb[18 * 150];  // combined bond1[a0]+bond2[a1], bf16-pair packed
  int tid = threadIdx.x;
  for (int i = tid; i < 18 * 150; i += 256) {
    int c = i / 150, u = i - c * 150;
    int a0 = c / 3, a1 = c - a0 * 3;
    float v0 = bond1[a0 * 300 + 2 * u] + bond2[a1 * 300 + 2 * u];
    float v1 = bond1[a0 * 300 + 2 * u + 1] + bond2[a1 * 300 + 2 * u + 1];
    sb[i] = pk2(v0, v1);
  }
  __syncthreads();
  int d = blockIdx.x * 4 + (tid >> 6);
  int l = tid & 63;
  int j0 = off2[d], j1 = off2[d + 1];
  const unsigned* hu = (const unsigned*)hb + (size_t)d * 150;
  const unsigned* vu = (const unsigned*)vnb + (size_t)batch[d] * 150;
  const int u0 = l, u1 = l + 64, u2 = l + 128;
  const bool has2 = (u2 < 150);
  float acc[6];
  {
    unsigned a = hu[u0], b = vu[u0];
    acc[0] = b2f((unsigned short)a) + b2f((unsigned short)b);
    acc[1] = b2f((unsigned short)(a >> 16)) + b2f((unsigned short)(b >> 16));
    a = hu[u1]; b = vu[u1];
    acc[2] = b2f((unsigned short)a) + b2f((unsigned short)b);
    acc[3] = b2f((unsigned short)(a >> 16)) + b2f((unsigned short)(b >> 16));
    if (has2) {
      a = hu[u2]; b = vu[u2];
      acc[4] = b2f((unsigned short)a) + b2f((unsigned short)b);
      acc[5] = b2f((unsigned short)(a >> 16)) + b2f((unsigned short)(b >> 16));
    } else {
      acc[4] = acc[5] = 0.f;
    }
  }
  for (int j = j0; j < j1; ++j) {
    int s = s2s[j], ec = ec2s[j], bs = b2s[j];
    const unsigned* hr = (const unsigned*)hb + (size_t)s * 150;
    const unsigned* vr = (const unsigned*)vnb + (size_t)bs * 150;
    const unsigned* eu = sb + ((ec >> 2) * 3 + (ec & 3)) * 150;
    unsigned a = hr[u0], b = vr[u0], e = eu[u0];
    acc[0] += fmaxf(b2f((unsigned short)a) + b2f((unsigned short)b) + b2f((unsigned short)e), 0.f);
    acc[1] += fmaxf(b2f((unsigned short)(a >> 16)) + b2f((unsigned short)(b >> 16)) +
                        b2f((unsigned short)(e >> 16)), 0.f);
    a = hr[u1]; b = vr[u1]; e = eu[u1];
    acc[2] += fmaxf(b2f((unsigned short)a) + b2f((unsigned short)b) + b2f((unsigned short)e), 0.f);
    acc[3] += fmaxf(b2f((unsigned short)(a >> 16)) + b2f((unsigned short)(b >> 16)) +
                        b2f((unsigned short)(e >> 16)), 0.f);
    if (has2) {
      a = hr[u2]; b = vr[u2]; e = eu[u2];
      acc[4] += fmaxf(b2f((unsigned short)a) + b2f((unsigned short)b) + b2f((unsigned short)e), 0.f);
      acc[5] += fmaxf(b2f((unsigned short)(a >> 16)) + b2f((unsigned short)(b >> 16)) +
                          b2f((unsigned short)(e >> 16)), 0.f);
    }
  }
  unsigned* outu = (unsigned*)aggb + (size_t)d * 160;
  outu[u0] = pk2(acc[0], acc[1]);
  outu[u1] = pk2(acc[2], acc[3]);
  if (u2 < 160) outu[u2] = has2 ? pk2(acc[4], acc[5]) : 0u;
}

// CFConv with bf16 table + bf16 x1
__global__ __launch_bounds__(256) void k_conv_gather4(
    const short* __restrict__ ftabb, const short* __restrict__ x1b, const int* __restrict__ off3,
    const int* __restrict__ s3s, const int* __restrict__ id3s, const float* __restrict__ fr3s,
    short* __restrict__ agg3b) {
  int tid = threadIdx.x;
  int d = blockIdx.x * 4 + (tid >> 6);
  int lane = tid & 63;
  int j0 = off3[d], j1 = off3[d + 1];
  float a0 = 0.f, a1 = 0.f;
  for (int j = j0; j < j1; ++j) {
    int s = s3s[j], idx = id3s[j];
    float fr = fr3s[j];
    unsigned t0 = ((const unsigned*)(ftabb + (size_t)idx * 128))[lane];
    unsigned t1 = ((const unsigned*)(ftabb + (size_t)(idx + 1) * 128))[lane];
    unsigned xv = ((const unsigned*)(x1b + (size_t)s * 128))[lane];
    float t0a = b2f((unsigned short)(t0 & 0xFFFF)), t0b = b2f((unsigned short)(t0 >> 16));
    float t1a = b2f((unsigned short)(t1 & 0xFFFF)), t1b = b2f((unsigned short)(t1 >> 16));
    a0 += (t0a + fr * (t1a - t0a)) * b2f((unsigned short)(xv & 0xFFFF));
    a1 += (t0b + fr * (t1b - t0b)) * b2f((unsigned short)(xv >> 16));
  }
  ((unsigned*)(agg3b + (size_t)d * 128))[lane] = pk2(a0, a1);
}

// fused: vnab[g][320] = bf16( sum_rows(hb) + vn[g] ), uint loads
__global__ __launch_bounds__(256) void k_poolvn(const short* __restrict__ hb,
                                                const int* __restrict__ goff,
                                                const float* __restrict__ vn,
                                                short* __restrict__ vnab) {
  int g = blockIdx.x * 4 + (threadIdx.x >> 6);
  int l = threadIdx.x & 63;
  if (g >= NG) return;
  int r0 = goff[g], r1 = goff[g + 1];
  const int u0 = l, u1 = l + 64, u2 = l + 128;
  const bool has2 = (u2 < 150);
  float acc[6] = {};
  for (int r = r0; r < r1; ++r) {
    const unsigned* hu = (const unsigned*)hb + (size_t)r * 150;
    unsigned a = hu[u0];
    acc[0] += b2f((unsigned short)a);
    acc[1] += b2f((unsigned short)(a >> 16));
    a = hu[u1];
    acc[2] += b2f((unsigned short)a);
    acc[3] += b2f((unsigned short)(a >> 16));
    if (has2) {
      a = hu[u2];
      acc[4] += b2f((unsigned short)a);
      acc[5] += b2f((unsigned short)(a >> 16));
    }
  }
  const float2* v2 = (const float2*)(vn + (size_t)g * 300);
  unsigned* outu = (unsigned*)vnab + (size_t)g * 160;
  float2 w = v2[u0];
  outu[u0] = pk2(acc[0] + w.x, acc[1] + w.y);
  w = v2[u1];
  outu[u1] = pk2(acc[2] + w.x, acc[3] + w.y);
  if (u2 < 160) {
    if (has2) {
      w = v2[u2];
      outu[u2] = pk2(acc[4] + w.x, acc[5] + w.y);
    } else {
      outu[u2] = 0u;
    }
  }
}

// head pool (GIN): xcat[g][0:320] = bf16(mean over hb rows)
__global__ __launch_bounds__(256) void k_poolhead2(const short* __restrict__ hb,
                                                   const int* __restrict__ goff,
                                                   short* __restrict__ xcat) {
  int g = blockIdx.x * 4 + (threadIdx.x >> 6);
  int l = threadIdx.x & 63;
  if (g >= NG) return;
  int r0 = goff[g], r1 = goff[g + 1];
  const int u0 = l, u1 = l + 64, u2 = l + 128;
  const bool has2 = (u2 < 150);
  float acc[6] = {};
  for (int r = r0; r < r1; ++r) {
    const unsigned* hu = (const unsigned*)hb + (size_t)r * 150;
    unsigned a = hu[u0];
    acc[0] += b2f((unsigned short)a);
    acc[1] += b2f((unsigned short)(a >> 16));
    a = hu[u1];
    acc[2] += b2f((unsigned short)a);
    acc[3] += b2f((unsigned short)(a >> 16));
    if (has2) {
      a = hu[u2];
      acc[4] += b2f((unsigned short)a);
      acc[5] += b2f((unsigned short)(a >> 16));
    }
  }
  float s = 1.0f / fmaxf((float)(r1 - r0), 1.0f);
  unsigned* outu = (unsigned*)xcat + (size_t)g * 224;
  outu[u0] = pk2(acc[0] * s, acc[1] * s);
  outu[u1] = pk2(acc[2] * s, acc[3] * s);
  if (u2 < 160) outu[u2] = has2 ? pk2(acc[4] * s, acc[5] * s) : 0u;
}

// head pool (SchNet): xcat[g][320:448] = bf16(mean over hsb rows)
__global__ __launch_bounds__(256) void k_poolhead3(const short* __restrict__ hsb,
                                                   const int* __restrict__ goff,
                                                   short* __restrict__ xcat) {
  int g = blockIdx.x * 4 + (threadIdx.x >> 6);
  int l = threadIdx.x & 63;
  if (g >= NG) return;
  int r0 = goff[g], r1 = goff[g + 1];
  float a0 = 0.f, a1 = 0.f;
  for (int r = r0; r < r1; ++r) {
    unsigned v = ((const unsigned*)hsb)[(size_t)r * 64 + l];
    a0 += b2f((unsigned short)(v & 0xFFFF));
    a1 += b2f((unsigned short)(v >> 16));
  }
  float s = 1.0f / fmaxf((float)(r1 - r0), 1.0f);
  ((unsigned*)xcat)[(size_t)g * 224 + 160 + l] = pk2(a0 * s, a1 * s);
}

// gate dot + sigmoid + blend: hfb[g][320] = bf16(g*h2p + (1-g)*h3p)
__global__ __launch_bounds__(256) void k_blend(const float* __restrict__ gh,
                                               const float* __restrict__ gW2,
                                               const float* __restrict__ gb2,
                                               const float* __restrict__ hcat,
                                               short* __restrict__ hfb) {
  int g = blockIdx.x * 4 + (threadIdx.x >> 6);
  int l = threadIdx.x & 63;
  if (g >= NG) return;
  float2 v = ((const float2*)(gh + (size_t)g * 128))[l];
  float dot = v.x * gW2[2 * l] + v.y * gW2[2 * l + 1];
  for (int m = 32; m; m >>= 1) dot += __shfl_xor(dot, m);
  float gg = 1.0f / (1.0f + expf(-(dot + gb2[0])));
  const float* hc = hcat + (size_t)g * 608;
  unsigned* outu = (unsigned*)hfb + (size_t)g * 160;
  const int u0 = l, u1 = l + 64, u2 = l + 128;
  float a0 = hc[2 * u0], a1 = hc[2 * u0 + 1], b0 = hc[304 + 2 * u0], b1 = hc[304 + 2 * u0 + 1];
  outu[u0] = pk2(gg * a0 + (1.f - gg) * b0, gg * a1 + (1.f - gg) * b1);
  a0 = hc[2 * u1]; a1 = hc[2 * u1 + 1]; b0 = hc[304 + 2 * u1]; b1 = hc[304 + 2 * u1 + 1];
  outu[u1] = pk2(gg * a0 + (1.f - gg) * b0, gg * a1 + (1.f - gg) * b1);
  if (u2 < 160) {
    if (u2 < 150) {
      a0 = hc[2 * u2]; a1 = hc[2 * u2 + 1]; b0 = hc[304 + 2 * u2]; b1 = hc[304 + 2 * u2 + 1];
      outu[u2] = pk2(gg * a0 + (1.f - gg) * b0, gg * a1 + (1.f - gg) * b1);
    } else {
      outu[u2] = 0u;
    }
  }
}

// ---------------- weight prep ----------------
__global__ void k_prepw2(const float* __restrict__ Wa, const float* __restrict__ Wb,
                         short* __restrict__ Wta, short* __restrict__ Wtb, int K, int N, int Kp,
                         int Np, int La, int Lb) {
  int i = blockIdx.x * blockDim.x + threadIdx.x;
  int per = Np * Kp;
  if (i >= (La + Lb) * per) return;
  int l = i / per, r = i - l * per;
  int n = r / Kp, k = r - n * Kp;
  const float* W = (l < La) ? Wa : Wb;
  int ll = (l < La) ? l : l - La;
  short* Wt = (l < La) ? Wta : Wtb;
  float v = (n < N && k < K) ? W[(size_t)ll * K * N + (size_t)k * N + n] : 0.f;
  Wt[(size_t)ll * per + r] = f2b(v);
}

__global__ void k_prepw3(const float* __restrict__ W0, const float* __restrict__ W1,
                         const float* __restrict__ W2, short* __restrict__ T0,
                         short* __restrict__ T1, short* __restrict__ T2) {
  int i = blockIdx.x * blockDim.x + threadIdx.x;
  const int per = 6 * 128 * 128;
  if (i >= 3 * per) return;
  int which = i / per, r = i - which * per;
  int l = r / 16384, rr = r - l * 16384;
  int n = rr / 128, k = rr - n * 128;
  const float* W = (which == 0) ? W0 : (which == 1) ? W1 : W2;
  short* T = (which == 0) ? T0 : (which == 1) ? T1 : T2;
  T[r] = f2b(W[(size_t)l * 16384 + (size_t)k * 128 + n]);
}

// head concat-weight prep
#define W1SZ (608 * 448)
#define G1SZ (128 * 608)
#define C1SZ (160 * 320)
#define C2SZ (12 * 160)
__global__ void k_prephead(const float* __restrict__ p2W, const float* __restrict__ p2b,
                           const float* __restrict__ p3W, const float* __restrict__ p3b,
                           const float* __restrict__ gW1, const float* __restrict__ cW1,
                           const float* __restrict__ cb1, const float* __restrict__ cW2,
                           short* __restrict__ Wcat, short* __restrict__ gW1cat,
                           short* __restrict__ cW1cat, short* __restrict__ cW2cat,
                           float* __restrict__ bcat, float* __restrict__ cb1p) {
  int i = blockIdx.x * blockDim.x + threadIdx.x;
  if (i < W1SZ) {
    int o = i / 448, k = i - o * 448;
    float v = 0.f;
    if (o < 300 && k < 300) v = p2W[(size_t)k * 300 + o];
    else if (o >= 304 && o < 604 && k >= 320) v = p3W[(size_t)(k - 320) * 300 + (o - 304)];
    Wcat[i] = f2b(v);
  } else if (i < W1SZ + G1SZ) {
    int r = i - W1SZ;
    int o = r / 608, k = r - o * 608;
    float v = 0.f;
    if (k < 300) v = gW1[(size_t)k * 128 + o];
    else if (k >= 304 && k < 604) v = gW1[(size_t)(300 + k - 304) * 128 + o];
    gW1cat[r] = f2b(v);
  } else if (i < W1SZ + G1SZ + C1SZ) {
    int r = i - W1SZ - G1SZ;
    int o = r / 320, k = r - o * 320;
    cW1cat[r] = f2b((o < 150 && k < 300) ? cW1[(size_t)k * 150 + o] : 0.f);
  } else if (i < W1SZ + G1SZ + C1SZ + C2SZ) {
    int r = i - W1SZ - G1SZ - C1SZ;
    int o = r / 160, k = r - o * 160;
    cW2cat[r] = f2b((k < 150) ? cW2[(size_t)k * 12 + o] : 0.f);
  } else if (i < W1SZ + G1SZ + C1SZ + C2SZ + 608) {
    int o = i - W1SZ - G1SZ - C1SZ - C2SZ;
    bcat[o] = (o < 300) ? p2b[o] : (o >= 304 && o < 604) ? p3b[o - 304] : 0.f;
  } else if (i < W1SZ + G1SZ + C1SZ + C2SZ + 608 + 160) {
    int o = i - W1SZ - G1SZ - C1SZ - C2SZ - 608;
    cb1p[o] = (o < 150) ? cb1[o] : 0.f;
  }
}

// ---------------- z-batched fp32 GEMM; optional bf16 output ----------------
template <int ACT>
__global__ __launch_bounds__(256) void k_gemmz(
    const float* __restrict__ A, const float* __restrict__ B, const float* __restrict__ bias,
    const float* __restrict__ rscale, float* __restrict__ Cout, short* __restrict__ Coutb,
    int M, int N, int K, int ldc, long strideA, long strideB, long strideBias, long strideC) {
  A += (size_t)blockIdx.z * strideA;
  B += (size_t)blockIdx.z * strideB;
  bias += (size_t)blockIdx.z * strideBias;
  __shared__ float sA[16][65];
  __shared__ float sB[16][64];
  int tid = threadIdx.x;
  int tx = tid & 15, ty = tid >> 4;
  int bm = blockIdx.y * 64, bn = blockIdx.x * 64;
  float acc[4][4] = {};
  for (int k0 = 0; k0 < K; k0 += 16) {
#pragma unroll
    for (int t = 0; t < 4; ++t) {
      int i = tid + t * 256;
      int m = i >> 4, kk = i & 15;
      int gm = bm + m, gk = k0 + kk;
      sA[kk][m] = (gm < M && gk < K) ? A[(size_t)gm * K + gk] : 0.f;
    }
#pragma unroll
    for (int t = 0; t < 4; ++t) {
      int i = tid + t * 256;
      int kk = i >> 6, n = i & 63;
      int gk = k0 + kk, gn = bn + n;
      sB[kk][n] = (gk < K && gn < N) ? B[(size_t)gk * N + gn] : 0.f;
    }
    __syncthreads();
#pragma unroll
    for (int kk = 0; kk < 16; ++kk) {
      float a[4], b[4];
#pragma unroll
      for (int i = 0; i < 4; ++i) a[i] = sA[kk][ty + 16 * i];
#pragma unroll
      for (int j = 0; j < 4; ++j) b[j] = sB[kk][tx + 16 * j];
#pragma unroll
      for (int i = 0; i < 4; ++i)
#pragma unroll
        for (int j = 0; j < 4; ++j) acc[i][j] = fmaf(a[i], b[j], acc[i][j]);
    }
    __syncthreads();
  }
#pragma unroll
  for (int i = 0; i < 4; ++i) {
    int gm = bm + ty + 16 * i;
    if (gm >= M) continue;
    float rs = rscale ? rscale[gm] : 1.0f;
#pragma unroll
    for (int j = 0; j < 4; ++j) {
      int gn = bn + tx + 16 * j;
      if (gn >= N) continue;
      float v = acc[i][j] + bias[gn];
      if (ACT == 1) v = fmaxf(v, 0.f);
      if (ACT == 2) v = sspf(v);
      v *= rs;
      if (Cout) Cout[(size_t)blockIdx.z * strideC + (size_t)gm * ldc + gn] = v;
      if (Coutb) Coutb[(size_t)blockIdx.z * strideC + (size_t)gm * ldc + gn] = f2b(v);
    }
  }
}

// ---------------- bf16 MFMA GEMM, 128x128 tile ----------------
template <int ACT>
__global__ __launch_bounds__(256) void k_mgemm_bf(
    const short* __restrict__ Ab, const short* __restrict__ Wt, const float* __restrict__ bias,
    const float* __restrict__ scale, const float* __restrict__ shift,
    const float* __restrict__ Cin, float* __restrict__ Cout, short* __restrict__ Coutb,
    int M, int N, int Kp, int ldc, int ldcb, int Nb) {
  __shared__ short sA[128 * 32];
  const int tid = threadIdx.x;
  const int lane = tid & 63;
  const int w = tid >> 6;
  const int wm = w >> 1, wn = w & 1;
  const int bm = blockIdx.y * 128, bn = blockIdx.x * 128;

  f32x4 acc[4][4] = {};

  const int sr = tid >> 1;
  const int sk = (tid & 1) * 16;
  const short* Arow = Ab + (size_t)(bm + sr) * Kp + sk;
  const int ssw = (sr + (sr >> 2)) & 3;
  const int s0 = (sk >> 3);
  bf16x8* sAv = (bf16x8*)sA;

  const int frow = wm * 64 + (lane & 15);
  const int fslot = lane >> 4;
  const short* Bbase = Wt + (size_t)(bn + wn * 64 + (lane & 15)) * Kp + (fslot * 8);

  for (int k0 = 0; k0 < Kp; k0 += 32) {
    __syncthreads();
    {
      bf16x8 p0 = *(const bf16x8*)(Arow + k0);
      bf16x8 p1 = *(const bf16x8*)(Arow + k0 + 8);
      sAv[sr * 4 + ((s0 + 0) ^ ssw)] = p0;
      sAv[sr * 4 + ((s0 + 1) ^ ssw)] = p1;
    }
    __syncthreads();

    bf16x8 af[4], bfr[4];
#pragma unroll
    for (int mf = 0; mf < 4; ++mf) {
      int r = frow + mf * 16;
      af[mf] = sAv[r * 4 + (fslot ^ ((r + (r >> 2)) & 3))];
    }
#pragma unroll
    for (int nf = 0; nf < 4; ++nf) bfr[nf] = *(const bf16x8*)(Bbase + (size_t)nf * 16 * Kp + k0);
#pragma unroll
    for (int mf = 0; mf < 4; ++mf)
#pragma unroll
      for (int nf = 0; nf < 4; ++nf)
        acc[mf][nf] =
            __builtin_amdgcn_mfma_f32_16x16x32_bf16(af[mf], bfr[nf], acc[mf][nf], 0, 0, 0);
  }

  const int colbase = bn + wn * 64 + (lane & 15);
  const int rowbase = bm + wm * 64 + ((lane >> 4) << 2);
#pragma unroll
  for (int nf = 0; nf < 4; ++nf) {
    int col = colbase + nf * 16;
    bool cv = col < N;
    float bi = (bias && cv) ? bias[col] : 0.f;
    float sc = (scale && cv) ? scale[col] : 1.f;
    float sh = (shift && cv) ? shift[col] : 0.f;
#pragma unroll
    for (int mf = 0; mf < 4; ++mf) {
      f32x4 v = acc[mf][nf];
#pragma unroll
      for (int j = 0; j < 4; ++j) {
        int row = rowbase + mf * 16 + j;
        float x = v[j] + bi;
        if (scale) x = x * sc + sh;
        if (ACT == 1) x = fmaxf(x, 0.f);
        if (ACT == 2) x = sspf(x);
        if (Cin && cv) x += Cin[(size_t)row * ldc + col];
        if (Cout && cv) Cout[(size_t)row * ldc + col] = x;
        if (Coutb && col < Nb) Coutb[(size_t)row * ldcb + col] = cv ? f2b(x) : (short)0;
      }
    }
  }
}

// ---------------- bf16 MFMA GEMM, 64x128 tile ----------------
template <int ACT>
__global__ __launch_bounds__(256) void k_mgemm_bf64(
    const short* __restrict__ Ab, const short* __restrict__ Wt, const float* __restrict__ bias,
    const float* __restrict__ scale, const float* __restrict__ shift,
    const float* __restrict__ Cin, float* __restrict__ Cout, short* __restrict__ Coutb,
    int M, int N, int Kp, int ldc, int ldcb, int Nb) {
  __shared__ short sA[64 * 32];
  const int tid = threadIdx.x;
  const int lane = tid & 63;
  const int w = tid >> 6;
  const int bm = blockIdx.y * 64, bn = blockIdx.x * 128;

  f32x4 acc[4][2] = {};

  const int sr = tid >> 2;
  const int sk = (tid & 3) * 8;
  const short* Arow = Ab + (size_t)(bm + sr) * Kp + sk;
  const int ssw = (sr + (sr >> 2)) & 3;
  const int s0 = tid & 3;
  bf16x8* sAv = (bf16x8*)sA;

  const int frow = lane & 15;
  const int fslot = lane >> 4;
  const short* Bbase = Wt + (size_t)(bn + w * 32 + (lane & 15)) * Kp + (fslot * 8);

  for (int k0 = 0; k0 < Kp; k0 += 32) {
    __syncthreads();
    sAv[sr * 4 + (s0 ^ ssw)] = *(const bf16x8*)(Arow + k0);
    __syncthreads();

    bf16x8 af[4], bfr[2];
#pragma unroll
    for (int mf = 0; mf < 4; ++mf) {
      int r = frow + mf * 16;
      af[mf] = sAv[r * 4 + (fslot ^ ((r + (r >> 2)) & 3))];
    }
#pragma unroll
    for (int nf = 0; nf < 2; ++nf) bfr[nf] = *(const bf16x8*)(Bbase + (size_t)nf * 16 * Kp + k0);
#pragma unroll
    for (int mf = 0; mf < 4; ++mf)
#pragma unroll
      for (int nf = 0; nf < 2; ++nf)
        acc[mf][nf] =
            __builtin_amdgcn_mfma_f32_16x16x32_bf16(af[mf], bfr[nf], acc[mf][nf], 0, 0, 0);
  }

  const int colbase = bn + w * 32 + (lane & 15);
  const int rowbase = bm + ((lane >> 4) << 2);
#pragma unroll
  for (int nf = 0; nf < 2; ++nf) {
    int col = colbase + nf * 16;
    bool cv = col < N;
    float bi = (bias && cv) ? bias[col] : 0.f;
    float sc = (scale && cv) ? scale[col] : 1.f;
    float sh = (shift && cv) ? shift[col] : 0.f;
#pragma unroll
    for (int mf = 0; mf < 4; ++mf) {
      f32x4 v = acc[mf][nf];
#pragma unroll
      for (int j = 0; j < 4; ++j) {
        int row = rowbase + mf * 16 + j;
        float x = v[j] + bi;
        if (scale) x = x * sc + sh;
        if (ACT == 1) x = fmaxf(x, 0.f);
        if (ACT == 2) x = sspf(x);
        if (Cin && cv) x += Cin[(size_t)row * ldc + col];
        if (Cout && cv) Cout[(size_t)row * ldc + col] = x;
        if (Coutb && col < Nb) Coutb[(size_t)row * ldcb + col] = cv ? f2b(x) : (short)0;
      }
    }
  }
}

// ---------------- fused SchNet layer ----------------
template <int LAST>
__global__ __launch_bounds__(256) void k_sch_fused(
    const short* __restrict__ agg3b, const short* __restrict__ W2t, const float* __restrict__ b2,
    const short* __restrict__ W3t, const float* __restrict__ b3, const short* __restrict__ W1n,
    float* __restrict__ hs, short* __restrict__ hsb, short* __restrict__ x1b) {
  __shared__ short sA[64 * 128];
  __shared__ short sY[64 * 128];
  const int tid = threadIdx.x;
  const int lane = tid & 63;
  const int w = tid >> 6;
  const int bm = blockIdx.x * 64;
  bf16x8* sAv = (bf16x8*)sA;
  bf16x8* sYv = (bf16x8*)sY;
  {
    int r = tid >> 2, q = tid & 3;
    int ssw = (r + (r >> 2)) & 3;
    const short* Arow = agg3b + (size_t)(bm + r) * 128 + q * 8;
#pragma unroll
    for (int c = 0; c < 4; ++c) sAv[r * 16 + c * 4 + (q ^ ssw)] = *(const bf16x8*)(Arow + c * 32);
  }
  __syncthreads();
  const int frow = lane & 15;
  const int fslot = lane >> 4;
  const int colw = w * 32 + (lane & 15);
  const int rw0 = (lane >> 4) << 2;
  {
    f32x4 acc[4][2] = {};
    const short* Bbase = W2t + (size_t)colw * 128 + fslot * 8;
#pragma unroll
    for (int c = 0; c < 4; ++c) {
      bf16x8 af[4], bfr[2];
#pragma unroll
      for (int mf = 0; mf < 4; ++mf) {
        int r = frow + mf * 16;
        af[mf] = sAv[r * 16 + c * 4 + (fslot ^ ((r + (r >> 2)) & 3))];
      }
#pragma unroll
      for (int nf = 0; nf < 2; ++nf) bfr[nf] = *(const bf16x8*)(Bbase + nf * 16 * 128 + c * 32);
#pragma unroll
      for (int mf = 0; mf < 4; ++mf)
#pragma unroll
        for (int nf = 0; nf < 2; ++nf)
          acc[mf][nf] =
              __builtin_amdgcn_mfma_f32_16x16x32_bf16(af[mf], bfr[nf], acc[mf][nf], 0, 0, 0);
    }
#pragma unroll
    for (int nf = 0; nf < 2; ++nf) {
      int cl = colw + nf * 16;
      float bi = b2[cl];
#pragma unroll
      for (int mf = 0; mf < 4; ++mf)
#pragma unroll
        for (int j = 0; j < 4; ++j) {
          int rw = rw0 + mf * 16 + j;
          float y = sspf(acc[mf][nf][j] + bi);
          int slot = (cl >> 5) * 4 + (((cl >> 3) & 3) ^ ((rw + (rw >> 2)) & 3));
          sY[rw * 128 + slot * 8 + (cl & 7)] = f2b(y);
        }
    }
  }
  __syncthreads();
  {
    f32x4 acc[4][2] = {};
    const short* Bbase = W3t + (size_t)colw * 128 + fslot * 8;
#pragma unroll
    for (int c = 0; c < 4; ++c) {
      bf16x8 af[4], bfr[2];
#pragma unroll
      for (int mf = 0; mf < 4; ++mf) {
        int r = frow + mf * 16;
        af[mf] = sYv[r * 16 + c * 4 + (fslot ^ ((r + (r >> 2)) & 3))];
      }
#pragma unroll
      for (int nf = 0; nf < 2; ++nf) bfr[nf] = *(const bf16x8*)(Bbase + nf * 16 * 128 + c * 32);
#pragma unroll
      for (int mf = 0; mf < 4; ++mf)
#pragma unroll
        for (int nf = 0; nf < 2; ++nf)
          acc[mf][nf] =
              __builtin_amdgcn_mfma_f32_16x16x32_bf16(af[mf], bfr[nf], acc[mf][nf], 0, 0, 0);
    }
#pragma unroll
    for (int nf = 0; nf < 2; ++nf) {
      int cl = colw + nf * 16;
      float bi = b3[cl];
#pragma unroll
      for (int mf = 0; mf < 4; ++mf)
#pragma unroll
        for (int j = 0; j < 4; ++j) {
          int rw = rw0 + mf * 16 + j;
          size_t gi = (size_t)(bm + rw) * 128 + cl;
          float x = acc[mf][nf][j] + bi + hs[gi];
          hs[gi] = x;
          short xb = f2b(x);
          hsb[gi] = xb;
          int slot = (cl >> 5) * 4 + (((cl >> 3) & 3) ^ ((rw + (rw >> 2)) & 3));
          sA[rw * 128 + slot * 8 + (cl & 7)] = xb;
        }
    }
  }
  if (LAST) return;
  __syncthreads();
  {
    f32x4 acc[4][2] = {};
    const short* Bbase = W1n + (size_t)colw * 128 + fslot * 8;
#pragma unroll
    for (int c = 0; c < 4; ++c) {
      bf16x8 af[4], bfr[2];
#pragma unroll
      for (int mf = 0; mf < 4; ++mf) {
        int r = frow + mf * 16;
        af[mf] = sAv[r * 16 + c * 4 + (fslot ^ ((r + (r >> 2)) & 3))];
      }
#pragma unroll
      for (int nf = 0; nf < 2; ++nf) bfr[nf] = *(const bf16x8*)(Bbase + nf * 16 * 128 + c * 32);
#pragma unroll
      for (int mf = 0; mf < 4; ++mf)
#pragma unroll
        for (int nf = 0; nf < 2; ++nf)
          acc[mf][nf] =
              __builtin_amdgcn_mfma_f32_16x16x32_bf16(af[mf], bfr[nf], acc[mf][nf], 0, 0, 0);
    }
#pragma unroll
    for (int nf = 0; nf < 2; ++nf) {
      int cl = colw + nf * 16;
#pragma unroll
      for (int mf = 0; mf < 4; ++mf)
#pragma unroll
        for (int j = 0; j < 4; ++j) {
          int rw = rw0 + mf * 16 + j;
          x1b[(size_t)(bm + rw) * 128 + cl] = f2b(acc[mf][nf][j]);
        }
    }
  }
}

// ---------------- host ----------------

static inline void run_mgemm_bf(hipStream_t st, const short* Ab, const short* Wt,
                                const float* bias, const float* scale, const float* shift,
                                const float* Cin, float* Cout, short* Coutb, int M, int N, int Kp,
                                int ldc, int ldcb, int Nb, int act) {
  dim3 grid((N + 127) / 128, M / 128);
  if (act == 0)
    k_mgemm_bf<0><<<grid, 256, 0, st>>>(Ab, Wt, bias, scale, shift, Cin, Cout, Coutb, M, N, Kp,
                                        ldc, ldcb, Nb);
  else if (act == 1)
    k_mgemm_bf<1><<<grid, 256, 0, st>>>(Ab, Wt, bias, scale, shift, Cin, Cout, Coutb, M, N, Kp,
                                        ldc, ldcb, Nb);
  else
    k_mgemm_bf<2><<<grid, 256, 0, st>>>(Ab, Wt, bias, scale, shift, Cin, Cout, Coutb, M, N, Kp,
                                        ldc, ldcb, Nb);
}

static inline void run_mgemm_bf64(hipStream_t st, const short* Ab, const short* Wt,
                                  const float* bias, const float* scale, const float* shift,
                                  const float* Cin, float* Cout, short* Coutb, int M, int N,
                                  int Kp, int ldc, int ldcb, int Nb, int act) {
  dim3 grid((N + 127) / 128, M / 64);
  if (act == 0)
    k_mgemm_bf64<0><<<grid, 256, 0, st>>>(Ab, Wt, bias, scale, shift, Cin, Cout, Coutb, M, N, Kp,
                                          ldc, ldcb, Nb);
  else if (act == 1)
    k_mgemm_bf64<1><<<grid, 256, 0, st>>>(Ab, Wt, bias, scale, shift, Cin, Cout, Coutb, M, N, Kp,
                                          ldc, ldcb, Nb);
  else
    k_mgemm_bf64<2><<<grid, 256, 0, st>>>(Ab, Wt, bias, scale, shift, Cin, Cout, Coutb, M, N, Kp,
                                          ldc, ldcb, Nb);
}

extern "C" void kernel_launch(void* const* d_in, const int* in_sizes, int n_in, void* d_out,
                              int out_size, void* d_ws, size_t ws_size, hipStream_t stream) {
  const int* x2d = (const int*)d_in[0];
  const int* ei2 = (const int*)d_in[1];
  const int* ea2 = (const int*)d_in[2];
  const int* batch = (const int*)d_in[3];
  const int* z = (const int*)d_in[4];
  const float* pos = (const float*)d_in[5];
  const int* ei3 = (const int*)d_in[6];
  const float* atom_emb1 = (const float*)d_in[7];
  const float* atom_emb2 = (const float*)d_in[8];
  const float* vn_init = (const float*)d_in[9];
  const float* gin_W1 = (const float*)d_in[10];
  const float* gin_b1 = (const float*)d_in[11];
  const float* gin_W2 = (const float*)d_in[12];
  const float* gin_b2 = (const float*)d_in[13];
  const float* gin_bond1 = (const float*)d_in[14];
  const float* gin_bond2 = (const float*)d_in[15];
  const float* gin_gamma = (const float*)d_in[16];
  const float* gin_beta = (const float*)d_in[17];
  const float* vn_W1 = (const float*)d_in[18];
  const float* vn_b1 = (const float*)d_in[19];
  const float* vn_W2 = (const float*)d_in[20];
  const float* vn_b2 = (const float*)d_in[21];
  const float* sch_emb = (const float*)d_in[22];
  const float* s_mW1 = (const float*)d_in[23];
  const float* s_mb1 = (const float*)d_in[24];
  const float* s_mW2 = (const float*)d_in[25];
  const float* s_mb2 = (const float*)d_in[26];
  const float* s_lin1W = (const float*)d_in[27];
  const float* s_lin2W = (const float*)d_in[28];
  const float* s_lin2b = (const float*)d_in[29];
  const float* s_linW = (const float*)d_in[30];
  const float* s_linb = (const float*)d_in[31];
  const float* p2W = (const float*)d_in[32];
  const float* p2b = (const float*)d_in[33];
  const float* p3W = (const float*)d_in[34];
  const float* p3b = (const float*)d_in[35];
  const float* gW1 = (const float*)d_in[36];
  const float* gb1 = (const float*)d_in[37];
  const float* gW2 = (const float*)d_in[38];
  const float* gb2 = (const float*)d_in[39];
  const float* cW1 = (const float*)d_in[40];
  const float* cb1 = (const float*)d_in[41];
  const float* cW2 = (const float*)d_in[42];
  const float* cb2 = (const float*)d_in[43];

  float* ws = (float*)d_ws;
  // GIN phase
  short* hb = (short*)ws;
  int* b2s = (int*)(ws + 2500000);
  short* aggb = (short*)(ws + 5000000);
  short* y1b = (short*)(ws + 7700000);
  // SchNet phase (aliases GIN region)
  float* rbs = ws + 400000;
  float* Cs = ws + 700000;
  float* t1all = ws + 800000;
  short* ftabb = (short*)(ws + 4800000);
  float* hs = ws + 8800000;
  short* x1b = (short*)(ws + 11000000);
  short* agg3b = (short*)(ws + 13200000);
  short* hsb = (short*)(ws + 15400000);
  // bf16 transposed weights
  short* W1t = (short*)(ws + 20000000);
  short* W2t = (short*)(ws + 20600000);
  short* s1t = (short*)(ws + 21200000);
  short* s2t = (short*)(ws + 21300000);
  short* s3t = (short*)(ws + 21400000);
  // CSR region
  int* I = (int*)(ws + 22000000);
  int* cnt2 = I + 0;
  int* cnt3 = I + 16384;
  int* cntg = I + 32768;
  int* cur2 = I + 33280;
  int* cur3 = I + 49664;  // zero region = 66048 ints
  int* off2 = I + 70000;
  int* off3 = I + 90000;
  int* goff = I + 110000;
  int* s2s = I + 120000;
  int* ec2s = I + 190000;
  int* s3s = I + 260000;
  int* id3s = I + 660000;
  float* fr3s = (float*)(I + 1060000);
  // vn-MLP bf16 weights + buffers
  short* vnW1t = (short*)(ws + 23500000);
  short* vnW2t = (short*)(ws + 24000000);
  short* vnab = (short*)(ws + 24500000);
  short* vnhb = (short*)(ws + 24600000);
  short* vnb = (short*)(ws + 24800000);
  // head buffers
  short* Wcat = (short*)(ws + 25000000);    // 608*448 sh (+pad reads ok)
  short* gW1cat = (short*)(ws + 25200000);  // 128*608 sh
  short* cW1cat = (short*)(ws + 25250000);  // 160*320 sh
  short* cW2cat = (short*)(ws + 25280000);  // 12*160 sh
  float* bcat = ws + 25290000;              // 608
  float* cb1p = ws + 25291000;              // 160
  short* xcat = (short*)(ws + 25300000);    // 512*448 sh
  float* hcat = ws + 25430000;              // 512*608 f32
  short* hcatb = (short*)(ws + 25750000);   // 512*608 sh
  float* gh = ws + 25920000;                // 512*128 f32
  short* hfb = (short*)(ws + 26000000);     // 512*320 sh
  short* c1b = (short*)(ws + 26100000);     // 512*160 sh
  // persistent tail
  float* vn = ws + 28443136;

  // ---- weight prep ----
  k_prepw2<<<(9 * 640 * 320 + 255) / 256, 256, 0, stream>>>(gin_W1, vn_W1, W1t, vnW1t, 300, 600,
                                                            320, 640, 5, 4);
  k_prepw2<<<(9 * 384 * 608 + 255) / 256, 256, 0, stream>>>(gin_W2, vn_W2, W2t, vnW2t, 600, 300,
                                                            608, 384, 5, 4);
  k_prepw3<<<(3 * 6 * 16384 + 255) / 256, 256, 0, stream>>>(s_lin1W, s_lin2W, s_linW, s1t, s2t,
                                                            s3t);
  k_prephead<<<(W1SZ + G1SZ + C1SZ + C2SZ + 608 + 160 + 255) / 256, 256, 0, stream>>>(
      p2W, p2b, p3W, p3b, gW1, cW1, cb1, cW2, Wcat, gW1cat, cW1cat, cW2cat, bcat, cb1p);

  // ---- CSR build ----
  hipMemsetAsync(I, 0, 66048 * sizeof(int), stream);
  k_hist3<<<(NE2 + NE3 + NN + 255) / 256, 256, 0, stream>>>(ei2, ei3, batch, cnt2, cnt3, cntg);
  k_scan3<<<3, 1024, 0, stream>>>(cnt2, off2, 16384, cnt3, off3, 16384, cntg, goff, 512);
  k_scatterB<<<(NE2 + NE3 + 255) / 256, 256, 0, stream>>>(ei2, ea2, batch, off2, cur2, s2s, ec2s,
                                                          b2s, ei3, pos, off3, cur3, s3s, id3s,
                                                          fr3s);

  // ---- GIN ----
  k_init_gin<<<(NN * DEMB + NG * DEMB + 255) / 256, 256, 0, stream>>>(x2d, atom_emb1, atom_emb2,
                                                                      hb, vn_init, vn, vnb);
  for (int l = 0; l < 5; ++l) {
    k_gin_gather5<<<NN / 4, 256, 0, stream>>>(hb, vnb, batch, off2, s2s, ec2s, b2s,
                                              gin_bond1 + l * 6 * DEMB, gin_bond2 + l * 3 * DEMB,
                                              aggb);
    run_mgemm_bf(stream, aggb, W1t + (size_t)l * 640 * 320, gin_b1 + l * 600, nullptr, nullptr,
                 nullptr, nullptr, y1b, NN, 600, 320, 0, 608, 608, 1);
    run_mgemm_bf(stream, y1b, W2t + (size_t)l * 384 * 608, gin_b2 + l * 300, gin_gamma + l * 300,
                 gin_beta + l * 300, nullptr, nullptr, hb, NN, 300, 608, 0, 300, 300,
                 (l < 4) ? 1 : 0);
    if (l < 4) {
      k_poolvn<<<NG / 4, 256, 0, stream>>>(hb, goff, vn, vnab);
      run_mgemm_bf64(stream, vnab, vnW1t + (size_t)l * 640 * 320, vn_b1 + l * 600, nullptr,
                     nullptr, nullptr, nullptr, vnhb, NG, 600, 320, 0, 608, 608, 1);
      run_mgemm_bf64(stream, vnhb, vnW2t + (size_t)l * 384 * 608, vn_b2 + l * 300, nullptr,
                     nullptr, nullptr, vn, vnb, NG, 300, 608, 300, 300, 300, 1);
    }
  }
  k_poolhead2<<<NG / 4, 256, 0, stream>>>(hb, goff, xcat);  // before SchNet clobbers hb region

  // ---- SchNet ----
  k_init_sch<<<(TROWS * NRBF + NN * DSCH + 255) / 256, 256, 0, stream>>>(rbs, Cs, z, sch_emb, hs,
                                                                         hsb);
  {
    dim3 ga(2, (TROWS + 63) / 64, 6);
    k_gemmz<2><<<ga, 256, 0, stream>>>(rbs, s_mW1, s_mb1, nullptr, t1all, nullptr, TROWS, 128, 50,
                                       128, 0L, 50L * 128, 128L, (long)TROWS * 128);
    k_gemmz<0><<<ga, 256, 0, stream>>>(t1all, s_mW2, s_mb2, Cs, nullptr, ftabb, TROWS, 128, 128,
                                       128, (long)TROWS * 128, 128L * 128, 128L,
                                       (long)TROWS * 128);
  }
  run_mgemm_bf64(stream, hsb, s1t, nullptr, nullptr, nullptr, nullptr, nullptr, x1b, NN, 128, 128,
                 0, 128, 128, 0);
  for (int l = 0; l < 6; ++l) {
    k_conv_gather4<<<NN / 4, 256, 0, stream>>>(ftabb + (size_t)l * TROWS * 128, x1b, off3, s3s,
                                               id3s, fr3s, agg3b);
    if (l < 5)
      k_sch_fused<0><<<NN / 64, 256, 0, stream>>>(agg3b, s2t + (size_t)l * 16384,
                                                  s_lin2b + l * 128, s3t + (size_t)l * 16384,
                                                  s_linb + l * 128, s1t + (size_t)(l + 1) * 16384,
                                                  hs, hsb, x1b);
    else
      k_sch_fused<1><<<NN / 64, 256, 0, stream>>>(agg3b, s2t + (size_t)l * 16384,
                                                  s_lin2b + l * 128, s3t + (size_t)l * 16384,
                                                  s_linb + l * 128, s1t, hs, hsb, x1b);
  }
  k_poolhead3<<<NG / 4, 256, 0, stream>>>(hsb, goff, xcat);

  // ---- batched MFMA head ----
  // A: hcat = xcat @ Wcat + bcat  (h2p | h3p), dual f32+bf16
  run_mgemm_bf64(stream, xcat, Wcat, bcat, nullptr, nullptr, nullptr, hcat, hcatb, NG, 608, 448,
                 608, 608, 608, 0);
  // B: gh = relu(hcatb @ gW1cat + gb1)
  run_mgemm_bf64(stream, hcatb, gW1cat, gb1, nullptr, nullptr, nullptr, gh, nullptr, NG, 128, 608,
                 128, 128, 0, 1);
  // gate + blend
  k_blend<<<NG / 4, 256, 0, stream>>>(gh, gW2, gb2, hcat, hfb);
  // C: c1b = bf16(relu(hfb @ cW1cat + cb1p))
  run_mgemm_bf64(stream, hfb, cW1cat, cb1p, nullptr, nullptr, nullptr, nullptr, c1b, NG, 160, 320,
                 0, 160, 160, 1);
  // D: out = c1b @ cW2cat + cb2
  run_mgemm_bf64(stream, c1b, cW2cat, cb2, nullptr, nullptr, nullptr, (float*)d_out, nullptr, NG,
                 12, 160, 12, 12, 0, 0);
}

// Round 14
// 1244.154 us; speedup vs baseline: 8.0138x; 1.0592x over previous
//
#include <hip/hip_runtime.h>
#include <hip/hip_bf16.h>
#include <math.h>

#define NN 16384
#define NG 512
#define NE2 65536
#define NE3 393216
#define DEMB 300
#define DSCH 128
#define NRBF 50
#define NTAB 5120
#define TROWS 5121
#define DMAX 25.0f

typedef __attribute__((ext_vector_type(8))) short bf16x8;
typedef __attribute__((ext_vector_type(4))) float f32x4;

__device__ __forceinline__ float sspf(float x) {
  float sp = log1pf(expf(-fabsf(x))) + fmaxf(x, 0.f);
  return sp - 0.69314718055994530942f;
}

__device__ __forceinline__ short f2b(float f) {
  union { float f; unsigned u; } v;
  v.f = f;
  unsigned r = v.u + 0x7FFF + ((v.u >> 16) & 1);  // RNE
  return (short)(r >> 16);
}

__device__ __forceinline__ float b2f(unsigned short b) {
  union { unsigned u; float f; } v;
  v.u = ((unsigned)b) << 16;
  return v.f;
}

__device__ __forceinline__ unsigned pk2(float a, float b) {
  return ((unsigned)(unsigned short)f2b(b) << 16) | (unsigned short)f2b(a);
}

// ---------------- CSR build ----------------

__global__ void k_hist3(const int* __restrict__ ei2, const int* __restrict__ ei3,
                        const int* __restrict__ batch, int* __restrict__ cnt2,
                        int* __restrict__ cnt3, int* __restrict__ cntg) {
  int i = blockIdx.x * blockDim.x + threadIdx.x;
  if (i < NE2) {
    atomicAdd(&cnt2[ei2[NE2 + i]], 1);
  } else if (i < NE2 + NE3) {
    atomicAdd(&cnt3[ei3[NE3 + (i - NE2)]], 1);
  } else if (i < NE2 + NE3 + NN) {
    atomicAdd(&cntg[batch[i - NE2 - NE3]], 1);
  }
}

__global__ __launch_bounds__(1024) void k_scan3(const int* __restrict__ c0, int* __restrict__ o0,
                                                int n0, const int* __restrict__ c1,
                                                int* __restrict__ o1, int n1,
                                                const int* __restrict__ c2, int* __restrict__ o2,
                                                int n2) {
  const int* cnt = (blockIdx.x == 0) ? c0 : (blockIdx.x == 1) ? c1 : c2;
  int* off = (blockIdx.x == 0) ? o0 : (blockIdx.x == 1) ? o1 : o2;
  int n = (blockIdx.x == 0) ? n0 : (blockIdx.x == 1) ? n1 : n2;
  __shared__ int part[1024];
  int tid = threadIdx.x;
  int per = (n + 1023) / 1024;
  int base = tid * per;
  int sum = 0;
  for (int i = 0; i < per; ++i) {
    int idx = base + i;
    if (idx < n) sum += cnt[idx];
  }
  part[tid] = sum;
  __syncthreads();
  for (int d = 1; d < 1024; d <<= 1) {
    int v = (tid >= d) ? part[tid - d] : 0;
    __syncthreads();
    part[tid] += v;
    __syncthreads();
  }
  int run = (tid == 0) ? 0 : part[tid - 1];
  for (int i = 0; i < per; ++i) {
    int idx = base + i;
    if (idx < n) {
      off[idx] = run;
      run += cnt[idx];
    }
  }
  if (tid == 0) off[n] = part[1023];
}

__global__ void k_scatterB(const int* __restrict__ ei2, const int* __restrict__ ea2,
                           const int* __restrict__ batch, const int* __restrict__ off2,
                           int* __restrict__ cur2, int4* __restrict__ em2,
                           const int* __restrict__ ei3, const float* __restrict__ pos,
                           const int* __restrict__ off3, int* __restrict__ cur3,
                           int4* __restrict__ em3) {
  int i = blockIdx.x * blockDim.x + threadIdx.x;
  if (i < NE2) {
    int e = i;
    int s = ei2[e], d = ei2[NE2 + e];
    int p = atomicAdd(&cur2[d], 1);
    int j = off2[d] + p;
    em2[j] = make_int4(s, ea2[2 * e] * 4 + ea2[2 * e + 1], batch[s], 0);
  } else if (i < NE2 + NE3) {
    int e = i - NE2;
    int s = ei3[e], d = ei3[NE3 + e];
    float dx = pos[3 * d] - pos[3 * s];
    float dy = pos[3 * d + 1] - pos[3 * s + 1];
    float dz = pos[3 * d + 2] - pos[3 * s + 2];
    float dist = sqrtf(dx * dx + dy * dy + dz * dz);
    float u = fminf(dist * ((float)NTAB / DMAX), (float)NTAB - 0.001f);
    int idx = (int)u;
    int p = atomicAdd(&cur3[d], 1);
    int j = off3[d] + p;
    em3[j] = make_int4(s, idx, __float_as_int(u - (float)idx), 0);
  }
}

// ---------------- consolidated init kernels ----------------

__global__ void k_init_gin(const int* __restrict__ x2d, const float* __restrict__ e1,
                           const float* __restrict__ e2, short* __restrict__ hb,
                           const float* __restrict__ vni, float* __restrict__ vn,
                           short* __restrict__ vnb) {
  int i = blockIdx.x * blockDim.x + threadIdx.x;
  if (i < NN * DEMB) {
    int n = i / DEMB, c = i - n * DEMB;
    hb[i] = f2b(e1[x2d[2 * n] * DEMB + c] + e2[x2d[2 * n + 1] * DEMB + c]);
  } else if (i < NN * DEMB + NG * DEMB) {
    int j = i - NN * DEMB;
    float v = vni[j % DEMB];
    vn[j] = v;
    vnb[j] = f2b(v);
  }
}

__global__ void k_init_sch(float* __restrict__ rbs, float* __restrict__ Cs,
                           const int* __restrict__ z, const float* __restrict__ emb,
                           float* __restrict__ hs, short* __restrict__ hsb) {
  int i = blockIdx.x * blockDim.x + threadIdx.x;
  if (i < TROWS * NRBF) {
    int j = i / NRBF, k = i - j * NRBF;
    float dj = (float)j * (DMAX / (float)NTAB);
    const float step = 10.0f / 49.0f;
    const float coeff = -0.5f / (step * step);
    float t = dj - (float)k * step;
    rbs[i] = expf(coeff * t * t);
    if (k == 0) Cs[j] = 0.5f * (cosf(dj * (3.14159265358979323846f / 10.0f)) + 1.0f);
  } else if (i < TROWS * NRBF + NN * DSCH) {
    int j = i - TROWS * NRBF;
    float v = emb[z[j >> 7] * DSCH + (j & 127)];
    hs[j] = v;
    hsb[j] = f2b(v);
  }
}

// ---------------- gather aggregations (uint-vectorized, int4 meta, 2-edge unroll) ----------------

__device__ __forceinline__ void gin_edge_add(const unsigned* __restrict__ hr,
                                             const unsigned* __restrict__ vr,
                                             const unsigned* __restrict__ eu, int u0, int u1,
                                             int u2, bool has2, float* acc) {
  unsigned a = hr[u0], b = vr[u0], e = eu[u0];
  acc[0] += fmaxf(b2f((unsigned short)a) + b2f((unsigned short)b) + b2f((unsigned short)e), 0.f);
  acc[1] += fmaxf(b2f((unsigned short)(a >> 16)) + b2f((unsigned short)(b >> 16)) +
                      b2f((unsigned short)(e >> 16)), 0.f);
  a = hr[u1]; b = vr[u1]; e = eu[u1];
  acc[2] += fmaxf(b2f((unsigned short)a) + b2f((unsigned short)b) + b2f((unsigned short)e), 0.f);
  acc[3] += fmaxf(b2f((unsigned short)(a >> 16)) + b2f((unsigned short)(b >> 16)) +
                      b2f((unsigned short)(e >> 16)), 0.f);
  if (has2) {
    a = hr[u2]; b = vr[u2]; e = eu[u2];
    acc[4] += fmaxf(b2f((unsigned short)a) + b2f((unsigned short)b) + b2f((unsigned short)e), 0.f);
    acc[5] += fmaxf(b2f((unsigned short)(a >> 16)) + b2f((unsigned short)(b >> 16)) +
                        b2f((unsigned short)(e >> 16)), 0.f);
  }
}

__global__ __launch_bounds__(256) void k_gin_gather6(
    const short* __restrict__ hb, const short* __restrict__ vnb, const int* __restrict__ batch,
    const int* __restrict__ off2, const int4* __restrict__ em2, const float* __restrict__ bond1,
    const float* __restrict__ bond2, short* __restrict__ aggb) {
  __shared__ unsigned sb[18 * 150];
  int tid = threadIdx.x;
  for (int i = tid; i < 18 * 150; i += 256) {
    int c = i / 150, u = i - c * 150;
    int a0 = c / 3, a1 = c - a0 * 3;
    float v0 = bond1[a0 * 300 + 2 * u] + bond2[a1 * 300 + 2 * u];
    float v1 = bond1[a0 * 300 + 2 * u + 1] + bond2[a1 * 300 + 2 * u + 1];
    sb[i] = pk2(v0, v1);
  }
  __syncthreads();
  int d = blockIdx.x * 4 + (tid >> 6);
  int l = tid & 63;
  int j0 = off2[d], j1 = off2[d + 1];
  const unsigned* hu = (const unsigned*)hb + (size_t)d * 150;
  const unsigned* vu = (const unsigned*)vnb + (size_t)batch[d] * 150;
  const int u0 = l, u1 = l + 64, u2 = l + 128;
  const bool has2 = (u2 < 150);
  float acc[6];
  {
    unsigned a = hu[u0], b = vu[u0];
    acc[0] = b2f((unsigned short)a) + b2f((unsigned short)b);
    acc[1] = b2f((unsigned short)(a >> 16)) + b2f((unsigned short)(b >> 16));
    a = hu[u1]; b = vu[u1];
    acc[2] = b2f((unsigned short)a) + b2f((unsigned short)b);
    acc[3] = b2f((unsigned short)(a >> 16)) + b2f((unsigned short)(b >> 16));
    if (has2) {
      a = hu[u2]; b = vu[u2];
      acc[4] = b2f((unsigned short)a) + b2f((unsigned short)b);
      acc[5] = b2f((unsigned short)(a >> 16)) + b2f((unsigned short)(b >> 16));
    } else {
      acc[4] = acc[5] = 0.f;
    }
  }
  int j = j0;
  for (; j + 1 < j1; j += 2) {
    int4 mA = em2[j], mB = em2[j + 1];
    const unsigned* hrA = (const unsigned*)hb + (size_t)mA.x * 150;
    const unsigned* vrA = (const unsigned*)vnb + (size_t)mA.z * 150;
    const unsigned* euA = sb + ((mA.y >> 2) * 3 + (mA.y & 3)) * 150;
    const unsigned* hrB = (const unsigned*)hb + (size_t)mB.x * 150;
    const unsigned* vrB = (const unsigned*)vnb + (size_t)mB.z * 150;
    const unsigned* euB = sb + ((mB.y >> 2) * 3 + (mB.y & 3)) * 150;
    gin_edge_add(hrA, vrA, euA, u0, u1, u2, has2, acc);
    gin_edge_add(hrB, vrB, euB, u0, u1, u2, has2, acc);
  }
  if (j < j1) {
    int4 m = em2[j];
    gin_edge_add((const unsigned*)hb + (size_t)m.x * 150, (const unsigned*)vnb + (size_t)m.z * 150,
                 sb + ((m.y >> 2) * 3 + (m.y & 3)) * 150, u0, u1, u2, has2, acc);
  }
  unsigned* outu = (unsigned*)aggb + (size_t)d * 160;
  outu[u0] = pk2(acc[0], acc[1]);
  outu[u1] = pk2(acc[2], acc[3]);
  if (u2 < 160) outu[u2] = has2 ? pk2(acc[4], acc[5]) : 0u;
}

// CFConv: int4 meta, 2-edge unroll
__global__ __launch_bounds__(256) void k_conv_gather5(
    const short* __restrict__ ftabb, const short* __restrict__ x1b, const int* __restrict__ off3,
    const int4* __restrict__ em3, short* __restrict__ agg3b) {
  int tid = threadIdx.x;
  int d = blockIdx.x * 4 + (tid >> 6);
  int lane = tid & 63;
  int j0 = off3[d], j1 = off3[d + 1];
  float a0 = 0.f, a1 = 0.f;
  int j = j0;
  for (; j + 1 < j1; j += 2) {
    int4 mA = em3[j], mB = em3[j + 1];
    float frA = __int_as_float(mA.z), frB = __int_as_float(mB.z);
    unsigned t0A = ((const unsigned*)(ftabb + (size_t)mA.y * 128))[lane];
    unsigned t1A = ((const unsigned*)(ftabb + (size_t)(mA.y + 1) * 128))[lane];
    unsigned xvA = ((const unsigned*)(x1b + (size_t)mA.x * 128))[lane];
    unsigned t0B = ((const unsigned*)(ftabb + (size_t)mB.y * 128))[lane];
    unsigned t1B = ((const unsigned*)(ftabb + (size_t)(mB.y + 1) * 128))[lane];
    unsigned xvB = ((const unsigned*)(x1b + (size_t)mB.x * 128))[lane];
    {
      float t0a = b2f((unsigned short)t0A), t0b = b2f((unsigned short)(t0A >> 16));
      float t1a = b2f((unsigned short)t1A), t1b = b2f((unsigned short)(t1A >> 16));
      a0 += (t0a + frA * (t1a - t0a)) * b2f((unsigned short)(xvA & 0xFFFF));
      a1 += (t0b + frA * (t1b - t0b)) * b2f((unsigned short)(xvA >> 16));
    }
    {
      float t0a = b2f((unsigned short)t0B), t0b = b2f((unsigned short)(t0B >> 16));
      float t1a = b2f((unsigned short)t1B), t1b = b2f((unsigned short)(t1B >> 16));
      a0 += (t0a + frB * (t1a - t0a)) * b2f((unsigned short)(xvB & 0xFFFF));
      a1 += (t0b + frB * (t1b - t0b)) * b2f((unsigned short)(xvB >> 16));
    }
  }
  if (j < j1) {
    int4 m = em3[j];
    float fr = __int_as_float(m.z);
    unsigned t0 = ((const unsigned*)(ftabb + (size_t)m.y * 128))[lane];
    unsigned t1 = ((const unsigned*)(ftabb + (size_t)(m.y + 1) * 128))[lane];
    unsigned xv = ((const unsigned*)(x1b + (size_t)m.x * 128))[lane];
    float t0a = b2f((unsigned short)t0), t0b = b2f((unsigned short)(t0 >> 16));
    float t1a = b2f((unsigned short)t1), t1b = b2f((unsigned short)(t1 >> 16));
    a0 += (t0a + fr * (t1a - t0a)) * b2f((unsigned short)(xv & 0xFFFF));
    a1 += (t0b + fr * (t1b - t0b)) * b2f((unsigned short)(xv >> 16));
  }
  ((unsigned*)(agg3b + (size_t)d * 128))[lane] = pk2(a0, a1);
}

// fused: vnab[g][320] = bf16( sum_rows(hb) + vn[g] )
__global__ __launch_bounds__(256) void k_poolvn(const short* __restrict__ hb,
                                                const int* __restrict__ goff,
                                                const float* __restrict__ vn,
                                                short* __restrict__ vnab) {
  int g = blockIdx.x * 4 + (threadIdx.x >> 6);
  int l = threadIdx.x & 63;
  if (g >= NG) return;
  int r0 = goff[g], r1 = goff[g + 1];
  const int u0 = l, u1 = l + 64, u2 = l + 128;
  const bool has2 = (u2 < 150);
  float acc[6] = {};
  for (int r = r0; r < r1; ++r) {
    const unsigned* hu = (const unsigned*)hb + (size_t)r * 150;
    unsigned a = hu[u0];
    acc[0] += b2f((unsigned short)a);
    acc[1] += b2f((unsigned short)(a >> 16));
    a = hu[u1];
    acc[2] += b2f((unsigned short)a);
    acc[3] += b2f((unsigned short)(a >> 16));
    if (has2) {
      a = hu[u2];
      acc[4] += b2f((unsigned short)a);
      acc[5] += b2f((unsigned short)(a >> 16));
    }
  }
  const float2* v2 = (const float2*)(vn + (size_t)g * 300);
  unsigned* outu = (unsigned*)vnab + (size_t)g * 160;
  float2 w = v2[u0];
  outu[u0] = pk2(acc[0] + w.x, acc[1] + w.y);
  w = v2[u1];
  outu[u1] = pk2(acc[2] + w.x, acc[3] + w.y);
  if (u2 < 160) {
    if (has2) {
      w = v2[u2];
      outu[u2] = pk2(acc[4] + w.x, acc[5] + w.y);
    } else {
      outu[u2] = 0u;
    }
  }
}

// head pool (GIN): xcat[g][0:320] = bf16(mean over hb rows)
__global__ __launch_bounds__(256) void k_poolhead2(const short* __restrict__ hb,
                                                   const int* __restrict__ goff,
                                                   short* __restrict__ xcat) {
  int g = blockIdx.x * 4 + (threadIdx.x >> 6);
  int l = threadIdx.x & 63;
  if (g >= NG) return;
  int r0 = goff[g], r1 = goff[g + 1];
  const int u0 = l, u1 = l + 64, u2 = l + 128;
  const bool has2 = (u2 < 150);
  float acc[6] = {};
  for (int r = r0; r < r1; ++r) {
    const unsigned* hu = (const unsigned*)hb + (size_t)r * 150;
    unsigned a = hu[u0];
    acc[0] += b2f((unsigned short)a);
    acc[1] += b2f((unsigned short)(a >> 16));
    a = hu[u1];
    acc[2] += b2f((unsigned short)a);
    acc[3] += b2f((unsigned short)(a >> 16));
    if (has2) {
      a = hu[u2];
      acc[4] += b2f((unsigned short)a);
      acc[5] += b2f((unsigned short)(a >> 16));
    }
  }
  float s = 1.0f / fmaxf((float)(r1 - r0), 1.0f);
  unsigned* outu = (unsigned*)xcat + (size_t)g * 224;
  outu[u0] = pk2(acc[0] * s, acc[1] * s);
  outu[u1] = pk2(acc[2] * s, acc[3] * s);
  if (u2 < 160) outu[u2] = has2 ? pk2(acc[4] * s, acc[5] * s) : 0u;
}

// head pool (SchNet): xcat[g][320:448]
__global__ __launch_bounds__(256) void k_poolhead3(const short* __restrict__ hsb,
                                                   const int* __restrict__ goff,
                                                   short* __restrict__ xcat) {
  int g = blockIdx.x * 4 + (threadIdx.x >> 6);
  int l = threadIdx.x & 63;
  if (g >= NG) return;
  int r0 = goff[g], r1 = goff[g + 1];
  float a0 = 0.f, a1 = 0.f;
  for (int r = r0; r < r1; ++r) {
    unsigned v = ((const unsigned*)hsb)[(size_t)r * 64 + l];
    a0 += b2f((unsigned short)(v & 0xFFFF));
    a1 += b2f((unsigned short)(v >> 16));
  }
  float s = 1.0f / fmaxf((float)(r1 - r0), 1.0f);
  ((unsigned*)xcat)[(size_t)g * 224 + 160 + l] = pk2(a0 * s, a1 * s);
}

// gate dot + sigmoid + blend
__global__ __launch_bounds__(256) void k_blend(const float* __restrict__ gh,
                                               const float* __restrict__ gW2,
                                               const float* __restrict__ gb2,
                                               const float* __restrict__ hcat,
                                               short* __restrict__ hfb) {
  int g = blockIdx.x * 4 + (threadIdx.x >> 6);
  int l = threadIdx.x & 63;
  if (g >= NG) return;
  float2 v = ((const float2*)(gh + (size_t)g * 128))[l];
  float dot = v.x * gW2[2 * l] + v.y * gW2[2 * l + 1];
  for (int m = 32; m; m >>= 1) dot += __shfl_xor(dot, m);
  float gg = 1.0f / (1.0f + expf(-(dot + gb2[0])));
  const float* hc = hcat + (size_t)g * 608;
  unsigned* outu = (unsigned*)hfb + (size_t)g * 160;
  const int u0 = l, u1 = l + 64, u2 = l + 128;
  float a0 = hc[2 * u0], a1 = hc[2 * u0 + 1], b0 = hc[304 + 2 * u0], b1 = hc[304 + 2 * u0 + 1];
  outu[u0] = pk2(gg * a0 + (1.f - gg) * b0, gg * a1 + (1.f - gg) * b1);
  a0 = hc[2 * u1]; a1 = hc[2 * u1 + 1]; b0 = hc[304 + 2 * u1]; b1 = hc[304 + 2 * u1 + 1];
  outu[u1] = pk2(gg * a0 + (1.f - gg) * b0, gg * a1 + (1.f - gg) * b1);
  if (u2 < 160) {
    if (u2 < 150) {
      a0 = hc[2 * u2]; a1 = hc[2 * u2 + 1]; b0 = hc[304 + 2 * u2]; b1 = hc[304 + 2 * u2 + 1];
      outu[u2] = pk2(gg * a0 + (1.f - gg) * b0, gg * a1 + (1.f - gg) * b1);
    } else {
      outu[u2] = 0u;
    }
  }
}

// ---------------- weight prep ----------------
__global__ void k_prepw2(const float* __restrict__ Wa, const float* __restrict__ Wb,
                         short* __restrict__ Wta, short* __restrict__ Wtb, int K, int N, int Kp,
                         int Np, int La, int Lb) {
  int i = blockIdx.x * blockDim.x + threadIdx.x;
  int per = Np * Kp;
  if (i >= (La + Lb) * per) return;
  int l = i / per, r = i - l * per;
  int n = r / Kp, k = r - n * Kp;
  const float* W = (l < La) ? Wa : Wb;
  int ll = (l < La) ? l : l - La;
  short* Wt = (l < La) ? Wta : Wtb;
  float v = (n < N && k < K) ? W[(size_t)ll * K * N + (size_t)k * N + n] : 0.f;
  Wt[(size_t)ll * per + r] = f2b(v);
}

__global__ void k_prepw3(const float* __restrict__ W0, const float* __restrict__ W1,
                         const float* __restrict__ W2, short* __restrict__ T0,
                         short* __restrict__ T1, short* __restrict__ T2) {
  int i = blockIdx.x * blockDim.x + threadIdx.x;
  const int per = 6 * 128 * 128;
  if (i >= 3 * per) return;
  int which = i / per, r = i - which * per;
  int l = r / 16384, rr = r - l * 16384;
  int n = rr / 128, k = rr - n * 128;
  const float* W = (which == 0) ? W0 : (which == 1) ? W1 : W2;
  short* T = (which == 0) ? T0 : (which == 1) ? T1 : T2;
  T[r] = f2b(W[(size_t)l * 16384 + (size_t)k * 128 + n]);
}

#define W1SZ (608 * 448)
#define G1SZ (128 * 608)
#define C1SZ (160 * 320)
#define C2SZ (12 * 160)
__global__ void k_prephead(const float* __restrict__ p2W, const float* __restrict__ p2b,
                           const float* __restrict__ p3W, const float* __restrict__ p3b,
                           const float* __restrict__ gW1, const float* __restrict__ cW1,
                           const float* __restrict__ cb1, const float* __restrict__ cW2,
                           short* __restrict__ Wcat, short* __restrict__ gW1cat,
                           short* __restrict__ cW1cat, short* __restrict__ cW2cat,
                           float* __restrict__ bcat, float* __restrict__ cb1p) {
  int i = blockIdx.x * blockDim.x + threadIdx.x;
  if (i < W1SZ) {
    int o = i / 448, k = i - o * 448;
    float v = 0.f;
    if (o < 300 && k < 300) v = p2W[(size_t)k * 300 + o];
    else if (o >= 304 && o < 604 && k >= 320) v = p3W[(size_t)(k - 320) * 300 + (o - 304)];
    Wcat[i] = f2b(v);
  } else if (i < W1SZ + G1SZ) {
    int r = i - W1SZ;
    int o = r / 608, k = r - o * 608;
    float v = 0.f;
    if (k < 300) v = gW1[(size_t)k * 128 + o];
    else if (k >= 304 && k < 604) v = gW1[(size_t)(300 + k - 304) * 128 + o];
    gW1cat[r] = f2b(v);
  } else if (i < W1SZ + G1SZ + C1SZ) {
    int r = i - W1SZ - G1SZ;
    int o = r / 320, k = r - o * 320;
    cW1cat[r] = f2b((o < 150 && k < 300) ? cW1[(size_t)k * 150 + o] : 0.f);
  } else if (i < W1SZ + G1SZ + C1SZ + C2SZ) {
    int r = i - W1SZ - G1SZ - C1SZ;
    int o = r / 160, k = r - o * 160;
    cW2cat[r] = f2b((k < 150) ? cW2[(size_t)k * 12 + o] : 0.f);
  } else if (i < W1SZ + G1SZ + C1SZ + C2SZ + 608) {
    int o = i - W1SZ - G1SZ - C1SZ - C2SZ;
    bcat[o] = (o < 300) ? p2b[o] : (o >= 304 && o < 604) ? p3b[o - 304] : 0.f;
  } else if (i < W1SZ + G1SZ + C1SZ + C2SZ + 608 + 160) {
    int o = i - W1SZ - G1SZ - C1SZ - C2SZ - 608;
    cb1p[o] = (o < 150) ? cb1[o] : 0.f;
  }
}

// ---------------- z-batched fp32 GEMM ----------------
template <int ACT>
__global__ __launch_bounds__(256) void k_gemmz(
    const float* __restrict__ A, const float* __restrict__ B, const float* __restrict__ bias,
    const float* __restrict__ rscale, float* __restrict__ Cout, short* __restrict__ Coutb,
    int M, int N, int K, int ldc, long strideA, long strideB, long strideBias, long strideC) {
  A += (size_t)blockIdx.z * strideA;
  B += (size_t)blockIdx.z * strideB;
  bias += (size_t)blockIdx.z * strideBias;
  __shared__ float sA[16][65];
  __shared__ float sB[16][64];
  int tid = threadIdx.x;
  int tx = tid & 15, ty = tid >> 4;
  int bm = blockIdx.y * 64, bn = blockIdx.x * 64;
  float acc[4][4] = {};
  for (int k0 = 0; k0 < K; k0 += 16) {
#pragma unroll
    for (int t = 0; t < 4; ++t) {
      int i = tid + t * 256;
      int m = i >> 4, kk = i & 15;
      int gm = bm + m, gk = k0 + kk;
      sA[kk][m] = (gm < M && gk < K) ? A[(size_t)gm * K + gk] : 0.f;
    }
#pragma unroll
    for (int t = 0; t < 4; ++t) {
      int i = tid + t * 256;
      int kk = i >> 6, n = i & 63;
      int gk = k0 + kk, gn = bn + n;
      sB[kk][n] = (gk < K && gn < N) ? B[(size_t)gk * N + gn] : 0.f;
    }
    __syncthreads();
#pragma unroll
    for (int kk = 0; kk < 16; ++kk) {
      float a[4], b[4];
#pragma unroll
      for (int i = 0; i < 4; ++i) a[i] = sA[kk][ty + 16 * i];
#pragma unroll
      for (int j = 0; j < 4; ++j) b[j] = sB[kk][tx + 16 * j];
#pragma unroll
      for (int i = 0; i < 4; ++i)
#pragma unroll
        for (int j = 0; j < 4; ++j) acc[i][j] = fmaf(a[i], b[j], acc[i][j]);
    }
    __syncthreads();
  }
#pragma unroll
  for (int i = 0; i < 4; ++i) {
    int gm = bm + ty + 16 * i;
    if (gm >= M) continue;
    float rs = rscale ? rscale[gm] : 1.0f;
#pragma unroll
    for (int j = 0; j < 4; ++j) {
      int gn = bn + tx + 16 * j;
      if (gn >= N) continue;
      float v = acc[i][j] + bias[gn];
      if (ACT == 1) v = fmaxf(v, 0.f);
      if (ACT == 2) v = sspf(v);
      v *= rs;
      if (Cout) Cout[(size_t)blockIdx.z * strideC + (size_t)gm * ldc + gn] = v;
      if (Coutb) Coutb[(size_t)blockIdx.z * strideC + (size_t)gm * ldc + gn] = f2b(v);
    }
  }
}

// ---------------- bf16 MFMA GEMM, 128x128 tile ----------------
template <int ACT>
__global__ __launch_bounds__(256) void k_mgemm_bf(
    const short* __restrict__ Ab, const short* __restrict__ Wt, const float* __restrict__ bias,
    const float* __restrict__ scale, const float* __restrict__ shift,
    const float* __restrict__ Cin, float* __restrict__ Cout, short* __restrict__ Coutb,
    int M, int N, int Kp, int ldc, int ldcb, int Nb) {
  __shared__ short sA[128 * 32];
  const int tid = threadIdx.x;
  const int lane = tid & 63;
  const int w = tid >> 6;
  const int wm = w >> 1, wn = w & 1;
  const int bm = blockIdx.y * 128, bn = blockIdx.x * 128;

  f32x4 acc[4][4] = {};

  const int sr = tid >> 1;
  const int sk = (tid & 1) * 16;
  const short* Arow = Ab + (size_t)(bm + sr) * Kp + sk;
  const int ssw = (sr + (sr >> 2)) & 3;
  const int s0 = (sk >> 3);
  bf16x8* sAv = (bf16x8*)sA;

  const int frow = wm * 64 + (lane & 15);
  const int fslot = lane >> 4;
  const short* Bbase = Wt + (size_t)(bn + wn * 64 + (lane & 15)) * Kp + (fslot * 8);

  for (int k0 = 0; k0 < Kp; k0 += 32) {
    __syncthreads();
    {
      bf16x8 p0 = *(const bf16x8*)(Arow + k0);
      bf16x8 p1 = *(const bf16x8*)(Arow + k0 + 8);
      sAv[sr * 4 + ((s0 + 0) ^ ssw)] = p0;
      sAv[sr * 4 + ((s0 + 1) ^ ssw)] = p1;
    }
    __syncthreads();

    bf16x8 af[4], bfr[4];
#pragma unroll
    for (int mf = 0; mf < 4; ++mf) {
      int r = frow + mf * 16;
      af[mf] = sAv[r * 4 + (fslot ^ ((r + (r >> 2)) & 3))];
    }
#pragma unroll
    for (int nf = 0; nf < 4; ++nf) bfr[nf] = *(const bf16x8*)(Bbase + (size_t)nf * 16 * Kp + k0);
#pragma unroll
    for (int mf = 0; mf < 4; ++mf)
#pragma unroll
      for (int nf = 0; nf < 4; ++nf)
        acc[mf][nf] =
            __builtin_amdgcn_mfma_f32_16x16x32_bf16(af[mf], bfr[nf], acc[mf][nf], 0, 0, 0);
  }

  const int colbase = bn + wn * 64 + (lane & 15);
  const int rowbase = bm + wm * 64 + ((lane >> 4) << 2);
#pragma unroll
  for (int nf = 0; nf < 4; ++nf) {
    int col = colbase + nf * 16;
    bool cv = col < N;
    float bi = (bias && cv) ? bias[col] : 0.f;
    float sc = (scale && cv) ? scale[col] : 1.f;
    float sh = (shift && cv) ? shift[col] : 0.f;
#pragma unroll
    for (int mf = 0; mf < 4; ++mf) {
      f32x4 v = acc[mf][nf];
#pragma unroll
      for (int j = 0; j < 4; ++j) {
        int row = rowbase + mf * 16 + j;
        float x = v[j] + bi;
        if (scale) x = x * sc + sh;
        if (ACT == 1) x = fmaxf(x, 0.f);
        if (ACT == 2) x = sspf(x);
        if (Cin && cv) x += Cin[(size_t)row * ldc + col];
        if (Cout && cv) Cout[(size_t)row * ldc + col] = x;
        if (Coutb && col < Nb) Coutb[(size_t)row * ldcb + col] = cv ? f2b(x) : (short)0;
      }
    }
  }
}

// ---------------- bf16 MFMA GEMM, 64x128 tile ----------------
template <int ACT>
__global__ __launch_bounds__(256) void k_mgemm_bf64(
    const short* __restrict__ Ab, const short* __restrict__ Wt, const float* __restrict__ bias,
    const float* __restrict__ scale, const float* __restrict__ shift,
    const float* __restrict__ Cin, float* __restrict__ Cout, short* __restrict__ Coutb,
    int M, int N, int Kp, int ldc, int ldcb, int Nb) {
  __shared__ short sA[64 * 32];
  const int tid = threadIdx.x;
  const int lane = tid & 63;
  const int w = tid >> 6;
  const int bm = blockIdx.y * 64, bn = blockIdx.x * 128;

  f32x4 acc[4][2] = {};

  const int sr = tid >> 2;
  const int sk = (tid & 3) * 8;
  const short* Arow = Ab + (size_t)(bm + sr) * Kp + sk;
  const int ssw = (sr + (sr >> 2)) & 3;
  const int s0 = tid & 3;
  bf16x8* sAv = (bf16x8*)sA;

  const int frow = lane & 15;
  const int fslot = lane >> 4;
  const short* Bbase = Wt + (size_t)(bn + w * 32 + (lane & 15)) * Kp + (fslot * 8);

  for (int k0 = 0; k0 < Kp; k0 += 32) {
    __syncthreads();
    sAv[sr * 4 + (s0 ^ ssw)] = *(const bf16x8*)(Arow + k0);
    __syncthreads();

    bf16x8 af[4], bfr[2];
#pragma unroll
    for (int mf = 0; mf < 4; ++mf) {
      int r = frow + mf * 16;
      af[mf] = sAv[r * 4 + (fslot ^ ((r + (r >> 2)) & 3))];
    }
#pragma unroll
    for (int nf = 0; nf < 2; ++nf) bfr[nf] = *(const bf16x8*)(Bbase + (size_t)nf * 16 * Kp + k0);
#pragma unroll
    for (int mf = 0; mf < 4; ++mf)
#pragma unroll
      for (int nf = 0; nf < 2; ++nf)
        acc[mf][nf] =
            __builtin_amdgcn_mfma_f32_16x16x32_bf16(af[mf], bfr[nf], acc[mf][nf], 0, 0, 0);
  }

  const int colbase = bn + w * 32 + (lane & 15);
  const int rowbase = bm + ((lane >> 4) << 2);
#pragma unroll
  for (int nf = 0; nf < 2; ++nf) {
    int col = colbase + nf * 16;
    bool cv = col < N;
    float bi = (bias && cv) ? bias[col] : 0.f;
    float sc = (scale && cv) ? scale[col] : 1.f;
    float sh = (shift && cv) ? shift[col] : 0.f;
#pragma unroll
    for (int mf = 0; mf < 2 * 2; ++mf) {
      f32x4 v = acc[mf][nf];
#pragma unroll
      for (int j = 0; j < 4; ++j) {
        int row = rowbase + mf * 16 + j;
        float x = v[j] + bi;
        if (scale) x = x * sc + sh;
        if (ACT == 1) x = fmaxf(x, 0.f);
        if (ACT == 2) x = sspf(x);
        if (Cin && cv) x += Cin[(size_t)row * ldc + col];
        if (Cout && cv) Cout[(size_t)row * ldc + col] = x;
        if (Coutb && col < Nb) Coutb[(size_t)row * ldcb + col] = cv ? f2b(x) : (short)0;
      }
    }
  }
}

// ---------------- fused SchNet layer ----------------
template <int LAST>
__global__ __launch_bounds__(256) void k_sch_fused(
    const short* __restrict__ agg3b, const short* __restrict__ W2t, const float* __restrict__ b2,
    const short* __restrict__ W3t, const float* __restrict__ b3, const short* __restrict__ W1n,
    float* __restrict__ hs, short* __restrict__ hsb, short* __restrict__ x1b) {
  __shared__ short sA[64 * 128];
  __shared__ short sY[64 * 128];
  const int tid = threadIdx.x;
  const int lane = tid & 63;
  const int w = tid >> 6;
  const int bm = blockIdx.x * 64;
  bf16x8* sAv = (bf16x8*)sA;
  bf16x8* sYv = (bf16x8*)sY;
  {
    int r = tid >> 2, q = tid & 3;
    int ssw = (r + (r >> 2)) & 3;
    const short* Arow = agg3b + (size_t)(bm + r) * 128 + q * 8;
#pragma unroll
    for (int c = 0; c < 4; ++c) sAv[r * 16 + c * 4 + (q ^ ssw)] = *(const bf16x8*)(Arow + c * 32);
  }
  __syncthreads();
  const int frow = lane & 15;
  const int fslot = lane >> 4;
  const int colw = w * 32 + (lane & 15);
  const int rw0 = (lane >> 4) << 2;
  {
    f32x4 acc[4][2] = {};
    const short* Bbase = W2t + (size_t)colw * 128 + fslot * 8;
#pragma unroll
    for (int c = 0; c < 4; ++c) {
      bf16x8 af[4], bfr[2];
#pragma unroll
      for (int mf = 0; mf < 4; ++mf) {
        int r = frow + mf * 16;
        af[mf] = sAv[r * 16 + c * 4 + (fslot ^ ((r + (r >> 2)) & 3))];
      }
#pragma unroll
      for (int nf = 0; nf < 2; ++nf) bfr[nf] = *(const bf16x8*)(Bbase + nf * 16 * 128 + c * 32);
#pragma unroll
      for (int mf = 0; mf < 4; ++mf)
#pragma unroll
        for (int nf = 0; nf < 2; ++nf)
          acc[mf][nf] =
              __builtin_amdgcn_mfma_f32_16x16x32_bf16(af[mf], bfr[nf], acc[mf][nf], 0, 0, 0);
    }
#pragma unroll
    for (int nf = 0; nf < 2; ++nf) {
      int cl = colw + nf * 16;
      float bi = b2[cl];
#pragma unroll
      for (int mf = 0; mf < 4; ++mf)
#pragma unroll
        for (int j = 0; j < 4; ++j) {
          int rw = rw0 + mf * 16 + j;
          float y = sspf(acc[mf][nf][j] + bi);
          int slot = (cl >> 5) * 4 + (((cl >> 3) & 3) ^ ((rw + (rw >> 2)) & 3));
          sY[rw * 128 + slot * 8 + (cl & 7)] = f2b(y);
        }
    }
  }
  __syncthreads();
  {
    f32x4 acc[4][2] = {};
    const short* Bbase = W3t + (size_t)colw * 128 + fslot * 8;
#pragma unroll
    for (int c = 0; c < 4; ++c) {
      bf16x8 af[4], bfr[2];
#pragma unroll
      for (int mf = 0; mf < 4; ++mf) {
        int r = frow + mf * 16;
        af[mf] = sYv[r * 16 + c * 4 + (fslot ^ ((r + (r >> 2)) & 3))];
      }
#pragma unroll
      for (int nf = 0; nf < 2; ++nf) bfr[nf] = *(const bf16x8*)(Bbase + nf * 16 * 128 + c * 32);
#pragma unroll
      for (int mf = 0; mf < 4; ++mf)
#pragma unroll
        for (int nf = 0; nf < 2; ++nf)
          acc[mf][nf] =
              __builtin_amdgcn_mfma_f32_16x16x32_bf16(af[mf], bfr[nf], acc[mf][nf], 0, 0, 0);
    }
#pragma unroll
    for (int nf = 0; nf < 2; ++nf) {
      int cl = colw + nf * 16;
      float bi = b3[cl];
#pragma unroll
      for (int mf = 0; mf < 4; ++mf)
#pragma unroll
        for (int j = 0; j < 4; ++j) {
          int rw = rw0 + mf * 16 + j;
          size_t gi = (size_t)(bm + rw) * 128 + cl;
          float x = acc[mf][nf][j] + bi + hs[gi];
          hs[gi] = x;
          short xb = f2b(x);
          hsb[gi] = xb;
          int slot = (cl >> 5) * 4 + (((cl >> 3) & 3) ^ ((rw + (rw >> 2)) & 3));
          sA[rw * 128 + slot * 8 + (cl & 7)] = xb;
        }
    }
  }
  if (LAST) return;
  __syncthreads();
  {
    f32x4 acc[4][2] = {};
    const short* Bbase = W1n + (size_t)colw * 128 + fslot * 8;
#pragma unroll
    for (int c = 0; c < 4; ++c) {
      bf16x8 af[4], bfr[2];
#pragma unroll
      for (int mf = 0; mf < 4; ++mf) {
        int r = frow + mf * 16;
        af[mf] = sAv[r * 16 + c * 4 + (fslot ^ ((r + (r >> 2)) & 3))];
      }
#pragma unroll
      for (int nf = 0; nf < 2; ++nf) bfr[nf] = *(const bf16x8*)(Bbase + nf * 16 * 128 + c * 32);
#pragma unroll
      for (int mf = 0; mf < 4; ++mf)
#pragma unroll
        for (int nf = 0; nf < 2; ++nf)
          acc[mf][nf] =
              __builtin_amdgcn_mfma_f32_16x16x32_bf16(af[mf], bfr[nf], acc[mf][nf], 0, 0, 0);
    }
#pragma unroll
    for (int nf = 0; nf < 2; ++nf) {
      int cl = colw + nf * 16;
#pragma unroll
      for (int mf = 0; mf < 4; ++mf)
#pragma unroll
        for (int j = 0; j < 4; ++j) {
          int rw = rw0 + mf * 16 + j;
          x1b[(size_t)(bm + rw) * 128 + cl] = f2b(acc[mf][nf][j]);
        }
    }
  }
}

// ---------------- host ----------------

static inline void run_mgemm_bf(hipStream_t st, const short* Ab, const short* Wt,
                                const float* bias, const float* scale, const float* shift,
                                const float* Cin, float* Cout, short* Coutb, int M, int N, int Kp,
                                int ldc, int ldcb, int Nb, int act) {
  dim3 grid((N + 127) / 128, M / 128);
  if (act == 0)
    k_mgemm_bf<0><<<grid, 256, 0, st>>>(Ab, Wt, bias, scale, shift, Cin, Cout, Coutb, M, N, Kp,
                                        ldc, ldcb, Nb);
  else if (act == 1)
    k_mgemm_bf<1><<<grid, 256, 0, st>>>(Ab, Wt, bias, scale, shift, Cin, Cout, Coutb, M, N, Kp,
                                        ldc, ldcb, Nb);
  else
    k_mgemm_bf<2><<<grid, 256, 0, st>>>(Ab, Wt, bias, scale, shift, Cin, Cout, Coutb, M, N, Kp,
                                        ldc, ldcb, Nb);
}

static inline void run_mgemm_bf64(hipStream_t st, const short* Ab, const short* Wt,
                                  const float* bias, const float* scale, const float* shift,
                                  const float* Cin, float* Cout, short* Coutb, int M, int N,
                                  int Kp, int ldc, int ldcb, int Nb, int act) {
  dim3 grid((N + 127) / 128, M / 64);
  if (act == 0)
    k_mgemm_bf64<0><<<grid, 256, 0, st>>>(Ab, Wt, bias, scale, shift, Cin, Cout, Coutb, M, N, Kp,
                                          ldc, ldcb, Nb);
  else if (act == 1)
    k_mgemm_bf64<1><<<grid, 256, 0, st>>>(Ab, Wt, bias, scale, shift, Cin, Cout, Coutb, M, N, Kp,
                                          ldc, ldcb, Nb);
  else
    k_mgemm_bf64<2><<<grid, 256, 0, st>>>(Ab, Wt, bias, scale, shift, Cin, Cout, Coutb, M, N, Kp,
                                          ldc, ldcb, Nb);
}

extern "C" void kernel_launch(void* const* d_in, const int* in_sizes, int n_in, void* d_out,
                              int out_size, void* d_ws, size_t ws_size, hipStream_t stream) {
  const int* x2d = (const int*)d_in[0];
  const int* ei2 = (const int*)d_in[1];
  const int* ea2 = (const int*)d_in[2];
  const int* batch = (const int*)d_in[3];
  const int* z = (const int*)d_in[4];
  const float* pos = (const float*)d_in[5];
  const int* ei3 = (const int*)d_in[6];
  const float* atom_emb1 = (const float*)d_in[7];
  const float* atom_emb2 = (const float*)d_in[8];
  const float* vn_init = (const float*)d_in[9];
  const float* gin_W1 = (const float*)d_in[10];
  const float* gin_b1 = (const float*)d_in[11];
  const float* gin_W2 = (const float*)d_in[12];
  const float* gin_b2 = (const float*)d_in[13];
  const float* gin_bond1 = (const float*)d_in[14];
  const float* gin_bond2 = (const float*)d_in[15];
  const float* gin_gamma = (const float*)d_in[16];
  const float* gin_beta = (const float*)d_in[17];
  const float* vn_W1 = (const float*)d_in[18];
  const float* vn_b1 = (const float*)d_in[19];
  const float* vn_W2 = (const float*)d_in[20];
  const float* vn_b2 = (const float*)d_in[21];
  const float* sch_emb = (const float*)d_in[22];
  const float* s_mW1 = (const float*)d_in[23];
  const float* s_mb1 = (const float*)d_in[24];
  const float* s_mW2 = (const float*)d_in[25];
  const float* s_mb2 = (const float*)d_in[26];
  const float* s_lin1W = (const float*)d_in[27];
  const float* s_lin2W = (const float*)d_in[28];
  const float* s_lin2b = (const float*)d_in[29];
  const float* s_linW = (const float*)d_in[30];
  const float* s_linb = (const float*)d_in[31];
  const float* p2W = (const float*)d_in[32];
  const float* p2b = (const float*)d_in[33];
  const float* p3W = (const float*)d_in[34];
  const float* p3b = (const float*)d_in[35];
  const float* gW1 = (const float*)d_in[36];
  const float* gb1 = (const float*)d_in[37];
  const float* gW2 = (const float*)d_in[38];
  const float* gb2 = (const float*)d_in[39];
  const float* cW1 = (const float*)d_in[40];
  const float* cb1 = (const float*)d_in[41];
  const float* cW2 = (const float*)d_in[42];
  const float* cb2 = (const float*)d_in[43];

  float* ws = (float*)d_ws;
  // GIN phase
  short* hb = (short*)ws;
  short* aggb = (short*)(ws + 5000000);
  short* y1b = (short*)(ws + 7700000);
  // SchNet phase (aliases GIN region)
  float* rbs = ws + 400000;
  float* Cs = ws + 700000;
  float* t1all = ws + 800000;
  short* ftabb = (short*)(ws + 4800000);
  float* hs = ws + 8800000;
  short* x1b = (short*)(ws + 11000000);
  short* agg3b = (short*)(ws + 13200000);
  short* hsb = (short*)(ws + 15400000);
  // bf16 transposed weights
  short* W1t = (short*)(ws + 20000000);
  short* W2t = (short*)(ws + 20600000);
  short* s1t = (short*)(ws + 21200000);
  short* s2t = (short*)(ws + 21300000);
  short* s3t = (short*)(ws + 21400000);
  // CSR region
  int* I = (int*)(ws + 22000000);
  int* cnt2 = I + 0;
  int* cnt3 = I + 16384;
  int* cntg = I + 32768;
  int* cur2 = I + 33280;
  int* cur3 = I + 49664;  // zero region = 66048 ints
  int* off2 = I + 70000;
  int* off3 = I + 90000;
  int* goff = I + 110000;
  int4* em2 = (int4*)(I + 120000);   // 65536*4 ints -> ends I+382144
  int4* em3 = (int4*)(I + 400000);   // 393216*4 ints -> ends I+1972864 = ws+23972864
  // vn-MLP bf16 weights + buffers
  short* vnW1t = (short*)(ws + 24000000);  // 409600 fl
  short* vnW2t = (short*)(ws + 24420000);  // 466944 fl
  short* vnab = (short*)(ws + 24900000);
  short* vnhb = (short*)(ws + 24990000);
  short* vnb = (short*)(ws + 25150000);
  // head buffers
  short* Wcat = (short*)(ws + 25300000);
  short* gW1cat = (short*)(ws + 25440000);
  short* cW1cat = (short*)(ws + 25480000);
  short* cW2cat = (short*)(ws + 25510000);
  float* bcat = ws + 25520000;
  float* cb1p = ws + 25521000;
  short* xcat = (short*)(ws + 25530000);
  float* hcat = ws + 25650000;
  short* hcatb = (short*)(ws + 25970000);
  float* gh = ws + 26130000;
  short* hfb = (short*)(ws + 26200000);
  short* c1b = (short*)(ws + 26290000);
  // persistent tail
  float* vn = ws + 28443136;

  // ---- weight prep ----
  k_prepw2<<<(9 * 640 * 320 + 255) / 256, 256, 0, stream>>>(gin_W1, vn_W1, W1t, vnW1t, 300, 600,
                                                            320, 640, 5, 4);
  k_prepw2<<<(9 * 384 * 608 + 255) / 256, 256, 0, stream>>>(gin_W2, vn_W2, W2t, vnW2t, 600, 300,
                                                            608, 384, 5, 4);
  k_prepw3<<<(3 * 6 * 16384 + 255) / 256, 256, 0, stream>>>(s_lin1W, s_lin2W, s_linW, s1t, s2t,
                                                            s3t);
  k_prephead<<<(W1SZ + G1SZ + C1SZ + C2SZ + 608 + 160 + 255) / 256, 256, 0, stream>>>(
      p2W, p2b, p3W, p3b, gW1, cW1, cb1, cW2, Wcat, gW1cat, cW1cat, cW2cat, bcat, cb1p);

  // ---- CSR build ----
  hipMemsetAsync(I, 0, 66048 * sizeof(int), stream);
  k_hist3<<<(NE2 + NE3 + NN + 255) / 256, 256, 0, stream>>>(ei2, ei3, batch, cnt2, cnt3, cntg);
  k_scan3<<<3, 1024, 0, stream>>>(cnt2, off2, 16384, cnt3, off3, 16384, cntg, goff, 512);
  k_scatterB<<<(NE2 + NE3 + 255) / 256, 256, 0, stream>>>(ei2, ea2, batch, off2, cur2, em2, ei3,
                                                          pos, off3, cur3, em3);

  // ---- GIN ----
  k_init_gin<<<(NN * DEMB + NG * DEMB + 255) / 256, 256, 0, stream>>>(x2d, atom_emb1, atom_emb2,
                                                                      hb, vn_init, vn, vnb);
  for (int l = 0; l < 5; ++l) {
    k_gin_gather6<<<NN / 4, 256, 0, stream>>>(hb, vnb, batch, off2, em2,
                                              gin_bond1 + l * 6 * DEMB, gin_bond2 + l * 3 * DEMB,
                                              aggb);
    run_mgemm_bf(stream, aggb, W1t + (size_t)l * 640 * 320, gin_b1 + l * 600, nullptr, nullptr,
                 nullptr, nullptr, y1b, NN, 600, 320, 0, 608, 608, 1);
    run_mgemm_bf(stream, y1b, W2t + (size_t)l * 384 * 608, gin_b2 + l * 300, gin_gamma + l * 300,
                 gin_beta + l * 300, nullptr, nullptr, hb, NN, 300, 608, 0, 300, 300,
                 (l < 4) ? 1 : 0);
    if (l < 4) {
      k_poolvn<<<NG / 4, 256, 0, stream>>>(hb, goff, vn, vnab);
      run_mgemm_bf64(stream, vnab, vnW1t + (size_t)l * 640 * 320, vn_b1 + l * 600, nullptr,
                     nullptr, nullptr, nullptr, vnhb, NG, 600, 320, 0, 608, 608, 1);
      run_mgemm_bf64(stream, vnhb, vnW2t + (size_t)l * 384 * 608, vn_b2 + l * 300, nullptr,
                     nullptr, nullptr, vn, vnb, NG, 300, 608, 300, 300, 300, 1);
    }
  }
  k_poolhead2<<<NG / 4, 256, 0, stream>>>(hb, goff, xcat);  // before SchNet clobbers hb region

  // ---- SchNet ----
  k_init_sch<<<(TROWS * NRBF + NN * DSCH + 255) / 256, 256, 0, stream>>>(rbs, Cs, z, sch_emb, hs,
                                                                         hsb);
  {
    dim3 ga(2, (TROWS + 63) / 64, 6);
    k_gemmz<2><<<ga, 256, 0, stream>>>(rbs, s_mW1, s_mb1, nullptr, t1all, nullptr, TROWS, 128, 50,
                                       128, 0L, 50L * 128, 128L, (long)TROWS * 128);
    k_gemmz<0><<<ga, 256, 0, stream>>>(t1all, s_mW2, s_mb2, Cs, nullptr, ftabb, TROWS, 128, 128,
                                       128, (long)TROWS * 128, 128L * 128, 128L,
                                       (long)TROWS * 128);
  }
  run_mgemm_bf64(stream, hsb, s1t, nullptr, nullptr, nullptr, nullptr, nullptr, x1b, NN, 128, 128,
                 0, 128, 128, 0);
  for (int l = 0; l < 6; ++l) {
    k_conv_gather5<<<NN / 4, 256, 0, stream>>>(ftabb + (size_t)l * TROWS * 128, x1b, off3, em3,
                                               agg3b);
    if (l < 5)
      k_sch_fused<0><<<NN / 64, 256, 0, stream>>>(agg3b, s2t + (size_t)l * 16384,
                                                  s_lin2b + l * 128, s3t + (size_t)l * 16384,
                                                  s_linb + l * 128, s1t + (size_t)(l + 1) * 16384,
                                                  hs, hsb, x1b);
    else
      k_sch_fused<1><<<NN / 64, 256, 0, stream>>>(agg3b, s2t + (size_t)l * 16384,
                                                  s_lin2b + l * 128, s3t + (size_t)l * 16384,
                                                  s_linb + l * 128, s1t, hs, hsb, x1b);
  }
  k_poolhead3<<<NG / 4, 256, 0, stream>>>(hsb, goff, xcat);

  // ---- batched MFMA head ----
  run_mgemm_bf64(stream, xcat, Wcat, bcat, nullptr, nullptr, nullptr, hcat, hcatb, NG, 608, 448,
                 608, 608, 608, 0);
  run_mgemm_bf64(stream, hcatb, gW1cat, gb1, nullptr, nullptr, nullptr, gh, nullptr, NG, 128, 608,
                 128, 128, 0, 1);
  k_blend<<<NG / 4, 256, 0, stream>>>(gh, gW2, gb2, hcat, hfb);
  run_mgemm_bf64(stream, hfb, cW1cat, cb1p, nullptr, nullptr, nullptr, nullptr, c1b, NG, 160, 320,
                 0, 160, 160, 1);
  run_mgemm_bf64(stream, c1b, cW2cat, cb2, nullptr, nullptr, nullptr, (float*)d_out, nullptr, NG,
                 12, 160, 12, 12, 0, 0);
}